// Round 16
// baseline (21622.815 us; speedup 1.0000x reference)
//
#include <hip/hip_runtime.h>

typedef unsigned short u16;
typedef __attribute__((ext_vector_type(8))) short short8;
typedef __attribute__((ext_vector_type(4))) float f32x4;

#define AXR __ATOMIC_RELAXED, __HIP_MEMORY_SCOPE_AGENT

__device__ __forceinline__ float bf2f(u16 v){
  union { unsigned u; float f; } t; t.u = ((unsigned)v) << 16; return t.f;
}
__device__ __forceinline__ u16 f2bf(float f){
  union { float f; unsigned u; } t; t.f = f;
  unsigned u = t.u;
  return (u16)((u + 0x7fffu + ((u >> 16) & 1u)) >> 16);
}
struct HiLo { short hi, lo; };
__device__ __forceinline__ HiLo split1(float v){
  HiLo r;
  u16 h = f2bf(v);
  r.hi = (short)h;
  r.lo = (short)f2bf(v - bf2f(h));
  return r;
}
__device__ __forceinline__ void ldw8s(const float* __restrict__ p, short8& hi, short8& lo){
  #pragma unroll
  for (int j = 0; j < 8; ++j){ HiLo s = split1(p[j]); hi[j] = s.hi; lo[j] = s.lo; }
}

#define MFMA(acc, a, b) acc = __builtin_amdgcn_mfma_f32_16x16x32_bf16(a, b, acc, 0,0,0)
#define SMACC(acc, ah, al, bh, bl) do{ MFMA(acc, ah, bh); MFMA(acc, ah, bl); MFMA(acc, al, bh); }while(0)

// ---- prepass: f32 -> (hi,lo) bf16 ------------------------------------------
__global__ void wsplit(const float* __restrict__ s, u16* __restrict__ hi,
                       u16* __restrict__ lo, int n){
  int i = blockIdx.x * blockDim.x + threadIdx.x;
  if (i < n){ HiLo r = split1(s[i]); hi[i] = (u16)r.hi; lo[i] = (u16)r.lo; }
}

// ---- prepass: Wcomb = Wih0 @ Wout (2048x512, split), bb = b0 + Wih0@bout ---
__global__ void __launch_bounds__(256) wcomb_k(
    const float* __restrict__ Wih0, const float* __restrict__ Wout,
    const float* __restrict__ bout, const float* __restrict__ bih0,
    const float* __restrict__ bhh0,
    u16* __restrict__ Wch, u16* __restrict__ Wcl, float* __restrict__ bb)
{
  __shared__ float wl[8*64];
  __shared__ float bo[64];
  const int wg = blockIdx.x, tid = threadIdx.x;
  const int r0 = wg*8;
  for (int i = tid; i < 512; i += 256) wl[i] = Wih0[(r0 + (i >> 6))*64 + (i & 63)];
  if (tid < 64) bo[tid] = bout[tid];
  __syncthreads();
  if (tid < 8){
    int n = r0 + tid;
    float a = bih0[n] + bhh0[n];
    #pragma unroll 8
    for (int d = 0; d < 64; ++d) a += wl[tid*64 + d]*bo[d];
    bb[n] = a;
  }
  #pragma unroll
  for (int jj = 0; jj < 2; ++jj){
    int j = tid + jj*256;
    float acc[8] = {0,0,0,0,0,0,0,0};
    for (int d = 0; d < 64; ++d){
      float wv = Wout[d*512 + j];
      #pragma unroll
      for (int r = 0; r < 8; ++r) acc[r] += wl[r*64 + d]*wv;
    }
    #pragma unroll
    for (int r = 0; r < 8; ++r){
      HiLo s = split1(acc[r]);
      Wch[(r0 + r)*512 + j] = (u16)s.hi;
      Wcl[(r0 + r)*512 + j] = (u16)s.lo;
    }
  }
}

// ---- init-only tree barrier (threadfence-based, proven R13/R14) ------------
__device__ __forceinline__ void gbar(unsigned* bar, unsigned phase){
  __syncthreads();
  if (threadIdx.x == 0){
    __threadfence();
    const unsigned gg = (unsigned)blockIdx.x >> 4;
    unsigned old = __hip_atomic_fetch_add(bar + 64 + gg*32, 1u, AXR);
    if (old == phase*16u - 1u){
      unsigned r = __hip_atomic_fetch_add(bar, 1u, AXR);
      if (r == phase*16u - 1u)
        __hip_atomic_store(bar + 32, phase, AXR);
    }
    while (__hip_atomic_load(bar + 32, AXR) < phase)
      __builtin_amdgcn_s_sleep(2);
    __threadfence();
  }
  __syncthreads();
}

// ---- global fallback barrier (R14 xbar, any WG placement) ------------------
__device__ __forceinline__ void xbar(unsigned* bar, unsigned phase,
                                     unsigned xcd, unsigned pop, unsigned nx){
  __syncthreads();
  if (threadIdx.x == 0){
    unsigned old = __hip_atomic_fetch_add(bar + 832 + xcd*32, 1u, AXR);
    const bool leader = (old == phase*pop - 1u);
    if (leader){
      asm volatile("buffer_wbl2 sc1\n\ts_waitcnt vmcnt(0)" ::: "memory");
      unsigned r = __hip_atomic_fetch_add(bar + 1344, 1u, AXR);
      if (r == phase*nx - 1u)
        __hip_atomic_store(bar + 1376, phase, AXR);
    }
    while (__hip_atomic_load(bar + 1376, AXR) < phase)
      __builtin_amdgcn_s_sleep(2);
    if (leader){
      asm volatile("buffer_inv sc1\n\ts_waitcnt vmcnt(0)" ::: "memory");
      __hip_atomic_store(bar + 1088 + xcd*32, phase, AXR);
    } else {
      while (__hip_atomic_load(bar + 1088 + xcd*32, AXR) < phase)
        __builtin_amdgcn_s_sleep(1);
      asm volatile("buffer_inv\n\ts_waitcnt vmcnt(0)" ::: "memory");
    }
  }
  __syncthreads();
}

// ---- group-local barrier (requires group co-located on one XCD) ------------
__device__ __forceinline__ void pbar(unsigned* bar, unsigned g, unsigned phase){
  __syncthreads();
  if (threadIdx.x == 0){
    unsigned* ctr = bar + 2048 + g*32;
    __hip_atomic_fetch_add(ctr, 1u, AXR);
    while (__hip_atomic_load(ctr, AXR) < phase*32u)
      __builtin_amdgcn_s_sleep(1);
    asm volatile("buffer_inv\n\ts_waitcnt vmcnt(0)" ::: "memory");
  }
  __syncthreads();
}

// ---- LDS weight-slice helpers (XOR-swizzled, G4) ---------------------------
__device__ __forceinline__ short8 lds8(const u16* base, int r, int kelem, int rowbytes){
  int bo = r*rowbytes + ((kelem*2) ^ ((r & 7) << 4));
  return *(const short8*)((const char*)base + bo);
}
// 64 gate rows (4 gates x 16 cols of col-group cg) x ldw K; 512-thread stride
__device__ __forceinline__ void load_slice64(
    const float* __restrict__ W, int ldw, int rowshift, int nelem,
    u16* lh, u16* ll, int cg, int tid)
{
  const int rowbytes = ldw*2;
  for (int i = tid; i < nelem; i += 512){
    int r = i >> rowshift, k = i & ((1 << rowshift) - 1);
    int n = ((r >> 4) << 9) + cg*16 + (r & 15);
    HiLo s = split1(W[n*ldw + k]);
    int bo = r*rowbytes + ((k*2) ^ ((r & 7) << 4));
    *(u16*)((char*)lh + bo) = (u16)s.hi;
    *(u16*)((char*)ll + bo) = (u16)s.lo;
  }
}

// ---- persistent kernel: batch-parallel groups, 8 waves/CU ------------------
// group g = wg&7 owns batches [g*32,+32); cg = wg>>3 owns 16 cols.
// wave wv in [0,8): gate g4 = wv>>1, M-tile mt = wv&1 (16 batches each).
__global__ void __launch_bounds__(512, 1) lstm_persist(
    const float* __restrict__ x,
    const float* __restrict__ Whh0, const float* __restrict__ Wih0,
    const u16* __restrict__ W1ih_h, const u16* __restrict__ W1ih_l,
    const u16* __restrict__ W1hh_h, const u16* __restrict__ W1hh_l,
    const u16* __restrict__ Wcmb_h, const u16* __restrict__ Wcmb_l,
    const float* __restrict__ bb,
    const float* __restrict__ bih0, const float* __restrict__ bhh0,
    const float* __restrict__ bih1, const float* __restrict__ bhh1,
    const float* __restrict__ Wout, const float* __restrict__ bout,
    float* __restrict__ out, unsigned* __restrict__ cnt,
    u16* __restrict__ h0h0, u16* __restrict__ h0h1,
    u16* __restrict__ h0l0, u16* __restrict__ h0l1,
    u16* __restrict__ h1h0, u16* __restrict__ h1h1,
    u16* __restrict__ h1l0, u16* __restrict__ h1l1)
{
  __shared__ u16 whh0_h[32768], whh0_l[32768];   // 64x512, swizzled
  __shared__ u16 w0ih_h[4096],  w0ih_l[4096];    // 64x64, swizzled
  __shared__ float gl[32*68];                    // gate exchange
  __shared__ float pr[512];                      // pred partials [d][kq]
  __shared__ float bs0[64], bs1[64], bsd[64];
  __shared__ unsigned s_pop, s_nx, s_all;

  const int wg = blockIdx.x, tid = threadIdx.x;
  const int g = wg & 7, cg = wg >> 3;
  const int b0 = g*32;
  const int lane = tid & 63, wv = tid >> 6;      // 0..7
  const int g4 = wv >> 1, mt = wv & 1;
  const int cI = lane & 15;
  const int kc = (lane >> 4) << 3;
  const int rl = g4*16 + cI;                     // local gate row

  // ---- one-time init: LDS weight slices + biases ----
  load_slice64(Whh0, 512, 9, 32768, whh0_h, whh0_l, cg, tid);
  load_slice64(Wih0,  64, 6,  4096, w0ih_h, w0ih_l, cg, tid);
  if (tid < 64){
    int n = ((tid >> 4) << 9) + cg*16 + (tid & 15);
    bs0[tid] = bih0[n] + bhh0[n];
    bs1[tid] = bih1[n] + bhh1[n];
    bsd[tid] = bb[n];
  }

  // ---- census: XCD id, per-XCD pop (fallback), group co-location ----
  unsigned xcd;
  asm volatile("s_getreg_b32 %0, hwreg(HW_REG_XCC_ID)" : "=s"(xcd));
  xcd &= 7u;
  if (tid == 0){
    __hip_atomic_fetch_add(cnt + 576 + xcd*32, 1u, AXR);
    __hip_atomic_store(cnt + 1536 + wg, xcd, AXR);
  }
  gbar(cnt, 1);
  if (tid == 0){
    unsigned nxl = 0;
    for (int i = 0; i < 8; ++i)
      nxl += (__hip_atomic_load(cnt + 576 + i*32, AXR) != 0u) ? 1u : 0u;
    s_pop = __hip_atomic_load(cnt + 576 + xcd*32, AXR);
    s_nx  = nxl;
    unsigned ok = 1;
    for (int i = 0; i < 32; ++i)
      ok &= (__hip_atomic_load(cnt + 1536 + (g + 8*i), AXR) == xcd) ? 1u : 0u;
    if (!ok) __hip_atomic_store(cnt + 1800 + g, 1u, AXR);
  }
  gbar(cnt, 2);
  if (tid == 0){
    unsigned bad = 0;
    for (int gg = 0; gg < 8; ++gg)
      bad |= __hip_atomic_load(cnt + 1800 + gg, AXR);
    s_all = (bad == 0u) ? 1u : 0u;
  }
  __syncthreads();
  const unsigned pop = s_pop, nx = s_nx;
  const bool allco = (s_all != 0u);

  const int ar = b0 + mt*16 + cI;                // A row (batch)
  const int aoff = ar*512 + kc;
  const int nb = (g4*512 + cg*16 + cI)*512 + kc; // streamed weight frag base

  u16* H0h[2] = { h0h0, h0h1 };  u16* H0l[2] = { h0l0, h0l1 };
  u16* H1h[2] = { h1h0, h1h1 };  u16* H1l[2] = { h1l0, h1l1 };

  const float* xb = x + ar*21504;

  float c0r = 0.f, c1r = 0.f;                    // cell state in registers
  unsigned ep = 0;

  for (int t = 0; t < 432; ++t){
    const int p = t & 1;
    const bool enc = (t < 336);

    // =============== phase A: layer 0 ===============
    f32x4 A = {0,0,0,0};
    if (enc){
      #pragma unroll
      for (int ks = 0; ks < 2; ++ks){            // x segment (K=64)
        int k = ks*32 + kc;
        short8 ah_, al_;
        #pragma unroll
        for (int j = 0; j < 8; ++j){
          HiLo s0 = split1(xb[(k + j)*336 + t]); ah_[j] = s0.hi; al_[j] = s0.lo;
        }
        short8 bh = lds8(w0ih_h, rl, k, 128);
        short8 bl = lds8(w0ih_l, rl, k, 128);
        SMACC(A, ah_, al_, bh, bl);
      }
    } else if (t > 336){                         // Wcomb segment over h1_{t-1}
      const u16* hH = H1h[p^1]; const u16* hL = H1l[p^1];
      const u16* wh = Wcmb_h + nb; const u16* wl_ = Wcmb_l + nb;
      #pragma unroll 4
      for (int ks = 0; ks < 16; ++ks){
        int k = ks*32;
        short8 ah_ = *(const short8*)(hH + aoff + k);
        short8 al_ = *(const short8*)(hL + aoff + k);
        short8 bh = *(const short8*)(wh + k);
        short8 bl = *(const short8*)(wl_ + k);
        SMACC(A, ah_, al_, bh, bl);
      }
    }
    {                                            // Whh0 (LDS) over h0_{t-1}
      const u16* hH = H0h[p^1]; const u16* hL = H0l[p^1];
      #pragma unroll 4
      for (int ks = 0; ks < 16; ++ks){
        int k = ks*32;
        short8 ah_ = *(const short8*)(hH + aoff + k);
        short8 al_ = *(const short8*)(hL + aoff + k);
        short8 bh = lds8(whh0_h, rl, kc + k, 1024);
        short8 bl = lds8(whh0_l, rl, kc + k, 1024);
        SMACC(A, ah_, al_, bh, bl);
      }
    }
    // decoder pred l=t-337 from h1_{t-1}: this WG owns batch b0+cg
    if (!enc && t > 336){
      const int d = tid & 63, kq = tid >> 6;     // kq 0..7
      const int b = b0 + cg;
      const u16* hH = H1h[p^1] + b*512 + kq*64;
      const u16* hL = H1l[p^1] + b*512 + kq*64;
      const float* wr = Wout + d*512 + kq*64;
      float part = 0.f;
      #pragma unroll 4
      for (int k = 0; k < 64; k += 8){
        short8 hv = *(const short8*)(hH + k);
        short8 lv = *(const short8*)(hL + k);
        #pragma unroll
        for (int j = 0; j < 8; ++j)
          part += (bf2f((u16)hv[j]) + bf2f((u16)lv[j])) * wr[k + j];
      }
      pr[d*8 + kq] = part;
      __syncthreads();
      if (tid < 64){
        float v = bout[tid];
        #pragma unroll
        for (int q = 0; q < 8; ++q) v += pr[tid*8 + q];
        out[131072 + (b*64 + tid)*96 + (t - 337)] = v;
      }
    }
    // cell update layer 0 (c in one register)
    {
      const float* bias = (enc || t == 336) ? bs0 : bsd;
      __syncthreads();
      const int rb_ = (lane >> 4) << 2;
      #pragma unroll
      for (int r = 0; r < 4; ++r)
        gl[(mt*16 + rb_ + r)*68 + rl] = A[r] + bias[rl];
      __syncthreads();
      u16* Hh = H0h[p]; u16* Hl = H0l[p];
      {
        int m = tid >> 4, col = tid & 15;
        float iv = gl[m*68 + col];
        float fv = gl[m*68 + 16 + col];
        float gv = gl[m*68 + 32 + col];
        float ov = gl[m*68 + 48 + col];
        float si = 1.f/(1.f + expf(-iv));
        float sf = 1.f/(1.f + expf(-fv));
        float so = 1.f/(1.f + expf(-ov));
        float cn = sf*c0r + si*tanhf(gv);
        c0r = cn;
        float h = so*tanhf(cn);
        int gi = (b0 + m)*512 + cg*16 + col;
        u16 hh = f2bf(h);
        Hh[gi] = hh;
        Hl[gi] = f2bf(h - bf2f(hh));
      }
    }
    ++ep;
    if (allco) pbar(cnt, g, ep); else xbar(cnt, ep, xcd, pop, nx);

    // =============== phase B: layer 1 ===============
    A = (f32x4){0,0,0,0};
    {
      const u16* hH = H0h[p]; const u16* hL = H0l[p];      // h0_t
      const u16* wh = W1ih_h + nb; const u16* wl_ = W1ih_l + nb;
      #pragma unroll 4
      for (int ks = 0; ks < 16; ++ks){
        int k = ks*32;
        short8 ah_ = *(const short8*)(hH + aoff + k);
        short8 al_ = *(const short8*)(hL + aoff + k);
        short8 bh = *(const short8*)(wh + k);
        short8 bl = *(const short8*)(wl_ + k);
        SMACC(A, ah_, al_, bh, bl);
      }
    }
    {
      const u16* hH = H1h[p^1]; const u16* hL = H1l[p^1];  // h1_{t-1}
      const u16* wh = W1hh_h + nb; const u16* wl_ = W1hh_l + nb;
      #pragma unroll 4
      for (int ks = 0; ks < 16; ++ks){
        int k = ks*32;
        short8 ah_ = *(const short8*)(hH + aoff + k);
        short8 al_ = *(const short8*)(hL + aoff + k);
        short8 bh = *(const short8*)(wh + k);
        short8 bl = *(const short8*)(wl_ + k);
        SMACC(A, ah_, al_, bh, bl);
      }
    }
    // cell update layer 1
    {
      float* gf = (t == 335) ? out : (float*)nullptr;
      __syncthreads();
      const int rb_ = (lane >> 4) << 2;
      #pragma unroll
      for (int r = 0; r < 4; ++r)
        gl[(mt*16 + rb_ + r)*68 + rl] = A[r] + bs1[rl];
      __syncthreads();
      u16* Hh = H1h[p]; u16* Hl = H1l[p];
      {
        int m = tid >> 4, col = tid & 15;
        float iv = gl[m*68 + col];
        float fv = gl[m*68 + 16 + col];
        float gv = gl[m*68 + 32 + col];
        float ov = gl[m*68 + 48 + col];
        float si = 1.f/(1.f + expf(-iv));
        float sf = 1.f/(1.f + expf(-fv));
        float so = 1.f/(1.f + expf(-ov));
        float cn = sf*c1r + si*tanhf(gv);
        c1r = cn;
        float h = so*tanhf(cn);
        int gi = (b0 + m)*512 + cg*16 + col;
        u16 hh = f2bf(h);
        Hh[gi] = hh;
        Hl[gi] = f2bf(h - bf2f(hh));
        if (gf) gf[gi] = h;
      }
    }
    ++ep;
    if (allco) pbar(cnt, g, ep); else xbar(cnt, ep, xcd, pop, nx);
  }
}

// ---- tail: pred for l=95 from h1_431 (parity 1) ----------------------------
__global__ void __launch_bounds__(256) pred_last(
    const u16* __restrict__ h1hi, const u16* __restrict__ h1lo,
    const float* __restrict__ Wout, const float* __restrict__ bout,
    float* __restrict__ out)
{
  const int wg = blockIdx.x, tid = threadIdx.x;
  const int bsub = tid >> 6, d = tid & 63;
  const int b = wg*4 + bsub;
  float acc = bout[d];
  const u16* hH = h1hi + b*512;
  const u16* hL = h1lo + b*512;
  const float* wr = Wout + d*512;
  #pragma unroll 8
  for (int k = 0; k < 512; k += 8){
    short8 hv = *(const short8*)(hH + k);
    short8 lv = *(const short8*)(hL + k);
    #pragma unroll
    for (int j = 0; j < 8; ++j)
      acc += (bf2f((u16)hv[j]) + bf2f((u16)lv[j])) * wr[k + j];
  }
  out[131072 + (b*64 + d)*96 + 95] = acc;
}

// ======================= fallback (R9 proven path) ==========================
__device__ __forceinline__ void cell_epilogue_fb(
    float* gl, const float* bs, float* __restrict__ cbuf,
    u16* __restrict__ hhi, u16* __restrict__ hlo,
    float* __restrict__ gfout, int mrow, int jblk,
    const f32x4& a0, const f32x4& a1, int wv, int lane, int tid)
{
  __syncthreads();
  const int rbase = wv*16 + ((lane >> 4) << 2);
  const int cI = lane & 15;
  #pragma unroll
  for (int r = 0; r < 4; ++r){
    gl[(rbase+r)*33 + cI]      = a0[r] + bs[cI];
    gl[(rbase+r)*33 + 16 + cI] = a1[r] + bs[16 + cI];
  }
  __syncthreads();
  #pragma unroll
  for (int q = 0; q < 2; ++q){
    int e = tid + q*256;
    int m = e >> 3, jj = e & 7;
    float iv = gl[m*33 + jj];
    float fv = gl[m*33 + 8 + jj];
    float gv = gl[m*33 + 16 + jj];
    float ov = gl[m*33 + 24 + jj];
    float si = 1.f/(1.f + expf(-iv));
    float sf = 1.f/(1.f + expf(-fv));
    float so = 1.f/(1.f + expf(-ov));
    int gi = (mrow*64 + m)*512 + jblk*8 + jj;
    float cn = sf*cbuf[gi] + si*tanhf(gv);
    cbuf[gi] = cn;
    float h = so*tanhf(cn);
    u16 hh = f2bf(h);
    hhi[gi] = hh;
    hlo[gi] = f2bf(h - bf2f(hh));
    if (gfout) gfout[gi] = h;
  }
}

template<bool ENC>
__global__ void __launch_bounds__(256) l0_fb(
    const float* __restrict__ x,
    const u16* __restrict__ predhi, const u16* __restrict__ predlo,
    const float* __restrict__ Wihf, const float* __restrict__ Whhf,
    const float* __restrict__ bih, const float* __restrict__ bhh,
    const u16* __restrict__ hphi, const u16* __restrict__ hplo,
    u16* __restrict__ hnhi, u16* __restrict__ hnlo,
    float* __restrict__ c0, int t)
{
  __shared__ float gl[64*33];
  __shared__ float bs[32];
  const int wg = blockIdx.x, tid = threadIdx.x;
  const int mrow = wg & 3, jblk = wg >> 2;
  const int lane = tid & 63, wv = tid >> 6;
  if (tid < 32){
    int n = ((tid >> 3) << 9) + jblk*8 + (tid & 7);
    bs[tid] = bih[n] + bhh[n];
  }
  const int ar = mrow*64 + wv*16 + (lane & 15);
  const int kc = (lane >> 4) << 3;
  const int cI = lane & 15;
  const int n0 = ((cI >> 3) << 9) + jblk*8 + (cI & 7);
  const int n1 = n0 + 1024;

  f32x4 acc0 = {0,0,0,0}, acc1 = {0,0,0,0};
  #pragma unroll
  for (int ks = 0; ks < 2; ++ks){
    int k = ks*32 + kc;
    short8 ah, al;
    if (ENC){
      const float* xb = x + ar*21504 + t;
      #pragma unroll
      for (int j = 0; j < 8; ++j){ HiLo s = split1(xb[(k + j)*336]); ah[j] = s.hi; al[j] = s.lo; }
    } else {
      ah = *(const short8*)(predhi + ar*64 + k);
      al = *(const short8*)(predlo + ar*64 + k);
    }
    short8 bh0, bl0, bh1, bl1;
    ldw8s(Wihf + n0*64 + k, bh0, bl0);
    ldw8s(Wihf + n1*64 + k, bh1, bl1);
    SMACC(acc0, ah, al, bh0, bl0);
    SMACC(acc1, ah, al, bh1, bl1);
  }
  const u16* hH = hphi + ar*512 + kc;
  const u16* hL = hplo + ar*512 + kc;
  #pragma unroll 4
  for (int ks = 0; ks < 16; ++ks){
    int k = ks*32;
    short8 ah = *(const short8*)(hH + k);
    short8 al = *(const short8*)(hL + k);
    short8 bh0, bl0, bh1, bl1;
    ldw8s(Whhf + n0*512 + kc + k, bh0, bl0);
    ldw8s(Whhf + n1*512 + kc + k, bh1, bl1);
    SMACC(acc0, ah, al, bh0, bl0);
    SMACC(acc1, ah, al, bh1, bl1);
  }
  cell_epilogue_fb(gl, bs, c0, hnhi, hnlo, nullptr, mrow, jblk, acc0, acc1, wv, lane, tid);
}

__global__ void __launch_bounds__(256) l1_fb(
    const float* __restrict__ Wihf, const float* __restrict__ Whhf,
    const float* __restrict__ bih, const float* __restrict__ bhh,
    const u16* __restrict__ h0hi, const u16* __restrict__ h0lo,
    const u16* __restrict__ h1phi, const u16* __restrict__ h1plo,
    u16* __restrict__ h1nhi, u16* __restrict__ h1nlo,
    float* __restrict__ c1, float* __restrict__ gfout)
{
  __shared__ float gl[64*33];
  __shared__ float bs[32];
  const int wg = blockIdx.x, tid = threadIdx.x;
  const int mrow = wg & 3, jblk = wg >> 2;
  const int lane = tid & 63, wv = tid >> 6;
  if (tid < 32){
    int n = ((tid >> 3) << 9) + jblk*8 + (tid & 7);
    bs[tid] = bih[n] + bhh[n];
  }
  const int ar = mrow*64 + wv*16 + (lane & 15);
  const int kc = (lane >> 4) << 3;
  const int cI = lane & 15;
  const int n0 = ((cI >> 3) << 9) + jblk*8 + (cI & 7);
  const int n1 = n0 + 1024;

  f32x4 acc0 = {0,0,0,0}, acc1 = {0,0,0,0};
  {
    const u16* hH = h0hi + ar*512 + kc;
    const u16* hL = h0lo + ar*512 + kc;
    #pragma unroll 4
    for (int ks = 0; ks < 16; ++ks){
      int k = ks*32;
      short8 ah = *(const short8*)(hH + k);
      short8 al = *(const short8*)(hL + k);
      short8 bh0, bl0, bh1, bl1;
      ldw8s(Wihf + n0*512 + kc + k, bh0, bl0);
      ldw8s(Wihf + n1*512 + kc + k, bh1, bl1);
      SMACC(acc0, ah, al, bh0, bl0);
      SMACC(acc1, ah, al, bh1, bl1);
    }
  }
  {
    const u16* hH = h1phi + ar*512 + kc;
    const u16* hL = h1plo + ar*512 + kc;
    #pragma unroll 4
    for (int ks = 0; ks < 16; ++ks){
      int k = ks*32;
      short8 ah = *(const short8*)(hH + k);
      short8 al = *(const short8*)(hL + k);
      short8 bh0, bl0, bh1, bl1;
      ldw8s(Whhf + n0*512 + kc + k, bh0, bl0);
      ldw8s(Whhf + n1*512 + kc + k, bh1, bl1);
      SMACC(acc0, ah, al, bh0, bl0);
      SMACC(acc1, ah, al, bh1, bl1);
    }
  }
  cell_epilogue_fb(gl, bs, c1, h1nhi, h1nlo, gfout, mrow, jblk, acc0, acc1, wv, lane, tid);
}

__global__ void __launch_bounds__(256) pred_fb(
    const u16* __restrict__ h1hi, const u16* __restrict__ h1lo,
    const float* __restrict__ Wout, const float* __restrict__ bout,
    u16* __restrict__ predhi, u16* __restrict__ predlo,
    float* __restrict__ out, int l)
{
  const int wg = blockIdx.x, tid = threadIdx.x;
  const int bsub = tid >> 6, d = tid & 63;
  const int b = wg*4 + bsub;
  float acc = bout[d];
  const u16* hH = h1hi + b*512;
  const u16* hL = h1lo + b*512;
  const float* wr = Wout + d*512;
  #pragma unroll 8
  for (int k = 0; k < 512; k += 8){
    short8 hv = *(const short8*)(hH + k);
    short8 lv = *(const short8*)(hL + k);
    #pragma unroll
    for (int j = 0; j < 8; ++j)
      acc += (bf2f((u16)hv[j]) + bf2f((u16)lv[j])) * wr[k + j];
  }
  HiLo s = split1(acc);
  predhi[b*64 + d] = (u16)s.hi;
  predlo[b*64 + d] = (u16)s.lo;
  out[131072 + (b*64 + d)*96 + l] = acc;
}

extern "C" void kernel_launch(void* const* d_in, const int* in_sizes, int n_in,
                              void* d_out, int out_size, void* d_ws, size_t ws_size,
                              hipStream_t stream)
{
  const float* x    = (const float*)d_in[0];
  const float* Wih0 = (const float*)d_in[1];
  const float* Whh0 = (const float*)d_in[2];
  const float* bih0 = (const float*)d_in[3];
  const float* bhh0 = (const float*)d_in[4];
  const float* Wih1 = (const float*)d_in[5];
  const float* Whh1 = (const float*)d_in[6];
  const float* bih1 = (const float*)d_in[7];
  const float* bhh1 = (const float*)d_in[8];
  const float* Wout = (const float*)d_in[9];
  const float* bout = (const float*)d_in[10];
  float* out = (float*)d_out;

  // ---- ws layout (main): h 2MB | cnt 64KB | split weights 12MB | bb 8KB
  char* ws = (char*)d_ws;
  u16* h0h[2] = { (u16*)(ws + 0),       (u16*)(ws + 262144) };
  u16* h0l[2] = { (u16*)(ws + 524288),  (u16*)(ws + 786432) };
  u16* h1h[2] = { (u16*)(ws + 1048576), (u16*)(ws + 1310720) };
  u16* h1l[2] = { (u16*)(ws + 1572864), (u16*)(ws + 1835008) };
  unsigned* cnt = (unsigned*)(ws + 2097152);
  u16* Wcmb_h = (u16*)(ws + 2162688);
  u16* Wcmb_l = Wcmb_h + 1048576;
  u16* W1ih_h = Wcmb_l + 1048576;
  u16* W1ih_l = W1ih_h + 1048576;
  u16* W1hh_h = W1ih_l + 1048576;
  u16* W1hh_l = W1hh_h + 1048576;
  float* bb   = (float*)(W1hh_l + 1048576);
  const size_t NEED = 2162688u + 6u*2097152u + 8192u;   // ~14.8 MB
  // fallback layout (only used when ws too small)
  float* fb_c0 = (float*)(ws + 2162688);
  float* fb_c1 = (float*)(ws + 2686976);
  u16* predh   = (u16*)(ws + 3211264);
  u16* predl   = (u16*)(ws + 3244032);
  const bool ps = (ws_size >= NEED);

  (void)hipMemsetAsync(d_ws, 0, 3276800, stream);   // h + cnt (+ fb c/pred)

  if (ps){
    wcomb_k<<<dim3(256), dim3(256), 0, stream>>>(Wih0, Wout, bout, bih0, bhh0,
                                                 Wcmb_h, Wcmb_l, bb);
    wsplit<<<dim3(4096), dim3(256), 0, stream>>>(Wih1, W1ih_h, W1ih_l, 1048576);
    wsplit<<<dim3(4096), dim3(256), 0, stream>>>(Whh1, W1hh_h, W1hh_l, 1048576);
    lstm_persist<<<dim3(256), dim3(512), 0, stream>>>(
        x, Whh0, Wih0, W1ih_h, W1ih_l, W1hh_h, W1hh_l, Wcmb_h, Wcmb_l, bb,
        bih0, bhh0, bih1, bhh1, Wout, bout, out, cnt,
        h0h[0], h0h[1], h0l[0], h0l[1], h1h[0], h1h[1], h1l[0], h1l[1]);
    pred_last<<<dim3(64), dim3(256), 0, stream>>>(h1h[1], h1l[1], Wout, bout, out);
  } else {
    for (int t = 0; t < 432; ++t){
      const int p = t & 1;
      float* gf = (t == 335) ? out : (float*)nullptr;
      if (t < 336)
        l0_fb<true><<<dim3(256), dim3(256), 0, stream>>>(
            x, predh, predl, Wih0, Whh0, bih0, bhh0,
            h0h[p^1], h0l[p^1], h0h[p], h0l[p], fb_c0, t);
      else
        l0_fb<false><<<dim3(256), dim3(256), 0, stream>>>(
            x, predh, predl, Wih0, Whh0, bih0, bhh0,
            h0h[p^1], h0l[p^1], h0h[p], h0l[p], fb_c0, t);
      l1_fb<<<dim3(256), dim3(256), 0, stream>>>(
          Wih1, Whh1, bih1, bhh1, h0h[p], h0l[p],
          h1h[p^1], h1l[p^1], h1h[p], h1l[p], fb_c1, gf);
      if (t >= 336)
        pred_fb<<<dim3(64), dim3(256), 0, stream>>>(
            h1h[p], h1l[p], Wout, bout, predh, predl, out, t - 336);
    }
  }
}

// Round 17
// 19100.597 us; speedup vs baseline: 1.1320x; 1.1320x over previous
//
#include <hip/hip_runtime.h>

typedef unsigned short u16;
typedef __attribute__((ext_vector_type(8))) short short8;
typedef __attribute__((ext_vector_type(4))) float f32x4;

#define AXR __ATOMIC_RELAXED, __HIP_MEMORY_SCOPE_AGENT

__device__ __forceinline__ float bf2f(u16 v){
  union { unsigned u; float f; } t; t.u = ((unsigned)v) << 16; return t.f;
}
__device__ __forceinline__ u16 f2bf(float f){
  union { float f; unsigned u; } t; t.f = f;
  unsigned u = t.u;
  return (u16)((u + 0x7fffu + ((u >> 16) & 1u)) >> 16);
}
struct HiLo { short hi, lo; };
__device__ __forceinline__ HiLo split1(float v){
  HiLo r;
  u16 h = f2bf(v);
  r.hi = (short)h;
  r.lo = (short)f2bf(v - bf2f(h));
  return r;
}
__device__ __forceinline__ void ldw8s(const float* __restrict__ p, short8& hi, short8& lo){
  #pragma unroll
  for (int j = 0; j < 8; ++j){ HiLo s = split1(p[j]); hi[j] = s.hi; lo[j] = s.lo; }
}

#define MFMA(acc, a, b) acc = __builtin_amdgcn_mfma_f32_16x16x32_bf16(a, b, acc, 0,0,0)
#define SMACC(acc, ah, al, bh, bl) do{ MFMA(acc, ah, bh); MFMA(acc, ah, bl); MFMA(acc, al, bh); }while(0)

// ---- prepass: f32 -> (hi,lo) bf16 ------------------------------------------
__global__ void wsplit(const float* __restrict__ s, u16* __restrict__ hi,
                       u16* __restrict__ lo, int n){
  int i = blockIdx.x * blockDim.x + threadIdx.x;
  if (i < n){ HiLo r = split1(s[i]); hi[i] = (u16)r.hi; lo[i] = (u16)r.lo; }
}

// ---- prepass: Wcomb = Wih0 @ Wout (2048x512, split), bb = b0 + Wih0@bout ---
__global__ void __launch_bounds__(256) wcomb_k(
    const float* __restrict__ Wih0, const float* __restrict__ Wout,
    const float* __restrict__ bout, const float* __restrict__ bih0,
    const float* __restrict__ bhh0,
    u16* __restrict__ Wch, u16* __restrict__ Wcl, float* __restrict__ bb)
{
  __shared__ float wl[8*64];
  __shared__ float bo[64];
  const int wg = blockIdx.x, tid = threadIdx.x;
  const int r0 = wg*8;
  for (int i = tid; i < 512; i += 256) wl[i] = Wih0[(r0 + (i >> 6))*64 + (i & 63)];
  if (tid < 64) bo[tid] = bout[tid];
  __syncthreads();
  if (tid < 8){
    int n = r0 + tid;
    float a = bih0[n] + bhh0[n];
    #pragma unroll 8
    for (int d = 0; d < 64; ++d) a += wl[tid*64 + d]*bo[d];
    bb[n] = a;
  }
  #pragma unroll
  for (int jj = 0; jj < 2; ++jj){
    int j = tid + jj*256;
    float acc[8] = {0,0,0,0,0,0,0,0};
    for (int d = 0; d < 64; ++d){
      float wv = Wout[d*512 + j];
      #pragma unroll
      for (int r = 0; r < 8; ++r) acc[r] += wl[r*64 + d]*wv;
    }
    #pragma unroll
    for (int r = 0; r < 8; ++r){
      HiLo s = split1(acc[r]);
      Wch[(r0 + r)*512 + j] = (u16)s.hi;
      Wcl[(r0 + r)*512 + j] = (u16)s.lo;
    }
  }
}

// ---- init-only tree barrier (threadfence-based, proven R13/R14) ------------
__device__ __forceinline__ void gbar(unsigned* bar, unsigned phase){
  __syncthreads();
  if (threadIdx.x == 0){
    __threadfence();
    const unsigned gg = (unsigned)blockIdx.x >> 4;
    unsigned old = __hip_atomic_fetch_add(bar + 64 + gg*32, 1u, AXR);
    if (old == phase*16u - 1u){
      unsigned r = __hip_atomic_fetch_add(bar, 1u, AXR);
      if (r == phase*16u - 1u)
        __hip_atomic_store(bar + 32, phase, AXR);
    }
    while (__hip_atomic_load(bar + 32, AXR) < phase)
      __builtin_amdgcn_s_sleep(2);
    __threadfence();
  }
  __syncthreads();
}

// ---- global fallback barrier (R14 xbar, any WG placement) ------------------
__device__ __forceinline__ void xbar(unsigned* bar, unsigned phase,
                                     unsigned xcd, unsigned pop, unsigned nx){
  __syncthreads();
  if (threadIdx.x == 0){
    unsigned old = __hip_atomic_fetch_add(bar + 832 + xcd*32, 1u, AXR);
    const bool leader = (old == phase*pop - 1u);
    if (leader){
      asm volatile("buffer_wbl2 sc1\n\ts_waitcnt vmcnt(0)" ::: "memory");
      unsigned r = __hip_atomic_fetch_add(bar + 1344, 1u, AXR);
      if (r == phase*nx - 1u)
        __hip_atomic_store(bar + 1376, phase, AXR);
    }
    while (__hip_atomic_load(bar + 1376, AXR) < phase)
      __builtin_amdgcn_s_sleep(2);
    if (leader){
      asm volatile("buffer_inv sc1\n\ts_waitcnt vmcnt(0)" ::: "memory");
      __hip_atomic_store(bar + 1088 + xcd*32, phase, AXR);
    } else {
      while (__hip_atomic_load(bar + 1088 + xcd*32, AXR) < phase)
        __builtin_amdgcn_s_sleep(1);
      asm volatile("buffer_inv\n\ts_waitcnt vmcnt(0)" ::: "memory");
    }
  }
  __syncthreads();
}

// ---- group-local barrier (requires group co-located on one XCD) ------------
__device__ __forceinline__ void pbar(unsigned* bar, unsigned g, unsigned phase){
  __syncthreads();
  if (threadIdx.x == 0){
    unsigned* ctr = bar + 2048 + g*32;
    __hip_atomic_fetch_add(ctr, 1u, AXR);
    while (__hip_atomic_load(ctr, AXR) < phase*32u)
      __builtin_amdgcn_s_sleep(1);
    asm volatile("buffer_inv\n\ts_waitcnt vmcnt(0)" ::: "memory");
  }
  __syncthreads();
}

// ---- LDS weight-slice helpers (XOR-swizzled, G4) ---------------------------
__device__ __forceinline__ short8 lds8(const u16* base, int r, int kelem, int rowbytes){
  int bo = r*rowbytes + ((kelem*2) ^ ((r & 7) << 4));
  return *(const short8*)((const char*)base + bo);
}
// 64 gate rows (4 gates x 16 cols of col-group cg) x ldw K
__device__ __forceinline__ void load_slice64(
    const float* __restrict__ W, int ldw, int rowshift, int nelem,
    u16* lh, u16* ll, int cg, int tid)
{
  const int rowbytes = ldw*2;
  for (int i = tid; i < nelem; i += 256){
    int r = i >> rowshift, k = i & ((1 << rowshift) - 1);
    int n = ((r >> 4) << 9) + cg*16 + (r & 15);
    HiLo s = split1(W[n*ldw + k]);
    int bo = r*rowbytes + ((k*2) ^ ((r & 7) << 4));
    *(u16*)((char*)lh + bo) = (u16)s.hi;
    *(u16*)((char*)ll + bo) = (u16)s.lo;
  }
}

// ---- persistent kernel: batch-parallel groups, XCD-local exchange ----------
// group g = wg&7 owns batches [g*32, +32); col-group cg = wg>>3 owns 16 cols.
// Streamed K-loops are SKEWED per group g so XCDs never read the same LLC
// line simultaneously (anti-lockstep).
__global__ void __launch_bounds__(256, 1) lstm_persist(
    const float* __restrict__ x,
    const float* __restrict__ Whh0, const float* __restrict__ Wih0,
    const u16* __restrict__ W1ih_h, const u16* __restrict__ W1ih_l,
    const u16* __restrict__ W1hh_h, const u16* __restrict__ W1hh_l,
    const u16* __restrict__ Wcmb_h, const u16* __restrict__ Wcmb_l,
    const float* __restrict__ bb,
    const float* __restrict__ bih0, const float* __restrict__ bhh0,
    const float* __restrict__ bih1, const float* __restrict__ bhh1,
    const float* __restrict__ Wout, const float* __restrict__ bout,
    float* __restrict__ out, unsigned* __restrict__ cnt,
    u16* __restrict__ h0h0, u16* __restrict__ h0h1,
    u16* __restrict__ h0l0, u16* __restrict__ h0l1,
    u16* __restrict__ h1h0, u16* __restrict__ h1h1,
    u16* __restrict__ h1l0, u16* __restrict__ h1l1)
{
  __shared__ u16 whh0_h[32768], whh0_l[32768];   // 64x512, swizzled
  __shared__ u16 w0ih_h[4096],  w0ih_l[4096];    // 64x64, swizzled
  __shared__ float gl[32*68];                    // gate exchange
  __shared__ float pr[256];                      // pred partials [d][kq]
  __shared__ float bs0[64], bs1[64], bsd[64];
  __shared__ unsigned s_pop, s_nx, s_all;

  const int wg = blockIdx.x, tid = threadIdx.x;
  const int g = wg & 7, cg = wg >> 3;
  const int b0 = g*32;
  const int lane = tid & 63, wv = tid >> 6;
  const int cI = lane & 15;
  const int kc = (lane >> 4) << 3;
  const int rl = wv*16 + cI;                     // local gate row

  // ---- one-time init: LDS weight slices + biases ----
  load_slice64(Whh0, 512, 9, 32768, whh0_h, whh0_l, cg, tid);
  load_slice64(Wih0,  64, 6,  4096, w0ih_h, w0ih_l, cg, tid);
  if (tid < 64){
    int n = ((tid >> 4) << 9) + cg*16 + (tid & 15);
    bs0[tid] = bih0[n] + bhh0[n];
    bs1[tid] = bih1[n] + bhh1[n];
    bsd[tid] = bb[n];
  }

  // ---- census: XCD id, per-XCD pop (fallback), group co-location ----
  unsigned xcd;
  asm volatile("s_getreg_b32 %0, hwreg(HW_REG_XCC_ID)" : "=s"(xcd));
  xcd &= 7u;
  if (tid == 0){
    __hip_atomic_fetch_add(cnt + 576 + xcd*32, 1u, AXR);
    __hip_atomic_store(cnt + 1536 + wg, xcd, AXR);
  }
  gbar(cnt, 1);
  if (tid == 0){
    unsigned nxl = 0;
    for (int i = 0; i < 8; ++i)
      nxl += (__hip_atomic_load(cnt + 576 + i*32, AXR) != 0u) ? 1u : 0u;
    s_pop = __hip_atomic_load(cnt + 576 + xcd*32, AXR);
    s_nx  = nxl;
    unsigned ok = 1;
    for (int i = 0; i < 32; ++i)
      ok &= (__hip_atomic_load(cnt + 1536 + (g + 8*i), AXR) == xcd) ? 1u : 0u;
    if (!ok) __hip_atomic_store(cnt + 1800 + g, 1u, AXR);
  }
  gbar(cnt, 2);
  if (tid == 0){
    unsigned bad = 0;
    for (int gg = 0; gg < 8; ++gg)
      bad |= __hip_atomic_load(cnt + 1800 + gg, AXR);
    s_all = (bad == 0u) ? 1u : 0u;
  }
  __syncthreads();
  const unsigned pop = s_pop, nx = s_nx;
  const bool allco = (s_all != 0u);

  const int ar0 = b0 + cI, ar1 = b0 + 16 + cI;   // A rows (batches)
  const int aoff0 = ar0*512 + kc, aoff1 = ar1*512 + kc;
  const int nb = (wv*512 + cg*16 + cI)*512 + kc; // streamed weight frag base

  u16* H0h[2] = { h0h0, h0h1 };  u16* H0l[2] = { h0l0, h0l1 };
  u16* H1h[2] = { h1h0, h1h1 };  u16* H1l[2] = { h1l0, h1l1 };

  const float* xb0 = x + ar0*21504;
  const float* xb1 = x + ar1*21504;

  float c0r[2] = {0.f, 0.f}, c1r[2] = {0.f, 0.f};   // cell state in registers
  unsigned ep = 0;

  const int sk1 = g*2;            // per-XCD K-chunk skew (16-chunk ring)
  const int sk2 = (g >> 1)*4;     // phase-B skew (combined with matrix-order)

  for (int t = 0; t < 432; ++t){
    const int p = t & 1;
    const bool enc = (t < 336);

    // =============== phase A: layer 0 ===============
    f32x4 A0 = {0,0,0,0}, A1 = {0,0,0,0};
    if (enc){
      #pragma unroll
      for (int ks = 0; ks < 2; ++ks){            // x segment (K=64)
        int k = ks*32 + kc;
        short8 a0h, a0l, a1h, a1l;
        #pragma unroll
        for (int j = 0; j < 8; ++j){
          HiLo s0 = split1(xb0[(k + j)*336 + t]); a0h[j] = s0.hi; a0l[j] = s0.lo;
          HiLo s1 = split1(xb1[(k + j)*336 + t]); a1h[j] = s1.hi; a1l[j] = s1.lo;
        }
        short8 bh = lds8(w0ih_h, rl, k, 128);
        short8 bl = lds8(w0ih_l, rl, k, 128);
        SMACC(A0, a0h, a0l, bh, bl);
        SMACC(A1, a1h, a1l, bh, bl);
      }
    } else if (t > 336){                         // Wcomb over h1_{t-1}, skewed
      const u16* hH = H1h[p^1]; const u16* hL = H1l[p^1];
      const u16* wh = Wcmb_h + nb; const u16* wl_ = Wcmb_l + nb;
      #pragma unroll 4
      for (int kss = 0; kss < 16; ++kss){
        int k = ((kss + sk1) & 15)*32;
        short8 a0h = *(const short8*)(hH + aoff0 + k);
        short8 a0l = *(const short8*)(hL + aoff0 + k);
        short8 a1h = *(const short8*)(hH + aoff1 + k);
        short8 a1l = *(const short8*)(hL + aoff1 + k);
        short8 bh = *(const short8*)(wh + k);
        short8 bl = *(const short8*)(wl_ + k);
        SMACC(A0, a0h, a0l, bh, bl);
        SMACC(A1, a1h, a1l, bh, bl);
      }
    }
    {                                            // Whh0 (LDS) over h0_{t-1}
      const u16* hH = H0h[p^1]; const u16* hL = H0l[p^1];
      #pragma unroll 4
      for (int ks = 0; ks < 16; ++ks){
        int k = ks*32;
        short8 a0h = *(const short8*)(hH + aoff0 + k);
        short8 a0l = *(const short8*)(hL + aoff0 + k);
        short8 a1h = *(const short8*)(hH + aoff1 + k);
        short8 a1l = *(const short8*)(hL + aoff1 + k);
        short8 bh = lds8(whh0_h, rl, kc + k, 1024);
        short8 bl = lds8(whh0_l, rl, kc + k, 1024);
        SMACC(A0, a0h, a0l, bh, bl);
        SMACC(A1, a1h, a1l, bh, bl);
      }
    }
    // decoder pred l=t-337 from h1_{t-1}: this WG owns batch b0+cg
    if (!enc && t > 336){
      const int d = tid & 63, kq = tid >> 6;
      const int b = b0 + cg;
      const u16* hH = H1h[p^1] + b*512 + kq*128;
      const u16* hL = H1l[p^1] + b*512 + kq*128;
      const float* wr = Wout + d*512 + kq*128;
      float part = 0.f;
      #pragma unroll 4
      for (int k = 0; k < 128; k += 8){
        short8 hv = *(const short8*)(hH + k);
        short8 lv = *(const short8*)(hL + k);
        #pragma unroll
        for (int j = 0; j < 8; ++j)
          part += (bf2f((u16)hv[j]) + bf2f((u16)lv[j])) * wr[k + j];
      }
      pr[d*4 + kq] = part;
      __syncthreads();
      if (tid < 64){
        float v = pr[tid*4] + pr[tid*4+1] + pr[tid*4+2] + pr[tid*4+3] + bout[tid];
        out[131072 + (b*64 + tid)*96 + (t - 337)] = v;
      }
    }
    // cell update layer 0 (c in registers)
    {
      const float* bias = (enc || t == 336) ? bs0 : bsd;
      __syncthreads();
      const int rb_ = (lane >> 4) << 2;
      #pragma unroll
      for (int r = 0; r < 4; ++r){
        gl[(rb_ + r)*68 + rl]      = A0[r] + bias[rl];
        gl[(16 + rb_ + r)*68 + rl] = A1[r] + bias[rl];
      }
      __syncthreads();
      u16* Hh = H0h[p]; u16* Hl = H0l[p];
      #pragma unroll
      for (int q = 0; q < 2; ++q){
        int e = tid + q*256;
        int m = e >> 4, col = e & 15;
        float iv = gl[m*68 + col];
        float fv = gl[m*68 + 16 + col];
        float gv = gl[m*68 + 32 + col];
        float ov = gl[m*68 + 48 + col];
        float si = 1.f/(1.f + expf(-iv));
        float sf = 1.f/(1.f + expf(-fv));
        float so = 1.f/(1.f + expf(-ov));
        float cn = sf*c0r[q] + si*tanhf(gv);
        c0r[q] = cn;
        float h = so*tanhf(cn);
        int gi = (b0 + m)*512 + cg*16 + col;
        u16 hh = f2bf(h);
        Hh[gi] = hh;
        Hl[gi] = f2bf(h - bf2f(hh));
      }
    }
    ++ep;
    if (allco) pbar(cnt, g, ep); else xbar(cnt, ep, xcd, pop, nx);

    // =============== phase B: layer 1 (skewed, order-alternated) ===========
    A0 = (f32x4){0,0,0,0}; A1 = (f32x4){0,0,0,0};
    auto segIH = [&](){                          // W1ih over h0_t
      const u16* hH = H0h[p]; const u16* hL = H0l[p];
      const u16* wh = W1ih_h + nb; const u16* wl_ = W1ih_l + nb;
      #pragma unroll 4
      for (int kss = 0; kss < 16; ++kss){
        int k = ((kss + sk2) & 15)*32;
        short8 a0h = *(const short8*)(hH + aoff0 + k);
        short8 a0l = *(const short8*)(hL + aoff0 + k);
        short8 a1h = *(const short8*)(hH + aoff1 + k);
        short8 a1l = *(const short8*)(hL + aoff1 + k);
        short8 bh = *(const short8*)(wh + k);
        short8 bl = *(const short8*)(wl_ + k);
        SMACC(A0, a0h, a0l, bh, bl);
        SMACC(A1, a1h, a1l, bh, bl);
      }
    };
    auto segHH = [&](){                          // W1hh over h1_{t-1}
      const u16* hH = H1h[p^1]; const u16* hL = H1l[p^1];
      const u16* wh = W1hh_h + nb; const u16* wl_ = W1hh_l + nb;
      #pragma unroll 4
      for (int kss = 0; kss < 16; ++kss){
        int k = ((kss + sk2) & 15)*32;
        short8 a0h = *(const short8*)(hH + aoff0 + k);
        short8 a0l = *(const short8*)(hL + aoff0 + k);
        short8 a1h = *(const short8*)(hH + aoff1 + k);
        short8 a1l = *(const short8*)(hL + aoff1 + k);
        short8 bh = *(const short8*)(wh + k);
        short8 bl = *(const short8*)(wl_ + k);
        SMACC(A0, a0h, a0l, bh, bl);
        SMACC(A1, a1h, a1l, bh, bl);
      }
    };
    if (g & 1){ segHH(); segIH(); } else { segIH(); segHH(); }
    // cell update layer 1
    {
      float* gf = (t == 335) ? out : (float*)nullptr;
      __syncthreads();
      const int rb_ = (lane >> 4) << 2;
      #pragma unroll
      for (int r = 0; r < 4; ++r){
        gl[(rb_ + r)*68 + rl]      = A0[r] + bs1[rl];
        gl[(16 + rb_ + r)*68 + rl] = A1[r] + bs1[rl];
      }
      __syncthreads();
      u16* Hh = H1h[p]; u16* Hl = H1l[p];
      #pragma unroll
      for (int q = 0; q < 2; ++q){
        int e = tid + q*256;
        int m = e >> 4, col = e & 15;
        float iv = gl[m*68 + col];
        float fv = gl[m*68 + 16 + col];
        float gv = gl[m*68 + 32 + col];
        float ov = gl[m*68 + 48 + col];
        float si = 1.f/(1.f + expf(-iv));
        float sf = 1.f/(1.f + expf(-fv));
        float so = 1.f/(1.f + expf(-ov));
        float cn = sf*c1r[q] + si*tanhf(gv);
        c1r[q] = cn;
        float h = so*tanhf(cn);
        int gi = (b0 + m)*512 + cg*16 + col;
        u16 hh = f2bf(h);
        Hh[gi] = hh;
        Hl[gi] = f2bf(h - bf2f(hh));
        if (gf) gf[gi] = h;
      }
    }
    ++ep;
    if (allco) pbar(cnt, g, ep); else xbar(cnt, ep, xcd, pop, nx);
  }
}

// ---- tail: pred for l=95 from h1_431 (parity 1) ----------------------------
__global__ void __launch_bounds__(256) pred_last(
    const u16* __restrict__ h1hi, const u16* __restrict__ h1lo,
    const float* __restrict__ Wout, const float* __restrict__ bout,
    float* __restrict__ out)
{
  const int wg = blockIdx.x, tid = threadIdx.x;
  const int bsub = tid >> 6, d = tid & 63;
  const int b = wg*4 + bsub;
  float acc = bout[d];
  const u16* hH = h1hi + b*512;
  const u16* hL = h1lo + b*512;
  const float* wr = Wout + d*512;
  #pragma unroll 8
  for (int k = 0; k < 512; k += 8){
    short8 hv = *(const short8*)(hH + k);
    short8 lv = *(const short8*)(hL + k);
    #pragma unroll
    for (int j = 0; j < 8; ++j)
      acc += (bf2f((u16)hv[j]) + bf2f((u16)lv[j])) * wr[k + j];
  }
  out[131072 + (b*64 + d)*96 + 95] = acc;
}

// ======================= fallback (R9 proven path) ==========================
__device__ __forceinline__ void cell_epilogue_fb(
    float* gl, const float* bs, float* __restrict__ cbuf,
    u16* __restrict__ hhi, u16* __restrict__ hlo,
    float* __restrict__ gfout, int mrow, int jblk,
    const f32x4& a0, const f32x4& a1, int wv, int lane, int tid)
{
  __syncthreads();
  const int rbase = wv*16 + ((lane >> 4) << 2);
  const int cI = lane & 15;
  #pragma unroll
  for (int r = 0; r < 4; ++r){
    gl[(rbase+r)*33 + cI]      = a0[r] + bs[cI];
    gl[(rbase+r)*33 + 16 + cI] = a1[r] + bs[16 + cI];
  }
  __syncthreads();
  #pragma unroll
  for (int q = 0; q < 2; ++q){
    int e = tid + q*256;
    int m = e >> 3, jj = e & 7;
    float iv = gl[m*33 + jj];
    float fv = gl[m*33 + 8 + jj];
    float gv = gl[m*33 + 16 + jj];
    float ov = gl[m*33 + 24 + jj];
    float si = 1.f/(1.f + expf(-iv));
    float sf = 1.f/(1.f + expf(-fv));
    float so = 1.f/(1.f + expf(-ov));
    int gi = (mrow*64 + m)*512 + jblk*8 + jj;
    float cn = sf*cbuf[gi] + si*tanhf(gv);
    cbuf[gi] = cn;
    float h = so*tanhf(cn);
    u16 hh = f2bf(h);
    hhi[gi] = hh;
    hlo[gi] = f2bf(h - bf2f(hh));
    if (gfout) gfout[gi] = h;
  }
}

template<bool ENC>
__global__ void __launch_bounds__(256) l0_fb(
    const float* __restrict__ x,
    const u16* __restrict__ predhi, const u16* __restrict__ predlo,
    const float* __restrict__ Wihf, const float* __restrict__ Whhf,
    const float* __restrict__ bih, const float* __restrict__ bhh,
    const u16* __restrict__ hphi, const u16* __restrict__ hplo,
    u16* __restrict__ hnhi, u16* __restrict__ hnlo,
    float* __restrict__ c0, int t)
{
  __shared__ float gl[64*33];
  __shared__ float bs[32];
  const int wg = blockIdx.x, tid = threadIdx.x;
  const int mrow = wg & 3, jblk = wg >> 2;
  const int lane = tid & 63, wv = tid >> 6;
  if (tid < 32){
    int n = ((tid >> 3) << 9) + jblk*8 + (tid & 7);
    bs[tid] = bih[n] + bhh[n];
  }
  const int ar = mrow*64 + wv*16 + (lane & 15);
  const int kc = (lane >> 4) << 3;
  const int cI = lane & 15;
  const int n0 = ((cI >> 3) << 9) + jblk*8 + (cI & 7);
  const int n1 = n0 + 1024;

  f32x4 acc0 = {0,0,0,0}, acc1 = {0,0,0,0};
  #pragma unroll
  for (int ks = 0; ks < 2; ++ks){
    int k = ks*32 + kc;
    short8 ah, al;
    if (ENC){
      const float* xb = x + ar*21504 + t;
      #pragma unroll
      for (int j = 0; j < 8; ++j){ HiLo s = split1(xb[(k + j)*336]); ah[j] = s.hi; al[j] = s.lo; }
    } else {
      ah = *(const short8*)(predhi + ar*64 + k);
      al = *(const short8*)(predlo + ar*64 + k);
    }
    short8 bh0, bl0, bh1, bl1;
    ldw8s(Wihf + n0*64 + k, bh0, bl0);
    ldw8s(Wihf + n1*64 + k, bh1, bl1);
    SMACC(acc0, ah, al, bh0, bl0);
    SMACC(acc1, ah, al, bh1, bl1);
  }
  const u16* hH = hphi + ar*512 + kc;
  const u16* hL = hplo + ar*512 + kc;
  #pragma unroll 4
  for (int ks = 0; ks < 16; ++ks){
    int k = ks*32;
    short8 ah = *(const short8*)(hH + k);
    short8 al = *(const short8*)(hL + k);
    short8 bh0, bl0, bh1, bl1;
    ldw8s(Whhf + n0*512 + kc + k, bh0, bl0);
    ldw8s(Whhf + n1*512 + kc + k, bh1, bl1);
    SMACC(acc0, ah, al, bh0, bl0);
    SMACC(acc1, ah, al, bh1, bl1);
  }
  cell_epilogue_fb(gl, bs, c0, hnhi, hnlo, nullptr, mrow, jblk, acc0, acc1, wv, lane, tid);
}

__global__ void __launch_bounds__(256) l1_fb(
    const float* __restrict__ Wihf, const float* __restrict__ Whhf,
    const float* __restrict__ bih, const float* __restrict__ bhh,
    const u16* __restrict__ h0hi, const u16* __restrict__ h0lo,
    const u16* __restrict__ h1phi, const u16* __restrict__ h1plo,
    u16* __restrict__ h1nhi, u16* __restrict__ h1nlo,
    float* __restrict__ c1, float* __restrict__ gfout)
{
  __shared__ float gl[64*33];
  __shared__ float bs[32];
  const int wg = blockIdx.x, tid = threadIdx.x;
  const int mrow = wg & 3, jblk = wg >> 2;
  const int lane = tid & 63, wv = tid >> 6;
  if (tid < 32){
    int n = ((tid >> 3) << 9) + jblk*8 + (tid & 7);
    bs[tid] = bih[n] + bhh[n];
  }
  const int ar = mrow*64 + wv*16 + (lane & 15);
  const int kc = (lane >> 4) << 3;
  const int cI = lane & 15;
  const int n0 = ((cI >> 3) << 9) + jblk*8 + (cI & 7);
  const int n1 = n0 + 1024;

  f32x4 acc0 = {0,0,0,0}, acc1 = {0,0,0,0};
  {
    const u16* hH = h0hi + ar*512 + kc;
    const u16* hL = h0lo + ar*512 + kc;
    #pragma unroll 4
    for (int ks = 0; ks < 16; ++ks){
      int k = ks*32;
      short8 ah = *(const short8*)(hH + k);
      short8 al = *(const short8*)(hL + k);
      short8 bh0, bl0, bh1, bl1;
      ldw8s(Wihf + n0*512 + kc + k, bh0, bl0);
      ldw8s(Wihf + n1*512 + kc + k, bh1, bl1);
      SMACC(acc0, ah, al, bh0, bl0);
      SMACC(acc1, ah, al, bh1, bl1);
    }
  }
  {
    const u16* hH = h1phi + ar*512 + kc;
    const u16* hL = h1plo + ar*512 + kc;
    #pragma unroll 4
    for (int ks = 0; ks < 16; ++ks){
      int k = ks*32;
      short8 ah = *(const short8*)(hH + k);
      short8 al = *(const short8*)(hL + k);
      short8 bh0, bl0, bh1, bl1;
      ldw8s(Whhf + n0*512 + kc + k, bh0, bl0);
      ldw8s(Whhf + n1*512 + kc + k, bh1, bl1);
      SMACC(acc0, ah, al, bh0, bl0);
      SMACC(acc1, ah, al, bh1, bl1);
    }
  }
  cell_epilogue_fb(gl, bs, c1, h1nhi, h1nlo, gfout, mrow, jblk, acc0, acc1, wv, lane, tid);
}

__global__ void __launch_bounds__(256) pred_fb(
    const u16* __restrict__ h1hi, const u16* __restrict__ h1lo,
    const float* __restrict__ Wout, const float* __restrict__ bout,
    u16* __restrict__ predhi, u16* __restrict__ predlo,
    float* __restrict__ out, int l)
{
  const int wg = blockIdx.x, tid = threadIdx.x;
  const int bsub = tid >> 6, d = tid & 63;
  const int b = wg*4 + bsub;
  float acc = bout[d];
  const u16* hH = h1hi + b*512;
  const u16* hL = h1lo + b*512;
  const float* wr = Wout + d*512;
  #pragma unroll 8
  for (int k = 0; k < 512; k += 8){
    short8 hv = *(const short8*)(hH + k);
    short8 lv = *(const short8*)(hL + k);
    #pragma unroll
    for (int j = 0; j < 8; ++j)
      acc += (bf2f((u16)hv[j]) + bf2f((u16)lv[j])) * wr[k + j];
  }
  HiLo s = split1(acc);
  predhi[b*64 + d] = (u16)s.hi;
  predlo[b*64 + d] = (u16)s.lo;
  out[131072 + (b*64 + d)*96 + l] = acc;
}

extern "C" void kernel_launch(void* const* d_in, const int* in_sizes, int n_in,
                              void* d_out, int out_size, void* d_ws, size_t ws_size,
                              hipStream_t stream)
{
  const float* x    = (const float*)d_in[0];
  const float* Wih0 = (const float*)d_in[1];
  const float* Whh0 = (const float*)d_in[2];
  const float* bih0 = (const float*)d_in[3];
  const float* bhh0 = (const float*)d_in[4];
  const float* Wih1 = (const float*)d_in[5];
  const float* Whh1 = (const float*)d_in[6];
  const float* bih1 = (const float*)d_in[7];
  const float* bhh1 = (const float*)d_in[8];
  const float* Wout = (const float*)d_in[9];
  const float* bout = (const float*)d_in[10];
  float* out = (float*)d_out;

  // ---- ws layout (main): h 2MB | cnt 64KB | split weights 12MB | bb 8KB
  char* ws = (char*)d_ws;
  u16* h0h[2] = { (u16*)(ws + 0),       (u16*)(ws + 262144) };
  u16* h0l[2] = { (u16*)(ws + 524288),  (u16*)(ws + 786432) };
  u16* h1h[2] = { (u16*)(ws + 1048576), (u16*)(ws + 1310720) };
  u16* h1l[2] = { (u16*)(ws + 1572864), (u16*)(ws + 1835008) };
  unsigned* cnt = (unsigned*)(ws + 2097152);
  u16* Wcmb_h = (u16*)(ws + 2162688);
  u16* Wcmb_l = Wcmb_h + 1048576;
  u16* W1ih_h = Wcmb_l + 1048576;
  u16* W1ih_l = W1ih_h + 1048576;
  u16* W1hh_h = W1ih_l + 1048576;
  u16* W1hh_l = W1hh_h + 1048576;
  float* bb   = (float*)(W1hh_l + 1048576);
  const size_t NEED = 2162688u + 6u*2097152u + 8192u;   // ~14.8 MB
  // fallback layout (only used when ws too small)
  float* fb_c0 = (float*)(ws + 2162688);
  float* fb_c1 = (float*)(ws + 2686976);
  u16* predh   = (u16*)(ws + 3211264);
  u16* predl   = (u16*)(ws + 3244032);
  const bool ps = (ws_size >= NEED);

  (void)hipMemsetAsync(d_ws, 0, 3276800, stream);   // h + cnt (+ fb c/pred)

  if (ps){
    wcomb_k<<<dim3(256), dim3(256), 0, stream>>>(Wih0, Wout, bout, bih0, bhh0,
                                                 Wcmb_h, Wcmb_l, bb);
    wsplit<<<dim3(4096), dim3(256), 0, stream>>>(Wih1, W1ih_h, W1ih_l, 1048576);
    wsplit<<<dim3(4096), dim3(256), 0, stream>>>(Whh1, W1hh_h, W1hh_l, 1048576);
    lstm_persist<<<dim3(256), dim3(256), 0, stream>>>(
        x, Whh0, Wih0, W1ih_h, W1ih_l, W1hh_h, W1hh_l, Wcmb_h, Wcmb_l, bb,
        bih0, bhh0, bih1, bhh1, Wout, bout, out, cnt,
        h0h[0], h0h[1], h0l[0], h0l[1], h1h[0], h1h[1], h1l[0], h1l[1]);
    pred_last<<<dim3(64), dim3(256), 0, stream>>>(h1h[1], h1l[1], Wout, bout, out);
  } else {
    for (int t = 0; t < 432; ++t){
      const int p = t & 1;
      float* gf = (t == 335) ? out : (float*)nullptr;
      if (t < 336)
        l0_fb<true><<<dim3(256), dim3(256), 0, stream>>>(
            x, predh, predl, Wih0, Whh0, bih0, bhh0,
            h0h[p^1], h0l[p^1], h0h[p], h0l[p], fb_c0, t);
      else
        l0_fb<false><<<dim3(256), dim3(256), 0, stream>>>(
            x, predh, predl, Wih0, Whh0, bih0, bhh0,
            h0h[p^1], h0l[p^1], h0h[p], h0l[p], fb_c0, t);
      l1_fb<<<dim3(256), dim3(256), 0, stream>>>(
          Wih1, Whh1, bih1, bhh1, h0h[p], h0l[p],
          h1h[p^1], h1l[p^1], h1h[p], h1l[p], fb_c1, gf);
      if (t >= 336)
        pred_fb<<<dim3(64), dim3(256), 0, stream>>>(
            h1h[p], h1l[p], Wout, bout, predh, predl, out, t - 336);
    }
  }
}

// Round 18
// 17290.846 us; speedup vs baseline: 1.2505x; 1.1047x over previous
//
#include <hip/hip_runtime.h>

typedef unsigned short u16;
typedef __attribute__((ext_vector_type(8))) short short8;
typedef __attribute__((ext_vector_type(4))) float f32x4;

#define AXR __ATOMIC_RELAXED, __HIP_MEMORY_SCOPE_AGENT

__device__ __forceinline__ float bf2f(u16 v){
  union { unsigned u; float f; } t; t.u = ((unsigned)v) << 16; return t.f;
}
__device__ __forceinline__ u16 f2bf(float f){
  union { float f; unsigned u; } t; t.f = f;
  unsigned u = t.u;
  return (u16)((u + 0x7fffu + ((u >> 16) & 1u)) >> 16);
}
struct HiLo { short hi, lo; };
__device__ __forceinline__ HiLo split1(float v){
  HiLo r;
  u16 h = f2bf(v);
  r.hi = (short)h;
  r.lo = (short)f2bf(v - bf2f(h));
  return r;
}
__device__ __forceinline__ void ldw8s(const float* __restrict__ p, short8& hi, short8& lo){
  #pragma unroll
  for (int j = 0; j < 8; ++j){ HiLo s = split1(p[j]); hi[j] = s.hi; lo[j] = s.lo; }
}

#define MFMA(acc, a, b) acc = __builtin_amdgcn_mfma_f32_16x16x32_bf16(a, b, acc, 0,0,0)
// full split (A and B hi/lo): 3 MFMAs
#define SMACC(acc, ah, al, bh, bl) do{ MFMA(acc, ah, bh); MFMA(acc, ah, bl); MFMA(acc, al, bh); }while(0)
// split-A x plain-B: 2 MFMAs (streamed hi-only weights)
#define SMACC2(acc, ah, al, bh) do{ MFMA(acc, ah, bh); MFMA(acc, al, bh); }while(0)

// ---- prepass: f32 -> bf16 (hi only, RNE) -----------------------------------
__global__ void wcvt(const float* __restrict__ s, u16* __restrict__ hi, int n){
  int i = blockIdx.x * blockDim.x + threadIdx.x;
  if (i < n) hi[i] = f2bf(s[i]);
}

// ---- prepass: Wcomb = Wih0 @ Wout (2048x512 bf16 hi), bb = b0 + Wih0@bout --
__global__ void __launch_bounds__(256) wcomb_k(
    const float* __restrict__ Wih0, const float* __restrict__ Wout,
    const float* __restrict__ bout, const float* __restrict__ bih0,
    const float* __restrict__ bhh0,
    u16* __restrict__ Wch, float* __restrict__ bb)
{
  __shared__ float wl[8*64];
  __shared__ float bo[64];
  const int wg = blockIdx.x, tid = threadIdx.x;
  const int r0 = wg*8;
  for (int i = tid; i < 512; i += 256) wl[i] = Wih0[(r0 + (i >> 6))*64 + (i & 63)];
  if (tid < 64) bo[tid] = bout[tid];
  __syncthreads();
  if (tid < 8){
    int n = r0 + tid;
    float a = bih0[n] + bhh0[n];
    #pragma unroll 8
    for (int d = 0; d < 64; ++d) a += wl[tid*64 + d]*bo[d];
    bb[n] = a;
  }
  #pragma unroll
  for (int jj = 0; jj < 2; ++jj){
    int j = tid + jj*256;
    float acc[8] = {0,0,0,0,0,0,0,0};
    for (int d = 0; d < 64; ++d){
      float wv = Wout[d*512 + j];
      #pragma unroll
      for (int r = 0; r < 8; ++r) acc[r] += wl[r*64 + d]*wv;
    }
    #pragma unroll
    for (int r = 0; r < 8; ++r) Wch[(r0 + r)*512 + j] = f2bf(acc[r]);
  }
}

// ---- init-only tree barrier (threadfence-based, proven R13/R14) ------------
__device__ __forceinline__ void gbar(unsigned* bar, unsigned phase){
  __syncthreads();
  if (threadIdx.x == 0){
    __threadfence();
    const unsigned gg = (unsigned)blockIdx.x >> 4;
    unsigned old = __hip_atomic_fetch_add(bar + 64 + gg*32, 1u, AXR);
    if (old == phase*16u - 1u){
      unsigned r = __hip_atomic_fetch_add(bar, 1u, AXR);
      if (r == phase*16u - 1u)
        __hip_atomic_store(bar + 32, phase, AXR);
    }
    while (__hip_atomic_load(bar + 32, AXR) < phase)
      __builtin_amdgcn_s_sleep(2);
    __threadfence();
  }
  __syncthreads();
}

// ---- global fallback barrier (R14 xbar, any WG placement) ------------------
__device__ __forceinline__ void xbar(unsigned* bar, unsigned phase,
                                     unsigned xcd, unsigned pop, unsigned nx){
  __syncthreads();
  if (threadIdx.x == 0){
    unsigned old = __hip_atomic_fetch_add(bar + 832 + xcd*32, 1u, AXR);
    const bool leader = (old == phase*pop - 1u);
    if (leader){
      asm volatile("buffer_wbl2 sc1\n\ts_waitcnt vmcnt(0)" ::: "memory");
      unsigned r = __hip_atomic_fetch_add(bar + 1344, 1u, AXR);
      if (r == phase*nx - 1u)
        __hip_atomic_store(bar + 1376, phase, AXR);
    }
    while (__hip_atomic_load(bar + 1376, AXR) < phase)
      __builtin_amdgcn_s_sleep(2);
    if (leader){
      asm volatile("buffer_inv sc1\n\ts_waitcnt vmcnt(0)" ::: "memory");
      __hip_atomic_store(bar + 1088 + xcd*32, phase, AXR);
    } else {
      while (__hip_atomic_load(bar + 1088 + xcd*32, AXR) < phase)
        __builtin_amdgcn_s_sleep(1);
      asm volatile("buffer_inv\n\ts_waitcnt vmcnt(0)" ::: "memory");
    }
  }
  __syncthreads();
}

// ---- group-local barrier (requires group co-located on one XCD) ------------
__device__ __forceinline__ void pbar(unsigned* bar, unsigned g, unsigned phase){
  __syncthreads();
  if (threadIdx.x == 0){
    unsigned* ctr = bar + 2048 + g*32;
    __hip_atomic_fetch_add(ctr, 1u, AXR);
    while (__hip_atomic_load(ctr, AXR) < phase*32u)
      __builtin_amdgcn_s_sleep(1);
    asm volatile("buffer_inv\n\ts_waitcnt vmcnt(0)" ::: "memory");
  }
  __syncthreads();
}

// ---- LDS weight-slice helpers (XOR-swizzled, G4) ---------------------------
__device__ __forceinline__ short8 lds8(const u16* base, int r, int kelem, int rowbytes){
  int bo = r*rowbytes + ((kelem*2) ^ ((r & 7) << 4));
  return *(const short8*)((const char*)base + bo);
}
// 64 gate rows (4 gates x 16 cols of col-group cg) x ldw K
__device__ __forceinline__ void load_slice64(
    const float* __restrict__ W, int ldw, int rowshift, int nelem,
    u16* lh, u16* ll, int cg, int tid)
{
  const int rowbytes = ldw*2;
  for (int i = tid; i < nelem; i += 256){
    int r = i >> rowshift, k = i & ((1 << rowshift) - 1);
    int n = ((r >> 4) << 9) + cg*16 + (r & 15);
    HiLo s = split1(W[n*ldw + k]);
    int bo = r*rowbytes + ((k*2) ^ ((r & 7) << 4));
    *(u16*)((char*)lh + bo) = (u16)s.hi;
    *(u16*)((char*)ll + bo) = (u16)s.lo;
  }
}

// ---- persistent kernel: batch-parallel groups, XCD-local exchange ----------
// group g = wg&7 owns batches [g*32, +32); col-group cg = wg>>3 owns 16 cols.
// Streamed weights (W1ih/W1hh/Wcomb) are HI-ONLY bf16 (halved stream bytes).
__global__ void __launch_bounds__(256, 1) lstm_persist(
    const float* __restrict__ x,
    const float* __restrict__ Whh0, const float* __restrict__ Wih0,
    const u16* __restrict__ W1ih_h, const u16* __restrict__ W1hh_h,
    const u16* __restrict__ Wcmb_h, const float* __restrict__ bb,
    const float* __restrict__ bih0, const float* __restrict__ bhh0,
    const float* __restrict__ bih1, const float* __restrict__ bhh1,
    const float* __restrict__ Wout, const float* __restrict__ bout,
    float* __restrict__ out, unsigned* __restrict__ cnt,
    u16* __restrict__ h0h0, u16* __restrict__ h0h1,
    u16* __restrict__ h0l0, u16* __restrict__ h0l1,
    u16* __restrict__ h1h0, u16* __restrict__ h1h1,
    u16* __restrict__ h1l0, u16* __restrict__ h1l1)
{
  __shared__ u16 whh0_h[32768], whh0_l[32768];   // 64x512, swizzled
  __shared__ u16 w0ih_h[4096],  w0ih_l[4096];    // 64x64, swizzled
  __shared__ float gl[32*68];                    // gate exchange
  __shared__ float pr[256];                      // pred partials [d][kq]
  __shared__ float bs0[64], bs1[64], bsd[64];
  __shared__ unsigned s_pop, s_nx, s_all;

  const int wg = blockIdx.x, tid = threadIdx.x;
  const int g = wg & 7, cg = wg >> 3;
  const int b0 = g*32;
  const int lane = tid & 63, wv = tid >> 6;
  const int cI = lane & 15;
  const int kc = (lane >> 4) << 3;
  const int rl = wv*16 + cI;                     // local gate row

  // ---- one-time init: LDS weight slices + biases ----
  load_slice64(Whh0, 512, 9, 32768, whh0_h, whh0_l, cg, tid);
  load_slice64(Wih0,  64, 6,  4096, w0ih_h, w0ih_l, cg, tid);
  if (tid < 64){
    int n = ((tid >> 4) << 9) + cg*16 + (tid & 15);
    bs0[tid] = bih0[n] + bhh0[n];
    bs1[tid] = bih1[n] + bhh1[n];
    bsd[tid] = bb[n];
  }

  // ---- census: XCD id, per-XCD pop (fallback), group co-location ----
  unsigned xcd;
  asm volatile("s_getreg_b32 %0, hwreg(HW_REG_XCC_ID)" : "=s"(xcd));
  xcd &= 7u;
  if (tid == 0){
    __hip_atomic_fetch_add(cnt + 576 + xcd*32, 1u, AXR);
    __hip_atomic_store(cnt + 1536 + wg, xcd, AXR);
  }
  gbar(cnt, 1);
  if (tid == 0){
    unsigned nxl = 0;
    for (int i = 0; i < 8; ++i)
      nxl += (__hip_atomic_load(cnt + 576 + i*32, AXR) != 0u) ? 1u : 0u;
    s_pop = __hip_atomic_load(cnt + 576 + xcd*32, AXR);
    s_nx  = nxl;
    unsigned ok = 1;
    for (int i = 0; i < 32; ++i)
      ok &= (__hip_atomic_load(cnt + 1536 + (g + 8*i), AXR) == xcd) ? 1u : 0u;
    if (!ok) __hip_atomic_store(cnt + 1800 + g, 1u, AXR);
  }
  gbar(cnt, 2);
  if (tid == 0){
    unsigned bad = 0;
    for (int gg = 0; gg < 8; ++gg)
      bad |= __hip_atomic_load(cnt + 1800 + gg, AXR);
    s_all = (bad == 0u) ? 1u : 0u;
  }
  __syncthreads();
  const unsigned pop = s_pop, nx = s_nx;
  const bool allco = (s_all != 0u);

  const int ar0 = b0 + cI, ar1 = b0 + 16 + cI;   // A rows (batches)
  const int aoff0 = ar0*512 + kc, aoff1 = ar1*512 + kc;
  const int nb = (wv*512 + cg*16 + cI)*512 + kc; // streamed weight frag base

  u16* H0h[2] = { h0h0, h0h1 };  u16* H0l[2] = { h0l0, h0l1 };
  u16* H1h[2] = { h1h0, h1h1 };  u16* H1l[2] = { h1l0, h1l1 };

  const float* xb0 = x + ar0*21504;
  const float* xb1 = x + ar1*21504;

  float c0r[2] = {0.f, 0.f}, c1r[2] = {0.f, 0.f};   // cell state in registers
  unsigned ep = 0;

  const int sk1 = g*2;            // per-XCD K-chunk skew (kept from R17)
  const int sk2 = (g >> 1)*4;

  for (int t = 0; t < 432; ++t){
    const int p = t & 1;
    const bool enc = (t < 336);

    // =============== phase A: layer 0 ===============
    f32x4 A0 = {0,0,0,0}, A1 = {0,0,0,0};
    if (enc){
      #pragma unroll
      for (int ks = 0; ks < 2; ++ks){            // x segment (K=64)
        int k = ks*32 + kc;
        short8 a0h, a0l, a1h, a1l;
        #pragma unroll
        for (int j = 0; j < 8; ++j){
          HiLo s0 = split1(xb0[(k + j)*336 + t]); a0h[j] = s0.hi; a0l[j] = s0.lo;
          HiLo s1 = split1(xb1[(k + j)*336 + t]); a1h[j] = s1.hi; a1l[j] = s1.lo;
        }
        short8 bh = lds8(w0ih_h, rl, k, 128);
        short8 bl = lds8(w0ih_l, rl, k, 128);
        SMACC(A0, a0h, a0l, bh, bl);
        SMACC(A1, a1h, a1l, bh, bl);
      }
    } else if (t > 336){                         // Wcomb (hi-only) over h1_{t-1}
      const u16* hH = H1h[p^1]; const u16* hL = H1l[p^1];
      const u16* wh = Wcmb_h + nb;
      #pragma unroll 4
      for (int kss = 0; kss < 16; ++kss){
        int k = ((kss + sk1) & 15)*32;
        short8 a0h = *(const short8*)(hH + aoff0 + k);
        short8 a0l = *(const short8*)(hL + aoff0 + k);
        short8 a1h = *(const short8*)(hH + aoff1 + k);
        short8 a1l = *(const short8*)(hL + aoff1 + k);
        short8 bh = *(const short8*)(wh + k);
        SMACC2(A0, a0h, a0l, bh);
        SMACC2(A1, a1h, a1l, bh);
      }
    }
    {                                            // Whh0 (LDS, split) over h0_{t-1}
      const u16* hH = H0h[p^1]; const u16* hL = H0l[p^1];
      #pragma unroll 4
      for (int ks = 0; ks < 16; ++ks){
        int k = ks*32;
        short8 a0h = *(const short8*)(hH + aoff0 + k);
        short8 a0l = *(const short8*)(hL + aoff0 + k);
        short8 a1h = *(const short8*)(hH + aoff1 + k);
        short8 a1l = *(const short8*)(hL + aoff1 + k);
        short8 bh = lds8(whh0_h, rl, kc + k, 1024);
        short8 bl = lds8(whh0_l, rl, kc + k, 1024);
        SMACC(A0, a0h, a0l, bh, bl);
        SMACC(A1, a1h, a1l, bh, bl);
      }
    }
    // decoder pred l=t-337 from h1_{t-1}: this WG owns batch b0+cg
    if (!enc && t > 336){
      const int d = tid & 63, kq = tid >> 6;
      const int b = b0 + cg;
      const u16* hH = H1h[p^1] + b*512 + kq*128;
      const u16* hL = H1l[p^1] + b*512 + kq*128;
      const float* wr = Wout + d*512 + kq*128;
      float part = 0.f;
      #pragma unroll 4
      for (int k = 0; k < 128; k += 8){
        short8 hv = *(const short8*)(hH + k);
        short8 lv = *(const short8*)(hL + k);
        #pragma unroll
        for (int j = 0; j < 8; ++j)
          part += (bf2f((u16)hv[j]) + bf2f((u16)lv[j])) * wr[k + j];
      }
      pr[d*4 + kq] = part;
      __syncthreads();
      if (tid < 64){
        float v = pr[tid*4] + pr[tid*4+1] + pr[tid*4+2] + pr[tid*4+3] + bout[tid];
        out[131072 + (b*64 + tid)*96 + (t - 337)] = v;
      }
    }
    // cell update layer 0 (c in registers)
    {
      const float* bias = (enc || t == 336) ? bs0 : bsd;
      __syncthreads();
      const int rb_ = (lane >> 4) << 2;
      #pragma unroll
      for (int r = 0; r < 4; ++r){
        gl[(rb_ + r)*68 + rl]      = A0[r] + bias[rl];
        gl[(16 + rb_ + r)*68 + rl] = A1[r] + bias[rl];
      }
      __syncthreads();
      u16* Hh = H0h[p]; u16* Hl = H0l[p];
      #pragma unroll
      for (int q = 0; q < 2; ++q){
        int e = tid + q*256;
        int m = e >> 4, col = e & 15;
        float iv = gl[m*68 + col];
        float fv = gl[m*68 + 16 + col];
        float gv = gl[m*68 + 32 + col];
        float ov = gl[m*68 + 48 + col];
        float si = 1.f/(1.f + expf(-iv));
        float sf = 1.f/(1.f + expf(-fv));
        float so = 1.f/(1.f + expf(-ov));
        float cn = sf*c0r[q] + si*tanhf(gv);
        c0r[q] = cn;
        float h = so*tanhf(cn);
        int gi = (b0 + m)*512 + cg*16 + col;
        u16 hh = f2bf(h);
        Hh[gi] = hh;
        Hl[gi] = f2bf(h - bf2f(hh));
      }
    }
    ++ep;
    if (allco) pbar(cnt, g, ep); else xbar(cnt, ep, xcd, pop, nx);

    // =============== phase B: layer 1 (hi-only streamed weights) ===========
    A0 = (f32x4){0,0,0,0}; A1 = (f32x4){0,0,0,0};
    auto segIH = [&](){                          // W1ih (hi) over h0_t
      const u16* hH = H0h[p]; const u16* hL = H0l[p];
      const u16* wh = W1ih_h + nb;
      #pragma unroll 4
      for (int kss = 0; kss < 16; ++kss){
        int k = ((kss + sk2) & 15)*32;
        short8 a0h = *(const short8*)(hH + aoff0 + k);
        short8 a0l = *(const short8*)(hL + aoff0 + k);
        short8 a1h = *(const short8*)(hH + aoff1 + k);
        short8 a1l = *(const short8*)(hL + aoff1 + k);
        short8 bh = *(const short8*)(wh + k);
        SMACC2(A0, a0h, a0l, bh);
        SMACC2(A1, a1h, a1l, bh);
      }
    };
    auto segHH = [&](){                          // W1hh (hi) over h1_{t-1}
      const u16* hH = H1h[p^1]; const u16* hL = H1l[p^1];
      const u16* wh = W1hh_h + nb;
      #pragma unroll 4
      for (int kss = 0; kss < 16; ++kss){
        int k = ((kss + sk2) & 15)*32;
        short8 a0h = *(const short8*)(hH + aoff0 + k);
        short8 a0l = *(const short8*)(hL + aoff0 + k);
        short8 a1h = *(const short8*)(hH + aoff1 + k);
        short8 a1l = *(const short8*)(hL + aoff1 + k);
        short8 bh = *(const short8*)(wh + k);
        SMACC2(A0, a0h, a0l, bh);
        SMACC2(A1, a1h, a1l, bh);
      }
    };
    if (g & 1){ segHH(); segIH(); } else { segIH(); segHH(); }
    // cell update layer 1
    {
      float* gf = (t == 335) ? out : (float*)nullptr;
      __syncthreads();
      const int rb_ = (lane >> 4) << 2;
      #pragma unroll
      for (int r = 0; r < 4; ++r){
        gl[(rb_ + r)*68 + rl]      = A0[r] + bs1[rl];
        gl[(16 + rb_ + r)*68 + rl] = A1[r] + bs1[rl];
      }
      __syncthreads();
      u16* Hh = H1h[p]; u16* Hl = H1l[p];
      #pragma unroll
      for (int q = 0; q < 2; ++q){
        int e = tid + q*256;
        int m = e >> 4, col = e & 15;
        float iv = gl[m*68 + col];
        float fv = gl[m*68 + 16 + col];
        float gv = gl[m*68 + 32 + col];
        float ov = gl[m*68 + 48 + col];
        float si = 1.f/(1.f + expf(-iv));
        float sf = 1.f/(1.f + expf(-fv));
        float so = 1.f/(1.f + expf(-ov));
        float cn = sf*c1r[q] + si*tanhf(gv);
        c1r[q] = cn;
        float h = so*tanhf(cn);
        int gi = (b0 + m)*512 + cg*16 + col;
        u16 hh = f2bf(h);
        Hh[gi] = hh;
        Hl[gi] = f2bf(h - bf2f(hh));
        if (gf) gf[gi] = h;
      }
    }
    ++ep;
    if (allco) pbar(cnt, g, ep); else xbar(cnt, ep, xcd, pop, nx);
  }
}

// ---- tail: pred for l=95 from h1_431 (parity 1) ----------------------------
__global__ void __launch_bounds__(256) pred_last(
    const u16* __restrict__ h1hi, const u16* __restrict__ h1lo,
    const float* __restrict__ Wout, const float* __restrict__ bout,
    float* __restrict__ out)
{
  const int wg = blockIdx.x, tid = threadIdx.x;
  const int bsub = tid >> 6, d = tid & 63;
  const int b = wg*4 + bsub;
  float acc = bout[d];
  const u16* hH = h1hi + b*512;
  const u16* hL = h1lo + b*512;
  const float* wr = Wout + d*512;
  #pragma unroll 8
  for (int k = 0; k < 512; k += 8){
    short8 hv = *(const short8*)(hH + k);
    short8 lv = *(const short8*)(hL + k);
    #pragma unroll
    for (int j = 0; j < 8; ++j)
      acc += (bf2f((u16)hv[j]) + bf2f((u16)lv[j])) * wr[k + j];
  }
  out[131072 + (b*64 + d)*96 + 95] = acc;
}

// ======================= fallback (R9 proven path) ==========================
__device__ __forceinline__ void cell_epilogue_fb(
    float* gl, const float* bs, float* __restrict__ cbuf,
    u16* __restrict__ hhi, u16* __restrict__ hlo,
    float* __restrict__ gfout, int mrow, int jblk,
    const f32x4& a0, const f32x4& a1, int wv, int lane, int tid)
{
  __syncthreads();
  const int rbase = wv*16 + ((lane >> 4) << 2);
  const int cI = lane & 15;
  #pragma unroll
  for (int r = 0; r < 4; ++r){
    gl[(rbase+r)*33 + cI]      = a0[r] + bs[cI];
    gl[(rbase+r)*33 + 16 + cI] = a1[r] + bs[16 + cI];
  }
  __syncthreads();
  #pragma unroll
  for (int q = 0; q < 2; ++q){
    int e = tid + q*256;
    int m = e >> 3, jj = e & 7;
    float iv = gl[m*33 + jj];
    float fv = gl[m*33 + 8 + jj];
    float gv = gl[m*33 + 16 + jj];
    float ov = gl[m*33 + 24 + jj];
    float si = 1.f/(1.f + expf(-iv));
    float sf = 1.f/(1.f + expf(-fv));
    float so = 1.f/(1.f + expf(-ov));
    int gi = (mrow*64 + m)*512 + jblk*8 + jj;
    float cn = sf*cbuf[gi] + si*tanhf(gv);
    cbuf[gi] = cn;
    float h = so*tanhf(cn);
    u16 hh = f2bf(h);
    hhi[gi] = hh;
    hlo[gi] = f2bf(h - bf2f(hh));
    if (gfout) gfout[gi] = h;
  }
}

template<bool ENC>
__global__ void __launch_bounds__(256) l0_fb(
    const float* __restrict__ x,
    const u16* __restrict__ predhi, const u16* __restrict__ predlo,
    const float* __restrict__ Wihf, const float* __restrict__ Whhf,
    const float* __restrict__ bih, const float* __restrict__ bhh,
    const u16* __restrict__ hphi, const u16* __restrict__ hplo,
    u16* __restrict__ hnhi, u16* __restrict__ hnlo,
    float* __restrict__ c0, int t)
{
  __shared__ float gl[64*33];
  __shared__ float bs[32];
  const int wg = blockIdx.x, tid = threadIdx.x;
  const int mrow = wg & 3, jblk = wg >> 2;
  const int lane = tid & 63, wv = tid >> 6;
  if (tid < 32){
    int n = ((tid >> 3) << 9) + jblk*8 + (tid & 7);
    bs[tid] = bih[n] + bhh[n];
  }
  const int ar = mrow*64 + wv*16 + (lane & 15);
  const int kc = (lane >> 4) << 3;
  const int cI = lane & 15;
  const int n0 = ((cI >> 3) << 9) + jblk*8 + (cI & 7);
  const int n1 = n0 + 1024;

  f32x4 acc0 = {0,0,0,0}, acc1 = {0,0,0,0};
  #pragma unroll
  for (int ks = 0; ks < 2; ++ks){
    int k = ks*32 + kc;
    short8 ah, al;
    if (ENC){
      const float* xb = x + ar*21504 + t;
      #pragma unroll
      for (int j = 0; j < 8; ++j){ HiLo s = split1(xb[(k + j)*336]); ah[j] = s.hi; al[j] = s.lo; }
    } else {
      ah = *(const short8*)(predhi + ar*64 + k);
      al = *(const short8*)(predlo + ar*64 + k);
    }
    short8 bh0, bl0, bh1, bl1;
    ldw8s(Wihf + n0*64 + k, bh0, bl0);
    ldw8s(Wihf + n1*64 + k, bh1, bl1);
    SMACC(acc0, ah, al, bh0, bl0);
    SMACC(acc1, ah, al, bh1, bl1);
  }
  const u16* hH = hphi + ar*512 + kc;
  const u16* hL = hplo + ar*512 + kc;
  #pragma unroll 4
  for (int ks = 0; ks < 16; ++ks){
    int k = ks*32;
    short8 ah = *(const short8*)(hH + k);
    short8 al = *(const short8*)(hL + k);
    short8 bh0, bl0, bh1, bl1;
    ldw8s(Whhf + n0*512 + kc + k, bh0, bl0);
    ldw8s(Whhf + n1*512 + kc + k, bh1, bl1);
    SMACC(acc0, ah, al, bh0, bl0);
    SMACC(acc1, ah, al, bh1, bl1);
  }
  cell_epilogue_fb(gl, bs, c0, hnhi, hnlo, nullptr, mrow, jblk, acc0, acc1, wv, lane, tid);
}

__global__ void __launch_bounds__(256) l1_fb(
    const float* __restrict__ Wihf, const float* __restrict__ Whhf,
    const float* __restrict__ bih, const float* __restrict__ bhh,
    const u16* __restrict__ h0hi, const u16* __restrict__ h0lo,
    const u16* __restrict__ h1phi, const u16* __restrict__ h1plo,
    u16* __restrict__ h1nhi, u16* __restrict__ h1nlo,
    float* __restrict__ c1, float* __restrict__ gfout)
{
  __shared__ float gl[64*33];
  __shared__ float bs[32];
  const int wg = blockIdx.x, tid = threadIdx.x;
  const int mrow = wg & 3, jblk = wg >> 2;
  const int lane = tid & 63, wv = tid >> 6;
  if (tid < 32){
    int n = ((tid >> 3) << 9) + jblk*8 + (tid & 7);
    bs[tid] = bih[n] + bhh[n];
  }
  const int ar = mrow*64 + wv*16 + (lane & 15);
  const int kc = (lane >> 4) << 3;
  const int cI = lane & 15;
  const int n0 = ((cI >> 3) << 9) + jblk*8 + (cI & 7);
  const int n1 = n0 + 1024;

  f32x4 acc0 = {0,0,0,0}, acc1 = {0,0,0,0};
  {
    const u16* hH = h0hi + ar*512 + kc;
    const u16* hL = h0lo + ar*512 + kc;
    #pragma unroll 4
    for (int ks = 0; ks < 16; ++ks){
      int k = ks*32;
      short8 ah = *(const short8*)(hH + k);
      short8 al = *(const short8*)(hL + k);
      short8 bh0, bl0, bh1, bl1;
      ldw8s(Wihf + n0*512 + kc + k, bh0, bl0);
      ldw8s(Wihf + n1*512 + kc + k, bh1, bl1);
      SMACC(acc0, ah, al, bh0, bl0);
      SMACC(acc1, ah, al, bh1, bl1);
    }
  }
  {
    const u16* hH = h1phi + ar*512 + kc;
    const u16* hL = h1plo + ar*512 + kc;
    #pragma unroll 4
    for (int ks = 0; ks < 16; ++ks){
      int k = ks*32;
      short8 ah = *(const short8*)(hH + k);
      short8 al = *(const short8*)(hL + k);
      short8 bh0, bl0, bh1, bl1;
      ldw8s(Whhf + n0*512 + kc + k, bh0, bl0);
      ldw8s(Whhf + n1*512 + kc + k, bh1, bl1);
      SMACC(acc0, ah, al, bh0, bl0);
      SMACC(acc1, ah, al, bh1, bl1);
    }
  }
  cell_epilogue_fb(gl, bs, c1, h1nhi, h1nlo, gfout, mrow, jblk, acc0, acc1, wv, lane, tid);
}

__global__ void __launch_bounds__(256) pred_fb(
    const u16* __restrict__ h1hi, const u16* __restrict__ h1lo,
    const float* __restrict__ Wout, const float* __restrict__ bout,
    u16* __restrict__ predhi, u16* __restrict__ predlo,
    float* __restrict__ out, int l)
{
  const int wg = blockIdx.x, tid = threadIdx.x;
  const int bsub = tid >> 6, d = tid & 63;
  const int b = wg*4 + bsub;
  float acc = bout[d];
  const u16* hH = h1hi + b*512;
  const u16* hL = h1lo + b*512;
  const float* wr = Wout + d*512;
  #pragma unroll 8
  for (int k = 0; k < 512; k += 8){
    short8 hv = *(const short8*)(hH + k);
    short8 lv = *(const short8*)(hL + k);
    #pragma unroll
    for (int j = 0; j < 8; ++j)
      acc += (bf2f((u16)hv[j]) + bf2f((u16)lv[j])) * wr[k + j];
  }
  HiLo s = split1(acc);
  predhi[b*64 + d] = (u16)s.hi;
  predlo[b*64 + d] = (u16)s.lo;
  out[131072 + (b*64 + d)*96 + l] = acc;
}

extern "C" void kernel_launch(void* const* d_in, const int* in_sizes, int n_in,
                              void* d_out, int out_size, void* d_ws, size_t ws_size,
                              hipStream_t stream)
{
  const float* x    = (const float*)d_in[0];
  const float* Wih0 = (const float*)d_in[1];
  const float* Whh0 = (const float*)d_in[2];
  const float* bih0 = (const float*)d_in[3];
  const float* bhh0 = (const float*)d_in[4];
  const float* Wih1 = (const float*)d_in[5];
  const float* Whh1 = (const float*)d_in[6];
  const float* bih1 = (const float*)d_in[7];
  const float* bhh1 = (const float*)d_in[8];
  const float* Wout = (const float*)d_in[9];
  const float* bout = (const float*)d_in[10];
  float* out = (float*)d_out;

  // ---- ws layout (main): h 2MB | cnt 64KB | hi-only weights 6MB | bb 8KB
  char* ws = (char*)d_ws;
  u16* h0h[2] = { (u16*)(ws + 0),       (u16*)(ws + 262144) };
  u16* h0l[2] = { (u16*)(ws + 524288),  (u16*)(ws + 786432) };
  u16* h1h[2] = { (u16*)(ws + 1048576), (u16*)(ws + 1310720) };
  u16* h1l[2] = { (u16*)(ws + 1572864), (u16*)(ws + 1835008) };
  unsigned* cnt = (unsigned*)(ws + 2097152);
  u16* Wcmb_h = (u16*)(ws + 2162688);
  u16* W1ih_h = Wcmb_h + 1048576;
  u16* W1hh_h = W1ih_h + 1048576;
  float* bb   = (float*)(W1hh_h + 1048576);
  const size_t NEED = 2162688u + 3u*2097152u + 8192u;   // ~8.5 MB
  // fallback layout (only used when ws too small)
  float* fb_c0 = (float*)(ws + 2162688);
  float* fb_c1 = (float*)(ws + 2686976);
  u16* predh   = (u16*)(ws + 3211264);
  u16* predl   = (u16*)(ws + 3244032);
  const bool ps = (ws_size >= NEED);

  (void)hipMemsetAsync(d_ws, 0, 3276800, stream);   // h + cnt (+ fb c/pred)

  if (ps){
    wcomb_k<<<dim3(256), dim3(256), 0, stream>>>(Wih0, Wout, bout, bih0, bhh0,
                                                 Wcmb_h, bb);
    wcvt<<<dim3(4096), dim3(256), 0, stream>>>(Wih1, W1ih_h, 1048576);
    wcvt<<<dim3(4096), dim3(256), 0, stream>>>(Whh1, W1hh_h, 1048576);
    lstm_persist<<<dim3(256), dim3(256), 0, stream>>>(
        x, Whh0, Wih0, W1ih_h, W1hh_h, Wcmb_h, bb,
        bih0, bhh0, bih1, bhh1, Wout, bout, out, cnt,
        h0h[0], h0h[1], h0l[0], h0l[1], h1h[0], h1h[1], h1l[0], h1l[1]);
    pred_last<<<dim3(64), dim3(256), 0, stream>>>(h1h[1], h1l[1], Wout, bout, out);
  } else {
    for (int t = 0; t < 432; ++t){
      const int p = t & 1;
      float* gf = (t == 335) ? out : (float*)nullptr;
      if (t < 336)
        l0_fb<true><<<dim3(256), dim3(256), 0, stream>>>(
            x, predh, predl, Wih0, Whh0, bih0, bhh0,
            h0h[p^1], h0l[p^1], h0h[p], h0l[p], fb_c0, t);
      else
        l0_fb<false><<<dim3(256), dim3(256), 0, stream>>>(
            x, predh, predl, Wih0, Whh0, bih0, bhh0,
            h0h[p^1], h0l[p^1], h0h[p], h0l[p], fb_c0, t);
      l1_fb<<<dim3(256), dim3(256), 0, stream>>>(
          Wih1, Whh1, bih1, bhh1, h0h[p], h0l[p],
          h1h[p^1], h1l[p^1], h1h[p], h1l[p], fb_c1, gf);
      if (t >= 336)
        pred_fb<<<dim3(64), dim3(256), 0, stream>>>(
            h1h[p], h1l[p], Wout, bout, predh, predl, out, t - 336);
    }
  }
}

// Round 19
// 15626.637 us; speedup vs baseline: 1.3837x; 1.1065x over previous
//
#include <hip/hip_runtime.h>

typedef unsigned short u16;
typedef __attribute__((ext_vector_type(8))) short short8;
typedef __attribute__((ext_vector_type(4))) float f32x4;

#define AXR __ATOMIC_RELAXED, __HIP_MEMORY_SCOPE_AGENT

__device__ __forceinline__ float bf2f(u16 v){
  union { unsigned u; float f; } t; t.u = ((unsigned)v) << 16; return t.f;
}
__device__ __forceinline__ u16 f2bf(float f){
  union { float f; unsigned u; } t; t.f = f;
  unsigned u = t.u;
  return (u16)((u + 0x7fffu + ((u >> 16) & 1u)) >> 16);
}
struct HiLo { short hi, lo; };
__device__ __forceinline__ HiLo split1(float v){
  HiLo r;
  u16 h = f2bf(v);
  r.hi = (short)h;
  r.lo = (short)f2bf(v - bf2f(h));
  return r;
}
__device__ __forceinline__ void ldw8s(const float* __restrict__ p, short8& hi, short8& lo){
  #pragma unroll
  for (int j = 0; j < 8; ++j){ HiLo s = split1(p[j]); hi[j] = s.hi; lo[j] = s.lo; }
}

#define MFMA(acc, a, b) acc = __builtin_amdgcn_mfma_f32_16x16x32_bf16(a, b, acc, 0,0,0)
// full split (A and B hi/lo): 3 MFMAs
#define SMACC(acc, ah, al, bh, bl) do{ MFMA(acc, ah, bh); MFMA(acc, ah, bl); MFMA(acc, al, bh); }while(0)
// split-A x plain-B: 2 MFMAs (hi-only weights)
#define SMACC2(acc, ah, al, bh) do{ MFMA(acc, ah, bh); MFMA(acc, al, bh); }while(0)

// ---- prepass: f32 -> bf16 (hi only, RNE) -----------------------------------
__global__ void wcvt(const float* __restrict__ s, u16* __restrict__ hi, int n){
  int i = blockIdx.x * blockDim.x + threadIdx.x;
  if (i < n) hi[i] = f2bf(s[i]);
}

// ---- prepass: Wcomb = Wih0 @ Wout (2048x512 bf16 hi), bb = b0 + Wih0@bout --
__global__ void __launch_bounds__(256) wcomb_k(
    const float* __restrict__ Wih0, const float* __restrict__ Wout,
    const float* __restrict__ bout, const float* __restrict__ bih0,
    const float* __restrict__ bhh0,
    u16* __restrict__ Wch, float* __restrict__ bb)
{
  __shared__ float wl[8*64];
  __shared__ float bo[64];
  const int wg = blockIdx.x, tid = threadIdx.x;
  const int r0 = wg*8;
  for (int i = tid; i < 512; i += 256) wl[i] = Wih0[(r0 + (i >> 6))*64 + (i & 63)];
  if (tid < 64) bo[tid] = bout[tid];
  __syncthreads();
  if (tid < 8){
    int n = r0 + tid;
    float a = bih0[n] + bhh0[n];
    #pragma unroll 8
    for (int d = 0; d < 64; ++d) a += wl[tid*64 + d]*bo[d];
    bb[n] = a;
  }
  #pragma unroll
  for (int jj = 0; jj < 2; ++jj){
    int j = tid + jj*256;
    float acc[8] = {0,0,0,0,0,0,0,0};
    for (int d = 0; d < 64; ++d){
      float wv = Wout[d*512 + j];
      #pragma unroll
      for (int r = 0; r < 8; ++r) acc[r] += wl[r*64 + d]*wv;
    }
    #pragma unroll
    for (int r = 0; r < 8; ++r) Wch[(r0 + r)*512 + j] = f2bf(acc[r]);
  }
}

// ---- init-only tree barrier (threadfence-based, proven R13/R14) ------------
__device__ __forceinline__ void gbar(unsigned* bar, unsigned phase){
  __syncthreads();
  if (threadIdx.x == 0){
    __threadfence();
    const unsigned gg = (unsigned)blockIdx.x >> 4;
    unsigned old = __hip_atomic_fetch_add(bar + 64 + gg*32, 1u, AXR);
    if (old == phase*16u - 1u){
      unsigned r = __hip_atomic_fetch_add(bar, 1u, AXR);
      if (r == phase*16u - 1u)
        __hip_atomic_store(bar + 32, phase, AXR);
    }
    while (__hip_atomic_load(bar + 32, AXR) < phase)
      __builtin_amdgcn_s_sleep(2);
    __threadfence();
  }
  __syncthreads();
}

// ---- global fallback barrier (R14 xbar, any WG placement) ------------------
__device__ __forceinline__ void xbar(unsigned* bar, unsigned phase,
                                     unsigned xcd, unsigned pop, unsigned nx){
  __syncthreads();
  if (threadIdx.x == 0){
    unsigned old = __hip_atomic_fetch_add(bar + 832 + xcd*32, 1u, AXR);
    const bool leader = (old == phase*pop - 1u);
    if (leader){
      asm volatile("buffer_wbl2 sc1\n\ts_waitcnt vmcnt(0)" ::: "memory");
      unsigned r = __hip_atomic_fetch_add(bar + 1344, 1u, AXR);
      if (r == phase*nx - 1u)
        __hip_atomic_store(bar + 1376, phase, AXR);
    }
    while (__hip_atomic_load(bar + 1376, AXR) < phase)
      __builtin_amdgcn_s_sleep(2);
    if (leader){
      asm volatile("buffer_inv sc1\n\ts_waitcnt vmcnt(0)" ::: "memory");
      __hip_atomic_store(bar + 1088 + xcd*32, phase, AXR);
    } else {
      while (__hip_atomic_load(bar + 1088 + xcd*32, AXR) < phase)
        __builtin_amdgcn_s_sleep(1);
      asm volatile("buffer_inv\n\ts_waitcnt vmcnt(0)" ::: "memory");
    }
  }
  __syncthreads();
}

// ---- group-local barrier (requires group co-located on one XCD) ------------
__device__ __forceinline__ void pbar(unsigned* bar, unsigned g, unsigned phase){
  __syncthreads();
  if (threadIdx.x == 0){
    unsigned* ctr = bar + 2048 + g*32;
    __hip_atomic_fetch_add(ctr, 1u, AXR);
    while (__hip_atomic_load(ctr, AXR) < phase*32u)
      __builtin_amdgcn_s_sleep(1);
    asm volatile("buffer_inv\n\ts_waitcnt vmcnt(0)" ::: "memory");
  }
  __syncthreads();
}

// ---- LDS weight-slice helpers (XOR-swizzled, G4) ---------------------------
__device__ __forceinline__ short8 lds8(const u16* base, int r, int kelem, int rowbytes){
  int bo = r*rowbytes + ((kelem*2) ^ ((r & 7) << 4));
  return *(const short8*)((const char*)base + bo);
}
// split (hi+lo) slice: 64 gate rows x ldw K
__device__ __forceinline__ void load_slice64(
    const float* __restrict__ W, int ldw, int rowshift, int nelem,
    u16* lh, u16* ll, int cg, int tid)
{
  const int rowbytes = ldw*2;
  for (int i = tid; i < nelem; i += 256){
    int r = i >> rowshift, k = i & ((1 << rowshift) - 1);
    int n = ((r >> 4) << 9) + cg*16 + (r & 15);
    HiLo s = split1(W[n*ldw + k]);
    int bo = r*rowbytes + ((k*2) ^ ((r & 7) << 4));
    *(u16*)((char*)lh + bo) = (u16)s.hi;
    *(u16*)((char*)ll + bo) = (u16)s.lo;
  }
}
// hi-only slice
__device__ __forceinline__ void load_slice64h(
    const float* __restrict__ W, int ldw, int rowshift, int nelem,
    u16* lh, int cg, int tid)
{
  const int rowbytes = ldw*2;
  for (int i = tid; i < nelem; i += 256){
    int r = i >> rowshift, k = i & ((1 << rowshift) - 1);
    int n = ((r >> 4) << 9) + cg*16 + (r & 15);
    int bo = r*rowbytes + ((k*2) ^ ((r & 7) << 4));
    *(u16*)((char*)lh + bo) = f2bf(W[n*ldw + k]);
  }
}

// ---- persistent kernel: batch-parallel groups, XCD-local exchange ----------
// group g = wg&7 owns batches [g*32, +32); col-group cg = wg>>3 owns 16 cols.
// LDS-resident: Whh0(hi), W1hh(hi), Wih0(hi+lo). Streamed: W1ih(hi), Wcomb(hi).
// Encoder streamed set = 2MB/XCD -> stays L2-resident.
__global__ void __launch_bounds__(256, 1) lstm_persist(
    const float* __restrict__ x,
    const float* __restrict__ Whh0, const float* __restrict__ Wih0,
    const float* __restrict__ Whh1,
    const u16* __restrict__ W1ih_h, const u16* __restrict__ Wcmb_h,
    const float* __restrict__ bb,
    const float* __restrict__ bih0, const float* __restrict__ bhh0,
    const float* __restrict__ bih1, const float* __restrict__ bhh1,
    const float* __restrict__ Wout, const float* __restrict__ bout,
    float* __restrict__ out, unsigned* __restrict__ cnt,
    u16* __restrict__ h0h0, u16* __restrict__ h0h1,
    u16* __restrict__ h0l0, u16* __restrict__ h0l1,
    u16* __restrict__ h1h0, u16* __restrict__ h1h1,
    u16* __restrict__ h1l0, u16* __restrict__ h1l1)
{
  __shared__ u16 whh0_h[32768];                  // 64x512 hi, swizzled
  __shared__ u16 w1hh_h[32768];                  // 64x512 hi, swizzled
  __shared__ u16 w0ih_h[4096],  w0ih_l[4096];    // 64x64 hi+lo, swizzled
  __shared__ float gl[32*68];                    // gate exchange
  __shared__ float pr[256];                      // pred partials [d][kq]
  __shared__ float bs0[64], bs1[64], bsd[64];
  __shared__ unsigned s_pop, s_nx, s_all;

  const int wg = blockIdx.x, tid = threadIdx.x;
  const int g = wg & 7, cg = wg >> 3;
  const int b0 = g*32;
  const int lane = tid & 63, wv = tid >> 6;
  const int cI = lane & 15;
  const int kc = (lane >> 4) << 3;
  const int rl = wv*16 + cI;                     // local gate row

  // ---- one-time init: LDS weight slices + biases ----
  load_slice64h(Whh0, 512, 9, 32768, whh0_h, cg, tid);
  load_slice64h(Whh1, 512, 9, 32768, w1hh_h, cg, tid);
  load_slice64(Wih0,  64, 6,  4096, w0ih_h, w0ih_l, cg, tid);
  if (tid < 64){
    int n = ((tid >> 4) << 9) + cg*16 + (tid & 15);
    bs0[tid] = bih0[n] + bhh0[n];
    bs1[tid] = bih1[n] + bhh1[n];
    bsd[tid] = bb[n];
  }

  // ---- census: XCD id, per-XCD pop (fallback), group co-location ----
  unsigned xcd;
  asm volatile("s_getreg_b32 %0, hwreg(HW_REG_XCC_ID)" : "=s"(xcd));
  xcd &= 7u;
  if (tid == 0){
    __hip_atomic_fetch_add(cnt + 576 + xcd*32, 1u, AXR);
    __hip_atomic_store(cnt + 1536 + wg, xcd, AXR);
  }
  gbar(cnt, 1);
  if (tid == 0){
    unsigned nxl = 0;
    for (int i = 0; i < 8; ++i)
      nxl += (__hip_atomic_load(cnt + 576 + i*32, AXR) != 0u) ? 1u : 0u;
    s_pop = __hip_atomic_load(cnt + 576 + xcd*32, AXR);
    s_nx  = nxl;
    unsigned ok = 1;
    for (int i = 0; i < 32; ++i)
      ok &= (__hip_atomic_load(cnt + 1536 + (g + 8*i), AXR) == xcd) ? 1u : 0u;
    if (!ok) __hip_atomic_store(cnt + 1800 + g, 1u, AXR);
  }
  gbar(cnt, 2);
  if (tid == 0){
    unsigned bad = 0;
    for (int gg = 0; gg < 8; ++gg)
      bad |= __hip_atomic_load(cnt + 1800 + gg, AXR);
    s_all = (bad == 0u) ? 1u : 0u;
  }
  __syncthreads();
  const unsigned pop = s_pop, nx = s_nx;
  const bool allco = (s_all != 0u);

  const int ar0 = b0 + cI, ar1 = b0 + 16 + cI;   // A rows (batches)
  const int aoff0 = ar0*512 + kc, aoff1 = ar1*512 + kc;
  const int nb = (wv*512 + cg*16 + cI)*512 + kc; // streamed weight frag base

  u16* H0h[2] = { h0h0, h0h1 };  u16* H0l[2] = { h0l0, h0l1 };
  u16* H1h[2] = { h1h0, h1h1 };  u16* H1l[2] = { h1l0, h1l1 };

  const float* xb0 = x + ar0*21504;
  const float* xb1 = x + ar1*21504;

  float c0r[2] = {0.f, 0.f}, c1r[2] = {0.f, 0.f};   // cell state in registers
  unsigned ep = 0;

  const int sk1 = g*2;            // per-XCD K-chunk skew (kept from R17)
  const int sk2 = (g >> 1)*4;

  for (int t = 0; t < 432; ++t){
    const int p = t & 1;
    const bool enc = (t < 336);

    // =============== phase A: layer 0 ===============
    f32x4 A0 = {0,0,0,0}, A1 = {0,0,0,0};
    if (enc){
      #pragma unroll
      for (int ks = 0; ks < 2; ++ks){            // x segment (K=64), split
        int k = ks*32 + kc;
        short8 a0h, a0l, a1h, a1l;
        #pragma unroll
        for (int j = 0; j < 8; ++j){
          HiLo s0 = split1(xb0[(k + j)*336 + t]); a0h[j] = s0.hi; a0l[j] = s0.lo;
          HiLo s1 = split1(xb1[(k + j)*336 + t]); a1h[j] = s1.hi; a1l[j] = s1.lo;
        }
        short8 bh = lds8(w0ih_h, rl, k, 128);
        short8 bl = lds8(w0ih_l, rl, k, 128);
        SMACC(A0, a0h, a0l, bh, bl);
        SMACC(A1, a1h, a1l, bh, bl);
      }
    } else if (t > 336){                         // Wcomb (hi, streamed) over h1_{t-1}
      const u16* hH = H1h[p^1]; const u16* hL = H1l[p^1];
      const u16* wh = Wcmb_h + nb;
      #pragma unroll 4
      for (int kss = 0; kss < 16; ++kss){
        int k = ((kss + sk1) & 15)*32;
        short8 a0h = *(const short8*)(hH + aoff0 + k);
        short8 a0l = *(const short8*)(hL + aoff0 + k);
        short8 a1h = *(const short8*)(hH + aoff1 + k);
        short8 a1l = *(const short8*)(hL + aoff1 + k);
        short8 bh = *(const short8*)(wh + k);
        SMACC2(A0, a0h, a0l, bh);
        SMACC2(A1, a1h, a1l, bh);
      }
    }
    {                                            // Whh0 (LDS hi) over h0_{t-1}
      const u16* hH = H0h[p^1]; const u16* hL = H0l[p^1];
      #pragma unroll 4
      for (int ks = 0; ks < 16; ++ks){
        int k = ks*32;
        short8 a0h = *(const short8*)(hH + aoff0 + k);
        short8 a0l = *(const short8*)(hL + aoff0 + k);
        short8 a1h = *(const short8*)(hH + aoff1 + k);
        short8 a1l = *(const short8*)(hL + aoff1 + k);
        short8 bh = lds8(whh0_h, rl, kc + k, 1024);
        SMACC2(A0, a0h, a0l, bh);
        SMACC2(A1, a1h, a1l, bh);
      }
    }
    // decoder pred l=t-337 from h1_{t-1}: this WG owns batch b0+cg
    if (!enc && t > 336){
      const int d = tid & 63, kq = tid >> 6;
      const int b = b0 + cg;
      const u16* hH = H1h[p^1] + b*512 + kq*128;
      const u16* hL = H1l[p^1] + b*512 + kq*128;
      const float* wr = Wout + d*512 + kq*128;
      float part = 0.f;
      #pragma unroll 4
      for (int k = 0; k < 128; k += 8){
        short8 hv = *(const short8*)(hH + k);
        short8 lv = *(const short8*)(hL + k);
        #pragma unroll
        for (int j = 0; j < 8; ++j)
          part += (bf2f((u16)hv[j]) + bf2f((u16)lv[j])) * wr[k + j];
      }
      pr[d*4 + kq] = part;
      __syncthreads();
      if (tid < 64){
        float v = pr[tid*4] + pr[tid*4+1] + pr[tid*4+2] + pr[tid*4+3] + bout[tid];
        out[131072 + (b*64 + tid)*96 + (t - 337)] = v;
      }
    }
    // cell update layer 0 (c in registers)
    {
      const float* bias = (enc || t == 336) ? bs0 : bsd;
      __syncthreads();
      const int rb_ = (lane >> 4) << 2;
      #pragma unroll
      for (int r = 0; r < 4; ++r){
        gl[(rb_ + r)*68 + rl]      = A0[r] + bias[rl];
        gl[(16 + rb_ + r)*68 + rl] = A1[r] + bias[rl];
      }
      __syncthreads();
      u16* Hh = H0h[p]; u16* Hl = H0l[p];
      #pragma unroll
      for (int q = 0; q < 2; ++q){
        int e = tid + q*256;
        int m = e >> 4, col = e & 15;
        float iv = gl[m*68 + col];
        float fv = gl[m*68 + 16 + col];
        float gv = gl[m*68 + 32 + col];
        float ov = gl[m*68 + 48 + col];
        float si = 1.f/(1.f + expf(-iv));
        float sf = 1.f/(1.f + expf(-fv));
        float so = 1.f/(1.f + expf(-ov));
        float cn = sf*c0r[q] + si*tanhf(gv);
        c0r[q] = cn;
        float h = so*tanhf(cn);
        int gi = (b0 + m)*512 + cg*16 + col;
        u16 hh = f2bf(h);
        Hh[gi] = hh;
        Hl[gi] = f2bf(h - bf2f(hh));
      }
    }
    ++ep;
    if (allco) pbar(cnt, g, ep); else xbar(cnt, ep, xcd, pop, nx);

    // =============== phase B: layer 1 ===============
    A0 = (f32x4){0,0,0,0}; A1 = (f32x4){0,0,0,0};
    {                                            // W1ih (hi, streamed) over h0_t
      const u16* hH = H0h[p]; const u16* hL = H0l[p];
      const u16* wh = W1ih_h + nb;
      #pragma unroll 4
      for (int kss = 0; kss < 16; ++kss){
        int k = ((kss + sk2) & 15)*32;
        short8 a0h = *(const short8*)(hH + aoff0 + k);
        short8 a0l = *(const short8*)(hL + aoff0 + k);
        short8 a1h = *(const short8*)(hH + aoff1 + k);
        short8 a1l = *(const short8*)(hL + aoff1 + k);
        short8 bh = *(const short8*)(wh + k);
        SMACC2(A0, a0h, a0l, bh);
        SMACC2(A1, a1h, a1l, bh);
      }
    }
    {                                            // W1hh (LDS hi) over h1_{t-1}
      const u16* hH = H1h[p^1]; const u16* hL = H1l[p^1];
      #pragma unroll 4
      for (int ks = 0; ks < 16; ++ks){
        int k = ks*32;
        short8 a0h = *(const short8*)(hH + aoff0 + k);
        short8 a0l = *(const short8*)(hL + aoff0 + k);
        short8 a1h = *(const short8*)(hH + aoff1 + k);
        short8 a1l = *(const short8*)(hL + aoff1 + k);
        short8 bh = lds8(w1hh_h, rl, kc + k, 1024);
        SMACC2(A0, a0h, a0l, bh);
        SMACC2(A1, a1h, a1l, bh);
      }
    }
    // cell update layer 1
    {
      float* gf = (t == 335) ? out : (float*)nullptr;
      __syncthreads();
      const int rb_ = (lane >> 4) << 2;
      #pragma unroll
      for (int r = 0; r < 4; ++r){
        gl[(rb_ + r)*68 + rl]      = A0[r] + bs1[rl];
        gl[(16 + rb_ + r)*68 + rl] = A1[r] + bs1[rl];
      }
      __syncthreads();
      u16* Hh = H1h[p]; u16* Hl = H1l[p];
      #pragma unroll
      for (int q = 0; q < 2; ++q){
        int e = tid + q*256;
        int m = e >> 4, col = e & 15;
        float iv = gl[m*68 + col];
        float fv = gl[m*68 + 16 + col];
        float gv = gl[m*68 + 32 + col];
        float ov = gl[m*68 + 48 + col];
        float si = 1.f/(1.f + expf(-iv));
        float sf = 1.f/(1.f + expf(-fv));
        float so = 1.f/(1.f + expf(-ov));
        float cn = sf*c1r[q] + si*tanhf(gv);
        c1r[q] = cn;
        float h = so*tanhf(cn);
        int gi = (b0 + m)*512 + cg*16 + col;
        u16 hh = f2bf(h);
        Hh[gi] = hh;
        Hl[gi] = f2bf(h - bf2f(hh));
        if (gf) gf[gi] = h;
      }
    }
    ++ep;
    if (allco) pbar(cnt, g, ep); else xbar(cnt, ep, xcd, pop, nx);
  }
}

// ---- tail: pred for l=95 from h1_431 (parity 1) ----------------------------
__global__ void __launch_bounds__(256) pred_last(
    const u16* __restrict__ h1hi, const u16* __restrict__ h1lo,
    const float* __restrict__ Wout, const float* __restrict__ bout,
    float* __restrict__ out)
{
  const int wg = blockIdx.x, tid = threadIdx.x;
  const int bsub = tid >> 6, d = tid & 63;
  const int b = wg*4 + bsub;
  float acc = bout[d];
  const u16* hH = h1hi + b*512;
  const u16* hL = h1lo + b*512;
  const float* wr = Wout + d*512;
  #pragma unroll 8
  for (int k = 0; k < 512; k += 8){
    short8 hv = *(const short8*)(hH + k);
    short8 lv = *(const short8*)(hL + k);
    #pragma unroll
    for (int j = 0; j < 8; ++j)
      acc += (bf2f((u16)hv[j]) + bf2f((u16)lv[j])) * wr[k + j];
  }
  out[131072 + (b*64 + d)*96 + 95] = acc;
}

// ======================= fallback (R9 proven path) ==========================
__device__ __forceinline__ void cell_epilogue_fb(
    float* gl, const float* bs, float* __restrict__ cbuf,
    u16* __restrict__ hhi, u16* __restrict__ hlo,
    float* __restrict__ gfout, int mrow, int jblk,
    const f32x4& a0, const f32x4& a1, int wv, int lane, int tid)
{
  __syncthreads();
  const int rbase = wv*16 + ((lane >> 4) << 2);
  const int cI = lane & 15;
  #pragma unroll
  for (int r = 0; r < 4; ++r){
    gl[(rbase+r)*33 + cI]      = a0[r] + bs[cI];
    gl[(rbase+r)*33 + 16 + cI] = a1[r] + bs[16 + cI];
  }
  __syncthreads();
  #pragma unroll
  for (int q = 0; q < 2; ++q){
    int e = tid + q*256;
    int m = e >> 3, jj = e & 7;
    float iv = gl[m*33 + jj];
    float fv = gl[m*33 + 8 + jj];
    float gv = gl[m*33 + 16 + jj];
    float ov = gl[m*33 + 24 + jj];
    float si = 1.f/(1.f + expf(-iv));
    float sf = 1.f/(1.f + expf(-fv));
    float so = 1.f/(1.f + expf(-ov));
    int gi = (mrow*64 + m)*512 + jblk*8 + jj;
    float cn = sf*cbuf[gi] + si*tanhf(gv);
    cbuf[gi] = cn;
    float h = so*tanhf(cn);
    u16 hh = f2bf(h);
    hhi[gi] = hh;
    hlo[gi] = f2bf(h - bf2f(hh));
    if (gfout) gfout[gi] = h;
  }
}

template<bool ENC>
__global__ void __launch_bounds__(256) l0_fb(
    const float* __restrict__ x,
    const u16* __restrict__ predhi, const u16* __restrict__ predlo,
    const float* __restrict__ Wihf, const float* __restrict__ Whhf,
    const float* __restrict__ bih, const float* __restrict__ bhh,
    const u16* __restrict__ hphi, const u16* __restrict__ hplo,
    u16* __restrict__ hnhi, u16* __restrict__ hnlo,
    float* __restrict__ c0, int t)
{
  __shared__ float gl[64*33];
  __shared__ float bs[32];
  const int wg = blockIdx.x, tid = threadIdx.x;
  const int mrow = wg & 3, jblk = wg >> 2;
  const int lane = tid & 63, wv = tid >> 6;
  if (tid < 32){
    int n = ((tid >> 3) << 9) + jblk*8 + (tid & 7);
    bs[tid] = bih[n] + bhh[n];
  }
  const int ar = mrow*64 + wv*16 + (lane & 15);
  const int kc = (lane >> 4) << 3;
  const int cI = lane & 15;
  const int n0 = ((cI >> 3) << 9) + jblk*8 + (cI & 7);
  const int n1 = n0 + 1024;

  f32x4 acc0 = {0,0,0,0}, acc1 = {0,0,0,0};
  #pragma unroll
  for (int ks = 0; ks < 2; ++ks){
    int k = ks*32 + kc;
    short8 ah, al;
    if (ENC){
      const float* xb = x + ar*21504 + t;
      #pragma unroll
      for (int j = 0; j < 8; ++j){ HiLo s = split1(xb[(k + j)*336]); ah[j] = s.hi; al[j] = s.lo; }
    } else {
      ah = *(const short8*)(predhi + ar*64 + k);
      al = *(const short8*)(predlo + ar*64 + k);
    }
    short8 bh0, bl0, bh1, bl1;
    ldw8s(Wihf + n0*64 + k, bh0, bl0);
    ldw8s(Wihf + n1*64 + k, bh1, bl1);
    SMACC(acc0, ah, al, bh0, bl0);
    SMACC(acc1, ah, al, bh1, bl1);
  }
  const u16* hH = hphi + ar*512 + kc;
  const u16* hL = hplo + ar*512 + kc;
  #pragma unroll 4
  for (int ks = 0; ks < 16; ++ks){
    int k = ks*32;
    short8 ah = *(const short8*)(hH + k);
    short8 al = *(const short8*)(hL + k);
    short8 bh0, bl0, bh1, bl1;
    ldw8s(Whhf + n0*512 + kc + k, bh0, bl0);
    ldw8s(Whhf + n1*512 + kc + k, bh1, bl1);
    SMACC(acc0, ah, al, bh0, bl0);
    SMACC(acc1, ah, al, bh1, bl1);
  }
  cell_epilogue_fb(gl, bs, c0, hnhi, hnlo, nullptr, mrow, jblk, acc0, acc1, wv, lane, tid);
}

__global__ void __launch_bounds__(256) l1_fb(
    const float* __restrict__ Wihf, const float* __restrict__ Whhf,
    const float* __restrict__ bih, const float* __restrict__ bhh,
    const u16* __restrict__ h0hi, const u16* __restrict__ h0lo,
    const u16* __restrict__ h1phi, const u16* __restrict__ h1plo,
    u16* __restrict__ h1nhi, u16* __restrict__ h1nlo,
    float* __restrict__ c1, float* __restrict__ gfout)
{
  __shared__ float gl[64*33];
  __shared__ float bs[32];
  const int wg = blockIdx.x, tid = threadIdx.x;
  const int mrow = wg & 3, jblk = wg >> 2;
  const int lane = tid & 63, wv = tid >> 6;
  if (tid < 32){
    int n = ((tid >> 3) << 9) + jblk*8 + (tid & 7);
    bs[tid] = bih[n] + bhh[n];
  }
  const int ar = mrow*64 + wv*16 + (lane & 15);
  const int kc = (lane >> 4) << 3;
  const int cI = lane & 15;
  const int n0 = ((cI >> 3) << 9) + jblk*8 + (cI & 7);
  const int n1 = n0 + 1024;

  f32x4 acc0 = {0,0,0,0}, acc1 = {0,0,0,0};
  {
    const u16* hH = h0hi + ar*512 + kc;
    const u16* hL = h0lo + ar*512 + kc;
    #pragma unroll 4
    for (int ks = 0; ks < 16; ++ks){
      int k = ks*32;
      short8 ah = *(const short8*)(hH + k);
      short8 al = *(const short8*)(hL + k);
      short8 bh0, bl0, bh1, bl1;
      ldw8s(Wihf + n0*512 + kc + k, bh0, bl0);
      ldw8s(Wihf + n1*512 + kc + k, bh1, bl1);
      SMACC(acc0, ah, al, bh0, bl0);
      SMACC(acc1, ah, al, bh1, bl1);
    }
  }
  {
    const u16* hH = h1phi + ar*512 + kc;
    const u16* hL = h1plo + ar*512 + kc;
    #pragma unroll 4
    for (int ks = 0; ks < 16; ++ks){
      int k = ks*32;
      short8 ah = *(const short8*)(hH + k);
      short8 al = *(const short8*)(hL + k);
      short8 bh0, bl0, bh1, bl1;
      ldw8s(Whhf + n0*512 + kc + k, bh0, bl0);
      ldw8s(Whhf + n1*512 + kc + k, bh1, bl1);
      SMACC(acc0, ah, al, bh0, bl0);
      SMACC(acc1, ah, al, bh1, bl1);
    }
  }
  cell_epilogue_fb(gl, bs, c1, h1nhi, h1nlo, gfout, mrow, jblk, acc0, acc1, wv, lane, tid);
}

__global__ void __launch_bounds__(256) pred_fb(
    const u16* __restrict__ h1hi, const u16* __restrict__ h1lo,
    const float* __restrict__ Wout, const float* __restrict__ bout,
    u16* __restrict__ predhi, u16* __restrict__ predlo,
    float* __restrict__ out, int l)
{
  const int wg = blockIdx.x, tid = threadIdx.x;
  const int bsub = tid >> 6, d = tid & 63;
  const int b = wg*4 + bsub;
  float acc = bout[d];
  const u16* hH = h1hi + b*512;
  const u16* hL = h1lo + b*512;
  const float* wr = Wout + d*512;
  #pragma unroll 8
  for (int k = 0; k < 512; k += 8){
    short8 hv = *(const short8*)(hH + k);
    short8 lv = *(const short8*)(hL + k);
    #pragma unroll
    for (int j = 0; j < 8; ++j)
      acc += (bf2f((u16)hv[j]) + bf2f((u16)lv[j])) * wr[k + j];
  }
  HiLo s = split1(acc);
  predhi[b*64 + d] = (u16)s.hi;
  predlo[b*64 + d] = (u16)s.lo;
  out[131072 + (b*64 + d)*96 + l] = acc;
}

extern "C" void kernel_launch(void* const* d_in, const int* in_sizes, int n_in,
                              void* d_out, int out_size, void* d_ws, size_t ws_size,
                              hipStream_t stream)
{
  const float* x    = (const float*)d_in[0];
  const float* Wih0 = (const float*)d_in[1];
  const float* Whh0 = (const float*)d_in[2];
  const float* bih0 = (const float*)d_in[3];
  const float* bhh0 = (const float*)d_in[4];
  const float* Wih1 = (const float*)d_in[5];
  const float* Whh1 = (const float*)d_in[6];
  const float* bih1 = (const float*)d_in[7];
  const float* bhh1 = (const float*)d_in[8];
  const float* Wout = (const float*)d_in[9];
  const float* bout = (const float*)d_in[10];
  float* out = (float*)d_out;

  // ---- ws layout (main): h 2MB | cnt 64KB | hi weights 4MB | bb 8KB
  char* ws = (char*)d_ws;
  u16* h0h[2] = { (u16*)(ws + 0),       (u16*)(ws + 262144) };
  u16* h0l[2] = { (u16*)(ws + 524288),  (u16*)(ws + 786432) };
  u16* h1h[2] = { (u16*)(ws + 1048576), (u16*)(ws + 1310720) };
  u16* h1l[2] = { (u16*)(ws + 1572864), (u16*)(ws + 1835008) };
  unsigned* cnt = (unsigned*)(ws + 2097152);
  u16* Wcmb_h = (u16*)(ws + 2162688);
  u16* W1ih_h = Wcmb_h + 1048576;
  float* bb   = (float*)(W1ih_h + 1048576);
  const size_t NEED = 2162688u + 2u*2097152u + 8192u;   // ~6.4 MB
  // fallback layout (only used when ws too small)
  float* fb_c0 = (float*)(ws + 2162688);
  float* fb_c1 = (float*)(ws + 2686976);
  u16* predh   = (u16*)(ws + 3211264);
  u16* predl   = (u16*)(ws + 3244032);
  const bool ps = (ws_size >= NEED);

  (void)hipMemsetAsync(d_ws, 0, 3276800, stream);   // h + cnt (+ fb c/pred)

  if (ps){
    wcomb_k<<<dim3(256), dim3(256), 0, stream>>>(Wih0, Wout, bout, bih0, bhh0,
                                                 Wcmb_h, bb);
    wcvt<<<dim3(4096), dim3(256), 0, stream>>>(Wih1, W1ih_h, 1048576);
    lstm_persist<<<dim3(256), dim3(256), 0, stream>>>(
        x, Whh0, Wih0, Whh1, W1ih_h, Wcmb_h, bb,
        bih0, bhh0, bih1, bhh1, Wout, bout, out, cnt,
        h0h[0], h0h[1], h0l[0], h0l[1], h1h[0], h1h[1], h1l[0], h1l[1]);
    pred_last<<<dim3(64), dim3(256), 0, stream>>>(h1h[1], h1l[1], Wout, bout, out);
  } else {
    for (int t = 0; t < 432; ++t){
      const int p = t & 1;
      float* gf = (t == 335) ? out : (float*)nullptr;
      if (t < 336)
        l0_fb<true><<<dim3(256), dim3(256), 0, stream>>>(
            x, predh, predl, Wih0, Whh0, bih0, bhh0,
            h0h[p^1], h0l[p^1], h0h[p], h0l[p], fb_c0, t);
      else
        l0_fb<false><<<dim3(256), dim3(256), 0, stream>>>(
            x, predh, predl, Wih0, Whh0, bih0, bhh0,
            h0h[p^1], h0l[p^1], h0h[p], h0l[p], fb_c0, t);
      l1_fb<<<dim3(256), dim3(256), 0, stream>>>(
          Wih1, Whh1, bih1, bhh1, h0h[p], h0l[p],
          h1h[p^1], h1l[p^1], h1h[p], h1l[p], fb_c1, gf);
      if (t >= 336)
        pred_fb<<<dim3(64), dim3(256), 0, stream>>>(
            h1h[p], h1l[p], Wout, bout, predh, predl, out, t - 336);
    }
  }
}

// Round 20
// 15616.158 us; speedup vs baseline: 1.3846x; 1.0007x over previous
//
#include <hip/hip_runtime.h>

typedef unsigned short u16;
typedef __attribute__((ext_vector_type(8))) short short8;
typedef __attribute__((ext_vector_type(4))) float f32x4;

#define AXR __ATOMIC_RELAXED, __HIP_MEMORY_SCOPE_AGENT

__device__ __forceinline__ float bf2f(u16 v){
  union { unsigned u; float f; } t; t.u = ((unsigned)v) << 16; return t.f;
}
__device__ __forceinline__ u16 f2bf(float f){
  union { float f; unsigned u; } t; t.f = f;
  unsigned u = t.u;
  return (u16)((u + 0x7fffu + ((u >> 16) & 1u)) >> 16);
}
struct HiLo { short hi, lo; };
__device__ __forceinline__ HiLo split1(float v){
  HiLo r;
  u16 h = f2bf(v);
  r.hi = (short)h;
  r.lo = (short)f2bf(v - bf2f(h));
  return r;
}
__device__ __forceinline__ void ldw8s(const float* __restrict__ p, short8& hi, short8& lo){
  #pragma unroll
  for (int j = 0; j < 8; ++j){ HiLo s = split1(p[j]); hi[j] = s.hi; lo[j] = s.lo; }
}

#define MFMA(acc, a, b) acc = __builtin_amdgcn_mfma_f32_16x16x32_bf16(a, b, acc, 0,0,0)
// full split (A and B hi/lo): 3 MFMAs
#define SMACC(acc, ah, al, bh, bl) do{ MFMA(acc, ah, bh); MFMA(acc, ah, bl); MFMA(acc, al, bh); }while(0)
// split-A x plain-B: 2 MFMAs (hi-only weights)
#define SMACC2(acc, ah, al, bh) do{ MFMA(acc, ah, bh); MFMA(acc, al, bh); }while(0)

// ---- prepass: f32 -> bf16 (hi only, RNE) -----------------------------------
__global__ void wcvt(const float* __restrict__ s, u16* __restrict__ hi, int n){
  int i = blockIdx.x * blockDim.x + threadIdx.x;
  if (i < n) hi[i] = f2bf(s[i]);
}

// ---- prepass: Wcomb = Wih0 @ Wout (2048x512 bf16 hi), bb = b0 + Wih0@bout --
__global__ void __launch_bounds__(256) wcomb_k(
    const float* __restrict__ Wih0, const float* __restrict__ Wout,
    const float* __restrict__ bout, const float* __restrict__ bih0,
    const float* __restrict__ bhh0,
    u16* __restrict__ Wch, float* __restrict__ bb)
{
  __shared__ float wl[8*64];
  __shared__ float bo[64];
  const int wg = blockIdx.x, tid = threadIdx.x;
  const int r0 = wg*8;
  for (int i = tid; i < 512; i += 256) wl[i] = Wih0[(r0 + (i >> 6))*64 + (i & 63)];
  if (tid < 64) bo[tid] = bout[tid];
  __syncthreads();
  if (tid < 8){
    int n = r0 + tid;
    float a = bih0[n] + bhh0[n];
    #pragma unroll 8
    for (int d = 0; d < 64; ++d) a += wl[tid*64 + d]*bo[d];
    bb[n] = a;
  }
  #pragma unroll
  for (int jj = 0; jj < 2; ++jj){
    int j = tid + jj*256;
    float acc[8] = {0,0,0,0,0,0,0,0};
    for (int d = 0; d < 64; ++d){
      float wv = Wout[d*512 + j];
      #pragma unroll
      for (int r = 0; r < 8; ++r) acc[r] += wl[r*64 + d]*wv;
    }
    #pragma unroll
    for (int r = 0; r < 8; ++r) Wch[(r0 + r)*512 + j] = f2bf(acc[r]);
  }
}

// ---- init-only tree barrier (threadfence-based, proven R13/R14) ------------
__device__ __forceinline__ void gbar(unsigned* bar, unsigned phase){
  __syncthreads();
  if (threadIdx.x == 0){
    __threadfence();
    const unsigned gg = (unsigned)blockIdx.x >> 4;
    unsigned old = __hip_atomic_fetch_add(bar + 64 + gg*32, 1u, AXR);
    if (old == phase*16u - 1u){
      unsigned r = __hip_atomic_fetch_add(bar, 1u, AXR);
      if (r == phase*16u - 1u)
        __hip_atomic_store(bar + 32, phase, AXR);
    }
    while (__hip_atomic_load(bar + 32, AXR) < phase)
      __builtin_amdgcn_s_sleep(2);
    __threadfence();
  }
  __syncthreads();
}

// ---- global fallback barrier (R14 xbar, any WG placement) ------------------
__device__ __forceinline__ void xbar(unsigned* bar, unsigned phase,
                                     unsigned xcd, unsigned pop, unsigned nx){
  __syncthreads();
  if (threadIdx.x == 0){
    unsigned old = __hip_atomic_fetch_add(bar + 832 + xcd*32, 1u, AXR);
    const bool leader = (old == phase*pop - 1u);
    if (leader){
      asm volatile("buffer_wbl2 sc1\n\ts_waitcnt vmcnt(0)" ::: "memory");
      unsigned r = __hip_atomic_fetch_add(bar + 1344, 1u, AXR);
      if (r == phase*nx - 1u)
        __hip_atomic_store(bar + 1376, phase, AXR);
    }
    while (__hip_atomic_load(bar + 1376, AXR) < phase)
      __builtin_amdgcn_s_sleep(2);
    if (leader){
      asm volatile("buffer_inv sc1\n\ts_waitcnt vmcnt(0)" ::: "memory");
      __hip_atomic_store(bar + 1088 + xcd*32, phase, AXR);
    } else {
      while (__hip_atomic_load(bar + 1088 + xcd*32, AXR) < phase)
        __builtin_amdgcn_s_sleep(1);
      asm volatile("buffer_inv\n\ts_waitcnt vmcnt(0)" ::: "memory");
    }
  }
  __syncthreads();
}

// ---- group-local barrier: arrival counter SPLIT from poll flag -------------
// Pollers read a separate, read-mostly flag line -> no RMW/poll interference
// on the counter line (the R13 lesson, applied to the XCD-local barrier).
__device__ __forceinline__ void pbar(unsigned* bar, unsigned g, unsigned phase){
  __syncthreads();
  if (threadIdx.x == 0){
    unsigned old = __hip_atomic_fetch_add(bar + 2048 + g*32, 1u, AXR);
    if (old == phase*32u - 1u){                   // last arriver of this group
      __hip_atomic_store(bar + 2304 + g*32, phase, AXR);
    } else {
      while (__hip_atomic_load(bar + 2304 + g*32, AXR) < phase)
        __builtin_amdgcn_s_sleep(2);
    }
    asm volatile("buffer_inv\n\ts_waitcnt vmcnt(0)" ::: "memory");
  }
  __syncthreads();
}

// ---- LDS weight-slice helpers (XOR-swizzled, G4) ---------------------------
__device__ __forceinline__ short8 lds8(const u16* base, int r, int kelem, int rowbytes){
  int bo = r*rowbytes + ((kelem*2) ^ ((r & 7) << 4));
  return *(const short8*)((const char*)base + bo);
}
// split (hi+lo) slice: 64 gate rows x ldw K
__device__ __forceinline__ void load_slice64(
    const float* __restrict__ W, int ldw, int rowshift, int nelem,
    u16* lh, u16* ll, int cg, int tid)
{
  const int rowbytes = ldw*2;
  for (int i = tid; i < nelem; i += 256){
    int r = i >> rowshift, k = i & ((1 << rowshift) - 1);
    int n = ((r >> 4) << 9) + cg*16 + (r & 15);
    HiLo s = split1(W[n*ldw + k]);
    int bo = r*rowbytes + ((k*2) ^ ((r & 7) << 4));
    *(u16*)((char*)lh + bo) = (u16)s.hi;
    *(u16*)((char*)ll + bo) = (u16)s.lo;
  }
}
// hi-only slice
__device__ __forceinline__ void load_slice64h(
    const float* __restrict__ W, int ldw, int rowshift, int nelem,
    u16* lh, int cg, int tid)
{
  const int rowbytes = ldw*2;
  for (int i = tid; i < nelem; i += 256){
    int r = i >> rowshift, k = i & ((1 << rowshift) - 1);
    int n = ((r >> 4) << 9) + cg*16 + (r & 15);
    int bo = r*rowbytes + ((k*2) ^ ((r & 7) << 4));
    *(u16*)((char*)lh + bo) = f2bf(W[n*ldw + k]);
  }
}

// ---- persistent kernel: batch-parallel groups, XCD-local exchange ----------
// group g = wg&7 owns batches [g*32, +32); col-group cg = wg>>3 owns 16 cols.
// LDS-resident: Whh0(hi), W1hh(hi), Wih0(hi+lo). Streamed: W1ih(hi), Wcomb(hi).
__global__ void __launch_bounds__(256, 1) lstm_persist(
    const float* __restrict__ x,
    const float* __restrict__ Whh0, const float* __restrict__ Wih0,
    const float* __restrict__ Whh1,
    const u16* __restrict__ W1ih_h, const u16* __restrict__ Wcmb_h,
    const float* __restrict__ bb,
    const float* __restrict__ bih0, const float* __restrict__ bhh0,
    const float* __restrict__ bih1, const float* __restrict__ bhh1,
    const float* __restrict__ Wout, const float* __restrict__ bout,
    float* __restrict__ out, unsigned* __restrict__ cnt,
    u16* __restrict__ h0h0, u16* __restrict__ h0h1,
    u16* __restrict__ h0l0, u16* __restrict__ h0l1,
    u16* __restrict__ h1h0, u16* __restrict__ h1h1,
    u16* __restrict__ h1l0, u16* __restrict__ h1l1)
{
  __shared__ u16 whh0_h[32768];                  // 64x512 hi, swizzled
  __shared__ u16 w1hh_h[32768];                  // 64x512 hi, swizzled
  __shared__ u16 w0ih_h[4096],  w0ih_l[4096];    // 64x64 hi+lo, swizzled
  __shared__ float gl[32*68];                    // gate exchange
  __shared__ float pr[256];                      // pred partials [d][kq]
  __shared__ float bs0[64], bs1[64], bsd[64];
  __shared__ unsigned s_pop, s_nx, s_all;

  const int wg = blockIdx.x, tid = threadIdx.x;
  const int g = wg & 7, cg = wg >> 3;
  const int b0 = g*32;
  const int lane = tid & 63, wv = tid >> 6;
  const int cI = lane & 15;
  const int kc = (lane >> 4) << 3;
  const int rl = wv*16 + cI;                     // local gate row

  // ---- one-time init: LDS weight slices + biases ----
  load_slice64h(Whh0, 512, 9, 32768, whh0_h, cg, tid);
  load_slice64h(Whh1, 512, 9, 32768, w1hh_h, cg, tid);
  load_slice64(Wih0,  64, 6,  4096, w0ih_h, w0ih_l, cg, tid);
  if (tid < 64){
    int n = ((tid >> 4) << 9) + cg*16 + (tid & 15);
    bs0[tid] = bih0[n] + bhh0[n];
    bs1[tid] = bih1[n] + bhh1[n];
    bsd[tid] = bb[n];
  }

  // ---- census: XCD id, per-XCD pop (fallback), group co-location ----
  unsigned xcd;
  asm volatile("s_getreg_b32 %0, hwreg(HW_REG_XCC_ID)" : "=s"(xcd));
  xcd &= 7u;
  if (tid == 0){
    __hip_atomic_fetch_add(cnt + 576 + xcd*32, 1u, AXR);
    __hip_atomic_store(cnt + 1536 + wg, xcd, AXR);
  }
  gbar(cnt, 1);
  if (tid == 0){
    unsigned nxl = 0;
    for (int i = 0; i < 8; ++i)
      nxl += (__hip_atomic_load(cnt + 576 + i*32, AXR) != 0u) ? 1u : 0u;
    s_pop = __hip_atomic_load(cnt + 576 + xcd*32, AXR);
    s_nx  = nxl;
    unsigned ok = 1;
    for (int i = 0; i < 32; ++i)
      ok &= (__hip_atomic_load(cnt + 1536 + (g + 8*i), AXR) == xcd) ? 1u : 0u;
    if (!ok) __hip_atomic_store(cnt + 1800 + g, 1u, AXR);
  }
  gbar(cnt, 2);
  if (tid == 0){
    unsigned bad = 0;
    for (int gg = 0; gg < 8; ++gg)
      bad |= __hip_atomic_load(cnt + 1800 + gg, AXR);
    s_all = (bad == 0u) ? 1u : 0u;
  }
  __syncthreads();
  const unsigned pop = s_pop, nx = s_nx;
  const bool allco = (s_all != 0u);

  const int ar0 = b0 + cI, ar1 = b0 + 16 + cI;   // A rows (batches)
  const int aoff0 = ar0*512 + kc, aoff1 = ar1*512 + kc;
  const int nb = (wv*512 + cg*16 + cI)*512 + kc; // streamed weight frag base

  u16* H0h[2] = { h0h0, h0h1 };  u16* H0l[2] = { h0l0, h0l1 };
  u16* H1h[2] = { h1h0, h1h1 };  u16* H1l[2] = { h1l0, h1l1 };

  const float* xb0 = x + ar0*21504;
  const float* xb1 = x + ar1*21504;

  float c0r[2] = {0.f, 0.f}, c1r[2] = {0.f, 0.f};   // cell state in registers
  unsigned ep = 0;

  const int sk1 = g*2;            // per-XCD K-chunk skew (kept from R17)
  const int sk2 = (g >> 1)*4;

  for (int t = 0; t < 432; ++t){
    const int p = t & 1;
    const bool enc = (t < 336);

    // =============== phase A: layer 0 ===============
    f32x4 A0 = {0,0,0,0}, A1 = {0,0,0,0};
    if (enc){
      #pragma unroll
      for (int ks = 0; ks < 2; ++ks){            // x segment (K=64), split
        int k = ks*32 + kc;
        short8 a0h, a0l, a1h, a1l;
        #pragma unroll
        for (int j = 0; j < 8; ++j){
          HiLo s0 = split1(xb0[(k + j)*336 + t]); a0h[j] = s0.hi; a0l[j] = s0.lo;
          HiLo s1 = split1(xb1[(k + j)*336 + t]); a1h[j] = s1.hi; a1l[j] = s1.lo;
        }
        short8 bh = lds8(w0ih_h, rl, k, 128);
        short8 bl = lds8(w0ih_l, rl, k, 128);
        SMACC(A0, a0h, a0l, bh, bl);
        SMACC(A1, a1h, a1l, bh, bl);
      }
    } else if (t > 336){                         // Wcomb (hi, streamed) over h1_{t-1}
      const u16* hH = H1h[p^1]; const u16* hL = H1l[p^1];
      const u16* wh = Wcmb_h + nb;
      #pragma unroll 4
      for (int kss = 0; kss < 16; ++kss){
        int k = ((kss + sk1) & 15)*32;
        short8 a0h = *(const short8*)(hH + aoff0 + k);
        short8 a0l = *(const short8*)(hL + aoff0 + k);
        short8 a1h = *(const short8*)(hH + aoff1 + k);
        short8 a1l = *(const short8*)(hL + aoff1 + k);
        short8 bh = *(const short8*)(wh + k);
        SMACC2(A0, a0h, a0l, bh);
        SMACC2(A1, a1h, a1l, bh);
      }
    }
    {                                            // Whh0 (LDS hi) over h0_{t-1}
      const u16* hH = H0h[p^1]; const u16* hL = H0l[p^1];
      #pragma unroll 4
      for (int ks = 0; ks < 16; ++ks){
        int k = ks*32;
        short8 a0h = *(const short8*)(hH + aoff0 + k);
        short8 a0l = *(const short8*)(hL + aoff0 + k);
        short8 a1h = *(const short8*)(hH + aoff1 + k);
        short8 a1l = *(const short8*)(hL + aoff1 + k);
        short8 bh = lds8(whh0_h, rl, kc + k, 1024);
        SMACC2(A0, a0h, a0l, bh);
        SMACC2(A1, a1h, a1l, bh);
      }
    }
    // decoder pred l=t-337 from h1_{t-1}: this WG owns batch b0+cg
    if (!enc && t > 336){
      const int d = tid & 63, kq = tid >> 6;
      const int b = b0 + cg;
      const u16* hH = H1h[p^1] + b*512 + kq*128;
      const u16* hL = H1l[p^1] + b*512 + kq*128;
      const float* wr = Wout + d*512 + kq*128;
      float part = 0.f;
      #pragma unroll 4
      for (int k = 0; k < 128; k += 8){
        short8 hv = *(const short8*)(hH + k);
        short8 lv = *(const short8*)(hL + k);
        #pragma unroll
        for (int j = 0; j < 8; ++j)
          part += (bf2f((u16)hv[j]) + bf2f((u16)lv[j])) * wr[k + j];
      }
      pr[d*4 + kq] = part;
      __syncthreads();
      if (tid < 64){
        float v = pr[tid*4] + pr[tid*4+1] + pr[tid*4+2] + pr[tid*4+3] + bout[tid];
        out[131072 + (b*64 + tid)*96 + (t - 337)] = v;
      }
    }
    // cell update layer 0 (c in registers)
    {
      const float* bias = (enc || t == 336) ? bs0 : bsd;
      __syncthreads();
      const int rb_ = (lane >> 4) << 2;
      #pragma unroll
      for (int r = 0; r < 4; ++r){
        gl[(rb_ + r)*68 + rl]      = A0[r] + bias[rl];
        gl[(16 + rb_ + r)*68 + rl] = A1[r] + bias[rl];
      }
      __syncthreads();
      u16* Hh = H0h[p]; u16* Hl = H0l[p];
      #pragma unroll
      for (int q = 0; q < 2; ++q){
        int e = tid + q*256;
        int m = e >> 4, col = e & 15;
        float iv = gl[m*68 + col];
        float fv = gl[m*68 + 16 + col];
        float gv = gl[m*68 + 32 + col];
        float ov = gl[m*68 + 48 + col];
        float si = 1.f/(1.f + expf(-iv));
        float sf = 1.f/(1.f + expf(-fv));
        float so = 1.f/(1.f + expf(-ov));
        float cn = sf*c0r[q] + si*tanhf(gv);
        c0r[q] = cn;
        float h = so*tanhf(cn);
        int gi = (b0 + m)*512 + cg*16 + col;
        u16 hh = f2bf(h);
        Hh[gi] = hh;
        Hl[gi] = f2bf(h - bf2f(hh));
      }
    }
    ++ep;
    if (allco) pbar(cnt, g, ep); else xbar(cnt, ep, xcd, pop, nx);

    // =============== phase B: layer 1 ===============
    A0 = (f32x4){0,0,0,0}; A1 = (f32x4){0,0,0,0};
    {                                            // W1ih (hi, streamed) over h0_t
      const u16* hH = H0h[p]; const u16* hL = H0l[p];
      const u16* wh = W1ih_h + nb;
      #pragma unroll 4
      for (int kss = 0; kss < 16; ++kss){
        int k = ((kss + sk2) & 15)*32;
        short8 a0h = *(const short8*)(hH + aoff0 + k);
        short8 a0l = *(const short8*)(hL + aoff0 + k);
        short8 a1h = *(const short8*)(hH + aoff1 + k);
        short8 a1l = *(const short8*)(hL + aoff1 + k);
        short8 bh = *(const short8*)(wh + k);
        SMACC2(A0, a0h, a0l, bh);
        SMACC2(A1, a1h, a1l, bh);
      }
    }
    {                                            // W1hh (LDS hi) over h1_{t-1}
      const u16* hH = H1h[p^1]; const u16* hL = H1l[p^1];
      #pragma unroll 4
      for (int ks = 0; ks < 16; ++ks){
        int k = ks*32;
        short8 a0h = *(const short8*)(hH + aoff0 + k);
        short8 a0l = *(const short8*)(hL + aoff0 + k);
        short8 a1h = *(const short8*)(hH + aoff1 + k);
        short8 a1l = *(const short8*)(hL + aoff1 + k);
        short8 bh = lds8(w1hh_h, rl, kc + k, 1024);
        SMACC2(A0, a0h, a0l, bh);
        SMACC2(A1, a1h, a1l, bh);
      }
    }
    // cell update layer 1
    {
      float* gf = (t == 335) ? out : (float*)nullptr;
      __syncthreads();
      const int rb_ = (lane >> 4) << 2;
      #pragma unroll
      for (int r = 0; r < 4; ++r){
        gl[(rb_ + r)*68 + rl]      = A0[r] + bs1[rl];
        gl[(16 + rb_ + r)*68 + rl] = A1[r] + bs1[rl];
      }
      __syncthreads();
      u16* Hh = H1h[p]; u16* Hl = H1l[p];
      #pragma unroll
      for (int q = 0; q < 2; ++q){
        int e = tid + q*256;
        int m = e >> 4, col = e & 15;
        float iv = gl[m*68 + col];
        float fv = gl[m*68 + 16 + col];
        float gv = gl[m*68 + 32 + col];
        float ov = gl[m*68 + 48 + col];
        float si = 1.f/(1.f + expf(-iv));
        float sf = 1.f/(1.f + expf(-fv));
        float so = 1.f/(1.f + expf(-ov));
        float cn = sf*c1r[q] + si*tanhf(gv);
        c1r[q] = cn;
        float h = so*tanhf(cn);
        int gi = (b0 + m)*512 + cg*16 + col;
        u16 hh = f2bf(h);
        Hh[gi] = hh;
        Hl[gi] = f2bf(h - bf2f(hh));
        if (gf) gf[gi] = h;
      }
    }
    ++ep;
    if (allco) pbar(cnt, g, ep); else xbar(cnt, ep, xcd, pop, nx);
  }
}

// ---- tail: pred for l=95 from h1_431 (parity 1) ----------------------------
__global__ void __launch_bounds__(256) pred_last(
    const u16* __restrict__ h1hi, const u16* __restrict__ h1lo,
    const float* __restrict__ Wout, const float* __restrict__ bout,
    float* __restrict__ out)
{
  const int wg = blockIdx.x, tid = threadIdx.x;
  const int bsub = tid >> 6, d = tid & 63;
  const int b = wg*4 + bsub;
  float acc = bout[d];
  const u16* hH = h1hi + b*512;
  const u16* hL = h1lo + b*512;
  const float* wr = Wout + d*512;
  #pragma unroll 8
  for (int k = 0; k < 512; k += 8){
    short8 hv = *(const short8*)(hH + k);
    short8 lv = *(const short8*)(hL + k);
    #pragma unroll
    for (int j = 0; j < 8; ++j)
      acc += (bf2f((u16)hv[j]) + bf2f((u16)lv[j])) * wr[k + j];
  }
  out[131072 + (b*64 + d)*96 + 95] = acc;
}

// ======================= fallback (R9 proven path) ==========================
__device__ __forceinline__ void cell_epilogue_fb(
    float* gl, const float* bs, float* __restrict__ cbuf,
    u16* __restrict__ hhi, u16* __restrict__ hlo,
    float* __restrict__ gfout, int mrow, int jblk,
    const f32x4& a0, const f32x4& a1, int wv, int lane, int tid)
{
  __syncthreads();
  const int rbase = wv*16 + ((lane >> 4) << 2);
  const int cI = lane & 15;
  #pragma unroll
  for (int r = 0; r < 4; ++r){
    gl[(rbase+r)*33 + cI]      = a0[r] + bs[cI];
    gl[(rbase+r)*33 + 16 + cI] = a1[r] + bs[16 + cI];
  }
  __syncthreads();
  #pragma unroll
  for (int q = 0; q < 2; ++q){
    int e = tid + q*256;
    int m = e >> 3, jj = e & 7;
    float iv = gl[m*33 + jj];
    float fv = gl[m*33 + 8 + jj];
    float gv = gl[m*33 + 16 + jj];
    float ov = gl[m*33 + 24 + jj];
    float si = 1.f/(1.f + expf(-iv));
    float sf = 1.f/(1.f + expf(-fv));
    float so = 1.f/(1.f + expf(-ov));
    int gi = (mrow*64 + m)*512 + jblk*8 + jj;
    float cn = sf*cbuf[gi] + si*tanhf(gv);
    cbuf[gi] = cn;
    float h = so*tanhf(cn);
    u16 hh = f2bf(h);
    hhi[gi] = hh;
    hlo[gi] = f2bf(h - bf2f(hh));
    if (gfout) gfout[gi] = h;
  }
}

template<bool ENC>
__global__ void __launch_bounds__(256) l0_fb(
    const float* __restrict__ x,
    const u16* __restrict__ predhi, const u16* __restrict__ predlo,
    const float* __restrict__ Wihf, const float* __restrict__ Whhf,
    const float* __restrict__ bih, const float* __restrict__ bhh,
    const u16* __restrict__ hphi, const u16* __restrict__ hplo,
    u16* __restrict__ hnhi, u16* __restrict__ hnlo,
    float* __restrict__ c0, int t)
{
  __shared__ float gl[64*33];
  __shared__ float bs[32];
  const int wg = blockIdx.x, tid = threadIdx.x;
  const int mrow = wg & 3, jblk = wg >> 2;
  const int lane = tid & 63, wv = tid >> 6;
  if (tid < 32){
    int n = ((tid >> 3) << 9) + jblk*8 + (tid & 7);
    bs[tid] = bih[n] + bhh[n];
  }
  const int ar = mrow*64 + wv*16 + (lane & 15);
  const int kc = (lane >> 4) << 3;
  const int cI = lane & 15;
  const int n0 = ((cI >> 3) << 9) + jblk*8 + (cI & 7);
  const int n1 = n0 + 1024;

  f32x4 acc0 = {0,0,0,0}, acc1 = {0,0,0,0};
  #pragma unroll
  for (int ks = 0; ks < 2; ++ks){
    int k = ks*32 + kc;
    short8 ah, al;
    if (ENC){
      const float* xb = x + ar*21504 + t;
      #pragma unroll
      for (int j = 0; j < 8; ++j){ HiLo s = split1(xb[(k + j)*336]); ah[j] = s.hi; al[j] = s.lo; }
    } else {
      ah = *(const short8*)(predhi + ar*64 + k);
      al = *(const short8*)(predlo + ar*64 + k);
    }
    short8 bh0, bl0, bh1, bl1;
    ldw8s(Wihf + n0*64 + k, bh0, bl0);
    ldw8s(Wihf + n1*64 + k, bh1, bl1);
    SMACC(acc0, ah, al, bh0, bl0);
    SMACC(acc1, ah, al, bh1, bl1);
  }
  const u16* hH = hphi + ar*512 + kc;
  const u16* hL = hplo + ar*512 + kc;
  #pragma unroll 4
  for (int ks = 0; ks < 16; ++ks){
    int k = ks*32;
    short8 ah = *(const short8*)(hH + k);
    short8 al = *(const short8*)(hL + k);
    short8 bh0, bl0, bh1, bl1;
    ldw8s(Whhf + n0*512 + kc + k, bh0, bl0);
    ldw8s(Whhf + n1*512 + kc + k, bh1, bl1);
    SMACC(acc0, ah, al, bh0, bl0);
    SMACC(acc1, ah, al, bh1, bl1);
  }
  cell_epilogue_fb(gl, bs, c0, hnhi, hnlo, nullptr, mrow, jblk, acc0, acc1, wv, lane, tid);
}

__global__ void __launch_bounds__(256) l1_fb(
    const float* __restrict__ Wihf, const float* __restrict__ Whhf,
    const float* __restrict__ bih, const float* __restrict__ bhh,
    const u16* __restrict__ h0hi, const u16* __restrict__ h0lo,
    const u16* __restrict__ h1phi, const u16* __restrict__ h1plo,
    u16* __restrict__ h1nhi, u16* __restrict__ h1nlo,
    float* __restrict__ c1, float* __restrict__ gfout)
{
  __shared__ float gl[64*33];
  __shared__ float bs[32];
  const int wg = blockIdx.x, tid = threadIdx.x;
  const int mrow = wg & 3, jblk = wg >> 2;
  const int lane = tid & 63, wv = tid >> 6;
  if (tid < 32){
    int n = ((tid >> 3) << 9) + jblk*8 + (tid & 7);
    bs[tid] = bih[n] + bhh[n];
  }
  const int ar = mrow*64 + wv*16 + (lane & 15);
  const int kc = (lane >> 4) << 3;
  const int cI = lane & 15;
  const int n0 = ((cI >> 3) << 9) + jblk*8 + (cI & 7);
  const int n1 = n0 + 1024;

  f32x4 acc0 = {0,0,0,0}, acc1 = {0,0,0,0};
  {
    const u16* hH = h0hi + ar*512 + kc;
    const u16* hL = h0lo + ar*512 + kc;
    #pragma unroll 4
    for (int ks = 0; ks < 16; ++ks){
      int k = ks*32;
      short8 ah = *(const short8*)(hH + k);
      short8 al = *(const short8*)(hL + k);
      short8 bh0, bl0, bh1, bl1;
      ldw8s(Wihf + n0*512 + kc + k, bh0, bl0);
      ldw8s(Wihf + n1*512 + kc + k, bh1, bl1);
      SMACC(acc0, ah, al, bh0, bl0);
      SMACC(acc1, ah, al, bh1, bl1);
    }
  }
  {
    const u16* hH = h1phi + ar*512 + kc;
    const u16* hL = h1plo + ar*512 + kc;
    #pragma unroll 4
    for (int ks = 0; ks < 16; ++ks){
      int k = ks*32;
      short8 ah = *(const short8*)(hH + k);
      short8 al = *(const short8*)(hL + k);
      short8 bh0, bl0, bh1, bl1;
      ldw8s(Whhf + n0*512 + kc + k, bh0, bl0);
      ldw8s(Whhf + n1*512 + kc + k, bh1, bl1);
      SMACC(acc0, ah, al, bh0, bl0);
      SMACC(acc1, ah, al, bh1, bl1);
    }
  }
  cell_epilogue_fb(gl, bs, c1, h1nhi, h1nlo, gfout, mrow, jblk, acc0, acc1, wv, lane, tid);
}

__global__ void __launch_bounds__(256) pred_fb(
    const u16* __restrict__ h1hi, const u16* __restrict__ h1lo,
    const float* __restrict__ Wout, const float* __restrict__ bout,
    u16* __restrict__ predhi, u16* __restrict__ predlo,
    float* __restrict__ out, int l)
{
  const int wg = blockIdx.x, tid = threadIdx.x;
  const int bsub = tid >> 6, d = tid & 63;
  const int b = wg*4 + bsub;
  float acc = bout[d];
  const u16* hH = h1hi + b*512;
  const u16* hL = h1lo + b*512;
  const float* wr = Wout + d*512;
  #pragma unroll 8
  for (int k = 0; k < 512; k += 8){
    short8 hv = *(const short8*)(hH + k);
    short8 lv = *(const short8*)(hL + k);
    #pragma unroll
    for (int j = 0; j < 8; ++j)
      acc += (bf2f((u16)hv[j]) + bf2f((u16)lv[j])) * wr[k + j];
  }
  HiLo s = split1(acc);
  predhi[b*64 + d] = (u16)s.hi;
  predlo[b*64 + d] = (u16)s.lo;
  out[131072 + (b*64 + d)*96 + l] = acc;
}

extern "C" void kernel_launch(void* const* d_in, const int* in_sizes, int n_in,
                              void* d_out, int out_size, void* d_ws, size_t ws_size,
                              hipStream_t stream)
{
  const float* x    = (const float*)d_in[0];
  const float* Wih0 = (const float*)d_in[1];
  const float* Whh0 = (const float*)d_in[2];
  const float* bih0 = (const float*)d_in[3];
  const float* bhh0 = (const float*)d_in[4];
  const float* Wih1 = (const float*)d_in[5];
  const float* Whh1 = (const float*)d_in[6];
  const float* bih1 = (const float*)d_in[7];
  const float* bhh1 = (const float*)d_in[8];
  const float* Wout = (const float*)d_in[9];
  const float* bout = (const float*)d_in[10];
  float* out = (float*)d_out;

  // ---- ws layout (main): h 2MB | cnt 64KB | hi weights 4MB | bb 8KB
  char* ws = (char*)d_ws;
  u16* h0h[2] = { (u16*)(ws + 0),       (u16*)(ws + 262144) };
  u16* h0l[2] = { (u16*)(ws + 524288),  (u16*)(ws + 786432) };
  u16* h1h[2] = { (u16*)(ws + 1048576), (u16*)(ws + 1310720) };
  u16* h1l[2] = { (u16*)(ws + 1572864), (u16*)(ws + 1835008) };
  unsigned* cnt = (unsigned*)(ws + 2097152);
  u16* Wcmb_h = (u16*)(ws + 2162688);
  u16* W1ih_h = Wcmb_h + 1048576;
  float* bb   = (float*)(W1ih_h + 1048576);
  const size_t NEED = 2162688u + 2u*2097152u + 8192u;   // ~6.4 MB
  // fallback layout (only used when ws too small)
  float* fb_c0 = (float*)(ws + 2162688);
  float* fb_c1 = (float*)(ws + 2686976);
  u16* predh   = (u16*)(ws + 3211264);
  u16* predl   = (u16*)(ws + 3244032);
  const bool ps = (ws_size >= NEED);

  (void)hipMemsetAsync(d_ws, 0, 3276800, stream);   // h + cnt (+ fb c/pred)

  if (ps){
    wcomb_k<<<dim3(256), dim3(256), 0, stream>>>(Wih0, Wout, bout, bih0, bhh0,
                                                 Wcmb_h, bb);
    wcvt<<<dim3(4096), dim3(256), 0, stream>>>(Wih1, W1ih_h, 1048576);
    lstm_persist<<<dim3(256), dim3(256), 0, stream>>>(
        x, Whh0, Wih0, Whh1, W1ih_h, Wcmb_h, bb,
        bih0, bhh0, bih1, bhh1, Wout, bout, out, cnt,
        h0h[0], h0h[1], h0l[0], h0l[1], h1h[0], h1h[1], h1l[0], h1l[1]);
    pred_last<<<dim3(64), dim3(256), 0, stream>>>(h1h[1], h1l[1], Wout, bout, out);
  } else {
    for (int t = 0; t < 432; ++t){
      const int p = t & 1;
      float* gf = (t == 335) ? out : (float*)nullptr;
      if (t < 336)
        l0_fb<true><<<dim3(256), dim3(256), 0, stream>>>(
            x, predh, predl, Wih0, Whh0, bih0, bhh0,
            h0h[p^1], h0l[p^1], h0h[p], h0l[p], fb_c0, t);
      else
        l0_fb<false><<<dim3(256), dim3(256), 0, stream>>>(
            x, predh, predl, Wih0, Whh0, bih0, bhh0,
            h0h[p^1], h0l[p^1], h0h[p], h0l[p], fb_c0, t);
      l1_fb<<<dim3(256), dim3(256), 0, stream>>>(
          Wih1, Whh1, bih1, bhh1, h0h[p], h0l[p],
          h1h[p^1], h1l[p^1], h1h[p], h1l[p], fb_c1, gf);
      if (t >= 336)
        pred_fb<<<dim3(64), dim3(256), 0, stream>>>(
            h1h[p], h1l[p], Wout, bout, predh, predl, out, t - 336);
    }
  }
}

// Round 21
// 15490.112 us; speedup vs baseline: 1.3959x; 1.0081x over previous
//
#include <hip/hip_runtime.h>

typedef unsigned short u16;
typedef __attribute__((ext_vector_type(8))) short short8;
typedef __attribute__((ext_vector_type(4))) float f32x4;

#define AXR __ATOMIC_RELAXED, __HIP_MEMORY_SCOPE_AGENT

__device__ __forceinline__ float bf2f(u16 v){
  union { unsigned u; float f; } t; t.u = ((unsigned)v) << 16; return t.f;
}
__device__ __forceinline__ u16 f2bf(float f){
  union { float f; unsigned u; } t; t.f = f;
  unsigned u = t.u;
  return (u16)((u + 0x7fffu + ((u >> 16) & 1u)) >> 16);
}
struct HiLo { short hi, lo; };
__device__ __forceinline__ HiLo split1(float v){
  HiLo r;
  u16 h = f2bf(v);
  r.hi = (short)h;
  r.lo = (short)f2bf(v - bf2f(h));
  return r;
}
__device__ __forceinline__ void ldw8s(const float* __restrict__ p, short8& hi, short8& lo){
  #pragma unroll
  for (int j = 0; j < 8; ++j){ HiLo s = split1(p[j]); hi[j] = s.hi; lo[j] = s.lo; }
}

#define MFMA(acc, a, b) acc = __builtin_amdgcn_mfma_f32_16x16x32_bf16(a, b, acc, 0,0,0)
#define SMACC(acc, ah, al, bh, bl) do{ MFMA(acc, ah, bh); MFMA(acc, ah, bl); MFMA(acc, al, bh); }while(0)
#define SMACC2(acc, ah, al, bh) do{ MFMA(acc, ah, bh); MFMA(acc, al, bh); }while(0)

// ---- prepass: f32 -> bf16 (hi only, RNE) -----------------------------------
__global__ void wcvt(const float* __restrict__ s, u16* __restrict__ hi, int n){
  int i = blockIdx.x * blockDim.x + threadIdx.x;
  if (i < n) hi[i] = f2bf(s[i]);
}

// ---- prepass: Wcomb = Wih0 @ Wout (2048x512 bf16 hi), bb = b0 + Wih0@bout --
__global__ void __launch_bounds__(256) wcomb_k(
    const float* __restrict__ Wih0, const float* __restrict__ Wout,
    const float* __restrict__ bout, const float* __restrict__ bih0,
    const float* __restrict__ bhh0,
    u16* __restrict__ Wch, float* __restrict__ bb)
{
  __shared__ float wl[8*64];
  __shared__ float bo[64];
  const int wg = blockIdx.x, tid = threadIdx.x;
  const int r0 = wg*8;
  for (int i = tid; i < 512; i += 256) wl[i] = Wih0[(r0 + (i >> 6))*64 + (i & 63)];
  if (tid < 64) bo[tid] = bout[tid];
  __syncthreads();
  if (tid < 8){
    int n = r0 + tid;
    float a = bih0[n] + bhh0[n];
    #pragma unroll 8
    for (int d = 0; d < 64; ++d) a += wl[tid*64 + d]*bo[d];
    bb[n] = a;
  }
  #pragma unroll
  for (int jj = 0; jj < 2; ++jj){
    int j = tid + jj*256;
    float acc[8] = {0,0,0,0,0,0,0,0};
    for (int d = 0; d < 64; ++d){
      float wv = Wout[d*512 + j];
      #pragma unroll
      for (int r = 0; r < 8; ++r) acc[r] += wl[r*64 + d]*wv;
    }
    #pragma unroll
    for (int r = 0; r < 8; ++r) Wch[(r0 + r)*512 + j] = f2bf(acc[r]);
  }
}

// ---- init-only tree barrier (threadfence-based, proven R13/R14) ------------
__device__ __forceinline__ void gbar(unsigned* bar, unsigned phase){
  __syncthreads();
  if (threadIdx.x == 0){
    __threadfence();
    const unsigned gg = (unsigned)blockIdx.x >> 4;
    unsigned old = __hip_atomic_fetch_add(bar + 64 + gg*32, 1u, AXR);
    if (old == phase*16u - 1u){
      unsigned r = __hip_atomic_fetch_add(bar, 1u, AXR);
      if (r == phase*16u - 1u)
        __hip_atomic_store(bar + 32, phase, AXR);
    }
    while (__hip_atomic_load(bar + 32, AXR) < phase)
      __builtin_amdgcn_s_sleep(2);
    __threadfence();
  }
  __syncthreads();
}

// ---- global fallback barrier (R14 xbar, any WG placement) ------------------
__device__ __forceinline__ void xbar(unsigned* bar, unsigned phase,
                                     unsigned xcd, unsigned pop, unsigned nx){
  __syncthreads();
  if (threadIdx.x == 0){
    unsigned old = __hip_atomic_fetch_add(bar + 832 + xcd*32, 1u, AXR);
    const bool leader = (old == phase*pop - 1u);
    if (leader){
      asm volatile("buffer_wbl2 sc1\n\ts_waitcnt vmcnt(0)" ::: "memory");
      unsigned r = __hip_atomic_fetch_add(bar + 1344, 1u, AXR);
      if (r == phase*nx - 1u)
        __hip_atomic_store(bar + 1376, phase, AXR);
    }
    while (__hip_atomic_load(bar + 1376, AXR) < phase)
      __builtin_amdgcn_s_sleep(2);
    if (leader){
      asm volatile("buffer_inv sc1\n\ts_waitcnt vmcnt(0)" ::: "memory");
      __hip_atomic_store(bar + 1088 + xcd*32, phase, AXR);
    } else {
      while (__hip_atomic_load(bar + 1088 + xcd*32, AXR) < phase)
        __builtin_amdgcn_s_sleep(1);
      asm volatile("buffer_inv\n\ts_waitcnt vmcnt(0)" ::: "memory");
    }
  }
  __syncthreads();
}

// ---- group-local barrier (group == one XCD by construction) ----------------
// Arrival counter split from poll flag (R20); acquire = vL1 invalidate only.
__device__ __forceinline__ void pbar(unsigned* bar, unsigned g, unsigned phase){
  __syncthreads();
  if (threadIdx.x == 0){
    unsigned old = __hip_atomic_fetch_add(bar + 2048 + g*32, 1u, AXR);
    if (old == phase*32u - 1u){
      __hip_atomic_store(bar + 2304 + g*32, phase, AXR);
    } else {
      while (__hip_atomic_load(bar + 2304 + g*32, AXR) < phase)
        __builtin_amdgcn_s_sleep(2);
    }
    asm volatile("buffer_inv\n\ts_waitcnt vmcnt(0)" ::: "memory");
  }
  __syncthreads();
}

// ---- LDS weight-slice helpers (XOR-swizzled, G4) ---------------------------
__device__ __forceinline__ short8 lds8(const u16* base, int r, int kelem, int rowbytes){
  int bo = r*rowbytes + ((kelem*2) ^ ((r & 7) << 4));
  return *(const short8*)((const char*)base + bo);
}
__device__ __forceinline__ void load_slice64(
    const float* __restrict__ W, int ldw, int rowshift, int nelem,
    u16* lh, u16* ll, int cg, int tid)
{
  const int rowbytes = ldw*2;
  for (int i = tid; i < nelem; i += 256){
    int r = i >> rowshift, k = i & ((1 << rowshift) - 1);
    int n = ((r >> 4) << 9) + cg*16 + (r & 15);
    HiLo s = split1(W[n*ldw + k]);
    int bo = r*rowbytes + ((k*2) ^ ((r & 7) << 4));
    *(u16*)((char*)lh + bo) = (u16)s.hi;
    *(u16*)((char*)ll + bo) = (u16)s.lo;
  }
}
__device__ __forceinline__ void load_slice64h(
    const float* __restrict__ W, int ldw, int rowshift, int nelem,
    u16* lh, int cg, int tid)
{
  const int rowbytes = ldw*2;
  for (int i = tid; i < nelem; i += 256){
    int r = i >> rowshift, k = i & ((1 << rowshift) - 1);
    int n = ((r >> 4) << 9) + cg*16 + (r & 15);
    int bo = r*rowbytes + ((k*2) ^ ((r & 7) << 4));
    *(u16*)((char*)lh + bo) = f2bf(W[n*ldw + k]);
  }
}

// ---- persistent kernel: groups DERIVED from measured XCD id ----------------
// census: rank = arrival order within my XCD. If every XCD has exactly 32 WGs:
//   g := xcd (co-located by construction -> pbar), cg := rank.
// else: static g=wg&7, cg=wg>>3 + global xbar (proven fallback).
__global__ void __launch_bounds__(256, 1) lstm_persist(
    const float* __restrict__ x,
    const float* __restrict__ Whh0, const float* __restrict__ Wih0,
    const float* __restrict__ Whh1,
    const u16* __restrict__ W1ih_h, const u16* __restrict__ Wcmb_h,
    const float* __restrict__ bb,
    const float* __restrict__ bih0, const float* __restrict__ bhh0,
    const float* __restrict__ bih1, const float* __restrict__ bhh1,
    const float* __restrict__ Wout, const float* __restrict__ bout,
    float* __restrict__ out, unsigned* __restrict__ cnt,
    u16* __restrict__ h0h0, u16* __restrict__ h0h1,
    u16* __restrict__ h0l0, u16* __restrict__ h0l1,
    u16* __restrict__ h1h0, u16* __restrict__ h1h1,
    u16* __restrict__ h1l0, u16* __restrict__ h1l1)
{
  __shared__ u16 whh0_h[32768];                  // 64x512 hi, swizzled
  __shared__ u16 w1hh_h[32768];                  // 64x512 hi, swizzled
  __shared__ u16 w0ih_h[4096],  w0ih_l[4096];    // 64x64 hi+lo, swizzled
  __shared__ float gl[32*68];                    // gate exchange
  __shared__ float pr[256];                      // pred partials [d][kq]
  __shared__ float bs0[64], bs1[64], bsd[64];
  __shared__ unsigned s_rank, s_pop, s_nx, s_all;

  const int wg = blockIdx.x, tid = threadIdx.x;
  const int lane = tid & 63, wv = tid >> 6;
  const int cI = lane & 15;
  const int kc = (lane >> 4) << 3;
  const int rl = wv*16 + cI;                     // local gate row

  // ---- census FIRST: measured XCD id + rank within XCD ----
  unsigned xcd;
  asm volatile("s_getreg_b32 %0, hwreg(HW_REG_XCC_ID)" : "=s"(xcd));
  xcd &= 7u;
  if (tid == 0)
    s_rank = __hip_atomic_fetch_add(cnt + 576 + xcd*32, 1u, AXR);
  gbar(cnt, 1);                   // all pops final
  if (tid == 0){
    unsigned nxl = 0, allc = 1;
    for (int i = 0; i < 8; ++i){
      unsigned pv = __hip_atomic_load(cnt + 576 + i*32, AXR);
      nxl += (pv != 0u) ? 1u : 0u;
      if (pv != 32u) allc = 0u;
    }
    s_pop = __hip_atomic_load(cnt + 576 + xcd*32, AXR);
    s_nx  = nxl;
    s_all = allc;
  }
  __syncthreads();
  const unsigned pop = s_pop, nx = s_nx;
  const bool allco = (s_all != 0u);
  const int g  = allco ? (int)xcd    : (wg & 7);
  const int cg = allco ? (int)s_rank : (wg >> 3);
  const int b0 = g*32;

  // ---- one-time init: LDS weight slices + biases (cg now known) ----
  load_slice64h(Whh0, 512, 9, 32768, whh0_h, cg, tid);
  load_slice64h(Whh1, 512, 9, 32768, w1hh_h, cg, tid);
  load_slice64(Wih0,  64, 6,  4096, w0ih_h, w0ih_l, cg, tid);
  if (tid < 64){
    int n = ((tid >> 4) << 9) + cg*16 + (tid & 15);
    bs0[tid] = bih0[n] + bhh0[n];
    bs1[tid] = bih1[n] + bhh1[n];
    bsd[tid] = bb[n];
  }
  __syncthreads();

  const int ar0 = b0 + cI, ar1 = b0 + 16 + cI;   // A rows (batches)
  const int aoff0 = ar0*512 + kc, aoff1 = ar1*512 + kc;
  const int nb = (wv*512 + cg*16 + cI)*512 + kc; // streamed weight frag base

  u16* H0h[2] = { h0h0, h0h1 };  u16* H0l[2] = { h0l0, h0l1 };
  u16* H1h[2] = { h1h0, h1h1 };  u16* H1l[2] = { h1l0, h1l1 };

  const float* xb0 = x + ar0*21504;
  const float* xb1 = x + ar1*21504;

  float c0r[2] = {0.f, 0.f}, c1r[2] = {0.f, 0.f};   // cell state in registers
  unsigned ep = 0;

  const int sk1 = g*2;            // per-XCD K-chunk skew
  const int sk2 = (g >> 1)*4;

  for (int t = 0; t < 432; ++t){
    const int p = t & 1;
    const bool enc = (t < 336);

    // =============== phase A: layer 0 ===============
    f32x4 A0 = {0,0,0,0}, A1 = {0,0,0,0};
    if (enc){
      #pragma unroll
      for (int ks = 0; ks < 2; ++ks){            // x segment (K=64), split
        int k = ks*32 + kc;
        short8 a0h, a0l, a1h, a1l;
        #pragma unroll
        for (int j = 0; j < 8; ++j){
          HiLo s0 = split1(xb0[(k + j)*336 + t]); a0h[j] = s0.hi; a0l[j] = s0.lo;
          HiLo s1 = split1(xb1[(k + j)*336 + t]); a1h[j] = s1.hi; a1l[j] = s1.lo;
        }
        short8 bh = lds8(w0ih_h, rl, k, 128);
        short8 bl = lds8(w0ih_l, rl, k, 128);
        SMACC(A0, a0h, a0l, bh, bl);
        SMACC(A1, a1h, a1l, bh, bl);
      }
    } else if (t > 336){                         // Wcomb (hi, streamed) over h1_{t-1}
      const u16* hH = H1h[p^1]; const u16* hL = H1l[p^1];
      const u16* wh = Wcmb_h + nb;
      #pragma unroll 4
      for (int kss = 0; kss < 16; ++kss){
        int k = ((kss + sk1) & 15)*32;
        short8 a0h = *(const short8*)(hH + aoff0 + k);
        short8 a0l = *(const short8*)(hL + aoff0 + k);
        short8 a1h = *(const short8*)(hH + aoff1 + k);
        short8 a1l = *(const short8*)(hL + aoff1 + k);
        short8 bh = *(const short8*)(wh + k);
        SMACC2(A0, a0h, a0l, bh);
        SMACC2(A1, a1h, a1l, bh);
      }
    }
    {                                            // Whh0 (LDS hi) over h0_{t-1}
      const u16* hH = H0h[p^1]; const u16* hL = H0l[p^1];
      #pragma unroll 4
      for (int ks = 0; ks < 16; ++ks){
        int k = ks*32;
        short8 a0h = *(const short8*)(hH + aoff0 + k);
        short8 a0l = *(const short8*)(hL + aoff0 + k);
        short8 a1h = *(const short8*)(hH + aoff1 + k);
        short8 a1l = *(const short8*)(hL + aoff1 + k);
        short8 bh = lds8(whh0_h, rl, kc + k, 1024);
        SMACC2(A0, a0h, a0l, bh);
        SMACC2(A1, a1h, a1l, bh);
      }
    }
    // decoder pred l=t-337 from h1_{t-1}: this WG owns batch b0+cg
    if (!enc && t > 336){
      const int d = tid & 63, kq = tid >> 6;
      const int b = b0 + cg;
      const u16* hH = H1h[p^1] + b*512 + kq*128;
      const u16* hL = H1l[p^1] + b*512 + kq*128;
      const float* wr = Wout + d*512 + kq*128;
      float part = 0.f;
      #pragma unroll 4
      for (int k = 0; k < 128; k += 8){
        short8 hv = *(const short8*)(hH + k);
        short8 lv = *(const short8*)(hL + k);
        #pragma unroll
        for (int j = 0; j < 8; ++j)
          part += (bf2f((u16)hv[j]) + bf2f((u16)lv[j])) * wr[k + j];
      }
      pr[d*4 + kq] = part;
      __syncthreads();
      if (tid < 64){
        float v = pr[tid*4] + pr[tid*4+1] + pr[tid*4+2] + pr[tid*4+3] + bout[tid];
        out[131072 + (b*64 + tid)*96 + (t - 337)] = v;
      }
    }
    // cell update layer 0 (c in registers)
    {
      const float* bias = (enc || t == 336) ? bs0 : bsd;
      __syncthreads();
      const int rb_ = (lane >> 4) << 2;
      #pragma unroll
      for (int r = 0; r < 4; ++r){
        gl[(rb_ + r)*68 + rl]      = A0[r] + bias[rl];
        gl[(16 + rb_ + r)*68 + rl] = A1[r] + bias[rl];
      }
      __syncthreads();
      u16* Hh = H0h[p]; u16* Hl = H0l[p];
      #pragma unroll
      for (int q = 0; q < 2; ++q){
        int e = tid + q*256;
        int m = e >> 4, col = e & 15;
        float iv = gl[m*68 + col];
        float fv = gl[m*68 + 16 + col];
        float gv = gl[m*68 + 32 + col];
        float ov = gl[m*68 + 48 + col];
        float si = 1.f/(1.f + expf(-iv));
        float sf = 1.f/(1.f + expf(-fv));
        float so = 1.f/(1.f + expf(-ov));
        float cn = sf*c0r[q] + si*tanhf(gv);
        c0r[q] = cn;
        float h = so*tanhf(cn);
        int gi = (b0 + m)*512 + cg*16 + col;
        u16 hh = f2bf(h);
        Hh[gi] = hh;
        Hl[gi] = f2bf(h - bf2f(hh));
      }
    }
    ++ep;
    if (allco) pbar(cnt, g, ep); else xbar(cnt, ep, xcd, pop, nx);

    // =============== phase B: layer 1 ===============
    A0 = (f32x4){0,0,0,0}; A1 = (f32x4){0,0,0,0};
    {                                            // W1ih (hi, streamed) over h0_t
      const u16* hH = H0h[p]; const u16* hL = H0l[p];
      const u16* wh = W1ih_h + nb;
      #pragma unroll 4
      for (int kss = 0; kss < 16; ++kss){
        int k = ((kss + sk2) & 15)*32;
        short8 a0h = *(const short8*)(hH + aoff0 + k);
        short8 a0l = *(const short8*)(hL + aoff0 + k);
        short8 a1h = *(const short8*)(hH + aoff1 + k);
        short8 a1l = *(const short8*)(hL + aoff1 + k);
        short8 bh = *(const short8*)(wh + k);
        SMACC2(A0, a0h, a0l, bh);
        SMACC2(A1, a1h, a1l, bh);
      }
    }
    {                                            // W1hh (LDS hi) over h1_{t-1}
      const u16* hH = H1h[p^1]; const u16* hL = H1l[p^1];
      #pragma unroll 4
      for (int ks = 0; ks < 16; ++ks){
        int k = ks*32;
        short8 a0h = *(const short8*)(hH + aoff0 + k);
        short8 a0l = *(const short8*)(hL + aoff0 + k);
        short8 a1h = *(const short8*)(hH + aoff1 + k);
        short8 a1l = *(const short8*)(hL + aoff1 + k);
        short8 bh = lds8(w1hh_h, rl, kc + k, 1024);
        SMACC2(A0, a0h, a0l, bh);
        SMACC2(A1, a1h, a1l, bh);
      }
    }
    // cell update layer 1
    {
      float* gf = (t == 335) ? out : (float*)nullptr;
      __syncthreads();
      const int rb_ = (lane >> 4) << 2;
      #pragma unroll
      for (int r = 0; r < 4; ++r){
        gl[(rb_ + r)*68 + rl]      = A0[r] + bs1[rl];
        gl[(16 + rb_ + r)*68 + rl] = A1[r] + bs1[rl];
      }
      __syncthreads();
      u16* Hh = H1h[p]; u16* Hl = H1l[p];
      #pragma unroll
      for (int q = 0; q < 2; ++q){
        int e = tid + q*256;
        int m = e >> 4, col = e & 15;
        float iv = gl[m*68 + col];
        float fv = gl[m*68 + 16 + col];
        float gv = gl[m*68 + 32 + col];
        float ov = gl[m*68 + 48 + col];
        float si = 1.f/(1.f + expf(-iv));
        float sf = 1.f/(1.f + expf(-fv));
        float so = 1.f/(1.f + expf(-ov));
        float cn = sf*c1r[q] + si*tanhf(gv);
        c1r[q] = cn;
        float h = so*tanhf(cn);
        int gi = (b0 + m)*512 + cg*16 + col;
        u16 hh = f2bf(h);
        Hh[gi] = hh;
        Hl[gi] = f2bf(h - bf2f(hh));
        if (gf) gf[gi] = h;
      }
    }
    ++ep;
    if (allco) pbar(cnt, g, ep); else xbar(cnt, ep, xcd, pop, nx);
  }
}

// ---- tail: pred for l=95 from h1_431 (parity 1) ----------------------------
__global__ void __launch_bounds__(256) pred_last(
    const u16* __restrict__ h1hi, const u16* __restrict__ h1lo,
    const float* __restrict__ Wout, const float* __restrict__ bout,
    float* __restrict__ out)
{
  const int wg = blockIdx.x, tid = threadIdx.x;
  const int bsub = tid >> 6, d = tid & 63;
  const int b = wg*4 + bsub;
  float acc = bout[d];
  const u16* hH = h1hi + b*512;
  const u16* hL = h1lo + b*512;
  const float* wr = Wout + d*512;
  #pragma unroll 8
  for (int k = 0; k < 512; k += 8){
    short8 hv = *(const short8*)(hH + k);
    short8 lv = *(const short8*)(hL + k);
    #pragma unroll
    for (int j = 0; j < 8; ++j)
      acc += (bf2f((u16)hv[j]) + bf2f((u16)lv[j])) * wr[k + j];
  }
  out[131072 + (b*64 + d)*96 + 95] = acc;
}

// ======================= fallback (R9 proven path) ==========================
__device__ __forceinline__ void cell_epilogue_fb(
    float* gl, const float* bs, float* __restrict__ cbuf,
    u16* __restrict__ hhi, u16* __restrict__ hlo,
    float* __restrict__ gfout, int mrow, int jblk,
    const f32x4& a0, const f32x4& a1, int wv, int lane, int tid)
{
  __syncthreads();
  const int rbase = wv*16 + ((lane >> 4) << 2);
  const int cI = lane & 15;
  #pragma unroll
  for (int r = 0; r < 4; ++r){
    gl[(rbase+r)*33 + cI]      = a0[r] + bs[cI];
    gl[(rbase+r)*33 + 16 + cI] = a1[r] + bs[16 + cI];
  }
  __syncthreads();
  #pragma unroll
  for (int q = 0; q < 2; ++q){
    int e = tid + q*256;
    int m = e >> 3, jj = e & 7;
    float iv = gl[m*33 + jj];
    float fv = gl[m*33 + 8 + jj];
    float gv = gl[m*33 + 16 + jj];
    float ov = gl[m*33 + 24 + jj];
    float si = 1.f/(1.f + expf(-iv));
    float sf = 1.f/(1.f + expf(-fv));
    float so = 1.f/(1.f + expf(-ov));
    int gi = (mrow*64 + m)*512 + jblk*8 + jj;
    float cn = sf*cbuf[gi] + si*tanhf(gv);
    cbuf[gi] = cn;
    float h = so*tanhf(cn);
    u16 hh = f2bf(h);
    hhi[gi] = hh;
    hlo[gi] = f2bf(h - bf2f(hh));
    if (gfout) gfout[gi] = h;
  }
}

template<bool ENC>
__global__ void __launch_bounds__(256) l0_fb(
    const float* __restrict__ x,
    const u16* __restrict__ predhi, const u16* __restrict__ predlo,
    const float* __restrict__ Wihf, const float* __restrict__ Whhf,
    const float* __restrict__ bih, const float* __restrict__ bhh,
    const u16* __restrict__ hphi, const u16* __restrict__ hplo,
    u16* __restrict__ hnhi, u16* __restrict__ hnlo,
    float* __restrict__ c0, int t)
{
  __shared__ float gl[64*33];
  __shared__ float bs[32];
  const int wg = blockIdx.x, tid = threadIdx.x;
  const int mrow = wg & 3, jblk = wg >> 2;
  const int lane = tid & 63, wv = tid >> 6;
  if (tid < 32){
    int n = ((tid >> 3) << 9) + jblk*8 + (tid & 7);
    bs[tid] = bih[n] + bhh[n];
  }
  const int ar = mrow*64 + wv*16 + (lane & 15);
  const int kc = (lane >> 4) << 3;
  const int cI = lane & 15;
  const int n0 = ((cI >> 3) << 9) + jblk*8 + (cI & 7);
  const int n1 = n0 + 1024;

  f32x4 acc0 = {0,0,0,0}, acc1 = {0,0,0,0};
  #pragma unroll
  for (int ks = 0; ks < 2; ++ks){
    int k = ks*32 + kc;
    short8 ah, al;
    if (ENC){
      const float* xb = x + ar*21504 + t;
      #pragma unroll
      for (int j = 0; j < 8; ++j){ HiLo s = split1(xb[(k + j)*336]); ah[j] = s.hi; al[j] = s.lo; }
    } else {
      ah = *(const short8*)(predhi + ar*64 + k);
      al = *(const short8*)(predlo + ar*64 + k);
    }
    short8 bh0, bl0, bh1, bl1;
    ldw8s(Wihf + n0*64 + k, bh0, bl0);
    ldw8s(Wihf + n1*64 + k, bh1, bl1);
    SMACC(acc0, ah, al, bh0, bl0);
    SMACC(acc1, ah, al, bh1, bl1);
  }
  const u16* hH = hphi + ar*512 + kc;
  const u16* hL = hplo + ar*512 + kc;
  #pragma unroll 4
  for (int ks = 0; ks < 16; ++ks){
    int k = ks*32;
    short8 ah = *(const short8*)(hH + k);
    short8 al = *(const short8*)(hL + k);
    short8 bh0, bl0, bh1, bl1;
    ldw8s(Whhf + n0*512 + kc + k, bh0, bl0);
    ldw8s(Whhf + n1*512 + kc + k, bh1, bl1);
    SMACC(acc0, ah, al, bh0, bl0);
    SMACC(acc1, ah, al, bh1, bl1);
  }
  cell_epilogue_fb(gl, bs, c0, hnhi, hnlo, nullptr, mrow, jblk, acc0, acc1, wv, lane, tid);
}

__global__ void __launch_bounds__(256) l1_fb(
    const float* __restrict__ Wihf, const float* __restrict__ Whhf,
    const float* __restrict__ bih, const float* __restrict__ bhh,
    const u16* __restrict__ h0hi, const u16* __restrict__ h0lo,
    const u16* __restrict__ h1phi, const u16* __restrict__ h1plo,
    u16* __restrict__ h1nhi, u16* __restrict__ h1nlo,
    float* __restrict__ c1, float* __restrict__ gfout)
{
  __shared__ float gl[64*33];
  __shared__ float bs[32];
  const int wg = blockIdx.x, tid = threadIdx.x;
  const int mrow = wg & 3, jblk = wg >> 2;
  const int lane = tid & 63, wv = tid >> 6;
  if (tid < 32){
    int n = ((tid >> 3) << 9) + jblk*8 + (tid & 7);
    bs[tid] = bih[n] + bhh[n];
  }
  const int ar = mrow*64 + wv*16 + (lane & 15);
  const int kc = (lane >> 4) << 3;
  const int cI = lane & 15;
  const int n0 = ((cI >> 3) << 9) + jblk*8 + (cI & 7);
  const int n1 = n0 + 1024;

  f32x4 acc0 = {0,0,0,0}, acc1 = {0,0,0,0};
  {
    const u16* hH = h0hi + ar*512 + kc;
    const u16* hL = h0lo + ar*512 + kc;
    #pragma unroll 4
    for (int ks = 0; ks < 16; ++ks){
      int k = ks*32;
      short8 ah = *(const short8*)(hH + k);
      short8 al = *(const short8*)(hL + k);
      short8 bh0, bl0, bh1, bl1;
      ldw8s(Wihf + n0*512 + kc + k, bh0, bl0);
      ldw8s(Wihf + n1*512 + kc + k, bh1, bl1);
      SMACC(acc0, ah, al, bh0, bl0);
      SMACC(acc1, ah, al, bh1, bl1);
    }
  }
  {
    const u16* hH = h1phi + ar*512 + kc;
    const u16* hL = h1plo + ar*512 + kc;
    #pragma unroll 4
    for (int ks = 0; ks < 16; ++ks){
      int k = ks*32;
      short8 ah = *(const short8*)(hH + k);
      short8 al = *(const short8*)(hL + k);
      short8 bh0, bl0, bh1, bl1;
      ldw8s(Whhf + n0*512 + kc + k, bh0, bl0);
      ldw8s(Whhf + n1*512 + kc + k, bh1, bl1);
      SMACC(acc0, ah, al, bh0, bl0);
      SMACC(acc1, ah, al, bh1, bl1);
    }
  }
  cell_epilogue_fb(gl, bs, c1, h1nhi, h1nlo, gfout, mrow, jblk, acc0, acc1, wv, lane, tid);
}

__global__ void __launch_bounds__(256) pred_fb(
    const u16* __restrict__ h1hi, const u16* __restrict__ h1lo,
    const float* __restrict__ Wout, const float* __restrict__ bout,
    u16* __restrict__ predhi, u16* __restrict__ predlo,
    float* __restrict__ out, int l)
{
  const int wg = blockIdx.x, tid = threadIdx.x;
  const int bsub = tid >> 6, d = tid & 63;
  const int b = wg*4 + bsub;
  float acc = bout[d];
  const u16* hH = h1hi + b*512;
  const u16* hL = h1lo + b*512;
  const float* wr = Wout + d*512;
  #pragma unroll 8
  for (int k = 0; k < 512; k += 8){
    short8 hv = *(const short8*)(hH + k);
    short8 lv = *(const short8*)(hL + k);
    #pragma unroll
    for (int j = 0; j < 8; ++j)
      acc += (bf2f((u16)hv[j]) + bf2f((u16)lv[j])) * wr[k + j];
  }
  HiLo s = split1(acc);
  predhi[b*64 + d] = (u16)s.hi;
  predlo[b*64 + d] = (u16)s.lo;
  out[131072 + (b*64 + d)*96 + l] = acc;
}

extern "C" void kernel_launch(void* const* d_in, const int* in_sizes, int n_in,
                              void* d_out, int out_size, void* d_ws, size_t ws_size,
                              hipStream_t stream)
{
  const float* x    = (const float*)d_in[0];
  const float* Wih0 = (const float*)d_in[1];
  const float* Whh0 = (const float*)d_in[2];
  const float* bih0 = (const float*)d_in[3];
  const float* bhh0 = (const float*)d_in[4];
  const float* Wih1 = (const float*)d_in[5];
  const float* Whh1 = (const float*)d_in[6];
  const float* bih1 = (const float*)d_in[7];
  const float* bhh1 = (const float*)d_in[8];
  const float* Wout = (const float*)d_in[9];
  const float* bout = (const float*)d_in[10];
  float* out = (float*)d_out;

  // ---- ws layout (main): h 2MB | cnt 64KB | hi weights 4MB | bb 8KB
  char* ws = (char*)d_ws;
  u16* h0h[2] = { (u16*)(ws + 0),       (u16*)(ws + 262144) };
  u16* h0l[2] = { (u16*)(ws + 524288),  (u16*)(ws + 786432) };
  u16* h1h[2] = { (u16*)(ws + 1048576), (u16*)(ws + 1310720) };
  u16* h1l[2] = { (u16*)(ws + 1572864), (u16*)(ws + 1835008) };
  unsigned* cnt = (unsigned*)(ws + 2097152);
  u16* Wcmb_h = (u16*)(ws + 2162688);
  u16* W1ih_h = Wcmb_h + 1048576;
  float* bb   = (float*)(W1ih_h + 1048576);
  const size_t NEED = 2162688u + 2u*2097152u + 8192u;   // ~6.4 MB
  // fallback layout (only used when ws too small)
  float* fb_c0 = (float*)(ws + 2162688);
  float* fb_c1 = (float*)(ws + 2686976);
  u16* predh   = (u16*)(ws + 3211264);
  u16* predl   = (u16*)(ws + 3244032);
  const bool ps = (ws_size >= NEED);

  (void)hipMemsetAsync(d_ws, 0, 3276800, stream);   // h + cnt (+ fb c/pred)

  if (ps){
    wcomb_k<<<dim3(256), dim3(256), 0, stream>>>(Wih0, Wout, bout, bih0, bhh0,
                                                 Wcmb_h, bb);
    wcvt<<<dim3(4096), dim3(256), 0, stream>>>(Wih1, W1ih_h, 1048576);
    lstm_persist<<<dim3(256), dim3(256), 0, stream>>>(
        x, Whh0, Wih0, Whh1, W1ih_h, Wcmb_h, bb,
        bih0, bhh0, bih1, bhh1, Wout, bout, out, cnt,
        h0h[0], h0h[1], h0l[0], h0l[1], h1h[0], h1h[1], h1l[0], h1l[1]);
    pred_last<<<dim3(64), dim3(256), 0, stream>>>(h1h[1], h1l[1], Wout, bout, out);
  } else {
    for (int t = 0; t < 432; ++t){
      const int p = t & 1;
      float* gf = (t == 335) ? out : (float*)nullptr;
      if (t < 336)
        l0_fb<true><<<dim3(256), dim3(256), 0, stream>>>(
            x, predh, predl, Wih0, Whh0, bih0, bhh0,
            h0h[p^1], h0l[p^1], h0h[p], h0l[p], fb_c0, t);
      else
        l0_fb<false><<<dim3(256), dim3(256), 0, stream>>>(
            x, predh, predl, Wih0, Whh0, bih0, bhh0,
            h0h[p^1], h0l[p^1], h0h[p], h0l[p], fb_c0, t);
      l1_fb<<<dim3(256), dim3(256), 0, stream>>>(
          Wih1, Whh1, bih1, bhh1, h0h[p], h0l[p],
          h1h[p^1], h1l[p^1], h1h[p], h1l[p], fb_c1, gf);
      if (t >= 336)
        pred_fb<<<dim3(64), dim3(256), 0, stream>>>(
            h1h[p], h1l[p], Wout, bout, predh, predl, out, t - 336);
    }
  }
}

// Round 22
// 15439.241 us; speedup vs baseline: 1.4005x; 1.0033x over previous
//
#include <hip/hip_runtime.h>

typedef unsigned short u16;
typedef __attribute__((ext_vector_type(8))) short short8;
typedef __attribute__((ext_vector_type(4))) float f32x4;

#define AXR __ATOMIC_RELAXED, __HIP_MEMORY_SCOPE_AGENT

__device__ __forceinline__ float bf2f(u16 v){
  union { unsigned u; float f; } t; t.u = ((unsigned)v) << 16; return t.f;
}
__device__ __forceinline__ u16 f2bf(float f){
  union { float f; unsigned u; } t; t.f = f;
  unsigned u = t.u;
  return (u16)((u + 0x7fffu + ((u >> 16) & 1u)) >> 16);
}
struct HiLo { short hi, lo; };
__device__ __forceinline__ HiLo split1(float v){
  HiLo r;
  u16 h = f2bf(v);
  r.hi = (short)h;
  r.lo = (short)f2bf(v - bf2f(h));
  return r;
}
__device__ __forceinline__ void ldw8s(const float* __restrict__ p, short8& hi, short8& lo){
  #pragma unroll
  for (int j = 0; j < 8; ++j){ HiLo s = split1(p[j]); hi[j] = s.hi; lo[j] = s.lo; }
}

#define MFMA(acc, a, b) acc = __builtin_amdgcn_mfma_f32_16x16x32_bf16(a, b, acc, 0,0,0)
#define SMACC(acc, ah, al, bh, bl) do{ MFMA(acc, ah, bh); MFMA(acc, ah, bl); MFMA(acc, al, bh); }while(0)
#define SMACC2(acc, ah, al, bh) do{ MFMA(acc, ah, bh); MFMA(acc, al, bh); }while(0)

// ---- prepass: f32 -> bf16 (hi only, RNE) -----------------------------------
__global__ void wcvt(const float* __restrict__ s, u16* __restrict__ hi, int n){
  int i = blockIdx.x * blockDim.x + threadIdx.x;
  if (i < n) hi[i] = f2bf(s[i]);
}

// ---- prepass: Wcomb = Wih0 @ Wout (2048x512 bf16 hi), bb = b0 + Wih0@bout --
__global__ void __launch_bounds__(256) wcomb_k(
    const float* __restrict__ Wih0, const float* __restrict__ Wout,
    const float* __restrict__ bout, const float* __restrict__ bih0,
    const float* __restrict__ bhh0,
    u16* __restrict__ Wch, float* __restrict__ bb)
{
  __shared__ float wl[8*64];
  __shared__ float bo[64];
  const int wg = blockIdx.x, tid = threadIdx.x;
  const int r0 = wg*8;
  for (int i = tid; i < 512; i += 256) wl[i] = Wih0[(r0 + (i >> 6))*64 + (i & 63)];
  if (tid < 64) bo[tid] = bout[tid];
  __syncthreads();
  if (tid < 8){
    int n = r0 + tid;
    float a = bih0[n] + bhh0[n];
    #pragma unroll 8
    for (int d = 0; d < 64; ++d) a += wl[tid*64 + d]*bo[d];
    bb[n] = a;
  }
  #pragma unroll
  for (int jj = 0; jj < 2; ++jj){
    int j = tid + jj*256;
    float acc[8] = {0,0,0,0,0,0,0,0};
    for (int d = 0; d < 64; ++d){
      float wv = Wout[d*512 + j];
      #pragma unroll
      for (int r = 0; r < 8; ++r) acc[r] += wl[r*64 + d]*wv;
    }
    #pragma unroll
    for (int r = 0; r < 8; ++r) Wch[(r0 + r)*512 + j] = f2bf(acc[r]);
  }
}

// ---- init-only tree barrier (threadfence-based, proven R13/R14) ------------
__device__ __forceinline__ void gbar(unsigned* bar, unsigned phase){
  __syncthreads();
  if (threadIdx.x == 0){
    __threadfence();
    const unsigned gg = (unsigned)blockIdx.x >> 4;
    unsigned old = __hip_atomic_fetch_add(bar + 64 + gg*32, 1u, AXR);
    if (old == phase*16u - 1u){
      unsigned r = __hip_atomic_fetch_add(bar, 1u, AXR);
      if (r == phase*16u - 1u)
        __hip_atomic_store(bar + 32, phase, AXR);
    }
    while (__hip_atomic_load(bar + 32, AXR) < phase)
      __builtin_amdgcn_s_sleep(2);
    __threadfence();
  }
  __syncthreads();
}

// ---- global fallback barrier (R14 xbar, any WG placement) ------------------
__device__ __forceinline__ void xbar(unsigned* bar, unsigned phase,
                                     unsigned xcd, unsigned pop, unsigned nx){
  __syncthreads();
  if (threadIdx.x == 0){
    unsigned old = __hip_atomic_fetch_add(bar + 832 + xcd*32, 1u, AXR);
    const bool leader = (old == phase*pop - 1u);
    if (leader){
      asm volatile("buffer_wbl2 sc1\n\ts_waitcnt vmcnt(0)" ::: "memory");
      unsigned r = __hip_atomic_fetch_add(bar + 1344, 1u, AXR);
      if (r == phase*nx - 1u)
        __hip_atomic_store(bar + 1376, phase, AXR);
    }
    while (__hip_atomic_load(bar + 1376, AXR) < phase)
      __builtin_amdgcn_s_sleep(2);
    if (leader){
      asm volatile("buffer_inv sc1\n\ts_waitcnt vmcnt(0)" ::: "memory");
      __hip_atomic_store(bar + 1088 + xcd*32, phase, AXR);
    } else {
      while (__hip_atomic_load(bar + 1088 + xcd*32, AXR) < phase)
        __builtin_amdgcn_s_sleep(1);
      asm volatile("buffer_inv\n\ts_waitcnt vmcnt(0)" ::: "memory");
    }
  }
  __syncthreads();
}

// ---- group-local FLAG-ARRAY barrier: zero RMWs -----------------------------
// Arrival: each WG stores `phase` to its OWN flag word (128B-spaced) — all 32
// stores proceed in parallel (no same-line RMW chain at the LLC).
// Detection: lanes 0..31 of wave 0 each poll a DIFFERENT flag; SIMT masking
// makes the wave exit when ALL 32 flags reached `phase` (parallel detection).
__device__ __forceinline__ void fbar(unsigned* bar, int g, int cg,
                                     unsigned phase, int tid){
  __syncthreads();                      // data stores drained to L2 (vmcnt 0)
  unsigned* flags = bar + 4096 + g*1024;          // 32 flags x 32-word stride
  if (tid == 0)
    __hip_atomic_store(flags + cg*32, phase, AXR);
  if (tid < 64){                        // wave 0: parallel poll, lane i -> flag i
    const int i = tid & 31;
    while (__hip_atomic_load(flags + i*32, AXR) < phase)
      __builtin_amdgcn_s_sleep(1);
    asm volatile("buffer_inv\n\ts_waitcnt vmcnt(0)" ::: "memory");  // vL1 inv (per-CU)
  }
  __syncthreads();                      // release waves 1..3 (share the CU vL1)
}

// ---- LDS weight-slice helpers (XOR-swizzled, G4) ---------------------------
__device__ __forceinline__ short8 lds8(const u16* base, int r, int kelem, int rowbytes){
  int bo = r*rowbytes + ((kelem*2) ^ ((r & 7) << 4));
  return *(const short8*)((const char*)base + bo);
}
__device__ __forceinline__ void load_slice64(
    const float* __restrict__ W, int ldw, int rowshift, int nelem,
    u16* lh, u16* ll, int cg, int tid)
{
  const int rowbytes = ldw*2;
  for (int i = tid; i < nelem; i += 256){
    int r = i >> rowshift, k = i & ((1 << rowshift) - 1);
    int n = ((r >> 4) << 9) + cg*16 + (r & 15);
    HiLo s = split1(W[n*ldw + k]);
    int bo = r*rowbytes + ((k*2) ^ ((r & 7) << 4));
    *(u16*)((char*)lh + bo) = (u16)s.hi;
    *(u16*)((char*)ll + bo) = (u16)s.lo;
  }
}
__device__ __forceinline__ void load_slice64h(
    const float* __restrict__ W, int ldw, int rowshift, int nelem,
    u16* lh, int cg, int tid)
{
  const int rowbytes = ldw*2;
  for (int i = tid; i < nelem; i += 256){
    int r = i >> rowshift, k = i & ((1 << rowshift) - 1);
    int n = ((r >> 4) << 9) + cg*16 + (r & 15);
    int bo = r*rowbytes + ((k*2) ^ ((r & 7) << 4));
    *(u16*)((char*)lh + bo) = f2bf(W[n*ldw + k]);
  }
}

// ---- persistent kernel: groups derived from measured XCD id ----------------
__global__ void __launch_bounds__(256, 1) lstm_persist(
    const float* __restrict__ x,
    const float* __restrict__ Whh0, const float* __restrict__ Wih0,
    const float* __restrict__ Whh1,
    const u16* __restrict__ W1ih_h, const u16* __restrict__ Wcmb_h,
    const float* __restrict__ bb,
    const float* __restrict__ bih0, const float* __restrict__ bhh0,
    const float* __restrict__ bih1, const float* __restrict__ bhh1,
    const float* __restrict__ Wout, const float* __restrict__ bout,
    float* __restrict__ out, unsigned* __restrict__ cnt,
    u16* __restrict__ h0h0, u16* __restrict__ h0h1,
    u16* __restrict__ h0l0, u16* __restrict__ h0l1,
    u16* __restrict__ h1h0, u16* __restrict__ h1h1,
    u16* __restrict__ h1l0, u16* __restrict__ h1l1)
{
  __shared__ u16 whh0_h[32768];                  // 64x512 hi, swizzled
  __shared__ u16 w1hh_h[32768];                  // 64x512 hi, swizzled
  __shared__ u16 w0ih_h[4096],  w0ih_l[4096];    // 64x64 hi+lo, swizzled
  __shared__ float gl[32*68];                    // gate exchange
  __shared__ float pr[256];                      // pred partials [d][kq]
  __shared__ float bs0[64], bs1[64], bsd[64];
  __shared__ unsigned s_rank, s_pop, s_nx, s_all;

  const int wg = blockIdx.x, tid = threadIdx.x;
  const int lane = tid & 63, wv = tid >> 6;
  const int cI = lane & 15;
  const int kc = (lane >> 4) << 3;
  const int rl = wv*16 + cI;                     // local gate row

  // ---- census FIRST: measured XCD id + rank within XCD ----
  unsigned xcd;
  asm volatile("s_getreg_b32 %0, hwreg(HW_REG_XCC_ID)" : "=s"(xcd));
  xcd &= 7u;
  if (tid == 0)
    s_rank = __hip_atomic_fetch_add(cnt + 576 + xcd*32, 1u, AXR);
  gbar(cnt, 1);                   // all pops final
  if (tid == 0){
    unsigned nxl = 0, allc = 1;
    for (int i = 0; i < 8; ++i){
      unsigned pv = __hip_atomic_load(cnt + 576 + i*32, AXR);
      nxl += (pv != 0u) ? 1u : 0u;
      if (pv != 32u) allc = 0u;
    }
    s_pop = __hip_atomic_load(cnt + 576 + xcd*32, AXR);
    s_nx  = nxl;
    s_all = allc;
  }
  __syncthreads();
  const unsigned pop = s_pop, nx = s_nx;
  const bool allco = (s_all != 0u);
  const int g  = allco ? (int)xcd    : (wg & 7);
  const int cg = allco ? (int)s_rank : (wg >> 3);
  const int b0 = g*32;

  // ---- one-time init: LDS weight slices + biases (cg now known) ----
  load_slice64h(Whh0, 512, 9, 32768, whh0_h, cg, tid);
  load_slice64h(Whh1, 512, 9, 32768, w1hh_h, cg, tid);
  load_slice64(Wih0,  64, 6,  4096, w0ih_h, w0ih_l, cg, tid);
  if (tid < 64){
    int n = ((tid >> 4) << 9) + cg*16 + (tid & 15);
    bs0[tid] = bih0[n] + bhh0[n];
    bs1[tid] = bih1[n] + bhh1[n];
    bsd[tid] = bb[n];
  }
  __syncthreads();

  const int ar0 = b0 + cI, ar1 = b0 + 16 + cI;   // A rows (batches)
  const int aoff0 = ar0*512 + kc, aoff1 = ar1*512 + kc;
  const int nb = (wv*512 + cg*16 + cI)*512 + kc; // streamed weight frag base

  u16* H0h[2] = { h0h0, h0h1 };  u16* H0l[2] = { h0l0, h0l1 };
  u16* H1h[2] = { h1h0, h1h1 };  u16* H1l[2] = { h1l0, h1l1 };

  const float* xb0 = x + ar0*21504;
  const float* xb1 = x + ar1*21504;

  float c0r[2] = {0.f, 0.f}, c1r[2] = {0.f, 0.f};   // cell state in registers
  unsigned ep = 0;

  const int sk1 = g*2;            // per-XCD K-chunk skew
  const int sk2 = (g >> 1)*4;

  for (int t = 0; t < 432; ++t){
    const int p = t & 1;
    const bool enc = (t < 336);

    // =============== phase A: layer 0 ===============
    f32x4 A0 = {0,0,0,0}, A1 = {0,0,0,0};
    if (enc){
      #pragma unroll
      for (int ks = 0; ks < 2; ++ks){            // x segment (K=64), split
        int k = ks*32 + kc;
        short8 a0h, a0l, a1h, a1l;
        #pragma unroll
        for (int j = 0; j < 8; ++j){
          HiLo s0 = split1(xb0[(k + j)*336 + t]); a0h[j] = s0.hi; a0l[j] = s0.lo;
          HiLo s1 = split1(xb1[(k + j)*336 + t]); a1h[j] = s1.hi; a1l[j] = s1.lo;
        }
        short8 bh = lds8(w0ih_h, rl, k, 128);
        short8 bl = lds8(w0ih_l, rl, k, 128);
        SMACC(A0, a0h, a0l, bh, bl);
        SMACC(A1, a1h, a1l, bh, bl);
      }
    } else if (t > 336){                         // Wcomb (hi, streamed) over h1_{t-1}
      const u16* hH = H1h[p^1]; const u16* hL = H1l[p^1];
      const u16* wh = Wcmb_h + nb;
      #pragma unroll 4
      for (int kss = 0; kss < 16; ++kss){
        int k = ((kss + sk1) & 15)*32;
        short8 a0h = *(const short8*)(hH + aoff0 + k);
        short8 a0l = *(const short8*)(hL + aoff0 + k);
        short8 a1h = *(const short8*)(hH + aoff1 + k);
        short8 a1l = *(const short8*)(hL + aoff1 + k);
        short8 bh = *(const short8*)(wh + k);
        SMACC2(A0, a0h, a0l, bh);
        SMACC2(A1, a1h, a1l, bh);
      }
    }
    {                                            // Whh0 (LDS hi) over h0_{t-1}
      const u16* hH = H0h[p^1]; const u16* hL = H0l[p^1];
      #pragma unroll 4
      for (int ks = 0; ks < 16; ++ks){
        int k = ks*32;
        short8 a0h = *(const short8*)(hH + aoff0 + k);
        short8 a0l = *(const short8*)(hL + aoff0 + k);
        short8 a1h = *(const short8*)(hH + aoff1 + k);
        short8 a1l = *(const short8*)(hL + aoff1 + k);
        short8 bh = lds8(whh0_h, rl, kc + k, 1024);
        SMACC2(A0, a0h, a0l, bh);
        SMACC2(A1, a1h, a1l, bh);
      }
    }
    // decoder pred l=t-337 from h1_{t-1}: this WG owns batch b0+cg
    if (!enc && t > 336){
      const int d = tid & 63, kq = tid >> 6;
      const int b = b0 + cg;
      const u16* hH = H1h[p^1] + b*512 + kq*128;
      const u16* hL = H1l[p^1] + b*512 + kq*128;
      const float* wr = Wout + d*512 + kq*128;
      float part = 0.f;
      #pragma unroll 4
      for (int k = 0; k < 128; k += 8){
        short8 hv = *(const short8*)(hH + k);
        short8 lv = *(const short8*)(hL + k);
        #pragma unroll
        for (int j = 0; j < 8; ++j)
          part += (bf2f((u16)hv[j]) + bf2f((u16)lv[j])) * wr[k + j];
      }
      pr[d*4 + kq] = part;
      __syncthreads();
      if (tid < 64){
        float v = pr[tid*4] + pr[tid*4+1] + pr[tid*4+2] + pr[tid*4+3] + bout[tid];
        out[131072 + (b*64 + tid)*96 + (t - 337)] = v;
      }
    }
    // cell update layer 0 (c in registers)
    {
      const float* bias = (enc || t == 336) ? bs0 : bsd;
      __syncthreads();
      const int rb_ = (lane >> 4) << 2;
      #pragma unroll
      for (int r = 0; r < 4; ++r){
        gl[(rb_ + r)*68 + rl]      = A0[r] + bias[rl];
        gl[(16 + rb_ + r)*68 + rl] = A1[r] + bias[rl];
      }
      __syncthreads();
      u16* Hh = H0h[p]; u16* Hl = H0l[p];
      #pragma unroll
      for (int q = 0; q < 2; ++q){
        int e = tid + q*256;
        int m = e >> 4, col = e & 15;
        float iv = gl[m*68 + col];
        float fv = gl[m*68 + 16 + col];
        float gv = gl[m*68 + 32 + col];
        float ov = gl[m*68 + 48 + col];
        float si = 1.f/(1.f + expf(-iv));
        float sf = 1.f/(1.f + expf(-fv));
        float so = 1.f/(1.f + expf(-ov));
        float cn = sf*c0r[q] + si*tanhf(gv);
        c0r[q] = cn;
        float h = so*tanhf(cn);
        int gi = (b0 + m)*512 + cg*16 + col;
        u16 hh = f2bf(h);
        Hh[gi] = hh;
        Hl[gi] = f2bf(h - bf2f(hh));
      }
    }
    ++ep;
    if (allco) fbar(cnt, g, cg, ep, tid); else xbar(cnt, ep, xcd, pop, nx);

    // =============== phase B: layer 1 ===============
    A0 = (f32x4){0,0,0,0}; A1 = (f32x4){0,0,0,0};
    {                                            // W1ih (hi, streamed) over h0_t
      const u16* hH = H0h[p]; const u16* hL = H0l[p];
      const u16* wh = W1ih_h + nb;
      #pragma unroll 4
      for (int kss = 0; kss < 16; ++kss){
        int k = ((kss + sk2) & 15)*32;
        short8 a0h = *(const short8*)(hH + aoff0 + k);
        short8 a0l = *(const short8*)(hL + aoff0 + k);
        short8 a1h = *(const short8*)(hH + aoff1 + k);
        short8 a1l = *(const short8*)(hL + aoff1 + k);
        short8 bh = *(const short8*)(wh + k);
        SMACC2(A0, a0h, a0l, bh);
        SMACC2(A1, a1h, a1l, bh);
      }
    }
    {                                            // W1hh (LDS hi) over h1_{t-1}
      const u16* hH = H1h[p^1]; const u16* hL = H1l[p^1];
      #pragma unroll 4
      for (int ks = 0; ks < 16; ++ks){
        int k = ks*32;
        short8 a0h = *(const short8*)(hH + aoff0 + k);
        short8 a0l = *(const short8*)(hL + aoff0 + k);
        short8 a1h = *(const short8*)(hH + aoff1 + k);
        short8 a1l = *(const short8*)(hL + aoff1 + k);
        short8 bh = lds8(w1hh_h, rl, kc + k, 1024);
        SMACC2(A0, a0h, a0l, bh);
        SMACC2(A1, a1h, a1l, bh);
      }
    }
    // cell update layer 1
    {
      float* gf = (t == 335) ? out : (float*)nullptr;
      __syncthreads();
      const int rb_ = (lane >> 4) << 2;
      #pragma unroll
      for (int r = 0; r < 4; ++r){
        gl[(rb_ + r)*68 + rl]      = A0[r] + bs1[rl];
        gl[(16 + rb_ + r)*68 + rl] = A1[r] + bs1[rl];
      }
      __syncthreads();
      u16* Hh = H1h[p]; u16* Hl = H1l[p];
      #pragma unroll
      for (int q = 0; q < 2; ++q){
        int e = tid + q*256;
        int m = e >> 4, col = e & 15;
        float iv = gl[m*68 + col];
        float fv = gl[m*68 + 16 + col];
        float gv = gl[m*68 + 32 + col];
        float ov = gl[m*68 + 48 + col];
        float si = 1.f/(1.f + expf(-iv));
        float sf = 1.f/(1.f + expf(-fv));
        float so = 1.f/(1.f + expf(-ov));
        float cn = sf*c1r[q] + si*tanhf(gv);
        c1r[q] = cn;
        float h = so*tanhf(cn);
        int gi = (b0 + m)*512 + cg*16 + col;
        u16 hh = f2bf(h);
        Hh[gi] = hh;
        Hl[gi] = f2bf(h - bf2f(hh));
        if (gf) gf[gi] = h;
      }
    }
    ++ep;
    if (allco) fbar(cnt, g, cg, ep, tid); else xbar(cnt, ep, xcd, pop, nx);
  }
}

// ---- tail: pred for l=95 from h1_431 (parity 1) ----------------------------
__global__ void __launch_bounds__(256) pred_last(
    const u16* __restrict__ h1hi, const u16* __restrict__ h1lo,
    const float* __restrict__ Wout, const float* __restrict__ bout,
    float* __restrict__ out)
{
  const int wg = blockIdx.x, tid = threadIdx.x;
  const int bsub = tid >> 6, d = tid & 63;
  const int b = wg*4 + bsub;
  float acc = bout[d];
  const u16* hH = h1hi + b*512;
  const u16* hL = h1lo + b*512;
  const float* wr = Wout + d*512;
  #pragma unroll 8
  for (int k = 0; k < 512; k += 8){
    short8 hv = *(const short8*)(hH + k);
    short8 lv = *(const short8*)(hL + k);
    #pragma unroll
    for (int j = 0; j < 8; ++j)
      acc += (bf2f((u16)hv[j]) + bf2f((u16)lv[j])) * wr[k + j];
  }
  out[131072 + (b*64 + d)*96 + 95] = acc;
}

// ======================= fallback (R9 proven path) ==========================
__device__ __forceinline__ void cell_epilogue_fb(
    float* gl, const float* bs, float* __restrict__ cbuf,
    u16* __restrict__ hhi, u16* __restrict__ hlo,
    float* __restrict__ gfout, int mrow, int jblk,
    const f32x4& a0, const f32x4& a1, int wv, int lane, int tid)
{
  __syncthreads();
  const int rbase = wv*16 + ((lane >> 4) << 2);
  const int cI = lane & 15;
  #pragma unroll
  for (int r = 0; r < 4; ++r){
    gl[(rbase+r)*33 + cI]      = a0[r] + bs[cI];
    gl[(rbase+r)*33 + 16 + cI] = a1[r] + bs[16 + cI];
  }
  __syncthreads();
  #pragma unroll
  for (int q = 0; q < 2; ++q){
    int e = tid + q*256;
    int m = e >> 3, jj = e & 7;
    float iv = gl[m*33 + jj];
    float fv = gl[m*33 + 8 + jj];
    float gv = gl[m*33 + 16 + jj];
    float ov = gl[m*33 + 24 + jj];
    float si = 1.f/(1.f + expf(-iv));
    float sf = 1.f/(1.f + expf(-fv));
    float so = 1.f/(1.f + expf(-ov));
    int gi = (mrow*64 + m)*512 + jblk*8 + jj;
    float cn = sf*cbuf[gi] + si*tanhf(gv);
    cbuf[gi] = cn;
    float h = so*tanhf(cn);
    u16 hh = f2bf(h);
    hhi[gi] = hh;
    hlo[gi] = f2bf(h - bf2f(hh));
    if (gfout) gfout[gi] = h;
  }
}

template<bool ENC>
__global__ void __launch_bounds__(256) l0_fb(
    const float* __restrict__ x,
    const u16* __restrict__ predhi, const u16* __restrict__ predlo,
    const float* __restrict__ Wihf, const float* __restrict__ Whhf,
    const float* __restrict__ bih, const float* __restrict__ bhh,
    const u16* __restrict__ hphi, const u16* __restrict__ hplo,
    u16* __restrict__ hnhi, u16* __restrict__ hnlo,
    float* __restrict__ c0, int t)
{
  __shared__ float gl[64*33];
  __shared__ float bs[32];
  const int wg = blockIdx.x, tid = threadIdx.x;
  const int mrow = wg & 3, jblk = wg >> 2;
  const int lane = tid & 63, wv = tid >> 6;
  if (tid < 32){
    int n = ((tid >> 3) << 9) + jblk*8 + (tid & 7);
    bs[tid] = bih[n] + bhh[n];
  }
  const int ar = mrow*64 + wv*16 + (lane & 15);
  const int kc = (lane >> 4) << 3;
  const int cI = lane & 15;
  const int n0 = ((cI >> 3) << 9) + jblk*8 + (cI & 7);
  const int n1 = n0 + 1024;

  f32x4 acc0 = {0,0,0,0}, acc1 = {0,0,0,0};
  #pragma unroll
  for (int ks = 0; ks < 2; ++ks){
    int k = ks*32 + kc;
    short8 ah, al;
    if (ENC){
      const float* xb = x + ar*21504 + t;
      #pragma unroll
      for (int j = 0; j < 8; ++j){ HiLo s = split1(xb[(k + j)*336]); ah[j] = s.hi; al[j] = s.lo; }
    } else {
      ah = *(const short8*)(predhi + ar*64 + k);
      al = *(const short8*)(predlo + ar*64 + k);
    }
    short8 bh0, bl0, bh1, bl1;
    ldw8s(Wihf + n0*64 + k, bh0, bl0);
    ldw8s(Wihf + n1*64 + k, bh1, bl1);
    SMACC(acc0, ah, al, bh0, bl0);
    SMACC(acc1, ah, al, bh1, bl1);
  }
  const u16* hH = hphi + ar*512 + kc;
  const u16* hL = hplo + ar*512 + kc;
  #pragma unroll 4
  for (int ks = 0; ks < 16; ++ks){
    int k = ks*32;
    short8 ah = *(const short8*)(hH + k);
    short8 al = *(const short8*)(hL + k);
    short8 bh0, bl0, bh1, bl1;
    ldw8s(Whhf + n0*512 + kc + k, bh0, bl0);
    ldw8s(Whhf + n1*512 + kc + k, bh1, bl1);
    SMACC(acc0, ah, al, bh0, bl0);
    SMACC(acc1, ah, al, bh1, bl1);
  }
  cell_epilogue_fb(gl, bs, c0, hnhi, hnlo, nullptr, mrow, jblk, acc0, acc1, wv, lane, tid);
}

__global__ void __launch_bounds__(256) l1_fb(
    const float* __restrict__ Wihf, const float* __restrict__ Whhf,
    const float* __restrict__ bih, const float* __restrict__ bhh,
    const u16* __restrict__ h0hi, const u16* __restrict__ h0lo,
    const u16* __restrict__ h1phi, const u16* __restrict__ h1plo,
    u16* __restrict__ h1nhi, u16* __restrict__ h1nlo,
    float* __restrict__ c1, float* __restrict__ gfout)
{
  __shared__ float gl[64*33];
  __shared__ float bs[32];
  const int wg = blockIdx.x, tid = threadIdx.x;
  const int mrow = wg & 3, jblk = wg >> 2;
  const int lane = tid & 63, wv = tid >> 6;
  if (tid < 32){
    int n = ((tid >> 3) << 9) + jblk*8 + (tid & 7);
    bs[tid] = bih[n] + bhh[n];
  }
  const int ar = mrow*64 + wv*16 + (lane & 15);
  const int kc = (lane >> 4) << 3;
  const int cI = lane & 15;
  const int n0 = ((cI >> 3) << 9) + jblk*8 + (cI & 7);
  const int n1 = n0 + 1024;

  f32x4 acc0 = {0,0,0,0}, acc1 = {0,0,0,0};
  {
    const u16* hH = h0hi + ar*512 + kc;
    const u16* hL = h0lo + ar*512 + kc;
    #pragma unroll 4
    for (int ks = 0; ks < 16; ++ks){
      int k = ks*32;
      short8 ah = *(const short8*)(hH + k);
      short8 al = *(const short8*)(hL + k);
      short8 bh0, bl0, bh1, bl1;
      ldw8s(Wihf + n0*512 + kc + k, bh0, bl0);
      ldw8s(Wihf + n1*512 + kc + k, bh1, bl1);
      SMACC(acc0, ah, al, bh0, bl0);
      SMACC(acc1, ah, al, bh1, bl1);
    }
  }
  {
    const u16* hH = h1phi + ar*512 + kc;
    const u16* hL = h1plo + ar*512 + kc;
    #pragma unroll 4
    for (int ks = 0; ks < 16; ++ks){
      int k = ks*32;
      short8 ah = *(const short8*)(hH + k);
      short8 al = *(const short8*)(hL + k);
      short8 bh0, bl0, bh1, bl1;
      ldw8s(Whhf + n0*512 + kc + k, bh0, bl0);
      ldw8s(Whhf + n1*512 + kc + k, bh1, bl1);
      SMACC(acc0, ah, al, bh0, bl0);
      SMACC(acc1, ah, al, bh1, bl1);
    }
  }
  cell_epilogue_fb(gl, bs, c1, h1nhi, h1nlo, gfout, mrow, jblk, acc0, acc1, wv, lane, tid);
}

__global__ void __launch_bounds__(256) pred_fb(
    const u16* __restrict__ h1hi, const u16* __restrict__ h1lo,
    const float* __restrict__ Wout, const float* __restrict__ bout,
    u16* __restrict__ predhi, u16* __restrict__ predlo,
    float* __restrict__ out, int l)
{
  const int wg = blockIdx.x, tid = threadIdx.x;
  const int bsub = tid >> 6, d = tid & 63;
  const int b = wg*4 + bsub;
  float acc = bout[d];
  const u16* hH = h1hi + b*512;
  const u16* hL = h1lo + b*512;
  const float* wr = Wout + d*512;
  #pragma unroll 8
  for (int k = 0; k < 512; k += 8){
    short8 hv = *(const short8*)(hH + k);
    short8 lv = *(const short8*)(hL + k);
    #pragma unroll
    for (int j = 0; j < 8; ++j)
      acc += (bf2f((u16)hv[j]) + bf2f((u16)lv[j])) * wr[k + j];
  }
  HiLo s = split1(acc);
  predhi[b*64 + d] = (u16)s.hi;
  predlo[b*64 + d] = (u16)s.lo;
  out[131072 + (b*64 + d)*96 + l] = acc;
}

extern "C" void kernel_launch(void* const* d_in, const int* in_sizes, int n_in,
                              void* d_out, int out_size, void* d_ws, size_t ws_size,
                              hipStream_t stream)
{
  const float* x    = (const float*)d_in[0];
  const float* Wih0 = (const float*)d_in[1];
  const float* Whh0 = (const float*)d_in[2];
  const float* bih0 = (const float*)d_in[3];
  const float* bhh0 = (const float*)d_in[4];
  const float* Wih1 = (const float*)d_in[5];
  const float* Whh1 = (const float*)d_in[6];
  const float* bih1 = (const float*)d_in[7];
  const float* bhh1 = (const float*)d_in[8];
  const float* Wout = (const float*)d_in[9];
  const float* bout = (const float*)d_in[10];
  float* out = (float*)d_out;

  // ---- ws layout (main): h 2MB | cnt 64KB | hi weights 4MB | bb 8KB
  char* ws = (char*)d_ws;
  u16* h0h[2] = { (u16*)(ws + 0),       (u16*)(ws + 262144) };
  u16* h0l[2] = { (u16*)(ws + 524288),  (u16*)(ws + 786432) };
  u16* h1h[2] = { (u16*)(ws + 1048576), (u16*)(ws + 1310720) };
  u16* h1l[2] = { (u16*)(ws + 1572864), (u16*)(ws + 1835008) };
  unsigned* cnt = (unsigned*)(ws + 2097152);
  u16* Wcmb_h = (u16*)(ws + 2162688);
  u16* W1ih_h = Wcmb_h + 1048576;
  float* bb   = (float*)(W1ih_h + 1048576);
  const size_t NEED = 2162688u + 2u*2097152u + 8192u;   // ~6.4 MB
  // fallback layout (only used when ws too small)
  float* fb_c0 = (float*)(ws + 2162688);
  float* fb_c1 = (float*)(ws + 2686976);
  u16* predh   = (u16*)(ws + 3211264);
  u16* predl   = (u16*)(ws + 3244032);
  const bool ps = (ws_size >= NEED);

  (void)hipMemsetAsync(d_ws, 0, 3276800, stream);   // h + cnt/flags (+ fb c/pred)

  if (ps){
    wcomb_k<<<dim3(256), dim3(256), 0, stream>>>(Wih0, Wout, bout, bih0, bhh0,
                                                 Wcmb_h, bb);
    wcvt<<<dim3(4096), dim3(256), 0, stream>>>(Wih1, W1ih_h, 1048576);
    lstm_persist<<<dim3(256), dim3(256), 0, stream>>>(
        x, Whh0, Wih0, Whh1, W1ih_h, Wcmb_h, bb,
        bih0, bhh0, bih1, bhh1, Wout, bout, out, cnt,
        h0h[0], h0h[1], h0l[0], h0l[1], h1h[0], h1h[1], h1l[0], h1l[1]);
    pred_last<<<dim3(64), dim3(256), 0, stream>>>(h1h[1], h1l[1], Wout, bout, out);
  } else {
    for (int t = 0; t < 432; ++t){
      const int p = t & 1;
      float* gf = (t == 335) ? out : (float*)nullptr;
      if (t < 336)
        l0_fb<true><<<dim3(256), dim3(256), 0, stream>>>(
            x, predh, predl, Wih0, Whh0, bih0, bhh0,
            h0h[p^1], h0l[p^1], h0h[p], h0l[p], fb_c0, t);
      else
        l0_fb<false><<<dim3(256), dim3(256), 0, stream>>>(
            x, predh, predl, Wih0, Whh0, bih0, bhh0,
            h0h[p^1], h0l[p^1], h0h[p], h0l[p], fb_c0, t);
      l1_fb<<<dim3(256), dim3(256), 0, stream>>>(
          Wih1, Whh1, bih1, bhh1, h0h[p], h0l[p],
          h1h[p^1], h1l[p^1], h1h[p], h1l[p], fb_c1, gf);
      if (t >= 336)
        pred_fb<<<dim3(64), dim3(256), 0, stream>>>(
            h1h[p], h1l[p], Wout, bout, predh, predl, out, t - 336);
    }
  }
}

// Round 23
// 14878.479 us; speedup vs baseline: 1.4533x; 1.0377x over previous
//
#include <hip/hip_runtime.h>

typedef unsigned short u16;
typedef __attribute__((ext_vector_type(8))) short short8;
typedef __attribute__((ext_vector_type(4))) float f32x4;

#define AXR __ATOMIC_RELAXED, __HIP_MEMORY_SCOPE_AGENT

__device__ __forceinline__ float bf2f(u16 v){
  union { unsigned u; float f; } t; t.u = ((unsigned)v) << 16; return t.f;
}
__device__ __forceinline__ u16 f2bf(float f){
  union { float f; unsigned u; } t; t.f = f;
  unsigned u = t.u;
  return (u16)((u + 0x7fffu + ((u >> 16) & 1u)) >> 16);
}
struct HiLo { short hi, lo; };
__device__ __forceinline__ HiLo split1(float v){
  HiLo r;
  u16 h = f2bf(v);
  r.hi = (short)h;
  r.lo = (short)f2bf(v - bf2f(h));
  return r;
}
__device__ __forceinline__ void ldw8s(const float* __restrict__ p, short8& hi, short8& lo){
  #pragma unroll
  for (int j = 0; j < 8; ++j){ HiLo s = split1(p[j]); hi[j] = s.hi; lo[j] = s.lo; }
}

#define MFMA(acc, a, b) acc = __builtin_amdgcn_mfma_f32_16x16x32_bf16(a, b, acc, 0,0,0)
#define SMACC(acc, ah, al, bh, bl) do{ MFMA(acc, ah, bh); MFMA(acc, ah, bl); MFMA(acc, al, bh); }while(0)
#define SMACC2(acc, ah, al, bh) do{ MFMA(acc, ah, bh); MFMA(acc, al, bh); }while(0)

// ---- prepass: f32 -> bf16 (hi only, RNE) -----------------------------------
__global__ void wcvt(const float* __restrict__ s, u16* __restrict__ hi, int n){
  int i = blockIdx.x * blockDim.x + threadIdx.x;
  if (i < n) hi[i] = f2bf(s[i]);
}

// ---- prepass: Wcomb = Wih0 @ Wout (2048x512 bf16 hi), bb = b0 + Wih0@bout --
__global__ void __launch_bounds__(256) wcomb_k(
    const float* __restrict__ Wih0, const float* __restrict__ Wout,
    const float* __restrict__ bout, const float* __restrict__ bih0,
    const float* __restrict__ bhh0,
    u16* __restrict__ Wch, float* __restrict__ bb)
{
  __shared__ float wl[8*64];
  __shared__ float bo[64];
  const int wg = blockIdx.x, tid = threadIdx.x;
  const int r0 = wg*8;
  for (int i = tid; i < 512; i += 256) wl[i] = Wih0[(r0 + (i >> 6))*64 + (i & 63)];
  if (tid < 64) bo[tid] = bout[tid];
  __syncthreads();
  if (tid < 8){
    int n = r0 + tid;
    float a = bih0[n] + bhh0[n];
    #pragma unroll 8
    for (int d = 0; d < 64; ++d) a += wl[tid*64 + d]*bo[d];
    bb[n] = a;
  }
  #pragma unroll
  for (int jj = 0; jj < 2; ++jj){
    int j = tid + jj*256;
    float acc[8] = {0,0,0,0,0,0,0,0};
    for (int d = 0; d < 64; ++d){
      float wv = Wout[d*512 + j];
      #pragma unroll
      for (int r = 0; r < 8; ++r) acc[r] += wl[r*64 + d]*wv;
    }
    #pragma unroll
    for (int r = 0; r < 8; ++r) Wch[(r0 + r)*512 + j] = f2bf(acc[r]);
  }
}

// ---- init-only tree barrier (threadfence-based, proven R13/R14) ------------
__device__ __forceinline__ void gbar(unsigned* bar, unsigned phase){
  __syncthreads();
  if (threadIdx.x == 0){
    __threadfence();
    const unsigned gg = (unsigned)blockIdx.x >> 4;
    unsigned old = __hip_atomic_fetch_add(bar + 64 + gg*32, 1u, AXR);
    if (old == phase*16u - 1u){
      unsigned r = __hip_atomic_fetch_add(bar, 1u, AXR);
      if (r == phase*16u - 1u)
        __hip_atomic_store(bar + 32, phase, AXR);
    }
    while (__hip_atomic_load(bar + 32, AXR) < phase)
      __builtin_amdgcn_s_sleep(2);
    __threadfence();
  }
  __syncthreads();
}

// ---- global fallback barrier (R14 xbar, any WG placement) ------------------
__device__ __forceinline__ void xbar(unsigned* bar, unsigned phase,
                                     unsigned xcd, unsigned pop, unsigned nx){
  __syncthreads();
  if (threadIdx.x == 0){
    unsigned old = __hip_atomic_fetch_add(bar + 832 + xcd*32, 1u, AXR);
    const bool leader = (old == phase*pop - 1u);
    if (leader){
      asm volatile("buffer_wbl2 sc1\n\ts_waitcnt vmcnt(0)" ::: "memory");
      unsigned r = __hip_atomic_fetch_add(bar + 1344, 1u, AXR);
      if (r == phase*nx - 1u)
        __hip_atomic_store(bar + 1376, phase, AXR);
    }
    while (__hip_atomic_load(bar + 1376, AXR) < phase)
      __builtin_amdgcn_s_sleep(2);
    if (leader){
      asm volatile("buffer_inv sc1\n\ts_waitcnt vmcnt(0)" ::: "memory");
      __hip_atomic_store(bar + 1088 + xcd*32, phase, AXR);
    } else {
      while (__hip_atomic_load(bar + 1088 + xcd*32, AXR) < phase)
        __builtin_amdgcn_s_sleep(1);
      asm volatile("buffer_inv\n\ts_waitcnt vmcnt(0)" ::: "memory");
    }
  }
  __syncthreads();
}

// ---- group-local FLAG-ARRAY barrier (R22): zero RMWs -----------------------
__device__ __forceinline__ void fbar(unsigned* bar, int g, int cg,
                                     unsigned phase, int tid){
  __syncthreads();
  unsigned* flags = bar + 4096 + g*1024;
  if (tid == 0)
    __hip_atomic_store(flags + cg*32, phase, AXR);
  if (tid < 64){
    const int i = tid & 31;
    while (__hip_atomic_load(flags + i*32, AXR) < phase)
      __builtin_amdgcn_s_sleep(1);
    asm volatile("buffer_inv\n\ts_waitcnt vmcnt(0)" ::: "memory");
  }
  __syncthreads();
}

// ---- LDS weight-slice helpers (XOR-swizzled, G4) ---------------------------
__device__ __forceinline__ short8 lds8(const u16* base, int r, int kelem, int rowbytes){
  int bo = r*rowbytes + ((kelem*2) ^ ((r & 7) << 4));
  return *(const short8*)((const char*)base + bo);
}
__device__ __forceinline__ void load_slice64(
    const float* __restrict__ W, int ldw, int rowshift, int nelem,
    u16* lh, u16* ll, int cg, int tid)
{
  const int rowbytes = ldw*2;
  for (int i = tid; i < nelem; i += 256){
    int r = i >> rowshift, k = i & ((1 << rowshift) - 1);
    int n = ((r >> 4) << 9) + cg*16 + (r & 15);
    HiLo s = split1(W[n*ldw + k]);
    int bo = r*rowbytes + ((k*2) ^ ((r & 7) << 4));
    *(u16*)((char*)lh + bo) = (u16)s.hi;
    *(u16*)((char*)ll + bo) = (u16)s.lo;
  }
}
__device__ __forceinline__ void load_slice64h(
    const float* __restrict__ W, int ldw, int rowshift, int nelem,
    u16* lh, int cg, int tid)
{
  const int rowbytes = ldw*2;
  for (int i = tid; i < nelem; i += 256){
    int r = i >> rowshift, k = i & ((1 << rowshift) - 1);
    int n = ((r >> 4) << 9) + cg*16 + (r & 15);
    int bo = r*rowbytes + ((k*2) ^ ((r & 7) << 4));
    *(u16*)((char*)lh + bo) = f2bf(W[n*ldw + k]);
  }
}

// ---- persistent kernel: SKEWED pipeline (phase k -> h0_k AND h1_{k-1}) -----
__global__ void __launch_bounds__(256, 1) lstm_persist(
    const float* __restrict__ x,
    const float* __restrict__ Whh0, const float* __restrict__ Wih0,
    const float* __restrict__ Whh1,
    const u16* __restrict__ W1ih_h, const u16* __restrict__ Wcmb_h,
    const float* __restrict__ bb,
    const float* __restrict__ bih0, const float* __restrict__ bhh0,
    const float* __restrict__ bih1, const float* __restrict__ bhh1,
    const float* __restrict__ Wout, const float* __restrict__ bout,
    float* __restrict__ out, unsigned* __restrict__ cnt,
    u16* __restrict__ h0h0, u16* __restrict__ h0h1,
    u16* __restrict__ h0l0, u16* __restrict__ h0l1,
    u16* __restrict__ h1h0, u16* __restrict__ h1h1,
    u16* __restrict__ h1l0, u16* __restrict__ h1l1)
{
  __shared__ u16 whh0_h[32768];                  // 64x512 hi, swizzled
  __shared__ u16 w1hh_h[32768];                  // 64x512 hi, swizzled
  __shared__ u16 w0ih_h[4096],  w0ih_l[4096];    // 64x64 hi+lo, swizzled
  __shared__ float gl[32*68];                    // gate exchange
  __shared__ float pr[256];                      // pred partials [d][kq]
  __shared__ float bs0[64], bs1[64], bsd[64];
  __shared__ unsigned s_rank, s_pop, s_nx, s_all;

  const int wg = blockIdx.x, tid = threadIdx.x;
  const int lane = tid & 63, wv = tid >> 6;
  const int cI = lane & 15;
  const int kc = (lane >> 4) << 3;
  const int rl = wv*16 + cI;                     // local gate row

  // ---- census: measured XCD id + rank within XCD ----
  unsigned xcd;
  asm volatile("s_getreg_b32 %0, hwreg(HW_REG_XCC_ID)" : "=s"(xcd));
  xcd &= 7u;
  if (tid == 0)
    s_rank = __hip_atomic_fetch_add(cnt + 576 + xcd*32, 1u, AXR);
  gbar(cnt, 1);
  if (tid == 0){
    unsigned nxl = 0, allc = 1;
    for (int i = 0; i < 8; ++i){
      unsigned pv = __hip_atomic_load(cnt + 576 + i*32, AXR);
      nxl += (pv != 0u) ? 1u : 0u;
      if (pv != 32u) allc = 0u;
    }
    s_pop = __hip_atomic_load(cnt + 576 + xcd*32, AXR);
    s_nx  = nxl;
    s_all = allc;
  }
  __syncthreads();
  const unsigned pop = s_pop, nx = s_nx;
  const bool allco = (s_all != 0u);
  const int g  = allco ? (int)xcd    : (wg & 7);
  const int cg = allco ? (int)s_rank : (wg >> 3);
  const int b0 = g*32;

  // ---- one-time init: LDS weight slices + biases ----
  load_slice64h(Whh0, 512, 9, 32768, whh0_h, cg, tid);
  load_slice64h(Whh1, 512, 9, 32768, w1hh_h, cg, tid);
  load_slice64(Wih0,  64, 6,  4096, w0ih_h, w0ih_l, cg, tid);
  if (tid < 64){
    int n = ((tid >> 4) << 9) + cg*16 + (tid & 15);
    bs0[tid] = bih0[n] + bhh0[n];
    bs1[tid] = bih1[n] + bhh1[n];
    bsd[tid] = bb[n];
  }
  __syncthreads();

  const int ar0 = b0 + cI, ar1 = b0 + 16 + cI;   // A rows (batches)
  const int aoff0 = ar0*512 + kc, aoff1 = ar1*512 + kc;
  const int nb = (wv*512 + cg*16 + cI)*512 + kc; // streamed weight frag base

  u16* H0h[2] = { h0h0, h0h1 };  u16* H0l[2] = { h0l0, h0l1 };
  u16* H1h[2] = { h1h0, h1h1 };  u16* H1l[2] = { h1l0, h1l1 };

  const float* xb0 = x + ar0*21504;
  const float* xb1 = x + ar1*21504;

  float c0r[2] = {0.f, 0.f}, c1r[2] = {0.f, 0.f};
  unsigned ep = 0;

  const int sk1 = g*2;
  const int sk2 = (g >> 1)*4;
  const int rb_ = (lane >> 4) << 2;

  // ======== skewed encoder: phase k computes h0_k and h1_{k-1} ========
  for (int k = 0; k <= 336; ++k){
    const int p0 = k & 1;                        // h0_k write parity

    // ---- l0 MFMA -> A0,A1 (gates for h0_k)
    f32x4 A0 = {0,0,0,0}, A1 = {0,0,0,0};
    if (k < 336){
      #pragma unroll
      for (int ks = 0; ks < 2; ++ks){            // x segment (K=64), split
        int kk = ks*32 + kc;
        short8 a0h, a0l, a1h, a1l;
        #pragma unroll
        for (int j = 0; j < 8; ++j){
          HiLo s0 = split1(xb0[(kk + j)*336 + k]); a0h[j] = s0.hi; a0l[j] = s0.lo;
          HiLo s1 = split1(xb1[(kk + j)*336 + k]); a1h[j] = s1.hi; a1l[j] = s1.lo;
        }
        short8 bh = lds8(w0ih_h, rl, kk, 128);
        short8 bl = lds8(w0ih_l, rl, kk, 128);
        SMACC(A0, a0h, a0l, bh, bl);
        SMACC(A1, a1h, a1l, bh, bl);
      }
    }
    {                                            // Whh0 (LDS hi) over h0_{k-1}
      const u16* hH = H0h[p0^1]; const u16* hL = H0l[p0^1];
      #pragma unroll 4
      for (int ks = 0; ks < 16; ++ks){
        int kk = ks*32;
        short8 a0h = *(const short8*)(hH + aoff0 + kk);
        short8 a0l = *(const short8*)(hL + aoff0 + kk);
        short8 a1h = *(const short8*)(hH + aoff1 + kk);
        short8 a1l = *(const short8*)(hL + aoff1 + kk);
        short8 bh = lds8(whh0_h, rl, kc + kk, 1024);
        SMACC2(A0, a0h, a0l, bh);
        SMACC2(A1, a1h, a1l, bh);
      }
    }

    // ---- l1 MFMA -> B0,B1 (gates for h1_{k-1}), k>=1
    f32x4 B0 = {0,0,0,0}, B1 = {0,0,0,0};
    if (k >= 1){
      {                                          // W1ih (streamed hi) over h0_{k-1}
        const u16* hH = H0h[p0^1]; const u16* hL = H0l[p0^1];
        const u16* wh = W1ih_h + nb;
        #pragma unroll 4
        for (int kss = 0; kss < 16; ++kss){
          int kk = ((kss + sk2) & 15)*32;
          short8 a0h = *(const short8*)(hH + aoff0 + kk);
          short8 a0l = *(const short8*)(hL + aoff0 + kk);
          short8 a1h = *(const short8*)(hH + aoff1 + kk);
          short8 a1l = *(const short8*)(hL + aoff1 + kk);
          short8 bh = *(const short8*)(wh + kk);
          SMACC2(B0, a0h, a0l, bh);
          SMACC2(B1, a1h, a1l, bh);
        }
      }
      {                                          // W1hh (LDS hi) over h1_{k-2} buf[p0]
        const u16* hH = H1h[p0]; const u16* hL = H1l[p0];
        #pragma unroll 4
        for (int ks = 0; ks < 16; ++ks){
          int kk = ks*32;
          short8 a0h = *(const short8*)(hH + aoff0 + kk);
          short8 a0l = *(const short8*)(hL + aoff0 + kk);
          short8 a1h = *(const short8*)(hH + aoff1 + kk);
          short8 a1l = *(const short8*)(hL + aoff1 + kk);
          short8 bh = lds8(w1hh_h, rl, kc + kk, 1024);
          SMACC2(B0, a0h, a0l, bh);
          SMACC2(B1, a1h, a1l, bh);
        }
      }
    }

    // ---- cell l0 -> h0_k buf[p0]
    {
      __syncthreads();
      #pragma unroll
      for (int r = 0; r < 4; ++r){
        gl[(rb_ + r)*68 + rl]      = A0[r] + bs0[rl];
        gl[(16 + rb_ + r)*68 + rl] = A1[r] + bs0[rl];
      }
      __syncthreads();
      u16* Hh = H0h[p0]; u16* Hl = H0l[p0];
      #pragma unroll
      for (int q = 0; q < 2; ++q){
        int e = tid + q*256;
        int m = e >> 4, col = e & 15;
        float iv = gl[m*68 + col];
        float fv = gl[m*68 + 16 + col];
        float gv = gl[m*68 + 32 + col];
        float ov = gl[m*68 + 48 + col];
        float si = 1.f/(1.f + expf(-iv));
        float sf = 1.f/(1.f + expf(-fv));
        float so = 1.f/(1.f + expf(-ov));
        float cn = sf*c0r[q] + si*tanhf(gv);
        c0r[q] = cn;
        float h = so*tanhf(cn);
        int gi = (b0 + m)*512 + cg*16 + col;
        u16 hh = f2bf(h);
        Hh[gi] = hh;
        Hl[gi] = f2bf(h - bf2f(hh));
      }
    }
    // ---- cell l1 -> h1_{k-1} buf[p0^1]  (global_feat at k==336)
    if (k >= 1){
      float* gf = (k == 336) ? out : (float*)nullptr;
      __syncthreads();
      #pragma unroll
      for (int r = 0; r < 4; ++r){
        gl[(rb_ + r)*68 + rl]      = B0[r] + bs1[rl];
        gl[(16 + rb_ + r)*68 + rl] = B1[r] + bs1[rl];
      }
      __syncthreads();
      u16* Hh = H1h[p0^1]; u16* Hl = H1l[p0^1];
      #pragma unroll
      for (int q = 0; q < 2; ++q){
        int e = tid + q*256;
        int m = e >> 4, col = e & 15;
        float iv = gl[m*68 + col];
        float fv = gl[m*68 + 16 + col];
        float gv = gl[m*68 + 32 + col];
        float ov = gl[m*68 + 48 + col];
        float si = 1.f/(1.f + expf(-iv));
        float sf = 1.f/(1.f + expf(-fv));
        float so = 1.f/(1.f + expf(-ov));
        float cn = sf*c1r[q] + si*tanhf(gv);
        c1r[q] = cn;
        float h = so*tanhf(cn);
        int gi = (b0 + m)*512 + cg*16 + col;
        u16 hh = f2bf(h);
        Hh[gi] = hh;
        Hl[gi] = f2bf(h - bf2f(hh));
        if (gf) gf[gi] = h;
      }
    }
    ++ep;
    if (allco) fbar(cnt, g, cg, ep, tid); else xbar(cnt, ep, xcd, pop, nx);
  }

  // ======== l1 catch-up phase: h1_336 (reads h0_336 buf[0], h1_335 buf[1]) ==
  {
    f32x4 B0 = {0,0,0,0}, B1 = {0,0,0,0};
    {
      const u16* hH = H0h[0]; const u16* hL = H0l[0];
      const u16* wh = W1ih_h + nb;
      #pragma unroll 4
      for (int kss = 0; kss < 16; ++kss){
        int kk = ((kss + sk2) & 15)*32;
        short8 a0h = *(const short8*)(hH + aoff0 + kk);
        short8 a0l = *(const short8*)(hL + aoff0 + kk);
        short8 a1h = *(const short8*)(hH + aoff1 + kk);
        short8 a1l = *(const short8*)(hL + aoff1 + kk);
        short8 bh = *(const short8*)(wh + kk);
        SMACC2(B0, a0h, a0l, bh);
        SMACC2(B1, a1h, a1l, bh);
      }
    }
    {
      const u16* hH = H1h[1]; const u16* hL = H1l[1];
      #pragma unroll 4
      for (int ks = 0; ks < 16; ++ks){
        int kk = ks*32;
        short8 a0h = *(const short8*)(hH + aoff0 + kk);
        short8 a0l = *(const short8*)(hL + aoff0 + kk);
        short8 a1h = *(const short8*)(hH + aoff1 + kk);
        short8 a1l = *(const short8*)(hL + aoff1 + kk);
        short8 bh = lds8(w1hh_h, rl, kc + kk, 1024);
        SMACC2(B0, a0h, a0l, bh);
        SMACC2(B1, a1h, a1l, bh);
      }
    }
    __syncthreads();
    #pragma unroll
    for (int r = 0; r < 4; ++r){
      gl[(rb_ + r)*68 + rl]      = B0[r] + bs1[rl];
      gl[(16 + rb_ + r)*68 + rl] = B1[r] + bs1[rl];
    }
    __syncthreads();
    u16* Hh = H1h[0]; u16* Hl = H1l[0];
    #pragma unroll
    for (int q = 0; q < 2; ++q){
      int e = tid + q*256;
      int m = e >> 4, col = e & 15;
      float iv = gl[m*68 + col];
      float fv = gl[m*68 + 16 + col];
      float gv = gl[m*68 + 32 + col];
      float ov = gl[m*68 + 48 + col];
      float si = 1.f/(1.f + expf(-iv));
      float sf = 1.f/(1.f + expf(-fv));
      float so = 1.f/(1.f + expf(-ov));
      float cn = sf*c1r[q] + si*tanhf(gv);
      c1r[q] = cn;
      float h = so*tanhf(cn);
      int gi = (b0 + m)*512 + cg*16 + col;
      u16 hh = f2bf(h);
      Hh[gi] = hh;
      Hl[gi] = f2bf(h - bf2f(hh));
    }
    ++ep;
    if (allco) fbar(cnt, g, cg, ep, tid); else xbar(cnt, ep, xcd, pop, nx);
  }

  // ======== decoder: t = 337..431, two phases per step ========
  for (int t = 337; t < 432; ++t){
    const int p = t & 1;

    // ---- phase A: l0 (Wcomb + Whh0) + pred output l=t-337 ----
    f32x4 A0 = {0,0,0,0}, A1 = {0,0,0,0};
    {                                            // Wcomb (hi) over h1_{t-1}
      const u16* hH = H1h[p^1]; const u16* hL = H1l[p^1];
      const u16* wh = Wcmb_h + nb;
      #pragma unroll 4
      for (int kss = 0; kss < 16; ++kss){
        int kk = ((kss + sk1) & 15)*32;
        short8 a0h = *(const short8*)(hH + aoff0 + kk);
        short8 a0l = *(const short8*)(hL + aoff0 + kk);
        short8 a1h = *(const short8*)(hH + aoff1 + kk);
        short8 a1l = *(const short8*)(hL + aoff1 + kk);
        short8 bh = *(const short8*)(wh + kk);
        SMACC2(A0, a0h, a0l, bh);
        SMACC2(A1, a1h, a1l, bh);
      }
    }
    {                                            // Whh0 (LDS hi) over h0_{t-1}
      const u16* hH = H0h[p^1]; const u16* hL = H0l[p^1];
      #pragma unroll 4
      for (int ks = 0; ks < 16; ++ks){
        int kk = ks*32;
        short8 a0h = *(const short8*)(hH + aoff0 + kk);
        short8 a0l = *(const short8*)(hL + aoff0 + kk);
        short8 a1h = *(const short8*)(hH + aoff1 + kk);
        short8 a1l = *(const short8*)(hL + aoff1 + kk);
        short8 bh = lds8(whh0_h, rl, kc + kk, 1024);
        SMACC2(A0, a0h, a0l, bh);
        SMACC2(A1, a1h, a1l, bh);
      }
    }
    {                                            // pred l=t-337 (batch b0+cg)
      const int d = tid & 63, kq = tid >> 6;
      const int b = b0 + cg;
      const u16* hH = H1h[p^1] + b*512 + kq*128;
      const u16* hL = H1l[p^1] + b*512 + kq*128;
      const float* wr = Wout + d*512 + kq*128;
      float part = 0.f;
      #pragma unroll 4
      for (int kk = 0; kk < 128; kk += 8){
        short8 hv = *(const short8*)(hH + kk);
        short8 lv = *(const short8*)(hL + kk);
        #pragma unroll
        for (int j = 0; j < 8; ++j)
          part += (bf2f((u16)hv[j]) + bf2f((u16)lv[j])) * wr[kk + j];
      }
      pr[d*4 + kq] = part;
      __syncthreads();
      if (tid < 64){
        float v = pr[tid*4] + pr[tid*4+1] + pr[tid*4+2] + pr[tid*4+3] + bout[tid];
        out[131072 + (b*64 + tid)*96 + (t - 337)] = v;
      }
    }
    {                                            // cell l0 -> h0_t buf[p]
      __syncthreads();
      #pragma unroll
      for (int r = 0; r < 4; ++r){
        gl[(rb_ + r)*68 + rl]      = A0[r] + bsd[rl];
        gl[(16 + rb_ + r)*68 + rl] = A1[r] + bsd[rl];
      }
      __syncthreads();
      u16* Hh = H0h[p]; u16* Hl = H0l[p];
      #pragma unroll
      for (int q = 0; q < 2; ++q){
        int e = tid + q*256;
        int m = e >> 4, col = e & 15;
        float iv = gl[m*68 + col];
        float fv = gl[m*68 + 16 + col];
        float gv = gl[m*68 + 32 + col];
        float ov = gl[m*68 + 48 + col];
        float si = 1.f/(1.f + expf(-iv));
        float sf = 1.f/(1.f + expf(-fv));
        float so = 1.f/(1.f + expf(-ov));
        float cn = sf*c0r[q] + si*tanhf(gv);
        c0r[q] = cn;
        float h = so*tanhf(cn);
        int gi = (b0 + m)*512 + cg*16 + col;
        u16 hh = f2bf(h);
        Hh[gi] = hh;
        Hl[gi] = f2bf(h - bf2f(hh));
      }
    }
    ++ep;
    if (allco) fbar(cnt, g, cg, ep, tid); else xbar(cnt, ep, xcd, pop, nx);

    // ---- phase B: l1 -> h1_t buf[p] ----
    f32x4 B0 = {0,0,0,0}, B1 = {0,0,0,0};
    {                                            // W1ih (hi) over h0_t
      const u16* hH = H0h[p]; const u16* hL = H0l[p];
      const u16* wh = W1ih_h + nb;
      #pragma unroll 4
      for (int kss = 0; kss < 16; ++kss){
        int kk = ((kss + sk2) & 15)*32;
        short8 a0h = *(const short8*)(hH + aoff0 + kk);
        short8 a0l = *(const short8*)(hL + aoff0 + kk);
        short8 a1h = *(const short8*)(hH + aoff1 + kk);
        short8 a1l = *(const short8*)(hL + aoff1 + kk);
        short8 bh = *(const short8*)(wh + kk);
        SMACC2(B0, a0h, a0l, bh);
        SMACC2(B1, a1h, a1l, bh);
      }
    }
    {                                            // W1hh (LDS hi) over h1_{t-1}
      const u16* hH = H1h[p^1]; const u16* hL = H1l[p^1];
      #pragma unroll 4
      for (int ks = 0; ks < 16; ++ks){
        int kk = ks*32;
        short8 a0h = *(const short8*)(hH + aoff0 + kk);
        short8 a0l = *(const short8*)(hL + aoff0 + kk);
        short8 a1h = *(const short8*)(hH + aoff1 + kk);
        short8 a1l = *(const short8*)(hL + aoff1 + kk);
        short8 bh = lds8(w1hh_h, rl, kc + kk, 1024);
        SMACC2(B0, a0h, a0l, bh);
        SMACC2(B1, a1h, a1l, bh);
      }
    }
    {
      __syncthreads();
      #pragma unroll
      for (int r = 0; r < 4; ++r){
        gl[(rb_ + r)*68 + rl]      = B0[r] + bs1[rl];
        gl[(16 + rb_ + r)*68 + rl] = B1[r] + bs1[rl];
      }
      __syncthreads();
      u16* Hh = H1h[p]; u16* Hl = H1l[p];
      #pragma unroll
      for (int q = 0; q < 2; ++q){
        int e = tid + q*256;
        int m = e >> 4, col = e & 15;
        float iv = gl[m*68 + col];
        float fv = gl[m*68 + 16 + col];
        float gv = gl[m*68 + 32 + col];
        float ov = gl[m*68 + 48 + col];
        float si = 1.f/(1.f + expf(-iv));
        float sf = 1.f/(1.f + expf(-fv));
        float so = 1.f/(1.f + expf(-ov));
        float cn = sf*c1r[q] + si*tanhf(gv);
        c1r[q] = cn;
        float h = so*tanhf(cn);
        int gi = (b0 + m)*512 + cg*16 + col;
        u16 hh = f2bf(h);
        Hh[gi] = hh;
        Hl[gi] = f2bf(h - bf2f(hh));
      }
    }
    ++ep;
    if (allco) fbar(cnt, g, cg, ep, tid); else xbar(cnt, ep, xcd, pop, nx);
  }
}

// ---- tail: pred for l=95 from h1_431 (parity 1) ----------------------------
__global__ void __launch_bounds__(256) pred_last(
    const u16* __restrict__ h1hi, const u16* __restrict__ h1lo,
    const float* __restrict__ Wout, const float* __restrict__ bout,
    float* __restrict__ out)
{
  const int wg = blockIdx.x, tid = threadIdx.x;
  const int bsub = tid >> 6, d = tid & 63;
  const int b = wg*4 + bsub;
  float acc = bout[d];
  const u16* hH = h1hi + b*512;
  const u16* hL = h1lo + b*512;
  const float* wr = Wout + d*512;
  #pragma unroll 8
  for (int k = 0; k < 512; k += 8){
    short8 hv = *(const short8*)(hH + k);
    short8 lv = *(const short8*)(hL + k);
    #pragma unroll
    for (int j = 0; j < 8; ++j)
      acc += (bf2f((u16)hv[j]) + bf2f((u16)lv[j])) * wr[k + j];
  }
  out[131072 + (b*64 + d)*96 + 95] = acc;
}

// ======================= fallback (R9 proven path) ==========================
__device__ __forceinline__ void cell_epilogue_fb(
    float* gl, const float* bs, float* __restrict__ cbuf,
    u16* __restrict__ hhi, u16* __restrict__ hlo,
    float* __restrict__ gfout, int mrow, int jblk,
    const f32x4& a0, const f32x4& a1, int wv, int lane, int tid)
{
  __syncthreads();
  const int rbase = wv*16 + ((lane >> 4) << 2);
  const int cI = lane & 15;
  #pragma unroll
  for (int r = 0; r < 4; ++r){
    gl[(rbase+r)*33 + cI]      = a0[r] + bs[cI];
    gl[(rbase+r)*33 + 16 + cI] = a1[r] + bs[16 + cI];
  }
  __syncthreads();
  #pragma unroll
  for (int q = 0; q < 2; ++q){
    int e = tid + q*256;
    int m = e >> 3, jj = e & 7;
    float iv = gl[m*33 + jj];
    float fv = gl[m*33 + 8 + jj];
    float gv = gl[m*33 + 16 + jj];
    float ov = gl[m*33 + 24 + jj];
    float si = 1.f/(1.f + expf(-iv));
    float sf = 1.f/(1.f + expf(-fv));
    float so = 1.f/(1.f + expf(-ov));
    int gi = (mrow*64 + m)*512 + jblk*8 + jj;
    float cn = sf*cbuf[gi] + si*tanhf(gv);
    cbuf[gi] = cn;
    float h = so*tanhf(cn);
    u16 hh = f2bf(h);
    hhi[gi] = hh;
    hlo[gi] = f2bf(h - bf2f(hh));
    if (gfout) gfout[gi] = h;
  }
}

template<bool ENC>
__global__ void __launch_bounds__(256) l0_fb(
    const float* __restrict__ x,
    const u16* __restrict__ predhi, const u16* __restrict__ predlo,
    const float* __restrict__ Wihf, const float* __restrict__ Whhf,
    const float* __restrict__ bih, const float* __restrict__ bhh,
    const u16* __restrict__ hphi, const u16* __restrict__ hplo,
    u16* __restrict__ hnhi, u16* __restrict__ hnlo,
    float* __restrict__ c0, int t)
{
  __shared__ float gl[64*33];
  __shared__ float bs[32];
  const int wg = blockIdx.x, tid = threadIdx.x;
  const int mrow = wg & 3, jblk = wg >> 2;
  const int lane = tid & 63, wv = tid >> 6;
  if (tid < 32){
    int n = ((tid >> 3) << 9) + jblk*8 + (tid & 7);
    bs[tid] = bih[n] + bhh[n];
  }
  const int ar = mrow*64 + wv*16 + (lane & 15);
  const int kc = (lane >> 4) << 3;
  const int cI = lane & 15;
  const int n0 = ((cI >> 3) << 9) + jblk*8 + (cI & 7);
  const int n1 = n0 + 1024;

  f32x4 acc0 = {0,0,0,0}, acc1 = {0,0,0,0};
  #pragma unroll
  for (int ks = 0; ks < 2; ++ks){
    int k = ks*32 + kc;
    short8 ah, al;
    if (ENC){
      const float* xb = x + ar*21504 + t;
      #pragma unroll
      for (int j = 0; j < 8; ++j){ HiLo s = split1(xb[(k + j)*336]); ah[j] = s.hi; al[j] = s.lo; }
    } else {
      ah = *(const short8*)(predhi + ar*64 + k);
      al = *(const short8*)(predlo + ar*64 + k);
    }
    short8 bh0, bl0, bh1, bl1;
    ldw8s(Wihf + n0*64 + k, bh0, bl0);
    ldw8s(Wihf + n1*64 + k, bh1, bl1);
    SMACC(acc0, ah, al, bh0, bl0);
    SMACC(acc1, ah, al, bh1, bl1);
  }
  const u16* hH = hphi + ar*512 + kc;
  const u16* hL = hplo + ar*512 + kc;
  #pragma unroll 4
  for (int ks = 0; ks < 16; ++ks){
    int k = ks*32;
    short8 ah = *(const short8*)(hH + k);
    short8 al = *(const short8*)(hL + k);
    short8 bh0, bl0, bh1, bl1;
    ldw8s(Whhf + n0*512 + kc + k, bh0, bl0);
    ldw8s(Whhf + n1*512 + kc + k, bh1, bl1);
    SMACC(acc0, ah, al, bh0, bl0);
    SMACC(acc1, ah, al, bh1, bl1);
  }
  cell_epilogue_fb(gl, bs, c0, hnhi, hnlo, nullptr, mrow, jblk, acc0, acc1, wv, lane, tid);
}

__global__ void __launch_bounds__(256) l1_fb(
    const float* __restrict__ Wihf, const float* __restrict__ Whhf,
    const float* __restrict__ bih, const float* __restrict__ bhh,
    const u16* __restrict__ h0hi, const u16* __restrict__ h0lo,
    const u16* __restrict__ h1phi, const u16* __restrict__ h1plo,
    u16* __restrict__ h1nhi, u16* __restrict__ h1nlo,
    float* __restrict__ c1, float* __restrict__ gfout)
{
  __shared__ float gl[64*33];
  __shared__ float bs[32];
  const int wg = blockIdx.x, tid = threadIdx.x;
  const int mrow = wg & 3, jblk = wg >> 2;
  const int lane = tid & 63, wv = tid >> 6;
  if (tid < 32){
    int n = ((tid >> 3) << 9) + jblk*8 + (tid & 7);
    bs[tid] = bih[n] + bhh[n];
  }
  const int ar = mrow*64 + wv*16 + (lane & 15);
  const int kc = (lane >> 4) << 3;
  const int cI = lane & 15;
  const int n0 = ((cI >> 3) << 9) + jblk*8 + (cI & 7);
  const int n1 = n0 + 1024;

  f32x4 acc0 = {0,0,0,0}, acc1 = {0,0,0,0};
  {
    const u16* hH = h0hi + ar*512 + kc;
    const u16* hL = h0lo + ar*512 + kc;
    #pragma unroll 4
    for (int ks = 0; ks < 16; ++ks){
      int k = ks*32;
      short8 ah = *(const short8*)(hH + k);
      short8 al = *(const short8*)(hL + k);
      short8 bh0, bl0, bh1, bl1;
      ldw8s(Wihf + n0*512 + kc + k, bh0, bl0);
      ldw8s(Wihf + n1*512 + kc + k, bh1, bl1);
      SMACC(acc0, ah, al, bh0, bl0);
      SMACC(acc1, ah, al, bh1, bl1);
    }
  }
  {
    const u16* hH = h1phi + ar*512 + kc;
    const u16* hL = h1plo + ar*512 + kc;
    #pragma unroll 4
    for (int ks = 0; ks < 16; ++ks){
      int k = ks*32;
      short8 ah = *(const short8*)(hH + k);
      short8 al = *(const short8*)(hL + k);
      short8 bh0, bl0, bh1, bl1;
      ldw8s(Whhf + n0*512 + kc + k, bh0, bl0);
      ldw8s(Whhf + n1*512 + kc + k, bh1, bl1);
      SMACC(acc0, ah, al, bh0, bl0);
      SMACC(acc1, ah, al, bh1, bl1);
    }
  }
  cell_epilogue_fb(gl, bs, c1, h1nhi, h1nlo, gfout, mrow, jblk, acc0, acc1, wv, lane, tid);
}

__global__ void __launch_bounds__(256) pred_fb(
    const u16* __restrict__ h1hi, const u16* __restrict__ h1lo,
    const float* __restrict__ Wout, const float* __restrict__ bout,
    u16* __restrict__ predhi, u16* __restrict__ predlo,
    float* __restrict__ out, int l)
{
  const int wg = blockIdx.x, tid = threadIdx.x;
  const int bsub = tid >> 6, d = tid & 63;
  const int b = wg*4 + bsub;
  float acc = bout[d];
  const u16* hH = h1hi + b*512;
  const u16* hL = h1lo + b*512;
  const float* wr = Wout + d*512;
  #pragma unroll 8
  for (int k = 0; k < 512; k += 8){
    short8 hv = *(const short8*)(hH + k);
    short8 lv = *(const short8*)(hL + k);
    #pragma unroll
    for (int j = 0; j < 8; ++j)
      acc += (bf2f((u16)hv[j]) + bf2f((u16)lv[j])) * wr[k + j];
  }
  HiLo s = split1(acc);
  predhi[b*64 + d] = (u16)s.hi;
  predlo[b*64 + d] = (u16)s.lo;
  out[131072 + (b*64 + d)*96 + l] = acc;
}

extern "C" void kernel_launch(void* const* d_in, const int* in_sizes, int n_in,
                              void* d_out, int out_size, void* d_ws, size_t ws_size,
                              hipStream_t stream)
{
  const float* x    = (const float*)d_in[0];
  const float* Wih0 = (const float*)d_in[1];
  const float* Whh0 = (const float*)d_in[2];
  const float* bih0 = (const float*)d_in[3];
  const float* bhh0 = (const float*)d_in[4];
  const float* Wih1 = (const float*)d_in[5];
  const float* Whh1 = (const float*)d_in[6];
  const float* bih1 = (const float*)d_in[7];
  const float* bhh1 = (const float*)d_in[8];
  const float* Wout = (const float*)d_in[9];
  const float* bout = (const float*)d_in[10];
  float* out = (float*)d_out;

  // ---- ws layout (main): h 2MB | cnt/flags 64KB | hi weights 4MB | bb 8KB
  char* ws = (char*)d_ws;
  u16* h0h[2] = { (u16*)(ws + 0),       (u16*)(ws + 262144) };
  u16* h0l[2] = { (u16*)(ws + 524288),  (u16*)(ws + 786432) };
  u16* h1h[2] = { (u16*)(ws + 1048576), (u16*)(ws + 1310720) };
  u16* h1l[2] = { (u16*)(ws + 1572864), (u16*)(ws + 1835008) };
  unsigned* cnt = (unsigned*)(ws + 2097152);
  u16* Wcmb_h = (u16*)(ws + 2162688);
  u16* W1ih_h = Wcmb_h + 1048576;
  float* bb   = (float*)(W1ih_h + 1048576);
  const size_t NEED = 2162688u + 2u*2097152u + 8192u;   // ~6.4 MB
  // fallback layout (only used when ws too small)
  float* fb_c0 = (float*)(ws + 2162688);
  float* fb_c1 = (float*)(ws + 2686976);
  u16* predh   = (u16*)(ws + 3211264);
  u16* predl   = (u16*)(ws + 3244032);
  const bool ps = (ws_size >= NEED);

  (void)hipMemsetAsync(d_ws, 0, 3276800, stream);   // h + cnt/flags (+ fb c/pred)

  if (ps){
    wcomb_k<<<dim3(256), dim3(256), 0, stream>>>(Wih0, Wout, bout, bih0, bhh0,
                                                 Wcmb_h, bb);
    wcvt<<<dim3(4096), dim3(256), 0, stream>>>(Wih1, W1ih_h, 1048576);
    lstm_persist<<<dim3(256), dim3(256), 0, stream>>>(
        x, Whh0, Wih0, Whh1, W1ih_h, Wcmb_h, bb,
        bih0, bhh0, bih1, bhh1, Wout, bout, out, cnt,
        h0h[0], h0h[1], h0l[0], h0l[1], h1h[0], h1h[1], h1l[0], h1l[1]);
    pred_last<<<dim3(64), dim3(256), 0, stream>>>(h1h[1], h1l[1], Wout, bout, out);
  } else {
    for (int t = 0; t < 432; ++t){
      const int p = t & 1;
      float* gf = (t == 335) ? out : (float*)nullptr;
      if (t < 336)
        l0_fb<true><<<dim3(256), dim3(256), 0, stream>>>(
            x, predh, predl, Wih0, Whh0, bih0, bhh0,
            h0h[p^1], h0l[p^1], h0h[p], h0l[p], fb_c0, t);
      else
        l0_fb<false><<<dim3(256), dim3(256), 0, stream>>>(
            x, predh, predl, Wih0, Whh0, bih0, bhh0,
            h0h[p^1], h0l[p^1], h0h[p], h0l[p], fb_c0, t);
      l1_fb<<<dim3(256), dim3(256), 0, stream>>>(
          Wih1, Whh1, bih1, bhh1, h0h[p], h0l[p],
          h1h[p^1], h1l[p^1], h1h[p], h1l[p], fb_c1, gf);
      if (t >= 336)
        pred_fb<<<dim3(64), dim3(256), 0, stream>>>(
            h1h[p], h1l[p], Wout, bout, predh, predl, out, t - 336);
    }
  }
}

// Round 24
// 6822.500 us; speedup vs baseline: 3.1693x; 2.1808x over previous
//
#include <hip/hip_runtime.h>

typedef unsigned short u16;
typedef __attribute__((ext_vector_type(8))) short short8;
typedef __attribute__((ext_vector_type(4))) float f32x4;

#define AXR __ATOMIC_RELAXED, __HIP_MEMORY_SCOPE_AGENT

__device__ __forceinline__ float bf2f(u16 v){
  union { unsigned u; float f; } t; t.u = ((unsigned)v) << 16; return t.f;
}
__device__ __forceinline__ u16 f2bf(float f){
  union { float f; unsigned u; } t; t.f = f;
  unsigned u = t.u;
  return (u16)((u + 0x7fffu + ((u >> 16) & 1u)) >> 16);
}
struct HiLo { short hi, lo; };
__device__ __forceinline__ HiLo split1(float v){
  HiLo r;
  u16 h = f2bf(v);
  r.hi = (short)h;
  r.lo = (short)f2bf(v - bf2f(h));
  return r;
}
__device__ __forceinline__ void ldw8s(const float* __restrict__ p, short8& hi, short8& lo){
  #pragma unroll
  for (int j = 0; j < 8; ++j){ HiLo s = split1(p[j]); hi[j] = s.hi; lo[j] = s.lo; }
}

#define MFMA(acc, a, b) acc = __builtin_amdgcn_mfma_f32_16x16x32_bf16(a, b, acc, 0,0,0)
#define SMACC(acc, ah, al, bh, bl) do{ MFMA(acc, ah, bh); MFMA(acc, ah, bl); MFMA(acc, al, bh); }while(0)
#define SMACC2(acc, ah, al, bh) do{ MFMA(acc, ah, bh); MFMA(acc, al, bh); }while(0)

// ---- prepass: f32 -> bf16 (hi only, RNE) -----------------------------------
__global__ void wcvt(const float* __restrict__ s, u16* __restrict__ hi, int n){
  int i = blockIdx.x * blockDim.x + threadIdx.x;
  if (i < n) hi[i] = f2bf(s[i]);
}

// ---- prepass: Wcomb = Wih0 @ Wout (2048x512 bf16 hi), bb = b0 + Wih0@bout --
__global__ void __launch_bounds__(256) wcomb_k(
    const float* __restrict__ Wih0, const float* __restrict__ Wout,
    const float* __restrict__ bout, const float* __restrict__ bih0,
    const float* __restrict__ bhh0,
    u16* __restrict__ Wch, float* __restrict__ bb)
{
  __shared__ float wl[8*64];
  __shared__ float bo[64];
  const int wg = blockIdx.x, tid = threadIdx.x;
  const int r0 = wg*8;
  for (int i = tid; i < 512; i += 256) wl[i] = Wih0[(r0 + (i >> 6))*64 + (i & 63)];
  if (tid < 64) bo[tid] = bout[tid];
  __syncthreads();
  if (tid < 8){
    int n = r0 + tid;
    float a = bih0[n] + bhh0[n];
    #pragma unroll 8
    for (int d = 0; d < 64; ++d) a += wl[tid*64 + d]*bo[d];
    bb[n] = a;
  }
  #pragma unroll
  for (int jj = 0; jj < 2; ++jj){
    int j = tid + jj*256;
    float acc[8] = {0,0,0,0,0,0,0,0};
    for (int d = 0; d < 64; ++d){
      float wv = Wout[d*512 + j];
      #pragma unroll
      for (int r = 0; r < 8; ++r) acc[r] += wl[r*64 + d]*wv;
    }
    #pragma unroll
    for (int r = 0; r < 8; ++r) Wch[(r0 + r)*512 + j] = f2bf(acc[r]);
  }
}

// ---- init-only tree barrier (threadfence-based, proven R13/R14) ------------
__device__ __forceinline__ void gbar(unsigned* bar, unsigned phase){
  __syncthreads();
  if (threadIdx.x == 0){
    __threadfence();
    const unsigned gg = (unsigned)blockIdx.x >> 4;
    unsigned old = __hip_atomic_fetch_add(bar + 64 + gg*32, 1u, AXR);
    if (old == phase*16u - 1u){
      unsigned r = __hip_atomic_fetch_add(bar, 1u, AXR);
      if (r == phase*16u - 1u)
        __hip_atomic_store(bar + 32, phase, AXR);
    }
    while (__hip_atomic_load(bar + 32, AXR) < phase)
      __builtin_amdgcn_s_sleep(2);
    __threadfence();
  }
  __syncthreads();
}

// ---- global fallback barrier (R14 xbar, any WG placement) ------------------
__device__ __forceinline__ void xbar(unsigned* bar, unsigned phase,
                                     unsigned xcd, unsigned pop, unsigned nx){
  __syncthreads();
  if (threadIdx.x == 0){
    unsigned old = __hip_atomic_fetch_add(bar + 832 + xcd*32, 1u, AXR);
    const bool leader = (old == phase*pop - 1u);
    if (leader){
      asm volatile("buffer_wbl2 sc1\n\ts_waitcnt vmcnt(0)" ::: "memory");
      unsigned r = __hip_atomic_fetch_add(bar + 1344, 1u, AXR);
      if (r == phase*nx - 1u)
        __hip_atomic_store(bar + 1376, phase, AXR);
    }
    while (__hip_atomic_load(bar + 1376, AXR) < phase)
      __builtin_amdgcn_s_sleep(2);
    if (leader){
      asm volatile("buffer_inv sc1\n\ts_waitcnt vmcnt(0)" ::: "memory");
      __hip_atomic_store(bar + 1088 + xcd*32, phase, AXR);
    } else {
      while (__hip_atomic_load(bar + 1088 + xcd*32, AXR) < phase)
        __builtin_amdgcn_s_sleep(1);
      asm volatile("buffer_inv\n\ts_waitcnt vmcnt(0)" ::: "memory");
    }
  }
  __syncthreads();
}

// ---- group-local FLAG-ARRAY barrier (R22): zero RMWs -----------------------
__device__ __forceinline__ void fbar(unsigned* bar, int g, int cg,
                                     unsigned phase, int tid){
  __syncthreads();
  unsigned* flags = bar + 4096 + g*1024;
  if (tid == 0)
    __hip_atomic_store(flags + cg*32, phase, AXR);
  if (tid < 64){
    const int i = tid & 31;
    while (__hip_atomic_load(flags + i*32, AXR) < phase)
      __builtin_amdgcn_s_sleep(1);
    asm volatile("buffer_inv\n\ts_waitcnt vmcnt(0)" ::: "memory");
  }
  __syncthreads();
}

// ---- LDS helpers (XOR-swizzled, G4) ----------------------------------------
__device__ __forceinline__ short8 lds8(const u16* base, int r, int kelem, int rowbytes){
  int bo = r*rowbytes + ((kelem*2) ^ ((r & 7) << 4));
  return *(const short8*)((const char*)base + bo);
}
__device__ __forceinline__ void load_slice64(
    const float* __restrict__ W, int ldw, int rowshift, int nelem,
    u16* lh, u16* ll, int cg, int tid)
{
  const int rowbytes = ldw*2;
  for (int i = tid; i < nelem; i += 256){
    int r = i >> rowshift, k = i & ((1 << rowshift) - 1);
    int n = ((r >> 4) << 9) + cg*16 + (r & 15);
    HiLo s = split1(W[n*ldw + k]);
    int bo = r*rowbytes + ((k*2) ^ ((r & 7) << 4));
    *(u16*)((char*)lh + bo) = (u16)s.hi;
    *(u16*)((char*)ll + bo) = (u16)s.lo;
  }
}
__device__ __forceinline__ void load_slice64h(
    const float* __restrict__ W, int ldw, int rowshift, int nelem,
    u16* lh, int cg, int tid)
{
  const int rowbytes = ldw*2;
  for (int i = tid; i < nelem; i += 256){
    int r = i >> rowshift, k = i & ((1 << rowshift) - 1);
    int n = ((r >> 4) << 9) + cg*16 + (r & 15);
    int bo = r*rowbytes + ((k*2) ^ ((r & 7) << 4));
    *(u16*)((char*)lh + bo) = f2bf(W[n*ldw + k]);
  }
}

// ---- h-block stage: 32 rows x 512 cols hi+lo, coalesced -> swizzled LDS ----
__device__ __forceinline__ void stage32(const u16* __restrict__ gh,
                                        const u16* __restrict__ glo,
                                        u16* sh, u16* sl, int tid){
  #pragma unroll
  for (int i = 0; i < 8; ++i){
    int e = (tid + i*256)*8;                     // u16 elem offset (16B chunks)
    int row = e >> 9, col = e & 511;
    int bo = row*1024 + ((col*2) ^ ((row & 7) << 4));
    *(short8*)((char*)sh + bo) = *(const short8*)(gh + e);
    *(short8*)((char*)sl + bo) = *(const short8*)(glo + e);
  }
}

// ---- persistent kernel: skewed pipeline + LDS-staged A operands ------------
__global__ void __launch_bounds__(256, 1) lstm_persist(
    const float* __restrict__ x,
    const float* __restrict__ Whh0, const float* __restrict__ Wih0,
    const u16* __restrict__ W1ih_h, const u16* __restrict__ W1hh_h,
    const u16* __restrict__ Wcmb_h, const float* __restrict__ bb,
    const float* __restrict__ bih0, const float* __restrict__ bhh0,
    const float* __restrict__ bih1, const float* __restrict__ bhh1,
    const float* __restrict__ Wout, const float* __restrict__ bout,
    float* __restrict__ out, unsigned* __restrict__ cnt,
    u16* __restrict__ h0h0, u16* __restrict__ h0h1,
    u16* __restrict__ h0l0, u16* __restrict__ h0l1,
    u16* __restrict__ h1h0, u16* __restrict__ h1h1,
    u16* __restrict__ h1l0, u16* __restrict__ h1l1)
{
  __shared__ u16 whh0_h[32768];                  // 64KB: Whh0 hi, swizzled
  __shared__ u16 hst_h[16384], hst_l[16384];     // 64KB: staged h block
  __shared__ u16 w0ih_h[4096],  w0ih_l[4096];    // 16KB: Wih0 hi+lo
  __shared__ float gl[32*68];                    // gate exchange (aliases xst)
  __shared__ float pr[256];                      // pred partials
  __shared__ float bs0[64], bs1[64], bsd[64];
  __shared__ unsigned s_rank, s_pop, s_nx, s_all;

  u16* xst_h = (u16*)gl;                         // x_t stage: 32x64 hi
  u16* xst_l = (u16*)gl + 2048;                  // 32x64 lo (8KB total <= gl)

  const int wg = blockIdx.x, tid = threadIdx.x;
  const int lane = tid & 63, wv = tid >> 6;
  const int cI = lane & 15;
  const int kc = (lane >> 4) << 3;
  const int rl = wv*16 + cI;

  // ---- census: measured XCD id + rank within XCD ----
  unsigned xcd;
  asm volatile("s_getreg_b32 %0, hwreg(HW_REG_XCC_ID)" : "=s"(xcd));
  xcd &= 7u;
  if (tid == 0)
    s_rank = __hip_atomic_fetch_add(cnt + 576 + xcd*32, 1u, AXR);
  gbar(cnt, 1);
  if (tid == 0){
    unsigned nxl = 0, allc = 1;
    for (int i = 0; i < 8; ++i){
      unsigned pv = __hip_atomic_load(cnt + 576 + i*32, AXR);
      nxl += (pv != 0u) ? 1u : 0u;
      if (pv != 32u) allc = 0u;
    }
    s_pop = __hip_atomic_load(cnt + 576 + xcd*32, AXR);
    s_nx  = nxl;
    s_all = allc;
  }
  __syncthreads();
  const unsigned pop = s_pop, nx = s_nx;
  const bool allco = (s_all != 0u);
  const int g  = allco ? (int)xcd    : (wg & 7);
  const int cg = allco ? (int)s_rank : (wg >> 3);
  const int b0 = g*32;

  // ---- one-time init ----
  load_slice64h(Whh0, 512, 9, 32768, whh0_h, cg, tid);
  load_slice64(Wih0,  64, 6,  4096, w0ih_h, w0ih_l, cg, tid);
  if (tid < 64){
    int n = ((tid >> 4) << 9) + cg*16 + (tid & 15);
    bs0[tid] = bih0[n] + bhh0[n];
    bs1[tid] = bih1[n] + bhh1[n];
    bsd[tid] = bb[n];
  }
  __syncthreads();

  const int nb = (wv*512 + cg*16 + cI)*512 + kc; // streamed weight frag base

  u16* H0h[2] = { h0h0, h0h1 };  u16* H0l[2] = { h0l0, h0l1 };
  u16* H1h[2] = { h1h0, h1h1 };  u16* H1l[2] = { h1l0, h1l1 };

  float c0r[2] = {0.f, 0.f}, c1r[2] = {0.f, 0.f};
  unsigned ep = 0;
  const int rb_ = (lane >> 4) << 2;
  const int hoff = b0*512;

  // fragment read macro: A rows cI / cI+16 from staged block
  #define LDA(kk, a0h_, a0l_, a1h_, a1l_) \
    short8 a0h_ = lds8(hst_h, cI, kc + (kk), 1024); \
    short8 a0l_ = lds8(hst_l, cI, kc + (kk), 1024); \
    short8 a1h_ = lds8(hst_h, cI + 16, kc + (kk), 1024); \
    short8 a1l_ = lds8(hst_l, cI + 16, kc + (kk), 1024);

  // ======== skewed encoder: phase k computes h0_k and h1_{k-1} ========
  for (int k = 0; k <= 336; ++k){
    const int p0 = k & 1;

    // stage x_t (into gl alias) + h0_{k-1}
    if (k < 336){
      #pragma unroll
      for (int i = 0; i < 8; ++i){
        int e = tid + i*256;
        int bb_ = e >> 6, d = e & 63;
        HiLo s = split1(x[(b0 + bb_)*21504 + d*336 + k]);
        int bo = bb_*128 + ((d*2) ^ ((bb_ & 7) << 4));
        *(u16*)((char*)xst_h + bo) = (u16)s.hi;
        *(u16*)((char*)xst_l + bo) = (u16)s.lo;
      }
    }
    stage32(H0h[p0^1] + hoff, H0l[p0^1] + hoff, hst_h, hst_l, tid);
    __syncthreads();

    // l0 gates -> A
    f32x4 A0 = {0,0,0,0}, A1 = {0,0,0,0};
    if (k < 336){
      #pragma unroll
      for (int ks = 0; ks < 2; ++ks){
        int kk = ks*32 + kc;
        short8 a0h = lds8(xst_h, cI, kk, 128);
        short8 a0l = lds8(xst_l, cI, kk, 128);
        short8 a1h = lds8(xst_h, cI + 16, kk, 128);
        short8 a1l = lds8(xst_l, cI + 16, kk, 128);
        short8 bh = lds8(w0ih_h, rl, kk, 128);
        short8 bl = lds8(w0ih_l, rl, kk, 128);
        SMACC(A0, a0h, a0l, bh, bl);
        SMACC(A1, a1h, a1l, bh, bl);
      }
    }
    #pragma unroll 4
    for (int ks = 0; ks < 16; ++ks){             // Whh0 (LDS) over staged h0
      int kk = ks*32;
      LDA(kk, a0h, a0l, a1h, a1l)
      short8 bh = lds8(whh0_h, rl, kc + kk, 1024);
      SMACC2(A0, a0h, a0l, bh);
      SMACC2(A1, a1h, a1l, bh);
    }

    // l1 part 1: W1ih (streamed) over staged h0_{k-1}
    f32x4 B0 = {0,0,0,0}, B1 = {0,0,0,0};
    if (k >= 1){
      const u16* wh = W1ih_h + nb;
      #pragma unroll 4
      for (int ks = 0; ks < 16; ++ks){
        int kk = ks*32;
        LDA(kk, a0h, a0l, a1h, a1l)
        short8 bh = *(const short8*)(wh + kk);
        SMACC2(B0, a0h, a0l, bh);
        SMACC2(B1, a1h, a1l, bh);
      }
      __syncthreads();                           // done with h0 stage
      stage32(H1h[p0] + hoff, H1l[p0] + hoff, hst_h, hst_l, tid);  // h1_{k-2}
      __syncthreads();
      const u16* wh2 = W1hh_h + nb;
      #pragma unroll 4
      for (int ks = 0; ks < 16; ++ks){           // W1hh (streamed) over h1_{k-2}
        int kk = ks*32;
        LDA(kk, a0h, a0l, a1h, a1l)
        short8 bh = *(const short8*)(wh2 + kk);
        SMACC2(B0, a0h, a0l, bh);
        SMACC2(B1, a1h, a1l, bh);
      }
    }

    // cell l0 -> h0_k buf[p0]
    {
      __syncthreads();
      #pragma unroll
      for (int r = 0; r < 4; ++r){
        gl[(rb_ + r)*68 + rl]      = A0[r] + bs0[rl];
        gl[(16 + rb_ + r)*68 + rl] = A1[r] + bs0[rl];
      }
      __syncthreads();
      u16* Hh = H0h[p0]; u16* Hl = H0l[p0];
      #pragma unroll
      for (int q = 0; q < 2; ++q){
        int e = tid + q*256;
        int m = e >> 4, col = e & 15;
        float iv = gl[m*68 + col];
        float fv = gl[m*68 + 16 + col];
        float gv = gl[m*68 + 32 + col];
        float ov = gl[m*68 + 48 + col];
        float si = 1.f/(1.f + expf(-iv));
        float sf = 1.f/(1.f + expf(-fv));
        float so = 1.f/(1.f + expf(-ov));
        float cn = sf*c0r[q] + si*tanhf(gv);
        c0r[q] = cn;
        float h = so*tanhf(cn);
        int gi = (b0 + m)*512 + cg*16 + col;
        u16 hh = f2bf(h);
        Hh[gi] = hh;
        Hl[gi] = f2bf(h - bf2f(hh));
      }
    }
    // cell l1 -> h1_{k-1} buf[p0^1]  (global_feat at k==336)
    if (k >= 1){
      float* gf = (k == 336) ? out : (float*)nullptr;
      __syncthreads();
      #pragma unroll
      for (int r = 0; r < 4; ++r){
        gl[(rb_ + r)*68 + rl]      = B0[r] + bs1[rl];
        gl[(16 + rb_ + r)*68 + rl] = B1[r] + bs1[rl];
      }
      __syncthreads();
      u16* Hh = H1h[p0^1]; u16* Hl = H1l[p0^1];
      #pragma unroll
      for (int q = 0; q < 2; ++q){
        int e = tid + q*256;
        int m = e >> 4, col = e & 15;
        float iv = gl[m*68 + col];
        float fv = gl[m*68 + 16 + col];
        float gv = gl[m*68 + 32 + col];
        float ov = gl[m*68 + 48 + col];
        float si = 1.f/(1.f + expf(-iv));
        float sf = 1.f/(1.f + expf(-fv));
        float so = 1.f/(1.f + expf(-ov));
        float cn = sf*c1r[q] + si*tanhf(gv);
        c1r[q] = cn;
        float h = so*tanhf(cn);
        int gi = (b0 + m)*512 + cg*16 + col;
        u16 hh = f2bf(h);
        Hh[gi] = hh;
        Hl[gi] = f2bf(h - bf2f(hh));
        if (gf) gf[gi] = h;
      }
    }
    ++ep;
    if (allco) fbar(cnt, g, cg, ep, tid); else xbar(cnt, ep, xcd, pop, nx);
  }

  // ======== l1 catch-up: h1_336 (h0_336 buf[0], h1_335 buf[1]) ========
  {
    f32x4 B0 = {0,0,0,0}, B1 = {0,0,0,0};
    stage32(H0h[0] + hoff, H0l[0] + hoff, hst_h, hst_l, tid);
    __syncthreads();
    {
      const u16* wh = W1ih_h + nb;
      #pragma unroll 4
      for (int ks = 0; ks < 16; ++ks){
        int kk = ks*32;
        LDA(kk, a0h, a0l, a1h, a1l)
        short8 bh = *(const short8*)(wh + kk);
        SMACC2(B0, a0h, a0l, bh);
        SMACC2(B1, a1h, a1l, bh);
      }
    }
    __syncthreads();
    stage32(H1h[1] + hoff, H1l[1] + hoff, hst_h, hst_l, tid);
    __syncthreads();
    {
      const u16* wh = W1hh_h + nb;
      #pragma unroll 4
      for (int ks = 0; ks < 16; ++ks){
        int kk = ks*32;
        LDA(kk, a0h, a0l, a1h, a1l)
        short8 bh = *(const short8*)(wh + kk);
        SMACC2(B0, a0h, a0l, bh);
        SMACC2(B1, a1h, a1l, bh);
      }
    }
    __syncthreads();
    #pragma unroll
    for (int r = 0; r < 4; ++r){
      gl[(rb_ + r)*68 + rl]      = B0[r] + bs1[rl];
      gl[(16 + rb_ + r)*68 + rl] = B1[r] + bs1[rl];
    }
    __syncthreads();
    u16* Hh = H1h[0]; u16* Hl = H1l[0];
    #pragma unroll
    for (int q = 0; q < 2; ++q){
      int e = tid + q*256;
      int m = e >> 4, col = e & 15;
      float iv = gl[m*68 + col];
      float fv = gl[m*68 + 16 + col];
      float gv = gl[m*68 + 32 + col];
      float ov = gl[m*68 + 48 + col];
      float si = 1.f/(1.f + expf(-iv));
      float sf = 1.f/(1.f + expf(-fv));
      float so = 1.f/(1.f + expf(-ov));
      float cn = sf*c1r[q] + si*tanhf(gv);
      c1r[q] = cn;
      float h = so*tanhf(cn);
      int gi = (b0 + m)*512 + cg*16 + col;
      u16 hh = f2bf(h);
      Hh[gi] = hh;
      Hl[gi] = f2bf(h - bf2f(hh));
    }
    ++ep;
    if (allco) fbar(cnt, g, cg, ep, tid); else xbar(cnt, ep, xcd, pop, nx);
  }

  // ======== decoder: t = 337..431 ========
  for (int t = 337; t < 432; ++t){
    const int p = t & 1;

    // ---- phase A: stage h1_{t-1} -> Wcomb + pred; restage h0_{t-1} -> Whh0
    f32x4 A0 = {0,0,0,0}, A1 = {0,0,0,0};
    stage32(H1h[p^1] + hoff, H1l[p^1] + hoff, hst_h, hst_l, tid);
    __syncthreads();
    {
      const u16* wh = Wcmb_h + nb;
      #pragma unroll 4
      for (int ks = 0; ks < 16; ++ks){
        int kk = ks*32;
        LDA(kk, a0h, a0l, a1h, a1l)
        short8 bh = *(const short8*)(wh + kk);
        SMACC2(A0, a0h, a0l, bh);
        SMACC2(A1, a1h, a1l, bh);
      }
    }
    {                                            // pred l=t-337 from staged h1
      const int d = tid & 63, kq = tid >> 6;
      float part = 0.f;
      const float* wr = Wout + d*512 + kq*128;
      #pragma unroll 4
      for (int kk = 0; kk < 128; kk += 8){
        short8 hv = lds8(hst_h, cg, kq*128 + kk, 1024);
        short8 lv = lds8(hst_l, cg, kq*128 + kk, 1024);
        #pragma unroll
        for (int j = 0; j < 8; ++j)
          part += (bf2f((u16)hv[j]) + bf2f((u16)lv[j])) * wr[kk + j];
      }
      pr[d*4 + kq] = part;
      __syncthreads();
      if (tid < 64){
        float v = pr[tid*4] + pr[tid*4+1] + pr[tid*4+2] + pr[tid*4+3] + bout[tid];
        out[131072 + ((b0 + cg)*64 + tid)*96 + (t - 337)] = v;
      }
      __syncthreads();
    }
    stage32(H0h[p^1] + hoff, H0l[p^1] + hoff, hst_h, hst_l, tid);
    __syncthreads();
    #pragma unroll 4
    for (int ks = 0; ks < 16; ++ks){             // Whh0 (LDS) over h0_{t-1}
      int kk = ks*32;
      LDA(kk, a0h, a0l, a1h, a1l)
      short8 bh = lds8(whh0_h, rl, kc + kk, 1024);
      SMACC2(A0, a0h, a0l, bh);
      SMACC2(A1, a1h, a1l, bh);
    }
    {                                            // cell l0 -> h0_t buf[p]
      __syncthreads();
      #pragma unroll
      for (int r = 0; r < 4; ++r){
        gl[(rb_ + r)*68 + rl]      = A0[r] + bsd[rl];
        gl[(16 + rb_ + r)*68 + rl] = A1[r] + bsd[rl];
      }
      __syncthreads();
      u16* Hh = H0h[p]; u16* Hl = H0l[p];
      #pragma unroll
      for (int q = 0; q < 2; ++q){
        int e = tid + q*256;
        int m = e >> 4, col = e & 15;
        float iv = gl[m*68 + col];
        float fv = gl[m*68 + 16 + col];
        float gv = gl[m*68 + 32 + col];
        float ov = gl[m*68 + 48 + col];
        float si = 1.f/(1.f + expf(-iv));
        float sf = 1.f/(1.f + expf(-fv));
        float so = 1.f/(1.f + expf(-ov));
        float cn = sf*c0r[q] + si*tanhf(gv);
        c0r[q] = cn;
        float h = so*tanhf(cn);
        int gi = (b0 + m)*512 + cg*16 + col;
        u16 hh = f2bf(h);
        Hh[gi] = hh;
        Hl[gi] = f2bf(h - bf2f(hh));
      }
    }
    ++ep;
    if (allco) fbar(cnt, g, cg, ep, tid); else xbar(cnt, ep, xcd, pop, nx);

    // ---- phase B: stage h0_t -> W1ih; restage h1_{t-1} -> W1hh; cell l1 ----
    f32x4 B0 = {0,0,0,0}, B1 = {0,0,0,0};
    stage32(H0h[p] + hoff, H0l[p] + hoff, hst_h, hst_l, tid);
    __syncthreads();
    {
      const u16* wh = W1ih_h + nb;
      #pragma unroll 4
      for (int ks = 0; ks < 16; ++ks){
        int kk = ks*32;
        LDA(kk, a0h, a0l, a1h, a1l)
        short8 bh = *(const short8*)(wh + kk);
        SMACC2(B0, a0h, a0l, bh);
        SMACC2(B1, a1h, a1l, bh);
      }
    }
    __syncthreads();
    stage32(H1h[p^1] + hoff, H1l[p^1] + hoff, hst_h, hst_l, tid);
    __syncthreads();
    {
      const u16* wh = W1hh_h + nb;
      #pragma unroll 4
      for (int ks = 0; ks < 16; ++ks){
        int kk = ks*32;
        LDA(kk, a0h, a0l, a1h, a1l)
        short8 bh = *(const short8*)(wh + kk);
        SMACC2(B0, a0h, a0l, bh);
        SMACC2(B1, a1h, a1l, bh);
      }
    }
    {
      __syncthreads();
      #pragma unroll
      for (int r = 0; r < 4; ++r){
        gl[(rb_ + r)*68 + rl]      = B0[r] + bs1[rl];
        gl[(16 + rb_ + r)*68 + rl] = B1[r] + bs1[rl];
      }
      __syncthreads();
      u16* Hh = H1h[p]; u16* Hl = H1l[p];
      #pragma unroll
      for (int q = 0; q < 2; ++q){
        int e = tid + q*256;
        int m = e >> 4, col = e & 15;
        float iv = gl[m*68 + col];
        float fv = gl[m*68 + 16 + col];
        float gv = gl[m*68 + 32 + col];
        float ov = gl[m*68 + 48 + col];
        float si = 1.f/(1.f + expf(-iv));
        float sf = 1.f/(1.f + expf(-fv));
        float so = 1.f/(1.f + expf(-ov));
        float cn = sf*c1r[q] + si*tanhf(gv);
        c1r[q] = cn;
        float h = so*tanhf(cn);
        int gi = (b0 + m)*512 + cg*16 + col;
        u16 hh = f2bf(h);
        Hh[gi] = hh;
        Hl[gi] = f2bf(h - bf2f(hh));
      }
    }
    ++ep;
    if (allco) fbar(cnt, g, cg, ep, tid); else xbar(cnt, ep, xcd, pop, nx);
  }
  #undef LDA
}

// ---- tail: pred for l=95 from h1_431 (parity 1) ----------------------------
__global__ void __launch_bounds__(256) pred_last(
    const u16* __restrict__ h1hi, const u16* __restrict__ h1lo,
    const float* __restrict__ Wout, const float* __restrict__ bout,
    float* __restrict__ out)
{
  const int wg = blockIdx.x, tid = threadIdx.x;
  const int bsub = tid >> 6, d = tid & 63;
  const int b = wg*4 + bsub;
  float acc = bout[d];
  const u16* hH = h1hi + b*512;
  const u16* hL = h1lo + b*512;
  const float* wr = Wout + d*512;
  #pragma unroll 8
  for (int k = 0; k < 512; k += 8){
    short8 hv = *(const short8*)(hH + k);
    short8 lv = *(const short8*)(hL + k);
    #pragma unroll
    for (int j = 0; j < 8; ++j)
      acc += (bf2f((u16)hv[j]) + bf2f((u16)lv[j])) * wr[k + j];
  }
  out[131072 + (b*64 + d)*96 + 95] = acc;
}

// ======================= fallback (R9 proven path) ==========================
__device__ __forceinline__ void cell_epilogue_fb(
    float* gl, const float* bs, float* __restrict__ cbuf,
    u16* __restrict__ hhi, u16* __restrict__ hlo,
    float* __restrict__ gfout, int mrow, int jblk,
    const f32x4& a0, const f32x4& a1, int wv, int lane, int tid)
{
  __syncthreads();
  const int rbase = wv*16 + ((lane >> 4) << 2);
  const int cI = lane & 15;
  #pragma unroll
  for (int r = 0; r < 4; ++r){
    gl[(rbase+r)*33 + cI]      = a0[r] + bs[cI];
    gl[(rbase+r)*33 + 16 + cI] = a1[r] + bs[16 + cI];
  }
  __syncthreads();
  #pragma unroll
  for (int q = 0; q < 2; ++q){
    int e = tid + q*256;
    int m = e >> 3, jj = e & 7;
    float iv = gl[m*33 + jj];
    float fv = gl[m*33 + 8 + jj];
    float gv = gl[m*33 + 16 + jj];
    float ov = gl[m*33 + 24 + jj];
    float si = 1.f/(1.f + expf(-iv));
    float sf = 1.f/(1.f + expf(-fv));
    float so = 1.f/(1.f + expf(-ov));
    int gi = (mrow*64 + m)*512 + jblk*8 + jj;
    float cn = sf*cbuf[gi] + si*tanhf(gv);
    cbuf[gi] = cn;
    float h = so*tanhf(cn);
    u16 hh = f2bf(h);
    hhi[gi] = hh;
    hlo[gi] = f2bf(h - bf2f(hh));
    if (gfout) gfout[gi] = h;
  }
}

template<bool ENC>
__global__ void __launch_bounds__(256) l0_fb(
    const float* __restrict__ x,
    const u16* __restrict__ predhi, const u16* __restrict__ predlo,
    const float* __restrict__ Wihf, const float* __restrict__ Whhf,
    const float* __restrict__ bih, const float* __restrict__ bhh,
    const u16* __restrict__ hphi, const u16* __restrict__ hplo,
    u16* __restrict__ hnhi, u16* __restrict__ hnlo,
    float* __restrict__ c0, int t)
{
  __shared__ float gl[64*33];
  __shared__ float bs[32];
  const int wg = blockIdx.x, tid = threadIdx.x;
  const int mrow = wg & 3, jblk = wg >> 2;
  const int lane = tid & 63, wv = tid >> 6;
  if (tid < 32){
    int n = ((tid >> 3) << 9) + jblk*8 + (tid & 7);
    bs[tid] = bih[n] + bhh[n];
  }
  const int ar = mrow*64 + wv*16 + (lane & 15);
  const int kc = (lane >> 4) << 3;
  const int cI = lane & 15;
  const int n0 = ((cI >> 3) << 9) + jblk*8 + (cI & 7);
  const int n1 = n0 + 1024;

  f32x4 acc0 = {0,0,0,0}, acc1 = {0,0,0,0};
  #pragma unroll
  for (int ks = 0; ks < 2; ++ks){
    int k = ks*32 + kc;
    short8 ah, al;
    if (ENC){
      const float* xb = x + ar*21504 + t;
      #pragma unroll
      for (int j = 0; j < 8; ++j){ HiLo s = split1(xb[(k + j)*336]); ah[j] = s.hi; al[j] = s.lo; }
    } else {
      ah = *(const short8*)(predhi + ar*64 + k);
      al = *(const short8*)(predlo + ar*64 + k);
    }
    short8 bh0, bl0, bh1, bl1;
    ldw8s(Wihf + n0*64 + k, bh0, bl0);
    ldw8s(Wihf + n1*64 + k, bh1, bl1);
    SMACC(acc0, ah, al, bh0, bl0);
    SMACC(acc1, ah, al, bh1, bl1);
  }
  const u16* hH = hphi + ar*512 + kc;
  const u16* hL = hplo + ar*512 + kc;
  #pragma unroll 4
  for (int ks = 0; ks < 16; ++ks){
    int k = ks*32;
    short8 ah = *(const short8*)(hH + k);
    short8 al = *(const short8*)(hL + k);
    short8 bh0, bl0, bh1, bl1;
    ldw8s(Whhf + n0*512 + kc + k, bh0, bl0);
    ldw8s(Whhf + n1*512 + kc + k, bh1, bl1);
    SMACC(acc0, ah, al, bh0, bl0);
    SMACC(acc1, ah, al, bh1, bl1);
  }
  cell_epilogue_fb(gl, bs, c0, hnhi, hnlo, nullptr, mrow, jblk, acc0, acc1, wv, lane, tid);
}

__global__ void __launch_bounds__(256) l1_fb(
    const float* __restrict__ Wihf, const float* __restrict__ Whhf,
    const float* __restrict__ bih, const float* __restrict__ bhh,
    const u16* __restrict__ h0hi, const u16* __restrict__ h0lo,
    const u16* __restrict__ h1phi, const u16* __restrict__ h1plo,
    u16* __restrict__ h1nhi, u16* __restrict__ h1nlo,
    float* __restrict__ c1, float* __restrict__ gfout)
{
  __shared__ float gl[64*33];
  __shared__ float bs[32];
  const int wg = blockIdx.x, tid = threadIdx.x;
  const int mrow = wg & 3, jblk = wg >> 2;
  const int lane = tid & 63, wv = tid >> 6;
  if (tid < 32){
    int n = ((tid >> 3) << 9) + jblk*8 + (tid & 7);
    bs[tid] = bih[n] + bhh[n];
  }
  const int ar = mrow*64 + wv*16 + (lane & 15);
  const int kc = (lane >> 4) << 3;
  const int cI = lane & 15;
  const int n0 = ((cI >> 3) << 9) + jblk*8 + (cI & 7);
  const int n1 = n0 + 1024;

  f32x4 acc0 = {0,0,0,0}, acc1 = {0,0,0,0};
  {
    const u16* hH = h0hi + ar*512 + kc;
    const u16* hL = h0lo + ar*512 + kc;
    #pragma unroll 4
    for (int ks = 0; ks < 16; ++ks){
      int k = ks*32;
      short8 ah = *(const short8*)(hH + k);
      short8 al = *(const short8*)(hL + k);
      short8 bh0, bl0, bh1, bl1;
      ldw8s(Wihf + n0*512 + kc + k, bh0, bl0);
      ldw8s(Wihf + n1*512 + kc + k, bh1, bl1);
      SMACC(acc0, ah, al, bh0, bl0);
      SMACC(acc1, ah, al, bh1, bl1);
    }
  }
  {
    const u16* hH = h1phi + ar*512 + kc;
    const u16* hL = h1plo + ar*512 + kc;
    #pragma unroll 4
    for (int ks = 0; ks < 16; ++ks){
      int k = ks*32;
      short8 ah = *(const short8*)(hH + k);
      short8 al = *(const short8*)(hL + k);
      short8 bh0, bl0, bh1, bl1;
      ldw8s(Whhf + n0*512 + kc + k, bh0, bl0);
      ldw8s(Whhf + n1*512 + kc + k, bh1, bl1);
      SMACC(acc0, ah, al, bh0, bl0);
      SMACC(acc1, ah, al, bh1, bl1);
    }
  }
  cell_epilogue_fb(gl, bs, c1, h1nhi, h1nlo, gfout, mrow, jblk, acc0, acc1, wv, lane, tid);
}

__global__ void __launch_bounds__(256) pred_fb(
    const u16* __restrict__ h1hi, const u16* __restrict__ h1lo,
    const float* __restrict__ Wout, const float* __restrict__ bout,
    u16* __restrict__ predhi, u16* __restrict__ predlo,
    float* __restrict__ out, int l)
{
  const int wg = blockIdx.x, tid = threadIdx.x;
  const int bsub = tid >> 6, d = tid & 63;
  const int b = wg*4 + bsub;
  float acc = bout[d];
  const u16* hH = h1hi + b*512;
  const u16* hL = h1lo + b*512;
  const float* wr = Wout + d*512;
  #pragma unroll 8
  for (int k = 0; k < 512; k += 8){
    short8 hv = *(const short8*)(hH + k);
    short8 lv = *(const short8*)(hL + k);
    #pragma unroll
    for (int j = 0; j < 8; ++j)
      acc += (bf2f((u16)hv[j]) + bf2f((u16)lv[j])) * wr[k + j];
  }
  HiLo s = split1(acc);
  predhi[b*64 + d] = (u16)s.hi;
  predlo[b*64 + d] = (u16)s.lo;
  out[131072 + (b*64 + d)*96 + l] = acc;
}

extern "C" void kernel_launch(void* const* d_in, const int* in_sizes, int n_in,
                              void* d_out, int out_size, void* d_ws, size_t ws_size,
                              hipStream_t stream)
{
  const float* x    = (const float*)d_in[0];
  const float* Wih0 = (const float*)d_in[1];
  const float* Whh0 = (const float*)d_in[2];
  const float* bih0 = (const float*)d_in[3];
  const float* bhh0 = (const float*)d_in[4];
  const float* Wih1 = (const float*)d_in[5];
  const float* Whh1 = (const float*)d_in[6];
  const float* bih1 = (const float*)d_in[7];
  const float* bhh1 = (const float*)d_in[8];
  const float* Wout = (const float*)d_in[9];
  const float* bout = (const float*)d_in[10];
  float* out = (float*)d_out;

  // ---- ws layout (main): h 2MB | cnt/flags 64KB | hi weights 6MB | bb 8KB
  char* ws = (char*)d_ws;
  u16* h0h[2] = { (u16*)(ws + 0),       (u16*)(ws + 262144) };
  u16* h0l[2] = { (u16*)(ws + 524288),  (u16*)(ws + 786432) };
  u16* h1h[2] = { (u16*)(ws + 1048576), (u16*)(ws + 1310720) };
  u16* h1l[2] = { (u16*)(ws + 1572864), (u16*)(ws + 1835008) };
  unsigned* cnt = (unsigned*)(ws + 2097152);
  u16* Wcmb_h = (u16*)(ws + 2162688);
  u16* W1ih_h = Wcmb_h + 1048576;
  u16* W1hh_h = W1ih_h + 1048576;
  float* bb   = (float*)(W1hh_h + 1048576);
  const size_t NEED = 2162688u + 3u*2097152u + 8192u;   // ~8.5 MB
  // fallback layout (only used when ws too small)
  float* fb_c0 = (float*)(ws + 2162688);
  float* fb_c1 = (float*)(ws + 2686976);
  u16* predh   = (u16*)(ws + 3211264);
  u16* predl   = (u16*)(ws + 3244032);
  const bool ps = (ws_size >= NEED);

  (void)hipMemsetAsync(d_ws, 0, 3276800, stream);   // h + cnt/flags (+ fb c/pred)

  if (ps){
    wcomb_k<<<dim3(256), dim3(256), 0, stream>>>(Wih0, Wout, bout, bih0, bhh0,
                                                 Wcmb_h, bb);
    wcvt<<<dim3(4096), dim3(256), 0, stream>>>(Wih1, W1ih_h, 1048576);
    wcvt<<<dim3(4096), dim3(256), 0, stream>>>(Whh1, W1hh_h, 1048576);
    lstm_persist<<<dim3(256), dim3(256), 0, stream>>>(
        x, Whh0, Wih0, W1ih_h, W1hh_h, Wcmb_h, bb,
        bih0, bhh0, bih1, bhh1, Wout, bout, out, cnt,
        h0h[0], h0h[1], h0l[0], h0l[1], h1h[0], h1h[1], h1l[0], h1l[1]);
    pred_last<<<dim3(64), dim3(256), 0, stream>>>(h1h[1], h1l[1], Wout, bout, out);
  } else {
    for (int t = 0; t < 432; ++t){
      const int p = t & 1;
      float* gf = (t == 335) ? out : (float*)nullptr;
      if (t < 336)
        l0_fb<true><<<dim3(256), dim3(256), 0, stream>>>(
            x, predh, predl, Wih0, Whh0, bih0, bhh0,
            h0h[p^1], h0l[p^1], h0h[p], h0l[p], fb_c0, t);
      else
        l0_fb<false><<<dim3(256), dim3(256), 0, stream>>>(
            x, predh, predl, Wih0, Whh0, bih0, bhh0,
            h0h[p^1], h0l[p^1], h0h[p], h0l[p], fb_c0, t);
      l1_fb<<<dim3(256), dim3(256), 0, stream>>>(
          Wih1, Whh1, bih1, bhh1, h0h[p], h0l[p],
          h1h[p^1], h1l[p^1], h1h[p], h1l[p], fb_c1, gf);
      if (t >= 336)
        pred_fb<<<dim3(64), dim3(256), 0, stream>>>(
            h1h[p], h1l[p], Wout, bout, predh, predl, out, t - 336);
    }
  }
}

// Round 25
// 6003.527 us; speedup vs baseline: 3.6017x; 1.1364x over previous
//
#include <hip/hip_runtime.h>

typedef unsigned short u16;
typedef __attribute__((ext_vector_type(8))) short short8;
typedef __attribute__((ext_vector_type(4))) float f32x4;

#define AXR __ATOMIC_RELAXED, __HIP_MEMORY_SCOPE_AGENT

__device__ __forceinline__ float bf2f(u16 v){
  union { unsigned u; float f; } t; t.u = ((unsigned)v) << 16; return t.f;
}
__device__ __forceinline__ u16 f2bf(float f){
  union { float f; unsigned u; } t; t.f = f;
  unsigned u = t.u;
  return (u16)((u + 0x7fffu + ((u >> 16) & 1u)) >> 16);
}
struct HiLo { short hi, lo; };
__device__ __forceinline__ HiLo split1(float v){
  HiLo r;
  u16 h = f2bf(v);
  r.hi = (short)h;
  r.lo = (short)f2bf(v - bf2f(h));
  return r;
}
__device__ __forceinline__ void ldw8s(const float* __restrict__ p, short8& hi, short8& lo){
  #pragma unroll
  for (int j = 0; j < 8; ++j){ HiLo s = split1(p[j]); hi[j] = s.hi; lo[j] = s.lo; }
}

#define MFMA(acc, a, b) acc = __builtin_amdgcn_mfma_f32_16x16x32_bf16(a, b, acc, 0,0,0)
#define SMACC(acc, ah, al, bh, bl) do{ MFMA(acc, ah, bh); MFMA(acc, ah, bl); MFMA(acc, al, bh); }while(0)
#define SMACC2(acc, ah, al, bh) do{ MFMA(acc, ah, bh); MFMA(acc, al, bh); }while(0)

// ---- prepass: f32 -> bf16 (hi only, RNE) -----------------------------------
__global__ void wcvt(const float* __restrict__ s, u16* __restrict__ hi, int n){
  int i = blockIdx.x * blockDim.x + threadIdx.x;
  if (i < n) hi[i] = f2bf(s[i]);
}

// ---- prepass: Wcomb = Wih0 @ Wout (2048x512 bf16 hi), bb = b0 + Wih0@bout --
__global__ void __launch_bounds__(256) wcomb_k(
    const float* __restrict__ Wih0, const float* __restrict__ Wout,
    const float* __restrict__ bout, const float* __restrict__ bih0,
    const float* __restrict__ bhh0,
    u16* __restrict__ Wch, float* __restrict__ bb)
{
  __shared__ float wl[8*64];
  __shared__ float bo[64];
  const int wg = blockIdx.x, tid = threadIdx.x;
  const int r0 = wg*8;
  for (int i = tid; i < 512; i += 256) wl[i] = Wih0[(r0 + (i >> 6))*64 + (i & 63)];
  if (tid < 64) bo[tid] = bout[tid];
  __syncthreads();
  if (tid < 8){
    int n = r0 + tid;
    float a = bih0[n] + bhh0[n];
    #pragma unroll 8
    for (int d = 0; d < 64; ++d) a += wl[tid*64 + d]*bo[d];
    bb[n] = a;
  }
  #pragma unroll
  for (int jj = 0; jj < 2; ++jj){
    int j = tid + jj*256;
    float acc[8] = {0,0,0,0,0,0,0,0};
    for (int d = 0; d < 64; ++d){
      float wv = Wout[d*512 + j];
      #pragma unroll
      for (int r = 0; r < 8; ++r) acc[r] += wl[r*64 + d]*wv;
    }
    #pragma unroll
    for (int r = 0; r < 8; ++r) Wch[(r0 + r)*512 + j] = f2bf(acc[r]);
  }
}

// ---- init-only tree barrier (threadfence-based, proven R13/R14) ------------
__device__ __forceinline__ void gbar(unsigned* bar, unsigned phase){
  __syncthreads();
  if (threadIdx.x == 0){
    __threadfence();
    const unsigned gg = (unsigned)blockIdx.x >> 4;
    unsigned old = __hip_atomic_fetch_add(bar + 64 + gg*32, 1u, AXR);
    if (old == phase*16u - 1u){
      unsigned r = __hip_atomic_fetch_add(bar, 1u, AXR);
      if (r == phase*16u - 1u)
        __hip_atomic_store(bar + 32, phase, AXR);
    }
    while (__hip_atomic_load(bar + 32, AXR) < phase)
      __builtin_amdgcn_s_sleep(2);
    __threadfence();
  }
  __syncthreads();
}

// ---- global fallback barrier (R14 xbar, any WG placement) ------------------
__device__ __forceinline__ void xbar(unsigned* bar, unsigned phase,
                                     unsigned xcd, unsigned pop, unsigned nx){
  __syncthreads();
  if (threadIdx.x == 0){
    unsigned old = __hip_atomic_fetch_add(bar + 832 + xcd*32, 1u, AXR);
    const bool leader = (old == phase*pop - 1u);
    if (leader){
      asm volatile("buffer_wbl2 sc1\n\ts_waitcnt vmcnt(0)" ::: "memory");
      unsigned r = __hip_atomic_fetch_add(bar + 1344, 1u, AXR);
      if (r == phase*nx - 1u)
        __hip_atomic_store(bar + 1376, phase, AXR);
    }
    while (__hip_atomic_load(bar + 1376, AXR) < phase)
      __builtin_amdgcn_s_sleep(2);
    if (leader){
      asm volatile("buffer_inv sc1\n\ts_waitcnt vmcnt(0)" ::: "memory");
      __hip_atomic_store(bar + 1088 + xcd*32, phase, AXR);
    } else {
      while (__hip_atomic_load(bar + 1088 + xcd*32, AXR) < phase)
        __builtin_amdgcn_s_sleep(1);
      asm volatile("buffer_inv\n\ts_waitcnt vmcnt(0)" ::: "memory");
    }
  }
  __syncthreads();
}

// ---- group-local FLAG-ARRAY barrier (R22): zero RMWs -----------------------
__device__ __forceinline__ void fbar(unsigned* bar, int g, int cg,
                                     unsigned phase, int tid){
  __syncthreads();
  unsigned* flags = bar + 4096 + g*1024;
  if (tid == 0)
    __hip_atomic_store(flags + cg*32, phase, AXR);
  if (tid < 64){
    const int i = tid & 31;
    while (__hip_atomic_load(flags + i*32, AXR) < phase)
      __builtin_amdgcn_s_sleep(1);
    asm volatile("buffer_inv\n\ts_waitcnt vmcnt(0)" ::: "memory");
  }
  __syncthreads();
}

// ---- LDS helpers (XOR-swizzled, G4) ----------------------------------------
__device__ __forceinline__ short8 lds8(const u16* base, int r, int kelem, int rowbytes){
  int bo = r*rowbytes + ((kelem*2) ^ ((r & 7) << 4));
  return *(const short8*)((const char*)base + bo);
}
__device__ __forceinline__ void load_slice64(
    const float* __restrict__ W, int ldw, int rowshift, int nelem,
    u16* lh, u16* ll, int cg, int tid)
{
  const int rowbytes = ldw*2;
  for (int i = tid; i < nelem; i += 256){
    int r = i >> rowshift, k = i & ((1 << rowshift) - 1);
    int n = ((r >> 4) << 9) + cg*16 + (r & 15);
    HiLo s = split1(W[n*ldw + k]);
    int bo = r*rowbytes + ((k*2) ^ ((r & 7) << 4));
    *(u16*)((char*)lh + bo) = (u16)s.hi;
    *(u16*)((char*)ll + bo) = (u16)s.lo;
  }
}
__device__ __forceinline__ void load_slice64h(
    const float* __restrict__ W, int ldw, int rowshift, int nelem,
    u16* lh, int cg, int tid)
{
  const int rowbytes = ldw*2;
  for (int i = tid; i < nelem; i += 256){
    int r = i >> rowshift, k = i & ((1 << rowshift) - 1);
    int n = ((r >> 4) << 9) + cg*16 + (r & 15);
    int bo = r*rowbytes + ((k*2) ^ ((r & 7) << 4));
    *(u16*)((char*)lh + bo) = f2bf(W[n*ldw + k]);
  }
}

// ---- h-block stage: 32 rows x 512 cols hi+lo, coalesced -> swizzled LDS ----
__device__ __forceinline__ void stage32(const u16* __restrict__ gh,
                                        const u16* __restrict__ glo,
                                        u16* sh, u16* sl, int tid){
  #pragma unroll
  for (int i = 0; i < 8; ++i){
    int e = (tid + i*256)*8;
    int row = e >> 9, col = e & 511;
    int bo = row*1024 + ((col*2) ^ ((row & 7) << 4));
    *(short8*)((char*)sh + bo) = *(const short8*)(gh + e);
    *(short8*)((char*)sl + bo) = *(const short8*)(glo + e);
  }
}

// ---- persistent kernel: skewed pipeline + LDS-staged h + REGISTER weights --
__global__ void __launch_bounds__(256, 1) lstm_persist(
    const float* __restrict__ x,
    const float* __restrict__ Whh0, const float* __restrict__ Wih0,
    const u16* __restrict__ W1ih_h, const u16* __restrict__ W1hh_h,
    const u16* __restrict__ Wcmb_h, const float* __restrict__ bb,
    const float* __restrict__ bih0, const float* __restrict__ bhh0,
    const float* __restrict__ bih1, const float* __restrict__ bhh1,
    const float* __restrict__ Wout, const float* __restrict__ bout,
    float* __restrict__ out, unsigned* __restrict__ cnt,
    u16* __restrict__ h0h0, u16* __restrict__ h0h1,
    u16* __restrict__ h0l0, u16* __restrict__ h0l1,
    u16* __restrict__ h1h0, u16* __restrict__ h1h1,
    u16* __restrict__ h1l0, u16* __restrict__ h1l1)
{
  __shared__ u16 whh0_h[32768];                  // 64KB: Whh0 hi, swizzled
  __shared__ u16 hst_h[16384], hst_l[16384];     // 64KB: staged h block
  __shared__ u16 w0ih_h[4096],  w0ih_l[4096];    // 16KB: Wih0 hi+lo
  __shared__ float gl[32*68];                    // gate exchange (aliases xst)
  __shared__ float pr[256];                      // pred partials
  __shared__ float bs0[64], bs1[64], bsd[64];
  __shared__ unsigned s_rank, s_pop, s_nx, s_all;

  u16* xst_h = (u16*)gl;                         // x_t stage: 32x64 hi
  u16* xst_l = (u16*)gl + 2048;                  // 32x64 lo

  const int wg = blockIdx.x, tid = threadIdx.x;
  const int lane = tid & 63, wv = tid >> 6;
  const int cI = lane & 15;
  const int kc = (lane >> 4) << 3;
  const int rl = wv*16 + cI;

  // ---- census: measured XCD id + rank within XCD ----
  unsigned xcd;
  asm volatile("s_getreg_b32 %0, hwreg(HW_REG_XCC_ID)" : "=s"(xcd));
  xcd &= 7u;
  if (tid == 0)
    s_rank = __hip_atomic_fetch_add(cnt + 576 + xcd*32, 1u, AXR);
  gbar(cnt, 1);
  if (tid == 0){
    unsigned nxl = 0, allc = 1;
    for (int i = 0; i < 8; ++i){
      unsigned pv = __hip_atomic_load(cnt + 576 + i*32, AXR);
      nxl += (pv != 0u) ? 1u : 0u;
      if (pv != 32u) allc = 0u;
    }
    s_pop = __hip_atomic_load(cnt + 576 + xcd*32, AXR);
    s_nx  = nxl;
    s_all = allc;
  }
  __syncthreads();
  const unsigned pop = s_pop, nx = s_nx;
  const bool allco = (s_all != 0u);
  const int g  = allco ? (int)xcd    : (wg & 7);
  const int cg = allco ? (int)s_rank : (wg >> 3);
  const int b0 = g*32;

  // ---- one-time init: LDS slices + biases + REGISTER weight fragments ----
  load_slice64h(Whh0, 512, 9, 32768, whh0_h, cg, tid);
  load_slice64(Wih0,  64, 6,  4096, w0ih_h, w0ih_l, cg, tid);
  if (tid < 64){
    int n = ((tid >> 4) << 9) + cg*16 + (tid & 15);
    bs0[tid] = bih0[n] + bhh0[n];
    bs1[tid] = bih1[n] + bhh1[n];
    bsd[tid] = bb[n];
  }
  const int nb = (wv*512 + cg*16 + cI)*512 + kc; // this thread's B-frag base
  short8 w1ih_r[16], w1hh_r[16], wcmb_r[16];     // 192 VGPRs of weights
  #pragma unroll
  for (int ks = 0; ks < 16; ++ks){
    w1ih_r[ks] = *(const short8*)(W1ih_h + nb + ks*32);
    w1hh_r[ks] = *(const short8*)(W1hh_h + nb + ks*32);
    wcmb_r[ks] = *(const short8*)(Wcmb_h + nb + ks*32);
  }
  __syncthreads();

  u16* H0h[2] = { h0h0, h0h1 };  u16* H0l[2] = { h0l0, h0l1 };
  u16* H1h[2] = { h1h0, h1h1 };  u16* H1l[2] = { h1l0, h1l1 };

  float c0r[2] = {0.f, 0.f}, c1r[2] = {0.f, 0.f};
  unsigned ep = 0;
  const int rb_ = (lane >> 4) << 2;
  const int hoff = b0*512;

  #define LDA(kk, a0h_, a0l_, a1h_, a1l_) \
    short8 a0h_ = lds8(hst_h, cI, kc + (kk), 1024); \
    short8 a0l_ = lds8(hst_l, cI, kc + (kk), 1024); \
    short8 a1h_ = lds8(hst_h, cI + 16, kc + (kk), 1024); \
    short8 a1l_ = lds8(hst_l, cI + 16, kc + (kk), 1024);

  // ======== skewed encoder: phase k computes h0_k and h1_{k-1} ========
  for (int k = 0; k <= 336; ++k){
    const int p0 = k & 1;

    if (k < 336){
      #pragma unroll
      for (int i = 0; i < 8; ++i){
        int e = tid + i*256;
        int bb_ = e >> 6, d = e & 63;
        HiLo s = split1(x[(b0 + bb_)*21504 + d*336 + k]);
        int bo = bb_*128 + ((d*2) ^ ((bb_ & 7) << 4));
        *(u16*)((char*)xst_h + bo) = (u16)s.hi;
        *(u16*)((char*)xst_l + bo) = (u16)s.lo;
      }
    }
    stage32(H0h[p0^1] + hoff, H0l[p0^1] + hoff, hst_h, hst_l, tid);
    __syncthreads();

    // l0 gates -> A
    f32x4 A0 = {0,0,0,0}, A1 = {0,0,0,0};
    if (k < 336){
      #pragma unroll
      for (int ks = 0; ks < 2; ++ks){
        int kk = ks*32 + kc;
        short8 a0h = lds8(xst_h, cI, kk, 128);
        short8 a0l = lds8(xst_l, cI, kk, 128);
        short8 a1h = lds8(xst_h, cI + 16, kk, 128);
        short8 a1l = lds8(xst_l, cI + 16, kk, 128);
        short8 bh = lds8(w0ih_h, rl, kk, 128);
        short8 bl = lds8(w0ih_l, rl, kk, 128);
        SMACC(A0, a0h, a0l, bh, bl);
        SMACC(A1, a1h, a1l, bh, bl);
      }
    }
    #pragma unroll 4
    for (int ks = 0; ks < 16; ++ks){             // Whh0 (LDS) over staged h0
      int kk = ks*32;
      LDA(kk, a0h, a0l, a1h, a1l)
      short8 bh = lds8(whh0_h, rl, kc + kk, 1024);
      SMACC2(A0, a0h, a0l, bh);
      SMACC2(A1, a1h, a1l, bh);
    }

    // l1: W1ih (REG) over staged h0_{k-1}, then W1hh (REG) over h1_{k-2}
    f32x4 B0 = {0,0,0,0}, B1 = {0,0,0,0};
    if (k >= 1){
      #pragma unroll
      for (int ks = 0; ks < 16; ++ks){
        int kk = ks*32;
        LDA(kk, a0h, a0l, a1h, a1l)
        SMACC2(B0, a0h, a0l, w1ih_r[ks]);
        SMACC2(B1, a1h, a1l, w1ih_r[ks]);
      }
      __syncthreads();
      stage32(H1h[p0] + hoff, H1l[p0] + hoff, hst_h, hst_l, tid);
      __syncthreads();
      #pragma unroll
      for (int ks = 0; ks < 16; ++ks){
        int kk = ks*32;
        LDA(kk, a0h, a0l, a1h, a1l)
        SMACC2(B0, a0h, a0l, w1hh_r[ks]);
        SMACC2(B1, a1h, a1l, w1hh_r[ks]);
      }
    }

    // cell l0 -> h0_k buf[p0]
    {
      __syncthreads();
      #pragma unroll
      for (int r = 0; r < 4; ++r){
        gl[(rb_ + r)*68 + rl]      = A0[r] + bs0[rl];
        gl[(16 + rb_ + r)*68 + rl] = A1[r] + bs0[rl];
      }
      __syncthreads();
      u16* Hh = H0h[p0]; u16* Hl = H0l[p0];
      #pragma unroll
      for (int q = 0; q < 2; ++q){
        int e = tid + q*256;
        int m = e >> 4, col = e & 15;
        float iv = gl[m*68 + col];
        float fv = gl[m*68 + 16 + col];
        float gv = gl[m*68 + 32 + col];
        float ov = gl[m*68 + 48 + col];
        float si = 1.f/(1.f + expf(-iv));
        float sf = 1.f/(1.f + expf(-fv));
        float so = 1.f/(1.f + expf(-ov));
        float cn = sf*c0r[q] + si*tanhf(gv);
        c0r[q] = cn;
        float h = so*tanhf(cn);
        int gi = (b0 + m)*512 + cg*16 + col;
        u16 hh = f2bf(h);
        Hh[gi] = hh;
        Hl[gi] = f2bf(h - bf2f(hh));
      }
    }
    // cell l1 -> h1_{k-1} buf[p0^1]  (global_feat at k==336)
    if (k >= 1){
      float* gf = (k == 336) ? out : (float*)nullptr;
      __syncthreads();
      #pragma unroll
      for (int r = 0; r < 4; ++r){
        gl[(rb_ + r)*68 + rl]      = B0[r] + bs1[rl];
        gl[(16 + rb_ + r)*68 + rl] = B1[r] + bs1[rl];
      }
      __syncthreads();
      u16* Hh = H1h[p0^1]; u16* Hl = H1l[p0^1];
      #pragma unroll
      for (int q = 0; q < 2; ++q){
        int e = tid + q*256;
        int m = e >> 4, col = e & 15;
        float iv = gl[m*68 + col];
        float fv = gl[m*68 + 16 + col];
        float gv = gl[m*68 + 32 + col];
        float ov = gl[m*68 + 48 + col];
        float si = 1.f/(1.f + expf(-iv));
        float sf = 1.f/(1.f + expf(-fv));
        float so = 1.f/(1.f + expf(-ov));
        float cn = sf*c1r[q] + si*tanhf(gv);
        c1r[q] = cn;
        float h = so*tanhf(cn);
        int gi = (b0 + m)*512 + cg*16 + col;
        u16 hh = f2bf(h);
        Hh[gi] = hh;
        Hl[gi] = f2bf(h - bf2f(hh));
        if (gf) gf[gi] = h;
      }
    }
    ++ep;
    if (allco) fbar(cnt, g, cg, ep, tid); else xbar(cnt, ep, xcd, pop, nx);
  }

  // ======== l1 catch-up: h1_336 (h0_336 buf[0], h1_335 buf[1]) ========
  {
    f32x4 B0 = {0,0,0,0}, B1 = {0,0,0,0};
    stage32(H0h[0] + hoff, H0l[0] + hoff, hst_h, hst_l, tid);
    __syncthreads();
    #pragma unroll
    for (int ks = 0; ks < 16; ++ks){
      int kk = ks*32;
      LDA(kk, a0h, a0l, a1h, a1l)
      SMACC2(B0, a0h, a0l, w1ih_r[ks]);
      SMACC2(B1, a1h, a1l, w1ih_r[ks]);
    }
    __syncthreads();
    stage32(H1h[1] + hoff, H1l[1] + hoff, hst_h, hst_l, tid);
    __syncthreads();
    #pragma unroll
    for (int ks = 0; ks < 16; ++ks){
      int kk = ks*32;
      LDA(kk, a0h, a0l, a1h, a1l)
      SMACC2(B0, a0h, a0l, w1hh_r[ks]);
      SMACC2(B1, a1h, a1l, w1hh_r[ks]);
    }
    __syncthreads();
    #pragma unroll
    for (int r = 0; r < 4; ++r){
      gl[(rb_ + r)*68 + rl]      = B0[r] + bs1[rl];
      gl[(16 + rb_ + r)*68 + rl] = B1[r] + bs1[rl];
    }
    __syncthreads();
    u16* Hh = H1h[0]; u16* Hl = H1l[0];
    #pragma unroll
    for (int q = 0; q < 2; ++q){
      int e = tid + q*256;
      int m = e >> 4, col = e & 15;
      float iv = gl[m*68 + col];
      float fv = gl[m*68 + 16 + col];
      float gv = gl[m*68 + 32 + col];
      float ov = gl[m*68 + 48 + col];
      float si = 1.f/(1.f + expf(-iv));
      float sf = 1.f/(1.f + expf(-fv));
      float so = 1.f/(1.f + expf(-ov));
      float cn = sf*c1r[q] + si*tanhf(gv);
      c1r[q] = cn;
      float h = so*tanhf(cn);
      int gi = (b0 + m)*512 + cg*16 + col;
      u16 hh = f2bf(h);
      Hh[gi] = hh;
      Hl[gi] = f2bf(h - bf2f(hh));
    }
    ++ep;
    if (allco) fbar(cnt, g, cg, ep, tid); else xbar(cnt, ep, xcd, pop, nx);
  }

  // ======== decoder: t = 337..431 ========
  for (int t = 337; t < 432; ++t){
    const int p = t & 1;

    // ---- phase A: stage h1_{t-1} -> Wcomb(REG) + pred; restage h0 -> Whh0
    f32x4 A0 = {0,0,0,0}, A1 = {0,0,0,0};
    stage32(H1h[p^1] + hoff, H1l[p^1] + hoff, hst_h, hst_l, tid);
    __syncthreads();
    #pragma unroll
    for (int ks = 0; ks < 16; ++ks){
      int kk = ks*32;
      LDA(kk, a0h, a0l, a1h, a1l)
      SMACC2(A0, a0h, a0l, wcmb_r[ks]);
      SMACC2(A1, a1h, a1l, wcmb_r[ks]);
    }
    {                                            // pred l=t-337 from staged h1
      const int d = tid & 63, kq = tid >> 6;
      float part = 0.f;
      const float* wr = Wout + d*512 + kq*128;
      #pragma unroll 4
      for (int kk = 0; kk < 128; kk += 8){
        short8 hv = lds8(hst_h, cg, kq*128 + kk, 1024);
        short8 lv = lds8(hst_l, cg, kq*128 + kk, 1024);
        #pragma unroll
        for (int j = 0; j < 8; ++j)
          part += (bf2f((u16)hv[j]) + bf2f((u16)lv[j])) * wr[kk + j];
      }
      pr[d*4 + kq] = part;
      __syncthreads();
      if (tid < 64){
        float v = pr[tid*4] + pr[tid*4+1] + pr[tid*4+2] + pr[tid*4+3] + bout[tid];
        out[131072 + ((b0 + cg)*64 + tid)*96 + (t - 337)] = v;
      }
      __syncthreads();
    }
    stage32(H0h[p^1] + hoff, H0l[p^1] + hoff, hst_h, hst_l, tid);
    __syncthreads();
    #pragma unroll 4
    for (int ks = 0; ks < 16; ++ks){             // Whh0 (LDS) over h0_{t-1}
      int kk = ks*32;
      LDA(kk, a0h, a0l, a1h, a1l)
      short8 bh = lds8(whh0_h, rl, kc + kk, 1024);
      SMACC2(A0, a0h, a0l, bh);
      SMACC2(A1, a1h, a1l, bh);
    }
    {                                            // cell l0 -> h0_t buf[p]
      __syncthreads();
      #pragma unroll
      for (int r = 0; r < 4; ++r){
        gl[(rb_ + r)*68 + rl]      = A0[r] + bsd[rl];
        gl[(16 + rb_ + r)*68 + rl] = A1[r] + bsd[rl];
      }
      __syncthreads();
      u16* Hh = H0h[p]; u16* Hl = H0l[p];
      #pragma unroll
      for (int q = 0; q < 2; ++q){
        int e = tid + q*256;
        int m = e >> 4, col = e & 15;
        float iv = gl[m*68 + col];
        float fv = gl[m*68 + 16 + col];
        float gv = gl[m*68 + 32 + col];
        float ov = gl[m*68 + 48 + col];
        float si = 1.f/(1.f + expf(-iv));
        float sf = 1.f/(1.f + expf(-fv));
        float so = 1.f/(1.f + expf(-ov));
        float cn = sf*c0r[q] + si*tanhf(gv);
        c0r[q] = cn;
        float h = so*tanhf(cn);
        int gi = (b0 + m)*512 + cg*16 + col;
        u16 hh = f2bf(h);
        Hh[gi] = hh;
        Hl[gi] = f2bf(h - bf2f(hh));
      }
    }
    ++ep;
    if (allco) fbar(cnt, g, cg, ep, tid); else xbar(cnt, ep, xcd, pop, nx);

    // ---- phase B: stage h0_t -> W1ih(REG); restage h1_{t-1} -> W1hh(REG) ---
    f32x4 B0 = {0,0,0,0}, B1 = {0,0,0,0};
    stage32(H0h[p] + hoff, H0l[p] + hoff, hst_h, hst_l, tid);
    __syncthreads();
    #pragma unroll
    for (int ks = 0; ks < 16; ++ks){
      int kk = ks*32;
      LDA(kk, a0h, a0l, a1h, a1l)
      SMACC2(B0, a0h, a0l, w1ih_r[ks]);
      SMACC2(B1, a1h, a1l, w1ih_r[ks]);
    }
    __syncthreads();
    stage32(H1h[p^1] + hoff, H1l[p^1] + hoff, hst_h, hst_l, tid);
    __syncthreads();
    #pragma unroll
    for (int ks = 0; ks < 16; ++ks){
      int kk = ks*32;
      LDA(kk, a0h, a0l, a1h, a1l)
      SMACC2(B0, a0h, a0l, w1hh_r[ks]);
      SMACC2(B1, a1h, a1l, w1hh_r[ks]);
    }
    {
      __syncthreads();
      #pragma unroll
      for (int r = 0; r < 4; ++r){
        gl[(rb_ + r)*68 + rl]      = B0[r] + bs1[rl];
        gl[(16 + rb_ + r)*68 + rl] = B1[r] + bs1[rl];
      }
      __syncthreads();
      u16* Hh = H1h[p]; u16* Hl = H1l[p];
      #pragma unroll
      for (int q = 0; q < 2; ++q){
        int e = tid + q*256;
        int m = e >> 4, col = e & 15;
        float iv = gl[m*68 + col];
        float fv = gl[m*68 + 16 + col];
        float gv = gl[m*68 + 32 + col];
        float ov = gl[m*68 + 48 + col];
        float si = 1.f/(1.f + expf(-iv));
        float sf = 1.f/(1.f + expf(-fv));
        float so = 1.f/(1.f + expf(-ov));
        float cn = sf*c1r[q] + si*tanhf(gv);
        c1r[q] = cn;
        float h = so*tanhf(cn);
        int gi = (b0 + m)*512 + cg*16 + col;
        u16 hh = f2bf(h);
        Hh[gi] = hh;
        Hl[gi] = f2bf(h - bf2f(hh));
      }
    }
    ++ep;
    if (allco) fbar(cnt, g, cg, ep, tid); else xbar(cnt, ep, xcd, pop, nx);
  }
  #undef LDA
}

// ---- tail: pred for l=95 from h1_431 (parity 1) ----------------------------
__global__ void __launch_bounds__(256) pred_last(
    const u16* __restrict__ h1hi, const u16* __restrict__ h1lo,
    const float* __restrict__ Wout, const float* __restrict__ bout,
    float* __restrict__ out)
{
  const int wg = blockIdx.x, tid = threadIdx.x;
  const int bsub = tid >> 6, d = tid & 63;
  const int b = wg*4 + bsub;
  float acc = bout[d];
  const u16* hH = h1hi + b*512;
  const u16* hL = h1lo + b*512;
  const float* wr = Wout + d*512;
  #pragma unroll 8
  for (int k = 0; k < 512; k += 8){
    short8 hv = *(const short8*)(hH + k);
    short8 lv = *(const short8*)(hL + k);
    #pragma unroll
    for (int j = 0; j < 8; ++j)
      acc += (bf2f((u16)hv[j]) + bf2f((u16)lv[j])) * wr[k + j];
  }
  out[131072 + (b*64 + d)*96 + 95] = acc;
}

// ======================= fallback (R9 proven path) ==========================
__device__ __forceinline__ void cell_epilogue_fb(
    float* gl, const float* bs, float* __restrict__ cbuf,
    u16* __restrict__ hhi, u16* __restrict__ hlo,
    float* __restrict__ gfout, int mrow, int jblk,
    const f32x4& a0, const f32x4& a1, int wv, int lane, int tid)
{
  __syncthreads();
  const int rbase = wv*16 + ((lane >> 4) << 2);
  const int cI = lane & 15;
  #pragma unroll
  for (int r = 0; r < 4; ++r){
    gl[(rbase+r)*33 + cI]      = a0[r] + bs[cI];
    gl[(rbase+r)*33 + 16 + cI] = a1[r] + bs[16 + cI];
  }
  __syncthreads();
  #pragma unroll
  for (int q = 0; q < 2; ++q){
    int e = tid + q*256;
    int m = e >> 3, jj = e & 7;
    float iv = gl[m*33 + jj];
    float fv = gl[m*33 + 8 + jj];
    float gv = gl[m*33 + 16 + jj];
    float ov = gl[m*33 + 24 + jj];
    float si = 1.f/(1.f + expf(-iv));
    float sf = 1.f/(1.f + expf(-fv));
    float so = 1.f/(1.f + expf(-ov));
    int gi = (mrow*64 + m)*512 + jblk*8 + jj;
    float cn = sf*cbuf[gi] + si*tanhf(gv);
    cbuf[gi] = cn;
    float h = so*tanhf(cn);
    u16 hh = f2bf(h);
    hhi[gi] = hh;
    hlo[gi] = f2bf(h - bf2f(hh));
    if (gfout) gfout[gi] = h;
  }
}

template<bool ENC>
__global__ void __launch_bounds__(256) l0_fb(
    const float* __restrict__ x,
    const u16* __restrict__ predhi, const u16* __restrict__ predlo,
    const float* __restrict__ Wihf, const float* __restrict__ Whhf,
    const float* __restrict__ bih, const float* __restrict__ bhh,
    const u16* __restrict__ hphi, const u16* __restrict__ hplo,
    u16* __restrict__ hnhi, u16* __restrict__ hnlo,
    float* __restrict__ c0, int t)
{
  __shared__ float gl[64*33];
  __shared__ float bs[32];
  const int wg = blockIdx.x, tid = threadIdx.x;
  const int mrow = wg & 3, jblk = wg >> 2;
  const int lane = tid & 63, wv = tid >> 6;
  if (tid < 32){
    int n = ((tid >> 3) << 9) + jblk*8 + (tid & 7);
    bs[tid] = bih[n] + bhh[n];
  }
  const int ar = mrow*64 + wv*16 + (lane & 15);
  const int kc = (lane >> 4) << 3;
  const int cI = lane & 15;
  const int n0 = ((cI >> 3) << 9) + jblk*8 + (cI & 7);
  const int n1 = n0 + 1024;

  f32x4 acc0 = {0,0,0,0}, acc1 = {0,0,0,0};
  #pragma unroll
  for (int ks = 0; ks < 2; ++ks){
    int k = ks*32 + kc;
    short8 ah, al;
    if (ENC){
      const float* xb = x + ar*21504 + t;
      #pragma unroll
      for (int j = 0; j < 8; ++j){ HiLo s = split1(xb[(k + j)*336]); ah[j] = s.hi; al[j] = s.lo; }
    } else {
      ah = *(const short8*)(predhi + ar*64 + k);
      al = *(const short8*)(predlo + ar*64 + k);
    }
    short8 bh0, bl0, bh1, bl1;
    ldw8s(Wihf + n0*64 + k, bh0, bl0);
    ldw8s(Wihf + n1*64 + k, bh1, bl1);
    SMACC(acc0, ah, al, bh0, bl0);
    SMACC(acc1, ah, al, bh1, bl1);
  }
  const u16* hH = hphi + ar*512 + kc;
  const u16* hL = hplo + ar*512 + kc;
  #pragma unroll 4
  for (int ks = 0; ks < 16; ++ks){
    int k = ks*32;
    short8 ah = *(const short8*)(hH + k);
    short8 al = *(const short8*)(hL + k);
    short8 bh0, bl0, bh1, bl1;
    ldw8s(Whhf + n0*512 + kc + k, bh0, bl0);
    ldw8s(Whhf + n1*512 + kc + k, bh1, bl1);
    SMACC(acc0, ah, al, bh0, bl0);
    SMACC(acc1, ah, al, bh1, bl1);
  }
  cell_epilogue_fb(gl, bs, c0, hnhi, hnlo, nullptr, mrow, jblk, acc0, acc1, wv, lane, tid);
}

__global__ void __launch_bounds__(256) l1_fb(
    const float* __restrict__ Wihf, const float* __restrict__ Whhf,
    const float* __restrict__ bih, const float* __restrict__ bhh,
    const u16* __restrict__ h0hi, const u16* __restrict__ h0lo,
    const u16* __restrict__ h1phi, const u16* __restrict__ h1plo,
    u16* __restrict__ h1nhi, u16* __restrict__ h1nlo,
    float* __restrict__ c1, float* __restrict__ gfout)
{
  __shared__ float gl[64*33];
  __shared__ float bs[32];
  const int wg = blockIdx.x, tid = threadIdx.x;
  const int mrow = wg & 3, jblk = wg >> 2;
  const int lane = tid & 63, wv = tid >> 6;
  if (tid < 32){
    int n = ((tid >> 3) << 9) + jblk*8 + (tid & 7);
    bs[tid] = bih[n] + bhh[n];
  }
  const int ar = mrow*64 + wv*16 + (lane & 15);
  const int kc = (lane >> 4) << 3;
  const int cI = lane & 15;
  const int n0 = ((cI >> 3) << 9) + jblk*8 + (cI & 7);
  const int n1 = n0 + 1024;

  f32x4 acc0 = {0,0,0,0}, acc1 = {0,0,0,0};
  {
    const u16* hH = h0hi + ar*512 + kc;
    const u16* hL = h0lo + ar*512 + kc;
    #pragma unroll 4
    for (int ks = 0; ks < 16; ++ks){
      int k = ks*32;
      short8 ah = *(const short8*)(hH + k);
      short8 al = *(const short8*)(hL + k);
      short8 bh0, bl0, bh1, bl1;
      ldw8s(Wihf + n0*512 + kc + k, bh0, bl0);
      ldw8s(Wihf + n1*512 + kc + k, bh1, bl1);
      SMACC(acc0, ah, al, bh0, bl0);
      SMACC(acc1, ah, al, bh1, bl1);
    }
  }
  {
    const u16* hH = h1phi + ar*512 + kc;
    const u16* hL = h1plo + ar*512 + kc;
    #pragma unroll 4
    for (int ks = 0; ks < 16; ++ks){
      int k = ks*32;
      short8 ah = *(const short8*)(hH + k);
      short8 al = *(const short8*)(hL + k);
      short8 bh0, bl0, bh1, bl1;
      ldw8s(Whhf + n0*512 + kc + k, bh0, bl0);
      ldw8s(Whhf + n1*512 + kc + k, bh1, bl1);
      SMACC(acc0, ah, al, bh0, bl0);
      SMACC(acc1, ah, al, bh1, bl1);
    }
  }
  cell_epilogue_fb(gl, bs, c1, h1nhi, h1nlo, gfout, mrow, jblk, acc0, acc1, wv, lane, tid);
}

__global__ void __launch_bounds__(256) pred_fb(
    const u16* __restrict__ h1hi, const u16* __restrict__ h1lo,
    const float* __restrict__ Wout, const float* __restrict__ bout,
    u16* __restrict__ predhi, u16* __restrict__ predlo,
    float* __restrict__ out, int l)
{
  const int wg = blockIdx.x, tid = threadIdx.x;
  const int bsub = tid >> 6, d = tid & 63;
  const int b = wg*4 + bsub;
  float acc = bout[d];
  const u16* hH = h1hi + b*512;
  const u16* hL = h1lo + b*512;
  const float* wr = Wout + d*512;
  #pragma unroll 8
  for (int k = 0; k < 512; k += 8){
    short8 hv = *(const short8*)(hH + k);
    short8 lv = *(const short8*)(hL + k);
    #pragma unroll
    for (int j = 0; j < 8; ++j)
      acc += (bf2f((u16)hv[j]) + bf2f((u16)lv[j])) * wr[k + j];
  }
  HiLo s = split1(acc);
  predhi[b*64 + d] = (u16)s.hi;
  predlo[b*64 + d] = (u16)s.lo;
  out[131072 + (b*64 + d)*96 + l] = acc;
}

extern "C" void kernel_launch(void* const* d_in, const int* in_sizes, int n_in,
                              void* d_out, int out_size, void* d_ws, size_t ws_size,
                              hipStream_t stream)
{
  const float* x    = (const float*)d_in[0];
  const float* Wih0 = (const float*)d_in[1];
  const float* Whh0 = (const float*)d_in[2];
  const float* bih0 = (const float*)d_in[3];
  const float* bhh0 = (const float*)d_in[4];
  const float* Wih1 = (const float*)d_in[5];
  const float* Whh1 = (const float*)d_in[6];
  const float* bih1 = (const float*)d_in[7];
  const float* bhh1 = (const float*)d_in[8];
  const float* Wout = (const float*)d_in[9];
  const float* bout = (const float*)d_in[10];
  float* out = (float*)d_out;

  // ---- ws layout (main): h 2MB | cnt/flags 64KB | hi weights 6MB | bb 8KB
  char* ws = (char*)d_ws;
  u16* h0h[2] = { (u16*)(ws + 0),       (u16*)(ws + 262144) };
  u16* h0l[2] = { (u16*)(ws + 524288),  (u16*)(ws + 786432) };
  u16* h1h[2] = { (u16*)(ws + 1048576), (u16*)(ws + 1310720) };
  u16* h1l[2] = { (u16*)(ws + 1572864), (u16*)(ws + 1835008) };
  unsigned* cnt = (unsigned*)(ws + 2097152);
  u16* Wcmb_h = (u16*)(ws + 2162688);
  u16* W1ih_h = Wcmb_h + 1048576;
  u16* W1hh_h = W1ih_h + 1048576;
  float* bb   = (float*)(W1hh_h + 1048576);
  const size_t NEED = 2162688u + 3u*2097152u + 8192u;   // ~8.5 MB
  // fallback layout (only used when ws too small)
  float* fb_c0 = (float*)(ws + 2162688);
  float* fb_c1 = (float*)(ws + 2686976);
  u16* predh   = (u16*)(ws + 3211264);
  u16* predl   = (u16*)(ws + 3244032);
  const bool ps = (ws_size >= NEED);

  (void)hipMemsetAsync(d_ws, 0, 3276800, stream);   // h + cnt/flags (+ fb c/pred)

  if (ps){
    wcomb_k<<<dim3(256), dim3(256), 0, stream>>>(Wih0, Wout, bout, bih0, bhh0,
                                                 Wcmb_h, bb);
    wcvt<<<dim3(4096), dim3(256), 0, stream>>>(Wih1, W1ih_h, 1048576);
    wcvt<<<dim3(4096), dim3(256), 0, stream>>>(Whh1, W1hh_h, 1048576);
    lstm_persist<<<dim3(256), dim3(256), 0, stream>>>(
        x, Whh0, Wih0, W1ih_h, W1hh_h, Wcmb_h, bb,
        bih0, bhh0, bih1, bhh1, Wout, bout, out, cnt,
        h0h[0], h0h[1], h0l[0], h0l[1], h1h[0], h1h[1], h1l[0], h1l[1]);
    pred_last<<<dim3(64), dim3(256), 0, stream>>>(h1h[1], h1l[1], Wout, bout, out);
  } else {
    for (int t = 0; t < 432; ++t){
      const int p = t & 1;
      float* gf = (t == 335) ? out : (float*)nullptr;
      if (t < 336)
        l0_fb<true><<<dim3(256), dim3(256), 0, stream>>>(
            x, predh, predl, Wih0, Whh0, bih0, bhh0,
            h0h[p^1], h0l[p^1], h0h[p], h0l[p], fb_c0, t);
      else
        l0_fb<false><<<dim3(256), dim3(256), 0, stream>>>(
            x, predh, predl, Wih0, Whh0, bih0, bhh0,
            h0h[p^1], h0l[p^1], h0h[p], h0l[p], fb_c0, t);
      l1_fb<<<dim3(256), dim3(256), 0, stream>>>(
          Wih1, Whh1, bih1, bhh1, h0h[p], h0l[p],
          h1h[p^1], h1l[p^1], h1h[p], h1l[p], fb_c1, gf);
      if (t >= 336)
        pred_fb<<<dim3(64), dim3(256), 0, stream>>>(
            h1h[p], h1l[p], Wout, bout, predh, predl, out, t - 336);
    }
  }
}

// Round 26
// 4170.832 us; speedup vs baseline: 5.1843x; 1.4394x over previous
//
#include <hip/hip_runtime.h>

typedef unsigned short u16;
typedef __attribute__((ext_vector_type(8))) short short8;
typedef __attribute__((ext_vector_type(4))) float f32x4;

#define AXR __ATOMIC_RELAXED, __HIP_MEMORY_SCOPE_AGENT

__device__ __forceinline__ float bf2f(u16 v){
  union { unsigned u; float f; } t; t.u = ((unsigned)v) << 16; return t.f;
}
__device__ __forceinline__ u16 f2bf(float f){
  union { float f; unsigned u; } t; t.f = f;
  unsigned u = t.u;
  return (u16)((u + 0x7fffu + ((u >> 16) & 1u)) >> 16);
}
struct HiLo { short hi, lo; };
__device__ __forceinline__ HiLo split1(float v){
  HiLo r;
  u16 h = f2bf(v);
  r.hi = (short)h;
  r.lo = (short)f2bf(v - bf2f(h));
  return r;
}
__device__ __forceinline__ void ldw8s(const float* __restrict__ p, short8& hi, short8& lo){
  #pragma unroll
  for (int j = 0; j < 8; ++j){ HiLo s = split1(p[j]); hi[j] = s.hi; lo[j] = s.lo; }
}

#define MFMA(acc, a, b) acc = __builtin_amdgcn_mfma_f32_16x16x32_bf16(a, b, acc, 0,0,0)
#define SMACC(acc, ah, al, bh, bl) do{ MFMA(acc, ah, bh); MFMA(acc, ah, bl); MFMA(acc, al, bh); }while(0)
#define SMACC2(acc, ah, al, bh) do{ MFMA(acc, ah, bh); MFMA(acc, al, bh); }while(0)

// ---- prepass: f32 -> bf16 (hi only, RNE) -----------------------------------
__global__ void wcvt(const float* __restrict__ s, u16* __restrict__ hi, int n){
  int i = blockIdx.x * blockDim.x + threadIdx.x;
  if (i < n) hi[i] = f2bf(s[i]);
}

// ---- prepass: Wcomb = Wih0 @ Wout (2048x512 bf16 hi), bb = b0 + Wih0@bout --
__global__ void __launch_bounds__(256) wcomb_k(
    const float* __restrict__ Wih0, const float* __restrict__ Wout,
    const float* __restrict__ bout, const float* __restrict__ bih0,
    const float* __restrict__ bhh0,
    u16* __restrict__ Wch, float* __restrict__ bb)
{
  __shared__ float wl[8*64];
  __shared__ float bo[64];
  const int wg = blockIdx.x, tid = threadIdx.x;
  const int r0 = wg*8;
  for (int i = tid; i < 512; i += 256) wl[i] = Wih0[(r0 + (i >> 6))*64 + (i & 63)];
  if (tid < 64) bo[tid] = bout[tid];
  __syncthreads();
  if (tid < 8){
    int n = r0 + tid;
    float a = bih0[n] + bhh0[n];
    #pragma unroll 8
    for (int d = 0; d < 64; ++d) a += wl[tid*64 + d]*bo[d];
    bb[n] = a;
  }
  #pragma unroll
  for (int jj = 0; jj < 2; ++jj){
    int j = tid + jj*256;
    float acc[8] = {0,0,0,0,0,0,0,0};
    for (int d = 0; d < 64; ++d){
      float wv = Wout[d*512 + j];
      #pragma unroll
      for (int r = 0; r < 8; ++r) acc[r] += wl[r*64 + d]*wv;
    }
    #pragma unroll
    for (int r = 0; r < 8; ++r) Wch[(r0 + r)*512 + j] = f2bf(acc[r]);
  }
}

// ---- init-only tree barrier (threadfence-based, proven R13/R14) ------------
__device__ __forceinline__ void gbar(unsigned* bar, unsigned phase){
  __syncthreads();
  if (threadIdx.x == 0){
    __threadfence();
    const unsigned gg = (unsigned)blockIdx.x >> 4;
    unsigned old = __hip_atomic_fetch_add(bar + 64 + gg*32, 1u, AXR);
    if (old == phase*16u - 1u){
      unsigned r = __hip_atomic_fetch_add(bar, 1u, AXR);
      if (r == phase*16u - 1u)
        __hip_atomic_store(bar + 32, phase, AXR);
    }
    while (__hip_atomic_load(bar + 32, AXR) < phase)
      __builtin_amdgcn_s_sleep(2);
    __threadfence();
  }
  __syncthreads();
}

// ---- global fallback barrier (R14 xbar, any WG placement) ------------------
__device__ __forceinline__ void xbar(unsigned* bar, unsigned phase,
                                     unsigned xcd, unsigned pop, unsigned nx){
  __syncthreads();
  if (threadIdx.x == 0){
    unsigned old = __hip_atomic_fetch_add(bar + 832 + xcd*32, 1u, AXR);
    const bool leader = (old == phase*pop - 1u);
    if (leader){
      asm volatile("buffer_wbl2 sc1\n\ts_waitcnt vmcnt(0)" ::: "memory");
      unsigned r = __hip_atomic_fetch_add(bar + 1344, 1u, AXR);
      if (r == phase*nx - 1u)
        __hip_atomic_store(bar + 1376, phase, AXR);
    }
    while (__hip_atomic_load(bar + 1376, AXR) < phase)
      __builtin_amdgcn_s_sleep(2);
    if (leader){
      asm volatile("buffer_inv sc1\n\ts_waitcnt vmcnt(0)" ::: "memory");
      __hip_atomic_store(bar + 1088 + xcd*32, phase, AXR);
    } else {
      while (__hip_atomic_load(bar + 1088 + xcd*32, AXR) < phase)
        __builtin_amdgcn_s_sleep(1);
      asm volatile("buffer_inv\n\ts_waitcnt vmcnt(0)" ::: "memory");
    }
  }
  __syncthreads();
}

// ---- group-local FLAG-ARRAY barrier (R22): zero RMWs -----------------------
__device__ __forceinline__ void fbar(unsigned* bar, int g, int cg,
                                     unsigned phase, int tid){
  __syncthreads();
  unsigned* flags = bar + 4096 + g*1024;
  if (tid == 0)
    __hip_atomic_store(flags + cg*32, phase, AXR);
  if (tid < 64){
    const int i = tid & 31;
    while (__hip_atomic_load(flags + i*32, AXR) < phase)
      __builtin_amdgcn_s_sleep(1);
    asm volatile("buffer_inv\n\ts_waitcnt vmcnt(0)" ::: "memory");
  }
  __syncthreads();
}

// ---- LDS helpers (XOR-swizzled, G4) ----------------------------------------
__device__ __forceinline__ short8 lds8(const u16* base, int r, int kelem, int rowbytes){
  int bo = r*rowbytes + ((kelem*2) ^ ((r & 7) << 4));
  return *(const short8*)((const char*)base + bo);
}
__device__ __forceinline__ void load_slice64(
    const float* __restrict__ W, int ldw, int rowshift, int nelem,
    u16* lh, u16* ll, int cg, int tid)
{
  const int rowbytes = ldw*2;
  for (int i = tid; i < nelem; i += 256){
    int r = i >> rowshift, k = i & ((1 << rowshift) - 1);
    int n = ((r >> 4) << 9) + cg*16 + (r & 15);
    HiLo s = split1(W[n*ldw + k]);
    int bo = r*rowbytes + ((k*2) ^ ((r & 7) << 4));
    *(u16*)((char*)lh + bo) = (u16)s.hi;
    *(u16*)((char*)ll + bo) = (u16)s.lo;
  }
}
__device__ __forceinline__ void load_slice64h(
    const float* __restrict__ W, int ldw, int rowshift, int nelem,
    u16* lh, int cg, int tid)
{
  const int rowbytes = ldw*2;
  for (int i = tid; i < nelem; i += 256){
    int r = i >> rowshift, k = i & ((1 << rowshift) - 1);
    int n = ((r >> 4) << 9) + cg*16 + (r & 15);
    int bo = r*rowbytes + ((k*2) ^ ((r & 7) << 4));
    *(u16*)((char*)lh + bo) = f2bf(W[n*ldw + k]);
  }
}

// ---- h-block stage (hi only): 32x512, coalesced -> swizzled LDS ------------
__device__ __forceinline__ void stage32h(const u16* __restrict__ gh,
                                         u16* sh, int tid){
  #pragma unroll
  for (int i = 0; i < 8; ++i){
    int e = (tid + i*256)*8;
    int row = e >> 9, col = e & 511;
    int bo = row*1024 + ((col*2) ^ ((row & 7) << 4));
    *(short8*)((char*)sh + bo) = *(const short8*)(gh + e);
  }
}

// ---- persistent kernel: skewed pipeline, hi-only h, register weights -------
__global__ void __launch_bounds__(256, 1) lstm_persist(
    const float* __restrict__ x,
    const float* __restrict__ Whh0, const float* __restrict__ Wih0,
    const u16* __restrict__ W1ih_h, const u16* __restrict__ W1hh_h,
    const u16* __restrict__ Wcmb_h, const float* __restrict__ bb,
    const float* __restrict__ bih0, const float* __restrict__ bhh0,
    const float* __restrict__ bih1, const float* __restrict__ bhh1,
    const float* __restrict__ Wout, const float* __restrict__ bout,
    float* __restrict__ out, unsigned* __restrict__ cnt,
    u16* __restrict__ h0h0, u16* __restrict__ h0h1,
    u16* __restrict__ h1h0, u16* __restrict__ h1h1)
{
  __shared__ u16 whh0_h[32768];                  // 64KB: Whh0 hi, swizzled
  __shared__ u16 hst_h[16384];                   // 32KB: staged h block (hi)
  __shared__ u16 w0ih_h[4096],  w0ih_l[4096];    // 16KB: Wih0 hi+lo
  __shared__ float gl[32*68];                    // gate exchange (aliases xst)
  __shared__ float pr[256];                      // pred partials
  __shared__ float bs0[64], bs1[64], bsd[64];
  __shared__ unsigned s_rank, s_pop, s_nx, s_all;

  u16* xst_h = (u16*)gl;                         // x_t stage: 32x64 hi
  u16* xst_l = (u16*)gl + 2048;                  // 32x64 lo

  const int wg = blockIdx.x, tid = threadIdx.x;
  const int lane = tid & 63, wv = tid >> 6;
  const int cI = lane & 15;
  const int kc = (lane >> 4) << 3;
  const int rl = wv*16 + cI;

  // ---- census: measured XCD id + rank within XCD ----
  unsigned xcd;
  asm volatile("s_getreg_b32 %0, hwreg(HW_REG_XCC_ID)" : "=s"(xcd));
  xcd &= 7u;
  if (tid == 0)
    s_rank = __hip_atomic_fetch_add(cnt + 576 + xcd*32, 1u, AXR);
  gbar(cnt, 1);
  if (tid == 0){
    unsigned nxl = 0, allc = 1;
    for (int i = 0; i < 8; ++i){
      unsigned pv = __hip_atomic_load(cnt + 576 + i*32, AXR);
      nxl += (pv != 0u) ? 1u : 0u;
      if (pv != 32u) allc = 0u;
    }
    s_pop = __hip_atomic_load(cnt + 576 + xcd*32, AXR);
    s_nx  = nxl;
    s_all = allc;
  }
  __syncthreads();
  const unsigned pop = s_pop, nx = s_nx;
  const bool allco = (s_all != 0u);
  const int g  = allco ? (int)xcd    : (wg & 7);
  const int cg = allco ? (int)s_rank : (wg >> 3);
  const int b0 = g*32;

  // ---- one-time init: LDS slices + biases + REGISTER weight fragments ----
  load_slice64h(Whh0, 512, 9, 32768, whh0_h, cg, tid);
  load_slice64(Wih0,  64, 6,  4096, w0ih_h, w0ih_l, cg, tid);
  if (tid < 64){
    int n = ((tid >> 4) << 9) + cg*16 + (tid & 15);
    bs0[tid] = bih0[n] + bhh0[n];
    bs1[tid] = bih1[n] + bhh1[n];
    bsd[tid] = bb[n];
  }
  const int nb = (wv*512 + cg*16 + cI)*512 + kc; // this thread's B-frag base
  short8 w1ih_r[16], w1hh_r[16], wcmb_r[16];     // 192 VGPRs of weights
  #pragma unroll
  for (int ks = 0; ks < 16; ++ks){
    w1ih_r[ks] = *(const short8*)(W1ih_h + nb + ks*32);
    w1hh_r[ks] = *(const short8*)(W1hh_h + nb + ks*32);
    wcmb_r[ks] = *(const short8*)(Wcmb_h + nb + ks*32);
  }
  __syncthreads();

  u16* H0h[2] = { h0h0, h0h1 };
  u16* H1h[2] = { h1h0, h1h1 };

  float c0r[2] = {0.f, 0.f}, c1r[2] = {0.f, 0.f};
  unsigned ep = 0;
  const int rb_ = (lane >> 4) << 2;
  const int hoff = b0*512;

  // hi-only A fragment reads from staged block
  #define LDA2(kk, a0h_, a1h_) \
    short8 a0h_ = lds8(hst_h, cI, kc + (kk), 1024); \
    short8 a1h_ = lds8(hst_h, cI + 16, kc + (kk), 1024);

  // ======== skewed encoder: phase k computes h0_k and h1_{k-1} ========
  for (int k = 0; k <= 336; ++k){
    const int p0 = k & 1;

    if (k < 336){
      #pragma unroll
      for (int i = 0; i < 8; ++i){
        int e = tid + i*256;
        int bb_ = e >> 6, d = e & 63;
        HiLo s = split1(x[(b0 + bb_)*21504 + d*336 + k]);
        int bo = bb_*128 + ((d*2) ^ ((bb_ & 7) << 4));
        *(u16*)((char*)xst_h + bo) = (u16)s.hi;
        *(u16*)((char*)xst_l + bo) = (u16)s.lo;
      }
    }
    stage32h(H0h[p0^1] + hoff, hst_h, tid);
    __syncthreads();

    // l0 gates -> A; fused W1ih(REG) accumulation into B over same staged h0
    f32x4 A0 = {0,0,0,0}, A1 = {0,0,0,0};
    f32x4 B0 = {0,0,0,0}, B1 = {0,0,0,0};
    if (k < 336){
      #pragma unroll
      for (int ks = 0; ks < 2; ++ks){
        int kk = ks*32 + kc;
        short8 a0h = lds8(xst_h, cI, kk, 128);
        short8 a0l = lds8(xst_l, cI, kk, 128);
        short8 a1h = lds8(xst_h, cI + 16, kk, 128);
        short8 a1l = lds8(xst_l, cI + 16, kk, 128);
        short8 bh = lds8(w0ih_h, rl, kk, 128);
        short8 bl = lds8(w0ih_l, rl, kk, 128);
        SMACC(A0, a0h, a0l, bh, bl);
        SMACC(A1, a1h, a1l, bh, bl);
      }
    }
    #pragma unroll
    for (int ks = 0; ks < 16; ++ks){             // fused: Whh0(LDS) + W1ih(REG)
      int kk = ks*32;
      LDA2(kk, a0h, a1h)
      short8 bh = lds8(whh0_h, rl, kc + kk, 1024);
      MFMA(A0, a0h, bh);
      MFMA(A1, a1h, bh);
      MFMA(B0, a0h, w1ih_r[ks]);
      MFMA(B1, a1h, w1ih_r[ks]);
    }

    // l1 part 2: W1hh (REG) over h1_{k-2}
    if (k >= 1){
      __syncthreads();
      stage32h(H1h[p0] + hoff, hst_h, tid);
      __syncthreads();
      #pragma unroll
      for (int ks = 0; ks < 16; ++ks){
        int kk = ks*32;
        LDA2(kk, a0h, a1h)
        MFMA(B0, a0h, w1hh_r[ks]);
        MFMA(B1, a1h, w1hh_r[ks]);
      }
    }

    // cell l0 -> h0_k buf[p0]
    {
      __syncthreads();
      #pragma unroll
      for (int r = 0; r < 4; ++r){
        gl[(rb_ + r)*68 + rl]      = A0[r] + bs0[rl];
        gl[(16 + rb_ + r)*68 + rl] = A1[r] + bs0[rl];
      }
      __syncthreads();
      u16* Hh = H0h[p0];
      #pragma unroll
      for (int q = 0; q < 2; ++q){
        int e = tid + q*256;
        int m = e >> 4, col = e & 15;
        float iv = gl[m*68 + col];
        float fv = gl[m*68 + 16 + col];
        float gv = gl[m*68 + 32 + col];
        float ov = gl[m*68 + 48 + col];
        float si = 1.f/(1.f + expf(-iv));
        float sf = 1.f/(1.f + expf(-fv));
        float so = 1.f/(1.f + expf(-ov));
        float cn = sf*c0r[q] + si*tanhf(gv);
        c0r[q] = cn;
        float h = so*tanhf(cn);
        Hh[(b0 + m)*512 + cg*16 + col] = f2bf(h);
      }
    }
    // cell l1 -> h1_{k-1} buf[p0^1]  (global_feat at k==336)
    if (k >= 1){
      float* gf = (k == 336) ? out : (float*)nullptr;
      __syncthreads();
      #pragma unroll
      for (int r = 0; r < 4; ++r){
        gl[(rb_ + r)*68 + rl]      = B0[r] + bs1[rl];
        gl[(16 + rb_ + r)*68 + rl] = B1[r] + bs1[rl];
      }
      __syncthreads();
      u16* Hh = H1h[p0^1];
      #pragma unroll
      for (int q = 0; q < 2; ++q){
        int e = tid + q*256;
        int m = e >> 4, col = e & 15;
        float iv = gl[m*68 + col];
        float fv = gl[m*68 + 16 + col];
        float gv = gl[m*68 + 32 + col];
        float ov = gl[m*68 + 48 + col];
        float si = 1.f/(1.f + expf(-iv));
        float sf = 1.f/(1.f + expf(-fv));
        float so = 1.f/(1.f + expf(-ov));
        float cn = sf*c1r[q] + si*tanhf(gv);
        c1r[q] = cn;
        float h = so*tanhf(cn);
        int gi = (b0 + m)*512 + cg*16 + col;
        Hh[gi] = f2bf(h);
        if (gf) gf[gi] = h;
      }
    }
    ++ep;
    if (allco) fbar(cnt, g, cg, ep, tid); else xbar(cnt, ep, xcd, pop, nx);
  }

  // ======== l1 catch-up: h1_336 (h0_336 buf[0], h1_335 buf[1]) ========
  {
    f32x4 B0 = {0,0,0,0}, B1 = {0,0,0,0};
    stage32h(H0h[0] + hoff, hst_h, tid);
    __syncthreads();
    #pragma unroll
    for (int ks = 0; ks < 16; ++ks){
      int kk = ks*32;
      LDA2(kk, a0h, a1h)
      MFMA(B0, a0h, w1ih_r[ks]);
      MFMA(B1, a1h, w1ih_r[ks]);
    }
    __syncthreads();
    stage32h(H1h[1] + hoff, hst_h, tid);
    __syncthreads();
    #pragma unroll
    for (int ks = 0; ks < 16; ++ks){
      int kk = ks*32;
      LDA2(kk, a0h, a1h)
      MFMA(B0, a0h, w1hh_r[ks]);
      MFMA(B1, a1h, w1hh_r[ks]);
    }
    __syncthreads();
    #pragma unroll
    for (int r = 0; r < 4; ++r){
      gl[(rb_ + r)*68 + rl]      = B0[r] + bs1[rl];
      gl[(16 + rb_ + r)*68 + rl] = B1[r] + bs1[rl];
    }
    __syncthreads();
    u16* Hh = H1h[0];
    #pragma unroll
    for (int q = 0; q < 2; ++q){
      int e = tid + q*256;
      int m = e >> 4, col = e & 15;
      float iv = gl[m*68 + col];
      float fv = gl[m*68 + 16 + col];
      float gv = gl[m*68 + 32 + col];
      float ov = gl[m*68 + 48 + col];
      float si = 1.f/(1.f + expf(-iv));
      float sf = 1.f/(1.f + expf(-fv));
      float so = 1.f/(1.f + expf(-ov));
      float cn = sf*c1r[q] + si*tanhf(gv);
      c1r[q] = cn;
      float h = so*tanhf(cn);
      Hh[(b0 + m)*512 + cg*16 + col] = f2bf(h);
    }
    ++ep;
    if (allco) fbar(cnt, g, cg, ep, tid); else xbar(cnt, ep, xcd, pop, nx);
  }

  // ======== decoder: t = 337..431 ========
  for (int t = 337; t < 432; ++t){
    const int p = t & 1;

    // ---- phase A: stage h1_{t-1} -> Wcomb(REG) + pred; restage h0 -> Whh0
    f32x4 A0 = {0,0,0,0}, A1 = {0,0,0,0};
    stage32h(H1h[p^1] + hoff, hst_h, tid);
    __syncthreads();
    #pragma unroll
    for (int ks = 0; ks < 16; ++ks){
      int kk = ks*32;
      LDA2(kk, a0h, a1h)
      MFMA(A0, a0h, wcmb_r[ks]);
      MFMA(A1, a1h, wcmb_r[ks]);
    }
    {                                            // pred l=t-337 from staged h1
      const int d = tid & 63, kq = tid >> 6;
      float part = 0.f;
      const float* wr = Wout + d*512 + kq*128;
      #pragma unroll 4
      for (int kk = 0; kk < 128; kk += 8){
        short8 hv = lds8(hst_h, cg, kq*128 + kk, 1024);
        #pragma unroll
        for (int j = 0; j < 8; ++j)
          part += bf2f((u16)hv[j]) * wr[kk + j];
      }
      pr[d*4 + kq] = part;
      __syncthreads();
      if (tid < 64){
        float v = pr[tid*4] + pr[tid*4+1] + pr[tid*4+2] + pr[tid*4+3] + bout[tid];
        out[131072 + ((b0 + cg)*64 + tid)*96 + (t - 337)] = v;
      }
      __syncthreads();
    }
    stage32h(H0h[p^1] + hoff, hst_h, tid);
    __syncthreads();
    #pragma unroll
    for (int ks = 0; ks < 16; ++ks){             // Whh0 (LDS) over h0_{t-1}
      int kk = ks*32;
      LDA2(kk, a0h, a1h)
      short8 bh = lds8(whh0_h, rl, kc + kk, 1024);
      MFMA(A0, a0h, bh);
      MFMA(A1, a1h, bh);
    }
    {                                            // cell l0 -> h0_t buf[p]
      __syncthreads();
      #pragma unroll
      for (int r = 0; r < 4; ++r){
        gl[(rb_ + r)*68 + rl]      = A0[r] + bsd[rl];
        gl[(16 + rb_ + r)*68 + rl] = A1[r] + bsd[rl];
      }
      __syncthreads();
      u16* Hh = H0h[p];
      #pragma unroll
      for (int q = 0; q < 2; ++q){
        int e = tid + q*256;
        int m = e >> 4, col = e & 15;
        float iv = gl[m*68 + col];
        float fv = gl[m*68 + 16 + col];
        float gv = gl[m*68 + 32 + col];
        float ov = gl[m*68 + 48 + col];
        float si = 1.f/(1.f + expf(-iv));
        float sf = 1.f/(1.f + expf(-fv));
        float so = 1.f/(1.f + expf(-ov));
        float cn = sf*c0r[q] + si*tanhf(gv);
        c0r[q] = cn;
        float h = so*tanhf(cn);
        Hh[(b0 + m)*512 + cg*16 + col] = f2bf(h);
      }
    }
    ++ep;
    if (allco) fbar(cnt, g, cg, ep, tid); else xbar(cnt, ep, xcd, pop, nx);

    // ---- phase B: stage h0_t -> W1ih(REG); restage h1_{t-1} -> W1hh(REG) ---
    f32x4 B0 = {0,0,0,0}, B1 = {0,0,0,0};
    stage32h(H0h[p] + hoff, hst_h, tid);
    __syncthreads();
    #pragma unroll
    for (int ks = 0; ks < 16; ++ks){
      int kk = ks*32;
      LDA2(kk, a0h, a1h)
      MFMA(B0, a0h, w1ih_r[ks]);
      MFMA(B1, a1h, w1ih_r[ks]);
    }
    __syncthreads();
    stage32h(H1h[p^1] + hoff, hst_h, tid);
    __syncthreads();
    #pragma unroll
    for (int ks = 0; ks < 16; ++ks){
      int kk = ks*32;
      LDA2(kk, a0h, a1h)
      MFMA(B0, a0h, w1hh_r[ks]);
      MFMA(B1, a1h, w1hh_r[ks]);
    }
    {
      __syncthreads();
      #pragma unroll
      for (int r = 0; r < 4; ++r){
        gl[(rb_ + r)*68 + rl]      = B0[r] + bs1[rl];
        gl[(16 + rb_ + r)*68 + rl] = B1[r] + bs1[rl];
      }
      __syncthreads();
      u16* Hh = H1h[p];
      #pragma unroll
      for (int q = 0; q < 2; ++q){
        int e = tid + q*256;
        int m = e >> 4, col = e & 15;
        float iv = gl[m*68 + col];
        float fv = gl[m*68 + 16 + col];
        float gv = gl[m*68 + 32 + col];
        float ov = gl[m*68 + 48 + col];
        float si = 1.f/(1.f + expf(-iv));
        float sf = 1.f/(1.f + expf(-fv));
        float so = 1.f/(1.f + expf(-ov));
        float cn = sf*c1r[q] + si*tanhf(gv);
        c1r[q] = cn;
        float h = so*tanhf(cn);
        Hh[(b0 + m)*512 + cg*16 + col] = f2bf(h);
      }
    }
    ++ep;
    if (allco) fbar(cnt, g, cg, ep, tid); else xbar(cnt, ep, xcd, pop, nx);
  }
  #undef LDA2
}

// ---- tail: pred for l=95 from h1_431 (parity 1) ----------------------------
__global__ void __launch_bounds__(256) pred_last(
    const u16* __restrict__ h1hi,
    const float* __restrict__ Wout, const float* __restrict__ bout,
    float* __restrict__ out)
{
  const int wg = blockIdx.x, tid = threadIdx.x;
  const int bsub = tid >> 6, d = tid & 63;
  const int b = wg*4 + bsub;
  float acc = bout[d];
  const u16* hH = h1hi + b*512;
  const float* wr = Wout + d*512;
  #pragma unroll 8
  for (int k = 0; k < 512; k += 8){
    short8 hv = *(const short8*)(hH + k);
    #pragma unroll
    for (int j = 0; j < 8; ++j)
      acc += bf2f((u16)hv[j]) * wr[k + j];
  }
  out[131072 + (b*64 + d)*96 + 95] = acc;
}

// ======================= fallback (R9 proven path) ==========================
__device__ __forceinline__ void cell_epilogue_fb(
    float* gl, const float* bs, float* __restrict__ cbuf,
    u16* __restrict__ hhi, u16* __restrict__ hlo,
    float* __restrict__ gfout, int mrow, int jblk,
    const f32x4& a0, const f32x4& a1, int wv, int lane, int tid)
{
  __syncthreads();
  const int rbase = wv*16 + ((lane >> 4) << 2);
  const int cI = lane & 15;
  #pragma unroll
  for (int r = 0; r < 4; ++r){
    gl[(rbase+r)*33 + cI]      = a0[r] + bs[cI];
    gl[(rbase+r)*33 + 16 + cI] = a1[r] + bs[16 + cI];
  }
  __syncthreads();
  #pragma unroll
  for (int q = 0; q < 2; ++q){
    int e = tid + q*256;
    int m = e >> 3, jj = e & 7;
    float iv = gl[m*33 + jj];
    float fv = gl[m*33 + 8 + jj];
    float gv = gl[m*33 + 16 + jj];
    float ov = gl[m*33 + 24 + jj];
    float si = 1.f/(1.f + expf(-iv));
    float sf = 1.f/(1.f + expf(-fv));
    float so = 1.f/(1.f + expf(-ov));
    int gi = (mrow*64 + m)*512 + jblk*8 + jj;
    float cn = sf*cbuf[gi] + si*tanhf(gv);
    cbuf[gi] = cn;
    float h = so*tanhf(cn);
    u16 hh = f2bf(h);
    hhi[gi] = hh;
    hlo[gi] = f2bf(h - bf2f(hh));
    if (gfout) gfout[gi] = h;
  }
}

template<bool ENC>
__global__ void __launch_bounds__(256) l0_fb(
    const float* __restrict__ x,
    const u16* __restrict__ predhi, const u16* __restrict__ predlo,
    const float* __restrict__ Wihf, const float* __restrict__ Whhf,
    const float* __restrict__ bih, const float* __restrict__ bhh,
    const u16* __restrict__ hphi, const u16* __restrict__ hplo,
    u16* __restrict__ hnhi, u16* __restrict__ hnlo,
    float* __restrict__ c0, int t)
{
  __shared__ float gl[64*33];
  __shared__ float bs[32];
  const int wg = blockIdx.x, tid = threadIdx.x;
  const int mrow = wg & 3, jblk = wg >> 2;
  const int lane = tid & 63, wv = tid >> 6;
  if (tid < 32){
    int n = ((tid >> 3) << 9) + jblk*8 + (tid & 7);
    bs[tid] = bih[n] + bhh[n];
  }
  const int ar = mrow*64 + wv*16 + (lane & 15);
  const int kc = (lane >> 4) << 3;
  const int cI = lane & 15;
  const int n0 = ((cI >> 3) << 9) + jblk*8 + (cI & 7);
  const int n1 = n0 + 1024;

  f32x4 acc0 = {0,0,0,0}, acc1 = {0,0,0,0};
  #pragma unroll
  for (int ks = 0; ks < 2; ++ks){
    int k = ks*32 + kc;
    short8 ah, al;
    if (ENC){
      const float* xb = x + ar*21504 + t;
      #pragma unroll
      for (int j = 0; j < 8; ++j){ HiLo s = split1(xb[(k + j)*336]); ah[j] = s.hi; al[j] = s.lo; }
    } else {
      ah = *(const short8*)(predhi + ar*64 + k);
      al = *(const short8*)(predlo + ar*64 + k);
    }
    short8 bh0, bl0, bh1, bl1;
    ldw8s(Wihf + n0*64 + k, bh0, bl0);
    ldw8s(Wihf + n1*64 + k, bh1, bl1);
    SMACC(acc0, ah, al, bh0, bl0);
    SMACC(acc1, ah, al, bh1, bl1);
  }
  const u16* hH = hphi + ar*512 + kc;
  const u16* hL = hplo + ar*512 + kc;
  #pragma unroll 4
  for (int ks = 0; ks < 16; ++ks){
    int k = ks*32;
    short8 ah = *(const short8*)(hH + k);
    short8 al = *(const short8*)(hL + k);
    short8 bh0, bl0, bh1, bl1;
    ldw8s(Whhf + n0*512 + kc + k, bh0, bl0);
    ldw8s(Whhf + n1*512 + kc + k, bh1, bl1);
    SMACC(acc0, ah, al, bh0, bl0);
    SMACC(acc1, ah, al, bh1, bl1);
  }
  cell_epilogue_fb(gl, bs, c0, hnhi, hnlo, nullptr, mrow, jblk, acc0, acc1, wv, lane, tid);
}

__global__ void __launch_bounds__(256) l1_fb(
    const float* __restrict__ Wihf, const float* __restrict__ Whhf,
    const float* __restrict__ bih, const float* __restrict__ bhh,
    const u16* __restrict__ h0hi, const u16* __restrict__ h0lo,
    const u16* __restrict__ h1phi, const u16* __restrict__ h1plo,
    u16* __restrict__ h1nhi, u16* __restrict__ h1nlo,
    float* __restrict__ c1, float* __restrict__ gfout)
{
  __shared__ float gl[64*33];
  __shared__ float bs[32];
  const int wg = blockIdx.x, tid = threadIdx.x;
  const int mrow = wg & 3, jblk = wg >> 2;
  const int lane = tid & 63, wv = tid >> 6;
  if (tid < 32){
    int n = ((tid >> 3) << 9) + jblk*8 + (tid & 7);
    bs[tid] = bih[n] + bhh[n];
  }
  const int ar = mrow*64 + wv*16 + (lane & 15);
  const int kc = (lane >> 4) << 3;
  const int cI = lane & 15;
  const int n0 = ((cI >> 3) << 9) + jblk*8 + (cI & 7);
  const int n1 = n0 + 1024;

  f32x4 acc0 = {0,0,0,0}, acc1 = {0,0,0,0};
  {
    const u16* hH = h0hi + ar*512 + kc;
    const u16* hL = h0lo + ar*512 + kc;
    #pragma unroll 4
    for (int ks = 0; ks < 16; ++ks){
      int k = ks*32;
      short8 ah = *(const short8*)(hH + k);
      short8 al = *(const short8*)(hL + k);
      short8 bh0, bl0, bh1, bl1;
      ldw8s(Wihf + n0*512 + kc + k, bh0, bl0);
      ldw8s(Wihf + n1*512 + kc + k, bh1, bl1);
      SMACC(acc0, ah, al, bh0, bl0);
      SMACC(acc1, ah, al, bh1, bl1);
    }
  }
  {
    const u16* hH = h1phi + ar*512 + kc;
    const u16* hL = h1plo + ar*512 + kc;
    #pragma unroll 4
    for (int ks = 0; ks < 16; ++ks){
      int k = ks*32;
      short8 ah = *(const short8*)(hH + k);
      short8 al = *(const short8*)(hL + k);
      short8 bh0, bl0, bh1, bl1;
      ldw8s(Whhf + n0*512 + kc + k, bh0, bl0);
      ldw8s(Whhf + n1*512 + kc + k, bh1, bl1);
      SMACC(acc0, ah, al, bh0, bl0);
      SMACC(acc1, ah, al, bh1, bl1);
    }
  }
  cell_epilogue_fb(gl, bs, c1, h1nhi, h1nlo, gfout, mrow, jblk, acc0, acc1, wv, lane, tid);
}

__global__ void __launch_bounds__(256) pred_fb(
    const u16* __restrict__ h1hi, const u16* __restrict__ h1lo,
    const float* __restrict__ Wout, const float* __restrict__ bout,
    u16* __restrict__ predhi, u16* __restrict__ predlo,
    float* __restrict__ out, int l)
{
  const int wg = blockIdx.x, tid = threadIdx.x;
  const int bsub = tid >> 6, d = tid & 63;
  const int b = wg*4 + bsub;
  float acc = bout[d];
  const u16* hH = h1hi + b*512;
  const u16* hL = h1lo + b*512;
  const float* wr = Wout + d*512;
  #pragma unroll 8
  for (int k = 0; k < 512; k += 8){
    short8 hv = *(const short8*)(hH + k);
    short8 lv = *(const short8*)(hL + k);
    #pragma unroll
    for (int j = 0; j < 8; ++j)
      acc += (bf2f((u16)hv[j]) + bf2f((u16)lv[j])) * wr[k + j];
  }
  HiLo s = split1(acc);
  predhi[b*64 + d] = (u16)s.hi;
  predlo[b*64 + d] = (u16)s.lo;
  out[131072 + (b*64 + d)*96 + l] = acc;
}

extern "C" void kernel_launch(void* const* d_in, const int* in_sizes, int n_in,
                              void* d_out, int out_size, void* d_ws, size_t ws_size,
                              hipStream_t stream)
{
  const float* x    = (const float*)d_in[0];
  const float* Wih0 = (const float*)d_in[1];
  const float* Whh0 = (const float*)d_in[2];
  const float* bih0 = (const float*)d_in[3];
  const float* bhh0 = (const float*)d_in[4];
  const float* Wih1 = (const float*)d_in[5];
  const float* Whh1 = (const float*)d_in[6];
  const float* bih1 = (const float*)d_in[7];
  const float* bhh1 = (const float*)d_in[8];
  const float* Wout = (const float*)d_in[9];
  const float* bout = (const float*)d_in[10];
  float* out = (float*)d_out;

  // ---- ws layout (identical offsets to R25; lo regions unused by main path)
  char* ws = (char*)d_ws;
  u16* h0h[2] = { (u16*)(ws + 0),       (u16*)(ws + 262144) };
  u16* h0l[2] = { (u16*)(ws + 524288),  (u16*)(ws + 786432) };
  u16* h1h[2] = { (u16*)(ws + 1048576), (u16*)(ws + 1310720) };
  u16* h1l[2] = { (u16*)(ws + 1572864), (u16*)(ws + 1835008) };
  unsigned* cnt = (unsigned*)(ws + 2097152);
  u16* Wcmb_h = (u16*)(ws + 2162688);
  u16* W1ih_h = Wcmb_h + 1048576;
  u16* W1hh_h = W1ih_h + 1048576;
  float* bb   = (float*)(W1hh_h + 1048576);
  const size_t NEED = 2162688u + 3u*2097152u + 8192u;   // ~8.5 MB
  // fallback layout (only used when ws too small)
  float* fb_c0 = (float*)(ws + 2162688);
  float* fb_c1 = (float*)(ws + 2686976);
  u16* predh   = (u16*)(ws + 3211264);
  u16* predl   = (u16*)(ws + 3244032);
  const bool ps = (ws_size >= NEED);

  (void)hipMemsetAsync(d_ws, 0, 3276800, stream);   // h + cnt/flags (+ fb c/pred)

  if (ps){
    wcomb_k<<<dim3(256), dim3(256), 0, stream>>>(Wih0, Wout, bout, bih0, bhh0,
                                                 Wcmb_h, bb);
    wcvt<<<dim3(4096), dim3(256), 0, stream>>>(Wih1, W1ih_h, 1048576);
    wcvt<<<dim3(4096), dim3(256), 0, stream>>>(Whh1, W1hh_h, 1048576);
    lstm_persist<<<dim3(256), dim3(256), 0, stream>>>(
        x, Whh0, Wih0, W1ih_h, W1hh_h, Wcmb_h, bb,
        bih0, bhh0, bih1, bhh1, Wout, bout, out, cnt,
        h0h[0], h0h[1], h1h[0], h1h[1]);
    pred_last<<<dim3(64), dim3(256), 0, stream>>>(h1h[1], Wout, bout, out);
  } else {
    for (int t = 0; t < 432; ++t){
      const int p = t & 1;
      float* gf = (t == 335) ? out : (float*)nullptr;
      if (t < 336)
        l0_fb<true><<<dim3(256), dim3(256), 0, stream>>>(
            x, predh, predl, Wih0, Whh0, bih0, bhh0,
            h0h[p^1], h0l[p^1], h0h[p], h0l[p], fb_c0, t);
      else
        l0_fb<false><<<dim3(256), dim3(256), 0, stream>>>(
            x, predh, predl, Wih0, Whh0, bih0, bhh0,
            h0h[p^1], h0l[p^1], h0h[p], h0l[p], fb_c0, t);
      l1_fb<<<dim3(256), dim3(256), 0, stream>>>(
          Wih1, Whh1, bih1, bhh1, h0h[p], h0l[p],
          h1h[p^1], h1l[p^1], h1h[p], h1l[p], fb_c1, gf);
      if (t >= 336)
        pred_fb<<<dim3(64), dim3(256), 0, stream>>>(
            h1h[p], h1l[p], Wout, bout, predh, predl, out, t - 336);
    }
  }
}

// Round 27
// 3887.402 us; speedup vs baseline: 5.5623x; 1.0729x over previous
//
#include <hip/hip_runtime.h>

typedef unsigned short u16;
typedef __attribute__((ext_vector_type(8))) short short8;
typedef __attribute__((ext_vector_type(4))) float f32x4;

#define AXR __ATOMIC_RELAXED, __HIP_MEMORY_SCOPE_AGENT

__device__ __forceinline__ float bf2f(u16 v){
  union { unsigned u; float f; } t; t.u = ((unsigned)v) << 16; return t.f;
}
__device__ __forceinline__ u16 f2bf(float f){
  union { float f; unsigned u; } t; t.f = f;
  unsigned u = t.u;
  return (u16)((u + 0x7fffu + ((u >> 16) & 1u)) >> 16);
}
struct HiLo { short hi, lo; };
__device__ __forceinline__ HiLo split1(float v){
  HiLo r;
  u16 h = f2bf(v);
  r.hi = (short)h;
  r.lo = (short)f2bf(v - bf2f(h));
  return r;
}
__device__ __forceinline__ void ldw8s(const float* __restrict__ p, short8& hi, short8& lo){
  #pragma unroll
  for (int j = 0; j < 8; ++j){ HiLo s = split1(p[j]); hi[j] = s.hi; lo[j] = s.lo; }
}

#define MFMA(acc, a, b) acc = __builtin_amdgcn_mfma_f32_16x16x32_bf16(a, b, acc, 0,0,0)
#define SMACC(acc, ah, al, bh, bl) do{ MFMA(acc, ah, bh); MFMA(acc, ah, bl); MFMA(acc, al, bh); }while(0)

// ---- prepass: f32 -> bf16 (hi only, RNE) -----------------------------------
__global__ void wcvt(const float* __restrict__ s, u16* __restrict__ hi, int n){
  int i = blockIdx.x * blockDim.x + threadIdx.x;
  if (i < n) hi[i] = f2bf(s[i]);
}

// ---- prepass: Wcomb = Wih0 @ Wout (2048x512 bf16 hi), bb = b0 + Wih0@bout --
__global__ void __launch_bounds__(256) wcomb_k(
    const float* __restrict__ Wih0, const float* __restrict__ Wout,
    const float* __restrict__ bout, const float* __restrict__ bih0,
    const float* __restrict__ bhh0,
    u16* __restrict__ Wch, float* __restrict__ bb)
{
  __shared__ float wl[8*64];
  __shared__ float bo[64];
  const int wg = blockIdx.x, tid = threadIdx.x;
  const int r0 = wg*8;
  for (int i = tid; i < 512; i += 256) wl[i] = Wih0[(r0 + (i >> 6))*64 + (i & 63)];
  if (tid < 64) bo[tid] = bout[tid];
  __syncthreads();
  if (tid < 8){
    int n = r0 + tid;
    float a = bih0[n] + bhh0[n];
    #pragma unroll 8
    for (int d = 0; d < 64; ++d) a += wl[tid*64 + d]*bo[d];
    bb[n] = a;
  }
  #pragma unroll
  for (int jj = 0; jj < 2; ++jj){
    int j = tid + jj*256;
    float acc[8] = {0,0,0,0,0,0,0,0};
    for (int d = 0; d < 64; ++d){
      float wv = Wout[d*512 + j];
      #pragma unroll
      for (int r = 0; r < 8; ++r) acc[r] += wl[r*64 + d]*wv;
    }
    #pragma unroll
    for (int r = 0; r < 8; ++r) Wch[(r0 + r)*512 + j] = f2bf(acc[r]);
  }
}

// ---- init-only tree barrier ------------------------------------------------
__device__ __forceinline__ void gbar(unsigned* bar, unsigned phase){
  __syncthreads();
  if (threadIdx.x == 0){
    __threadfence();
    const unsigned gg = (unsigned)blockIdx.x >> 4;
    unsigned old = __hip_atomic_fetch_add(bar + 64 + gg*32, 1u, AXR);
    if (old == phase*16u - 1u){
      unsigned r = __hip_atomic_fetch_add(bar, 1u, AXR);
      if (r == phase*16u - 1u)
        __hip_atomic_store(bar + 32, phase, AXR);
    }
    while (__hip_atomic_load(bar + 32, AXR) < phase)
      __builtin_amdgcn_s_sleep(2);
    __threadfence();
  }
  __syncthreads();
}

// ---- global fallback barrier (R14 xbar) ------------------------------------
__device__ __forceinline__ void xbar(unsigned* bar, unsigned phase,
                                     unsigned xcd, unsigned pop, unsigned nx){
  __syncthreads();
  if (threadIdx.x == 0){
    unsigned old = __hip_atomic_fetch_add(bar + 832 + xcd*32, 1u, AXR);
    const bool leader = (old == phase*pop - 1u);
    if (leader){
      asm volatile("buffer_wbl2 sc1\n\ts_waitcnt vmcnt(0)" ::: "memory");
      unsigned r = __hip_atomic_fetch_add(bar + 1344, 1u, AXR);
      if (r == phase*nx - 1u)
        __hip_atomic_store(bar + 1376, phase, AXR);
    }
    while (__hip_atomic_load(bar + 1376, AXR) < phase)
      __builtin_amdgcn_s_sleep(2);
    if (leader){
      asm volatile("buffer_inv sc1\n\ts_waitcnt vmcnt(0)" ::: "memory");
      __hip_atomic_store(bar + 1088 + xcd*32, phase, AXR);
    } else {
      while (__hip_atomic_load(bar + 1088 + xcd*32, AXR) < phase)
        __builtin_amdgcn_s_sleep(1);
      asm volatile("buffer_inv\n\ts_waitcnt vmcnt(0)" ::: "memory");
    }
  }
  __syncthreads();
}

// ---- group-local FLAG-ARRAY barrier (R22) ----------------------------------
__device__ __forceinline__ void fbar(unsigned* bar, int g, int cg,
                                     unsigned phase, int tid){
  __syncthreads();
  unsigned* flags = bar + 4096 + g*1024;
  if (tid == 0)
    __hip_atomic_store(flags + cg*32, phase, AXR);
  if (tid < 64){
    const int i = tid & 31;
    while (__hip_atomic_load(flags + i*32, AXR) < phase)
      __builtin_amdgcn_s_sleep(1);
    asm volatile("buffer_inv\n\ts_waitcnt vmcnt(0)" ::: "memory");
  }
  __syncthreads();
}

// ---- LDS helpers (XOR-swizzled, G4) ----------------------------------------
__device__ __forceinline__ short8 lds8(const u16* base, int r, int kelem, int rowbytes){
  int bo = r*rowbytes + ((kelem*2) ^ ((r & 7) << 4));
  return *(const short8*)((const char*)base + bo);
}
__device__ __forceinline__ void load_slice64(
    const float* __restrict__ W, int ldw, int rowshift, int nelem,
    u16* lh, u16* ll, int cg, int tid)
{
  const int rowbytes = ldw*2;
  for (int i = tid; i < nelem; i += 256){
    int r = i >> rowshift, k = i & ((1 << rowshift) - 1);
    int n = ((r >> 4) << 9) + cg*16 + (r & 15);
    HiLo s = split1(W[n*ldw + k]);
    int bo = r*rowbytes + ((k*2) ^ ((r & 7) << 4));
    *(u16*)((char*)lh + bo) = (u16)s.hi;
    *(u16*)((char*)ll + bo) = (u16)s.lo;
  }
}
__device__ __forceinline__ void load_slice64h(
    const float* __restrict__ W, int ldw, int rowshift, int nelem,
    u16* lh, int cg, int tid)
{
  const int rowbytes = ldw*2;
  for (int i = tid; i < nelem; i += 256){
    int r = i >> rowshift, k = i & ((1 << rowshift) - 1);
    int n = ((r >> 4) << 9) + cg*16 + (r & 15);
    int bo = r*rowbytes + ((k*2) ^ ((r & 7) << 4));
    *(u16*)((char*)lh + bo) = f2bf(W[n*ldw + k]);
  }
}

// ---- h-block stage split into load (regs) and write (swizzled LDS) ---------
__device__ __forceinline__ void stage_ld(const u16* __restrict__ gh,
                                         short8* r, int tid){
  #pragma unroll
  for (int i = 0; i < 8; ++i)
    r[i] = *(const short8*)(gh + (tid + i*256)*8);
}
__device__ __forceinline__ void stage_wr(const short8* r, u16* sh, int tid){
  #pragma unroll
  for (int i = 0; i < 8; ++i){
    int e = (tid + i*256)*8;
    int row = e >> 9, col = e & 511;
    int bo = row*1024 + ((col*2) ^ ((row & 7) << 4));
    *(short8*)((char*)sh + bo) = r[i];
  }
}

// ---- persistent kernel: async double-buffered stages -----------------------
__global__ void __launch_bounds__(256, 1) lstm_persist(
    const float* __restrict__ x,
    const float* __restrict__ Whh0, const float* __restrict__ Wih0,
    const u16* __restrict__ W1ih_h, const u16* __restrict__ W1hh_h,
    const u16* __restrict__ Wcmb_h, const float* __restrict__ bb,
    const float* __restrict__ bih0, const float* __restrict__ bhh0,
    const float* __restrict__ bih1, const float* __restrict__ bhh1,
    const float* __restrict__ Wout, const float* __restrict__ bout,
    float* __restrict__ out, unsigned* __restrict__ cnt,
    u16* __restrict__ h0h0, u16* __restrict__ h0h1,
    u16* __restrict__ h1h0, u16* __restrict__ h1h1)
{
  __shared__ u16 whh0_h[32768];                  // 64KB: Whh0 hi, swizzled
  __shared__ u16 hstA[16384], hstB[16384];       // 2x32KB: staged h blocks
  __shared__ u16 w0ih_h[4096],  w0ih_l[4096];    // 16KB: Wih0 hi+lo
  __shared__ float gl[32*68];                    // gate exchange (aliases xst)
  __shared__ float pr[256];                      // pred partials
  __shared__ float bs0[64], bs1[64], bsd[64];
  __shared__ unsigned s_rank, s_pop, s_nx, s_all;

  u16* xst_h = (u16*)gl;                         // x_t stage: 32x64 hi
  u16* xst_l = (u16*)gl + 2048;                  // 32x64 lo

  const int wg = blockIdx.x, tid = threadIdx.x;
  const int lane = tid & 63, wv = tid >> 6;
  const int cI = lane & 15;
  const int kc = (lane >> 4) << 3;
  const int rl = wv*16 + cI;

  // ---- census ----
  unsigned xcd;
  asm volatile("s_getreg_b32 %0, hwreg(HW_REG_XCC_ID)" : "=s"(xcd));
  xcd &= 7u;
  if (tid == 0)
    s_rank = __hip_atomic_fetch_add(cnt + 576 + xcd*32, 1u, AXR);
  gbar(cnt, 1);
  if (tid == 0){
    unsigned nxl = 0, allc = 1;
    for (int i = 0; i < 8; ++i){
      unsigned pv = __hip_atomic_load(cnt + 576 + i*32, AXR);
      nxl += (pv != 0u) ? 1u : 0u;
      if (pv != 32u) allc = 0u;
    }
    s_pop = __hip_atomic_load(cnt + 576 + xcd*32, AXR);
    s_nx  = nxl;
    s_all = allc;
  }
  __syncthreads();
  const unsigned pop = s_pop, nx = s_nx;
  const bool allco = (s_all != 0u);
  const int g  = allco ? (int)xcd    : (wg & 7);
  const int cg = allco ? (int)s_rank : (wg >> 3);
  const int b0 = g*32;

  // ---- one-time init ----
  load_slice64h(Whh0, 512, 9, 32768, whh0_h, cg, tid);
  load_slice64(Wih0,  64, 6,  4096, w0ih_h, w0ih_l, cg, tid);
  if (tid < 64){
    int n = ((tid >> 4) << 9) + cg*16 + (tid & 15);
    bs0[tid] = bih0[n] + bhh0[n];
    bs1[tid] = bih1[n] + bhh1[n];
    bsd[tid] = bb[n];
  }
  const int nb = (wv*512 + cg*16 + cI)*512 + kc;
  short8 w1ih_r[16], w1hh_r[16], wcmb_r[16];
  #pragma unroll
  for (int ks = 0; ks < 16; ++ks){
    w1ih_r[ks] = *(const short8*)(W1ih_h + nb + ks*32);
    w1hh_r[ks] = *(const short8*)(W1hh_h + nb + ks*32);
    wcmb_r[ks] = *(const short8*)(Wcmb_h + nb + ks*32);
  }
  __syncthreads();

  u16* H0h[2] = { h0h0, h0h1 };
  u16* H1h[2] = { h1h0, h1h1 };

  float c0r[2] = {0.f, 0.f}, c1r[2] = {0.f, 0.f};
  unsigned ep = 0;
  const int rb_ = (lane >> 4) << 2;
  const int hoff = b0*512;

  #define LDA(buf, kk, a0h_, a1h_) \
    short8 a0h_ = lds8(buf, cI, kc + (kk), 1024); \
    short8 a1h_ = lds8(buf, cI + 16, kc + (kk), 1024);

  // ======== skewed encoder: phase k computes h0_k and h1_{k-1} ========
  for (int k = 0; k <= 336; ++k){
    const int p0 = k & 1;

    // ---- phase start: issue ALL global loads, write both stage buffers ----
    short8 r0s[8], r1s[8];
    float xr[8];
    stage_ld(H0h[p0^1] + hoff, r0s, tid);
    if (k >= 1) stage_ld(H1h[p0] + hoff, r1s, tid);
    if (k < 336){
      #pragma unroll
      for (int i = 0; i < 8; ++i){
        int e = tid + i*256;
        xr[i] = x[(b0 + (e >> 6))*21504 + (e & 63)*336 + k];
      }
    }
    stage_wr(r0s, hstA, tid);
    if (k >= 1) stage_wr(r1s, hstB, tid);
    if (k < 336){
      #pragma unroll
      for (int i = 0; i < 8; ++i){
        int e = tid + i*256;
        int bb_ = e >> 6, d = e & 63;
        HiLo s = split1(xr[i]);
        int bo = bb_*128 + ((d*2) ^ ((bb_ & 7) << 4));
        *(u16*)((char*)xst_h + bo) = (u16)s.hi;
        *(u16*)((char*)xst_l + bo) = (u16)s.lo;
      }
    }
    __syncthreads();

    // ---- MFMA block: x + fused(Whh0,W1ih) + W1hh, no mid-phase syncs ----
    f32x4 A0 = {0,0,0,0}, A1 = {0,0,0,0};
    f32x4 B0 = {0,0,0,0}, B1 = {0,0,0,0};
    if (k < 336){
      #pragma unroll
      for (int ks = 0; ks < 2; ++ks){
        int kk = ks*32 + kc;
        short8 a0h = lds8(xst_h, cI, kk, 128);
        short8 a0l = lds8(xst_l, cI, kk, 128);
        short8 a1h = lds8(xst_h, cI + 16, kk, 128);
        short8 a1l = lds8(xst_l, cI + 16, kk, 128);
        short8 bh = lds8(w0ih_h, rl, kk, 128);
        short8 bl = lds8(w0ih_l, rl, kk, 128);
        SMACC(A0, a0h, a0l, bh, bl);
        SMACC(A1, a1h, a1l, bh, bl);
      }
    }
    #pragma unroll
    for (int ks = 0; ks < 16; ++ks){             // fused: Whh0(LDS) + W1ih(REG)
      int kk = ks*32;
      LDA(hstA, kk, a0h, a1h)
      short8 bh = lds8(whh0_h, rl, kc + kk, 1024);
      MFMA(A0, a0h, bh);
      MFMA(A1, a1h, bh);
      MFMA(B0, a0h, w1ih_r[ks]);
      MFMA(B1, a1h, w1ih_r[ks]);
    }
    if (k >= 1){
      #pragma unroll
      for (int ks = 0; ks < 16; ++ks){           // W1hh (REG) over h1_{k-2}
        int kk = ks*32;
        LDA(hstB, kk, a0h, a1h)
        MFMA(B0, a0h, w1hh_r[ks]);
        MFMA(B1, a1h, w1hh_r[ks]);
      }
    }

    // ---- cell l0 -> h0_k buf[p0] ----
    {
      __syncthreads();
      #pragma unroll
      for (int r = 0; r < 4; ++r){
        gl[(rb_ + r)*68 + rl]      = A0[r] + bs0[rl];
        gl[(16 + rb_ + r)*68 + rl] = A1[r] + bs0[rl];
      }
      __syncthreads();
      u16* Hh = H0h[p0];
      #pragma unroll
      for (int q = 0; q < 2; ++q){
        int e = tid + q*256;
        int m = e >> 4, col = e & 15;
        float iv = gl[m*68 + col];
        float fv = gl[m*68 + 16 + col];
        float gv = gl[m*68 + 32 + col];
        float ov = gl[m*68 + 48 + col];
        float si = 1.f/(1.f + expf(-iv));
        float sf = 1.f/(1.f + expf(-fv));
        float so = 1.f/(1.f + expf(-ov));
        float cn = sf*c0r[q] + si*tanhf(gv);
        c0r[q] = cn;
        float h = so*tanhf(cn);
        Hh[(b0 + m)*512 + cg*16 + col] = f2bf(h);
      }
    }
    // ---- cell l1 -> h1_{k-1} buf[p0^1]  (global_feat at k==336) ----
    if (k >= 1){
      float* gf = (k == 336) ? out : (float*)nullptr;
      __syncthreads();
      #pragma unroll
      for (int r = 0; r < 4; ++r){
        gl[(rb_ + r)*68 + rl]      = B0[r] + bs1[rl];
        gl[(16 + rb_ + r)*68 + rl] = B1[r] + bs1[rl];
      }
      __syncthreads();
      u16* Hh = H1h[p0^1];
      #pragma unroll
      for (int q = 0; q < 2; ++q){
        int e = tid + q*256;
        int m = e >> 4, col = e & 15;
        float iv = gl[m*68 + col];
        float fv = gl[m*68 + 16 + col];
        float gv = gl[m*68 + 32 + col];
        float ov = gl[m*68 + 48 + col];
        float si = 1.f/(1.f + expf(-iv));
        float sf = 1.f/(1.f + expf(-fv));
        float so = 1.f/(1.f + expf(-ov));
        float cn = sf*c1r[q] + si*tanhf(gv);
        c1r[q] = cn;
        float h = so*tanhf(cn);
        int gi = (b0 + m)*512 + cg*16 + col;
        Hh[gi] = f2bf(h);
        if (gf) gf[gi] = h;
      }
    }
    ++ep;
    if (allco) fbar(cnt, g, cg, ep, tid); else xbar(cnt, ep, xcd, pop, nx);
  }

  // ======== l1 catch-up: h1_336 (h0_336 buf[0], h1_335 buf[1]) ========
  {
    short8 r0s[8], r1s[8];
    stage_ld(H0h[0] + hoff, r0s, tid);
    stage_ld(H1h[1] + hoff, r1s, tid);
    stage_wr(r0s, hstA, tid);
    stage_wr(r1s, hstB, tid);
    __syncthreads();
    f32x4 B0 = {0,0,0,0}, B1 = {0,0,0,0};
    #pragma unroll
    for (int ks = 0; ks < 16; ++ks){
      int kk = ks*32;
      LDA(hstA, kk, a0h, a1h)
      MFMA(B0, a0h, w1ih_r[ks]);
      MFMA(B1, a1h, w1ih_r[ks]);
    }
    #pragma unroll
    for (int ks = 0; ks < 16; ++ks){
      int kk = ks*32;
      LDA(hstB, kk, a0h, a1h)
      MFMA(B0, a0h, w1hh_r[ks]);
      MFMA(B1, a1h, w1hh_r[ks]);
    }
    __syncthreads();
    #pragma unroll
    for (int r = 0; r < 4; ++r){
      gl[(rb_ + r)*68 + rl]      = B0[r] + bs1[rl];
      gl[(16 + rb_ + r)*68 + rl] = B1[r] + bs1[rl];
    }
    __syncthreads();
    u16* Hh = H1h[0];
    #pragma unroll
    for (int q = 0; q < 2; ++q){
      int e = tid + q*256;
      int m = e >> 4, col = e & 15;
      float iv = gl[m*68 + col];
      float fv = gl[m*68 + 16 + col];
      float gv = gl[m*68 + 32 + col];
      float ov = gl[m*68 + 48 + col];
      float si = 1.f/(1.f + expf(-iv));
      float sf = 1.f/(1.f + expf(-fv));
      float so = 1.f/(1.f + expf(-ov));
      float cn = sf*c1r[q] + si*tanhf(gv);
      c1r[q] = cn;
      float h = so*tanhf(cn);
      Hh[(b0 + m)*512 + cg*16 + col] = f2bf(h);
    }
    ++ep;
    if (allco) fbar(cnt, g, cg, ep, tid); else xbar(cnt, ep, xcd, pop, nx);
  }

  // ======== decoder: t = 337..431 ========
  for (int t = 337; t < 432; ++t){
    const int p = t & 1;

    // ---- phase A: h1_{t-1}->hstA (Wcomb+pred), h0_{t-1}->hstB (Whh0) ----
    {
      short8 r0s[8], r1s[8];
      stage_ld(H1h[p^1] + hoff, r0s, tid);
      stage_ld(H0h[p^1] + hoff, r1s, tid);
      stage_wr(r0s, hstA, tid);
      stage_wr(r1s, hstB, tid);
      __syncthreads();
      f32x4 A0 = {0,0,0,0}, A1 = {0,0,0,0};
      #pragma unroll
      for (int ks = 0; ks < 16; ++ks){
        int kk = ks*32;
        LDA(hstA, kk, a0h, a1h)
        MFMA(A0, a0h, wcmb_r[ks]);
        MFMA(A1, a1h, wcmb_r[ks]);
      }
      #pragma unroll
      for (int ks = 0; ks < 16; ++ks){           // Whh0 (LDS) over h0_{t-1}
        int kk = ks*32;
        LDA(hstB, kk, a0h, a1h)
        short8 bh = lds8(whh0_h, rl, kc + kk, 1024);
        MFMA(A0, a0h, bh);
        MFMA(A1, a1h, bh);
      }
      {                                          // pred l=t-337 from hstA
        const int d = tid & 63, kq = tid >> 6;
        float part = 0.f;
        const float* wr = Wout + d*512 + kq*128;
        #pragma unroll 4
        for (int kk = 0; kk < 128; kk += 8){
          short8 hv = lds8(hstA, cg, kq*128 + kk, 1024);
          #pragma unroll
          for (int j = 0; j < 8; ++j)
            part += bf2f((u16)hv[j]) * wr[kk + j];
        }
        pr[d*4 + kq] = part;
        __syncthreads();
        if (tid < 64){
          float v = pr[tid*4] + pr[tid*4+1] + pr[tid*4+2] + pr[tid*4+3] + bout[tid];
          out[131072 + ((b0 + cg)*64 + tid)*96 + (t - 337)] = v;
        }
      }
      {                                          // cell l0 -> h0_t buf[p]
        __syncthreads();
        #pragma unroll
        for (int r = 0; r < 4; ++r){
          gl[(rb_ + r)*68 + rl]      = A0[r] + bsd[rl];
          gl[(16 + rb_ + r)*68 + rl] = A1[r] + bsd[rl];
        }
        __syncthreads();
        u16* Hh = H0h[p];
        #pragma unroll
        for (int q = 0; q < 2; ++q){
          int e = tid + q*256;
          int m = e >> 4, col = e & 15;
          float iv = gl[m*68 + col];
          float fv = gl[m*68 + 16 + col];
          float gv = gl[m*68 + 32 + col];
          float ov = gl[m*68 + 48 + col];
          float si = 1.f/(1.f + expf(-iv));
          float sf = 1.f/(1.f + expf(-fv));
          float so = 1.f/(1.f + expf(-ov));
          float cn = sf*c0r[q] + si*tanhf(gv);
          c0r[q] = cn;
          float h = so*tanhf(cn);
          Hh[(b0 + m)*512 + cg*16 + col] = f2bf(h);
        }
      }
      ++ep;
      if (allco) fbar(cnt, g, cg, ep, tid); else xbar(cnt, ep, xcd, pop, nx);
    }

    // ---- phase B: h0_t->hstA (W1ih), h1_{t-1}->hstB (W1hh) ----
    {
      short8 r0s[8], r1s[8];
      stage_ld(H0h[p] + hoff, r0s, tid);
      stage_ld(H1h[p^1] + hoff, r1s, tid);
      stage_wr(r0s, hstA, tid);
      stage_wr(r1s, hstB, tid);
      __syncthreads();
      f32x4 B0 = {0,0,0,0}, B1 = {0,0,0,0};
      #pragma unroll
      for (int ks = 0; ks < 16; ++ks){
        int kk = ks*32;
        LDA(hstA, kk, a0h, a1h)
        MFMA(B0, a0h, w1ih_r[ks]);
        MFMA(B1, a1h, w1ih_r[ks]);
      }
      #pragma unroll
      for (int ks = 0; ks < 16; ++ks){
        int kk = ks*32;
        LDA(hstB, kk, a0h, a1h)
        MFMA(B0, a0h, w1hh_r[ks]);
        MFMA(B1, a1h, w1hh_r[ks]);
      }
      {
        __syncthreads();
        #pragma unroll
        for (int r = 0; r < 4; ++r){
          gl[(rb_ + r)*68 + rl]      = B0[r] + bs1[rl];
          gl[(16 + rb_ + r)*68 + rl] = B1[r] + bs1[rl];
        }
        __syncthreads();
        u16* Hh = H1h[p];
        #pragma unroll
        for (int q = 0; q < 2; ++q){
          int e = tid + q*256;
          int m = e >> 4, col = e & 15;
          float iv = gl[m*68 + col];
          float fv = gl[m*68 + 16 + col];
          float gv = gl[m*68 + 32 + col];
          float ov = gl[m*68 + 48 + col];
          float si = 1.f/(1.f + expf(-iv));
          float sf = 1.f/(1.f + expf(-fv));
          float so = 1.f/(1.f + expf(-ov));
          float cn = sf*c1r[q] + si*tanhf(gv);
          c1r[q] = cn;
          float h = so*tanhf(cn);
          Hh[(b0 + m)*512 + cg*16 + col] = f2bf(h);
        }
      }
      ++ep;
      if (allco) fbar(cnt, g, cg, ep, tid); else xbar(cnt, ep, xcd, pop, nx);
    }
  }
  #undef LDA
}

// ---- tail: pred for l=95 from h1_431 (parity 1) ----------------------------
__global__ void __launch_bounds__(256) pred_last(
    const u16* __restrict__ h1hi,
    const float* __restrict__ Wout, const float* __restrict__ bout,
    float* __restrict__ out)
{
  const int wg = blockIdx.x, tid = threadIdx.x;
  const int bsub = tid >> 6, d = tid & 63;
  const int b = wg*4 + bsub;
  float acc = bout[d];
  const u16* hH = h1hi + b*512;
  const float* wr = Wout + d*512;
  #pragma unroll 8
  for (int k = 0; k < 512; k += 8){
    short8 hv = *(const short8*)(hH + k);
    #pragma unroll
    for (int j = 0; j < 8; ++j)
      acc += bf2f((u16)hv[j]) * wr[k + j];
  }
  out[131072 + (b*64 + d)*96 + 95] = acc;
}

// ======================= fallback (R9 proven path) ==========================
__device__ __forceinline__ void cell_epilogue_fb(
    float* gl, const float* bs, float* __restrict__ cbuf,
    u16* __restrict__ hhi, u16* __restrict__ hlo,
    float* __restrict__ gfout, int mrow, int jblk,
    const f32x4& a0, const f32x4& a1, int wv, int lane, int tid)
{
  __syncthreads();
  const int rbase = wv*16 + ((lane >> 4) << 2);
  const int cI = lane & 15;
  #pragma unroll
  for (int r = 0; r < 4; ++r){
    gl[(rbase+r)*33 + cI]      = a0[r] + bs[cI];
    gl[(rbase+r)*33 + 16 + cI] = a1[r] + bs[16 + cI];
  }
  __syncthreads();
  #pragma unroll
  for (int q = 0; q < 2; ++q){
    int e = tid + q*256;
    int m = e >> 3, jj = e & 7;
    float iv = gl[m*33 + jj];
    float fv = gl[m*33 + 8 + jj];
    float gv = gl[m*33 + 16 + jj];
    float ov = gl[m*33 + 24 + jj];
    float si = 1.f/(1.f + expf(-iv));
    float sf = 1.f/(1.f + expf(-fv));
    float so = 1.f/(1.f + expf(-ov));
    int gi = (mrow*64 + m)*512 + jblk*8 + jj;
    float cn = sf*cbuf[gi] + si*tanhf(gv);
    cbuf[gi] = cn;
    float h = so*tanhf(cn);
    u16 hh = f2bf(h);
    hhi[gi] = hh;
    hlo[gi] = f2bf(h - bf2f(hh));
    if (gfout) gfout[gi] = h;
  }
}

template<bool ENC>
__global__ void __launch_bounds__(256) l0_fb(
    const float* __restrict__ x,
    const u16* __restrict__ predhi, const u16* __restrict__ predlo,
    const float* __restrict__ Wihf, const float* __restrict__ Whhf,
    const float* __restrict__ bih, const float* __restrict__ bhh,
    const u16* __restrict__ hphi, const u16* __restrict__ hplo,
    u16* __restrict__ hnhi, u16* __restrict__ hnlo,
    float* __restrict__ c0, int t)
{
  __shared__ float gl[64*33];
  __shared__ float bs[32];
  const int wg = blockIdx.x, tid = threadIdx.x;
  const int mrow = wg & 3, jblk = wg >> 2;
  const int lane = tid & 63, wv = tid >> 6;
  if (tid < 32){
    int n = ((tid >> 3) << 9) + jblk*8 + (tid & 7);
    bs[tid] = bih[n] + bhh[n];
  }
  const int ar = mrow*64 + wv*16 + (lane & 15);
  const int kc = (lane >> 4) << 3;
  const int cI = lane & 15;
  const int n0 = ((cI >> 3) << 9) + jblk*8 + (cI & 7);
  const int n1 = n0 + 1024;

  f32x4 acc0 = {0,0,0,0}, acc1 = {0,0,0,0};
  #pragma unroll
  for (int ks = 0; ks < 2; ++ks){
    int k = ks*32 + kc;
    short8 ah, al;
    if (ENC){
      const float* xb = x + ar*21504 + t;
      #pragma unroll
      for (int j = 0; j < 8; ++j){ HiLo s = split1(xb[(k + j)*336]); ah[j] = s.hi; al[j] = s.lo; }
    } else {
      ah = *(const short8*)(predhi + ar*64 + k);
      al = *(const short8*)(predlo + ar*64 + k);
    }
    short8 bh0, bl0, bh1, bl1;
    ldw8s(Wihf + n0*64 + k, bh0, bl0);
    ldw8s(Wihf + n1*64 + k, bh1, bl1);
    SMACC(acc0, ah, al, bh0, bl0);
    SMACC(acc1, ah, al, bh1, bl1);
  }
  const u16* hH = hphi + ar*512 + kc;
  const u16* hL = hplo + ar*512 + kc;
  #pragma unroll 4
  for (int ks = 0; ks < 16; ++ks){
    int k = ks*32;
    short8 ah = *(const short8*)(hH + k);
    short8 al = *(const short8*)(hL + k);
    short8 bh0, bl0, bh1, bl1;
    ldw8s(Whhf + n0*512 + kc + k, bh0, bl0);
    ldw8s(Whhf + n1*512 + kc + k, bh1, bl1);
    SMACC(acc0, ah, al, bh0, bl0);
    SMACC(acc1, ah, al, bh1, bl1);
  }
  cell_epilogue_fb(gl, bs, c0, hnhi, hnlo, nullptr, mrow, jblk, acc0, acc1, wv, lane, tid);
}

__global__ void __launch_bounds__(256) l1_fb(
    const float* __restrict__ Wihf, const float* __restrict__ Whhf,
    const float* __restrict__ bih, const float* __restrict__ bhh,
    const u16* __restrict__ h0hi, const u16* __restrict__ h0lo,
    const u16* __restrict__ h1phi, const u16* __restrict__ h1plo,
    u16* __restrict__ h1nhi, u16* __restrict__ h1nlo,
    float* __restrict__ c1, float* __restrict__ gfout)
{
  __shared__ float gl[64*33];
  __shared__ float bs[32];
  const int wg = blockIdx.x, tid = threadIdx.x;
  const int mrow = wg & 3, jblk = wg >> 2;
  const int lane = tid & 63, wv = tid >> 6;
  if (tid < 32){
    int n = ((tid >> 3) << 9) + jblk*8 + (tid & 7);
    bs[tid] = bih[n] + bhh[n];
  }
  const int ar = mrow*64 + wv*16 + (lane & 15);
  const int kc = (lane >> 4) << 3;
  const int cI = lane & 15;
  const int n0 = ((cI >> 3) << 9) + jblk*8 + (cI & 7);
  const int n1 = n0 + 1024;

  f32x4 acc0 = {0,0,0,0}, acc1 = {0,0,0,0};
  {
    const u16* hH = h0hi + ar*512 + kc;
    const u16* hL = h0lo + ar*512 + kc;
    #pragma unroll 4
    for (int ks = 0; ks < 16; ++ks){
      int k = ks*32;
      short8 ah = *(const short8*)(hH + k);
      short8 al = *(const short8*)(hL + k);
      short8 bh0, bl0, bh1, bl1;
      ldw8s(Wihf + n0*512 + kc + k, bh0, bl0);
      ldw8s(Wihf + n1*512 + kc + k, bh1, bl1);
      SMACC(acc0, ah, al, bh0, bl0);
      SMACC(acc1, ah, al, bh1, bl1);
    }
  }
  {
    const u16* hH = h1phi + ar*512 + kc;
    const u16* hL = h1plo + ar*512 + kc;
    #pragma unroll 4
    for (int ks = 0; ks < 16; ++ks){
      int k = ks*32;
      short8 ah = *(const short8*)(hH + k);
      short8 al = *(const short8*)(hL + k);
      short8 bh0, bl0, bh1, bl1;
      ldw8s(Whhf + n0*512 + kc + k, bh0, bl0);
      ldw8s(Whhf + n1*512 + kc + k, bh1, bl1);
      SMACC(acc0, ah, al, bh0, bl0);
      SMACC(acc1, ah, al, bh1, bl1);
    }
  }
  cell_epilogue_fb(gl, bs, c1, h1nhi, h1nlo, gfout, mrow, jblk, acc0, acc1, wv, lane, tid);
}

__global__ void __launch_bounds__(256) pred_fb(
    const u16* __restrict__ h1hi, const u16* __restrict__ h1lo,
    const float* __restrict__ Wout, const float* __restrict__ bout,
    u16* __restrict__ predhi, u16* __restrict__ predlo,
    float* __restrict__ out, int l)
{
  const int wg = blockIdx.x, tid = threadIdx.x;
  const int bsub = tid >> 6, d = tid & 63;
  const int b = wg*4 + bsub;
  float acc = bout[d];
  const u16* hH = h1hi + b*512;
  const u16* hL = h1lo + b*512;
  const float* wr = Wout + d*512;
  #pragma unroll 8
  for (int k = 0; k < 512; k += 8){
    short8 hv = *(const short8*)(hH + k);
    short8 lv = *(const short8*)(hL + k);
    #pragma unroll
    for (int j = 0; j < 8; ++j)
      acc += (bf2f((u16)hv[j]) + bf2f((u16)lv[j])) * wr[k + j];
  }
  HiLo s = split1(acc);
  predhi[b*64 + d] = (u16)s.hi;
  predlo[b*64 + d] = (u16)s.lo;
  out[131072 + (b*64 + d)*96 + l] = acc;
}

extern "C" void kernel_launch(void* const* d_in, const int* in_sizes, int n_in,
                              void* d_out, int out_size, void* d_ws, size_t ws_size,
                              hipStream_t stream)
{
  const float* x    = (const float*)d_in[0];
  const float* Wih0 = (const float*)d_in[1];
  const float* Whh0 = (const float*)d_in[2];
  const float* bih0 = (const float*)d_in[3];
  const float* bhh0 = (const float*)d_in[4];
  const float* Wih1 = (const float*)d_in[5];
  const float* Whh1 = (const float*)d_in[6];
  const float* bih1 = (const float*)d_in[7];
  const float* bhh1 = (const float*)d_in[8];
  const float* Wout = (const float*)d_in[9];
  const float* bout = (const float*)d_in[10];
  float* out = (float*)d_out;

  // ---- ws layout (identical offsets to R26)
  char* ws = (char*)d_ws;
  u16* h0h[2] = { (u16*)(ws + 0),       (u16*)(ws + 262144) };
  u16* h0l[2] = { (u16*)(ws + 524288),  (u16*)(ws + 786432) };
  u16* h1h[2] = { (u16*)(ws + 1048576), (u16*)(ws + 1310720) };
  u16* h1l[2] = { (u16*)(ws + 1572864), (u16*)(ws + 1835008) };
  unsigned* cnt = (unsigned*)(ws + 2097152);
  u16* Wcmb_h = (u16*)(ws + 2162688);
  u16* W1ih_h = Wcmb_h + 1048576;
  u16* W1hh_h = W1ih_h + 1048576;
  float* bb   = (float*)(W1hh_h + 1048576);
  const size_t NEED = 2162688u + 3u*2097152u + 8192u;   // ~8.5 MB
  // fallback layout (only used when ws too small)
  float* fb_c0 = (float*)(ws + 2162688);
  float* fb_c1 = (float*)(ws + 2686976);
  u16* predh   = (u16*)(ws + 3211264);
  u16* predl   = (u16*)(ws + 3244032);
  const bool ps = (ws_size >= NEED);

  (void)hipMemsetAsync(d_ws, 0, 3276800, stream);

  if (ps){
    wcomb_k<<<dim3(256), dim3(256), 0, stream>>>(Wih0, Wout, bout, bih0, bhh0,
                                                 Wcmb_h, bb);
    wcvt<<<dim3(4096), dim3(256), 0, stream>>>(Wih1, W1ih_h, 1048576);
    wcvt<<<dim3(4096), dim3(256), 0, stream>>>(Whh1, W1hh_h, 1048576);
    lstm_persist<<<dim3(256), dim3(256), 0, stream>>>(
        x, Whh0, Wih0, W1ih_h, W1hh_h, Wcmb_h, bb,
        bih0, bhh0, bih1, bhh1, Wout, bout, out, cnt,
        h0h[0], h0h[1], h1h[0], h1h[1]);
    pred_last<<<dim3(64), dim3(256), 0, stream>>>(h1h[1], Wout, bout, out);
  } else {
    for (int t = 0; t < 432; ++t){
      const int p = t & 1;
      float* gf = (t == 335) ? out : (float*)nullptr;
      if (t < 336)
        l0_fb<true><<<dim3(256), dim3(256), 0, stream>>>(
            x, predh, predl, Wih0, Whh0, bih0, bhh0,
            h0h[p^1], h0l[p^1], h0h[p], h0l[p], fb_c0, t);
      else
        l0_fb<false><<<dim3(256), dim3(256), 0, stream>>>(
            x, predh, predl, Wih0, Whh0, bih0, bhh0,
            h0h[p^1], h0l[p^1], h0h[p], h0l[p], fb_c0, t);
      l1_fb<<<dim3(256), dim3(256), 0, stream>>>(
          Wih1, Whh1, bih1, bhh1, h0h[p], h0l[p],
          h1h[p^1], h1l[p^1], h1h[p], h1l[p], fb_c1, gf);
      if (t >= 336)
        pred_fb<<<dim3(64), dim3(256), 0, stream>>>(
            h1h[p], h1l[p], Wout, bout, predh, predl, out, t - 336);
    }
  }
}

// Round 29
// 3758.080 us; speedup vs baseline: 5.7537x; 1.0344x over previous
//
#include <hip/hip_runtime.h>

typedef unsigned short u16;
typedef __attribute__((ext_vector_type(8))) short short8;
typedef __attribute__((ext_vector_type(4))) float f32x4;

#define AXR __ATOMIC_RELAXED, __HIP_MEMORY_SCOPE_AGENT

__device__ __forceinline__ float bf2f(u16 v){
  union { unsigned u; float f; } t; t.u = ((unsigned)v) << 16; return t.f;
}
__device__ __forceinline__ u16 f2bf(float f){
  union { float f; unsigned u; } t; t.f = f;
  unsigned u = t.u;
  return (u16)((u + 0x7fffu + ((u >> 16) & 1u)) >> 16);
}
struct HiLo { short hi, lo; };
__device__ __forceinline__ HiLo split1(float v){
  HiLo r;
  u16 h = f2bf(v);
  r.hi = (short)h;
  r.lo = (short)f2bf(v - bf2f(h));
  return r;
}
__device__ __forceinline__ void ldw8s(const float* __restrict__ p, short8& hi, short8& lo){
  #pragma unroll
  for (int j = 0; j < 8; ++j){ HiLo s = split1(p[j]); hi[j] = s.hi; lo[j] = s.lo; }
}

#define MFMA(acc, a, b) acc = __builtin_amdgcn_mfma_f32_16x16x32_bf16(a, b, acc, 0,0,0)
#define SMACC(acc, ah, al, bh, bl) do{ MFMA(acc, ah, bh); MFMA(acc, ah, bl); MFMA(acc, al, bh); }while(0)

// ---- prepass: f32 -> bf16 (hi only, RNE) -----------------------------------
__global__ void wcvt(const float* __restrict__ s, u16* __restrict__ hi, int n){
  int i = blockIdx.x * blockDim.x + threadIdx.x;
  if (i < n) hi[i] = f2bf(s[i]);
}

// ---- prepass: Wcomb = Wih0 @ Wout (2048x512 bf16 hi), bb = b0 + Wih0@bout --
__global__ void __launch_bounds__(256) wcomb_k(
    const float* __restrict__ Wih0, const float* __restrict__ Wout,
    const float* __restrict__ bout, const float* __restrict__ bih0,
    const float* __restrict__ bhh0,
    u16* __restrict__ Wch, float* __restrict__ bb)
{
  __shared__ float wl[8*64];
  __shared__ float bo[64];
  const int wg = blockIdx.x, tid = threadIdx.x;
  const int r0 = wg*8;
  for (int i = tid; i < 512; i += 256) wl[i] = Wih0[(r0 + (i >> 6))*64 + (i & 63)];
  if (tid < 64) bo[tid] = bout[tid];
  __syncthreads();
  if (tid < 8){
    int n = r0 + tid;
    float a = bih0[n] + bhh0[n];
    #pragma unroll 8
    for (int d = 0; d < 64; ++d) a += wl[tid*64 + d]*bo[d];
    bb[n] = a;
  }
  #pragma unroll
  for (int jj = 0; jj < 2; ++jj){
    int j = tid + jj*256;
    float acc[8] = {0,0,0,0,0,0,0,0};
    for (int d = 0; d < 64; ++d){
      float wv = Wout[d*512 + j];
      #pragma unroll
      for (int r = 0; r < 8; ++r) acc[r] += wl[r*64 + d]*wv;
    }
    #pragma unroll
    for (int r = 0; r < 8; ++r) Wch[(r0 + r)*512 + j] = f2bf(acc[r]);
  }
}

// ---- init-only tree barrier ------------------------------------------------
__device__ __forceinline__ void gbar(unsigned* bar, unsigned phase){
  __syncthreads();
  if (threadIdx.x == 0){
    __threadfence();
    const unsigned gg = (unsigned)blockIdx.x >> 4;
    unsigned old = __hip_atomic_fetch_add(bar + 64 + gg*32, 1u, AXR);
    if (old == phase*16u - 1u){
      unsigned r = __hip_atomic_fetch_add(bar, 1u, AXR);
      if (r == phase*16u - 1u)
        __hip_atomic_store(bar + 32, phase, AXR);
    }
    while (__hip_atomic_load(bar + 32, AXR) < phase)
      __builtin_amdgcn_s_sleep(2);
    __threadfence();
  }
  __syncthreads();
}

// ---- global fallback barrier (R14 xbar) ------------------------------------
__device__ __forceinline__ void xbar(unsigned* bar, unsigned phase,
                                     unsigned xcd, unsigned pop, unsigned nx){
  __syncthreads();
  if (threadIdx.x == 0){
    unsigned old = __hip_atomic_fetch_add(bar + 832 + xcd*32, 1u, AXR);
    const bool leader = (old == phase*pop - 1u);
    if (leader){
      asm volatile("buffer_wbl2 sc1\n\ts_waitcnt vmcnt(0)" ::: "memory");
      unsigned r = __hip_atomic_fetch_add(bar + 1344, 1u, AXR);
      if (r == phase*nx - 1u)
        __hip_atomic_store(bar + 1376, phase, AXR);
    }
    while (__hip_atomic_load(bar + 1376, AXR) < phase)
      __builtin_amdgcn_s_sleep(2);
    if (leader){
      asm volatile("buffer_inv sc1\n\ts_waitcnt vmcnt(0)" ::: "memory");
      __hip_atomic_store(bar + 1088 + xcd*32, phase, AXR);
    } else {
      while (__hip_atomic_load(bar + 1088 + xcd*32, AXR) < phase)
        __builtin_amdgcn_s_sleep(1);
      asm volatile("buffer_inv\n\ts_waitcnt vmcnt(0)" ::: "memory");
    }
  }
  __syncthreads();
}

// ---- group-local FLAG-ARRAY barrier (R22) ----------------------------------
__device__ __forceinline__ void fbar(unsigned* bar, int g, int cg,
                                     unsigned phase, int tid){
  __syncthreads();
  unsigned* flags = bar + 4096 + g*1024;
  if (tid == 0)
    __hip_atomic_store(flags + cg*32, phase, AXR);
  if (tid < 64){
    const int i = tid & 31;
    while (__hip_atomic_load(flags + i*32, AXR) < phase)
      __builtin_amdgcn_s_sleep(1);
    asm volatile("buffer_inv\n\ts_waitcnt vmcnt(0)" ::: "memory");
  }
  __syncthreads();
}

// ---- LDS helpers (XOR-swizzled, G4) ----------------------------------------
__device__ __forceinline__ short8 lds8(const u16* base, int r, int kelem, int rowbytes){
  int bo = r*rowbytes + ((kelem*2) ^ ((r & 7) << 4));
  return *(const short8*)((const char*)base + bo);
}

// ---- h-block stage split into load (regs) and write (swizzled LDS) ---------
__device__ __forceinline__ void stage_ld(const u16* __restrict__ gh,
                                         short8* r, int tid){
  #pragma unroll
  for (int i = 0; i < 8; ++i)
    r[i] = *(const short8*)(gh + (tid + i*256)*8);
}
__device__ __forceinline__ void stage_wr(const short8* r, u16* sh, int tid){
  #pragma unroll
  for (int i = 0; i < 8; ++i){
    int e = (tid + i*256)*8;
    int row = e >> 9, col = e & 511;
    int bo = row*1024 + ((col*2) ^ ((row & 7) << 4));
    *(short8*)((char*)sh + bo) = r[i];
  }
}

// ---- persistent kernel: ALL weights in registers, merged exchanges ---------
__global__ void __launch_bounds__(256, 1) lstm_persist(
    const float* __restrict__ x,
    const float* __restrict__ Whh0, const float* __restrict__ Wih0,
    const u16* __restrict__ W1ih_h, const u16* __restrict__ W1hh_h,
    const u16* __restrict__ Wcmb_h, const float* __restrict__ bb,
    const float* __restrict__ bih0, const float* __restrict__ bhh0,
    const float* __restrict__ bih1, const float* __restrict__ bhh1,
    const float* __restrict__ Wout, const float* __restrict__ bout,
    float* __restrict__ out, unsigned* __restrict__ cnt,
    u16* __restrict__ h0h0, u16* __restrict__ h0h1,
    u16* __restrict__ h1h0, u16* __restrict__ h1h1)
{
  __shared__ u16 hstA[16384], hstB[16384];       // 2x32KB: staged h blocks
  __shared__ float glA[32*68];                   // l0 gate exchange (aliases xst)
  __shared__ float glB[32*68];                   // l1 gate exchange
  __shared__ float pr[256];                      // pred partials
  __shared__ float bs0[64], bs1[64], bsd[64];
  __shared__ unsigned s_rank, s_pop, s_nx, s_all;

  u16* xst_h = (u16*)glA;                        // x_t stage: 32x64 hi
  u16* xst_l = (u16*)glA + 2048;                 // 32x64 lo

  const int wg = blockIdx.x, tid = threadIdx.x;
  const int lane = tid & 63, wv = tid >> 6;
  const int cI = lane & 15;
  const int kc = (lane >> 4) << 3;
  const int rl = wv*16 + cI;

  // ---- census ----
  unsigned xcd;
  asm volatile("s_getreg_b32 %0, hwreg(HW_REG_XCC_ID)" : "=s"(xcd));
  xcd &= 7u;
  if (tid == 0)
    s_rank = __hip_atomic_fetch_add(cnt + 576 + xcd*32, 1u, AXR);
  gbar(cnt, 1);
  if (tid == 0){
    unsigned nxl = 0, allc = 1;
    for (int i = 0; i < 8; ++i){
      unsigned pv = __hip_atomic_load(cnt + 576 + i*32, AXR);
      nxl += (pv != 0u) ? 1u : 0u;
      if (pv != 32u) allc = 0u;
    }
    s_pop = __hip_atomic_load(cnt + 576 + xcd*32, AXR);
    s_nx  = nxl;
    s_all = allc;
  }
  __syncthreads();
  const unsigned pop = s_pop, nx = s_nx;
  const bool allco = (s_all != 0u);
  const int g  = allco ? (int)xcd    : (wg & 7);
  const int cg = allco ? (int)s_rank : (wg >> 3);
  const int b0 = g*32;

  // ---- one-time init: biases + ALL weight fragments into registers ----
  if (tid < 64){
    int n = ((tid >> 4) << 9) + cg*16 + (tid & 15);
    bs0[tid] = bih0[n] + bhh0[n];
    bs1[tid] = bih1[n] + bhh1[n];
    bsd[tid] = bb[n];
  }
  const int nrow = wv*512 + cg*16 + cI;          // this thread's gate row
  const int nb = nrow*512 + kc;                  // K=512 frag base
  short8 w1ih_r[16], w1hh_r[16], wcmb_r[16], w0hh_r[16];
  #pragma unroll
  for (int ks = 0; ks < 16; ++ks){
    w1ih_r[ks] = *(const short8*)(W1ih_h + nb + ks*32);
    w1hh_r[ks] = *(const short8*)(W1hh_h + nb + ks*32);
    wcmb_r[ks] = *(const short8*)(Wcmb_h + nb + ks*32);
    short8 t;
    #pragma unroll
    for (int j = 0; j < 8; ++j) t[j] = (short)f2bf(Whh0[nb + ks*32 + j]);
    w0hh_r[ks] = t;
  }
  short8 w0ih_rh[2], w0ih_rl[2];                 // Wih0 frag (K=64), split
  #pragma unroll
  for (int ks = 0; ks < 2; ++ks){
    short8 th, tl;
    #pragma unroll
    for (int j = 0; j < 8; ++j){
      HiLo s = split1(Wih0[nrow*64 + ks*32 + kc + j]);
      th[j] = s.hi; tl[j] = s.lo;
    }
    w0ih_rh[ks] = th; w0ih_rl[ks] = tl;
  }
  __syncthreads();

  u16* H0h[2] = { h0h0, h0h1 };
  u16* H1h[2] = { h1h0, h1h1 };

  float c0r[2] = {0.f, 0.f}, c1r[2] = {0.f, 0.f};
  unsigned ep = 0;
  const int rb_ = (lane >> 4) << 2;
  const int hoff = b0*512;

  #define LDA(buf, kk, a0h_, a1h_) \
    short8 a0h_ = lds8(buf, cI, kc + (kk), 1024); \
    short8 a1h_ = lds8(buf, cI + 16, kc + (kk), 1024);

  #define CELL(GL, CREG, HDST, GF) { \
    u16* Hh_ = (HDST); \
    _Pragma("unroll") \
    for (int q = 0; q < 2; ++q){ \
      int e = tid + q*256; \
      int m = e >> 4, col = e & 15; \
      float iv = GL[m*68 + col]; \
      float fv = GL[m*68 + 16 + col]; \
      float gv = GL[m*68 + 32 + col]; \
      float ov = GL[m*68 + 48 + col]; \
      float si = 1.f/(1.f + expf(-iv)); \
      float sf = 1.f/(1.f + expf(-fv)); \
      float so = 1.f/(1.f + expf(-ov)); \
      float cn = sf*CREG[q] + si*tanhf(gv); \
      CREG[q] = cn; \
      float h = so*tanhf(cn); \
      int gi = (b0 + m)*512 + cg*16 + col; \
      Hh_[gi] = f2bf(h); \
      if (GF) ((float*)(GF))[gi] = h; \
    } }

  // ======== skewed encoder: phase k computes h0_k and h1_{k-1} ========
  // (k==336 computes h0_336, the decoder's first l0 step with zero input)
  for (int k = 0; k <= 336; ++k){
    const int p0 = k & 1;

    // ---- phase start: all global loads, write stage buffers ----
    short8 r0s[8], r1s[8];
    float xr[8];
    stage_ld(H0h[p0^1] + hoff, r0s, tid);
    if (k >= 1) stage_ld(H1h[p0] + hoff, r1s, tid);
    if (k < 336){
      #pragma unroll
      for (int i = 0; i < 8; ++i){
        int e = tid + i*256;
        xr[i] = x[(b0 + (e >> 6))*21504 + (e & 63)*336 + k];
      }
    }
    stage_wr(r0s, hstA, tid);
    if (k >= 1) stage_wr(r1s, hstB, tid);
    if (k < 336){
      #pragma unroll
      for (int i = 0; i < 8; ++i){
        int e = tid + i*256;
        int bb_ = e >> 6, d = e & 63;
        HiLo s = split1(xr[i]);
        int bo = bb_*128 + ((d*2) ^ ((bb_ & 7) << 4));
        *(u16*)((char*)xst_h + bo) = (u16)s.hi;
        *(u16*)((char*)xst_l + bo) = (u16)s.lo;
      }
    }
    __syncthreads();

    // ---- MFMA block: x + fused(Whh0,W1ih) + W1hh (all weights in regs) ----
    f32x4 A0 = {0,0,0,0}, A1 = {0,0,0,0};
    f32x4 B0 = {0,0,0,0}, B1 = {0,0,0,0};
    if (k < 336){
      #pragma unroll
      for (int ks = 0; ks < 2; ++ks){
        int kk = ks*32 + kc;
        short8 a0h = lds8(xst_h, cI, kk, 128);
        short8 a0l = lds8(xst_l, cI, kk, 128);
        short8 a1h = lds8(xst_h, cI + 16, kk, 128);
        short8 a1l = lds8(xst_l, cI + 16, kk, 128);
        SMACC(A0, a0h, a0l, w0ih_rh[ks], w0ih_rl[ks]);
        SMACC(A1, a1h, a1l, w0ih_rh[ks], w0ih_rl[ks]);
      }
    }
    #pragma unroll
    for (int ks = 0; ks < 16; ++ks){             // fused: Whh0(REG) + W1ih(REG)
      int kk = ks*32;
      LDA(hstA, kk, a0h, a1h)
      MFMA(A0, a0h, w0hh_r[ks]);
      MFMA(A1, a1h, w0hh_r[ks]);
      MFMA(B0, a0h, w1ih_r[ks]);
      MFMA(B1, a1h, w1ih_r[ks]);
    }
    if (k >= 1){
      #pragma unroll
      for (int ks = 0; ks < 16; ++ks){           // W1hh (REG) over h1_{k-2}
        int kk = ks*32;
        LDA(hstB, kk, a0h, a1h)
        MFMA(B0, a0h, w1hh_r[ks]);
        MFMA(B1, a1h, w1hh_r[ks]);
      }
    }

    // ---- MERGED exchange: one sync pair for both cells ----
    // l0 exchange+cell runs for ALL k (k==336 produces h0_336, zero-input).
    __syncthreads();                             // xst reads done (glA reuse)
    #pragma unroll
    for (int r = 0; r < 4; ++r){
      glA[(rb_ + r)*68 + rl]      = A0[r] + bs0[rl];
      glA[(16 + rb_ + r)*68 + rl] = A1[r] + bs0[rl];
    }
    if (k >= 1){
      #pragma unroll
      for (int r = 0; r < 4; ++r){
        glB[(rb_ + r)*68 + rl]      = B0[r] + bs1[rl];
        glB[(16 + rb_ + r)*68 + rl] = B1[r] + bs1[rl];
      }
    }
    __syncthreads();
    CELL(glA, c0r, H0h[p0], (float*)nullptr)
    if (k >= 1)  CELL(glB, c1r, H1h[p0^1], (k == 336) ? out : nullptr)
    ++ep;
    if (allco) fbar(cnt, g, cg, ep, tid); else xbar(cnt, ep, xcd, pop, nx);
  }

  // ======== l1 catch-up: h1_336 (h0_336 buf[0], h1_335 buf[1]) ========
  {
    short8 r0s[8], r1s[8];
    stage_ld(H0h[0] + hoff, r0s, tid);
    stage_ld(H1h[1] + hoff, r1s, tid);
    stage_wr(r0s, hstA, tid);
    stage_wr(r1s, hstB, tid);
    __syncthreads();
    f32x4 B0 = {0,0,0,0}, B1 = {0,0,0,0};
    #pragma unroll
    for (int ks = 0; ks < 16; ++ks){
      int kk = ks*32;
      LDA(hstA, kk, a0h, a1h)
      MFMA(B0, a0h, w1ih_r[ks]);
      MFMA(B1, a1h, w1ih_r[ks]);
    }
    #pragma unroll
    for (int ks = 0; ks < 16; ++ks){
      int kk = ks*32;
      LDA(hstB, kk, a0h, a1h)
      MFMA(B0, a0h, w1hh_r[ks]);
      MFMA(B1, a1h, w1hh_r[ks]);
    }
    __syncthreads();
    #pragma unroll
    for (int r = 0; r < 4; ++r){
      glB[(rb_ + r)*68 + rl]      = B0[r] + bs1[rl];
      glB[(16 + rb_ + r)*68 + rl] = B1[r] + bs1[rl];
    }
    __syncthreads();
    CELL(glB, c1r, H1h[0], (float*)nullptr)
    ++ep;
    if (allco) fbar(cnt, g, cg, ep, tid); else xbar(cnt, ep, xcd, pop, nx);
  }

  // ======== decoder: t = 337..431 ========
  for (int t = 337; t < 432; ++t){
    const int p = t & 1;

    // ---- phase A: h1_{t-1}->hstA (Wcomb+pred), h0_{t-1}->hstB (Whh0) ----
    {
      short8 r0s[8], r1s[8];
      stage_ld(H1h[p^1] + hoff, r0s, tid);
      stage_ld(H0h[p^1] + hoff, r1s, tid);
      stage_wr(r0s, hstA, tid);
      stage_wr(r1s, hstB, tid);
      __syncthreads();
      f32x4 A0 = {0,0,0,0}, A1 = {0,0,0,0};
      #pragma unroll
      for (int ks = 0; ks < 16; ++ks){
        int kk = ks*32;
        LDA(hstA, kk, a0h, a1h)
        MFMA(A0, a0h, wcmb_r[ks]);
        MFMA(A1, a1h, wcmb_r[ks]);
      }
      #pragma unroll
      for (int ks = 0; ks < 16; ++ks){           // Whh0 (REG) over h0_{t-1}
        int kk = ks*32;
        LDA(hstB, kk, a0h, a1h)
        MFMA(A0, a0h, w0hh_r[ks]);
        MFMA(A1, a1h, w0hh_r[ks]);
      }
      {                                          // pred l=t-337 from hstA
        const int d = tid & 63, kq = tid >> 6;
        float part = 0.f;
        const float* wr = Wout + d*512 + kq*128;
        #pragma unroll 4
        for (int kk = 0; kk < 128; kk += 8){
          short8 hv = lds8(hstA, cg, kq*128 + kk, 1024);
          #pragma unroll
          for (int j = 0; j < 8; ++j)
            part += bf2f((u16)hv[j]) * wr[kk + j];
        }
        pr[d*4 + kq] = part;
        __syncthreads();
        if (tid < 64){
          float v = pr[tid*4] + pr[tid*4+1] + pr[tid*4+2] + pr[tid*4+3] + bout[tid];
          out[131072 + ((b0 + cg)*64 + tid)*96 + (t - 337)] = v;
        }
      }
      __syncthreads();
      #pragma unroll
      for (int r = 0; r < 4; ++r){
        glA[(rb_ + r)*68 + rl]      = A0[r] + bsd[rl];
        glA[(16 + rb_ + r)*68 + rl] = A1[r] + bsd[rl];
      }
      __syncthreads();
      CELL(glA, c0r, H0h[p], (float*)nullptr)
      ++ep;
      if (allco) fbar(cnt, g, cg, ep, tid); else xbar(cnt, ep, xcd, pop, nx);
    }

    // ---- phase B: h0_t->hstA (W1ih), h1_{t-1}->hstB (W1hh) ----
    {
      short8 r0s[8], r1s[8];
      stage_ld(H0h[p] + hoff, r0s, tid);
      stage_ld(H1h[p^1] + hoff, r1s, tid);
      stage_wr(r0s, hstA, tid);
      stage_wr(r1s, hstB, tid);
      __syncthreads();
      f32x4 B0 = {0,0,0,0}, B1 = {0,0,0,0};
      #pragma unroll
      for (int ks = 0; ks < 16; ++ks){
        int kk = ks*32;
        LDA(hstA, kk, a0h, a1h)
        MFMA(B0, a0h, w1ih_r[ks]);
        MFMA(B1, a1h, w1ih_r[ks]);
      }
      #pragma unroll
      for (int ks = 0; ks < 16; ++ks){
        int kk = ks*32;
        LDA(hstB, kk, a0h, a1h)
        MFMA(B0, a0h, w1hh_r[ks]);
        MFMA(B1, a1h, w1hh_r[ks]);
      }
      __syncthreads();
      #pragma unroll
      for (int r = 0; r < 4; ++r){
        glB[(rb_ + r)*68 + rl]      = B0[r] + bs1[rl];
        glB[(16 + rb_ + r)*68 + rl] = B1[r] + bs1[rl];
      }
      __syncthreads();
      CELL(glB, c1r, H1h[p], (float*)nullptr)
      ++ep;
      if (allco) fbar(cnt, g, cg, ep, tid); else xbar(cnt, ep, xcd, pop, nx);
    }
  }
  #undef LDA
  #undef CELL
}

// ---- tail: pred for l=95 from h1_431 (parity 1) ----------------------------
__global__ void __launch_bounds__(256) pred_last(
    const u16* __restrict__ h1hi,
    const float* __restrict__ Wout, const float* __restrict__ bout,
    float* __restrict__ out)
{
  const int wg = blockIdx.x, tid = threadIdx.x;
  const int bsub = tid >> 6, d = tid & 63;
  const int b = wg*4 + bsub;
  float acc = bout[d];
  const u16* hH = h1hi + b*512;
  const float* wr = Wout + d*512;
  #pragma unroll 8
  for (int k = 0; k < 512; k += 8){
    short8 hv = *(const short8*)(hH + k);
    #pragma unroll
    for (int j = 0; j < 8; ++j)
      acc += bf2f((u16)hv[j]) * wr[k + j];
  }
  out[131072 + (b*64 + d)*96 + 95] = acc;
}

// ======================= fallback (R9 proven path) ==========================
__device__ __forceinline__ void cell_epilogue_fb(
    float* gl, const float* bs, float* __restrict__ cbuf,
    u16* __restrict__ hhi, u16* __restrict__ hlo,
    float* __restrict__ gfout, int mrow, int jblk,
    const f32x4& a0, const f32x4& a1, int wv, int lane, int tid)
{
  __syncthreads();
  const int rbase = wv*16 + ((lane >> 4) << 2);
  const int cI = lane & 15;
  #pragma unroll
  for (int r = 0; r < 4; ++r){
    gl[(rbase+r)*33 + cI]      = a0[r] + bs[cI];
    gl[(rbase+r)*33 + 16 + cI] = a1[r] + bs[16 + cI];
  }
  __syncthreads();
  #pragma unroll
  for (int q = 0; q < 2; ++q){
    int e = tid + q*256;
    int m = e >> 3, jj = e & 7;
    float iv = gl[m*33 + jj];
    float fv = gl[m*33 + 8 + jj];
    float gv = gl[m*33 + 16 + jj];
    float ov = gl[m*33 + 24 + jj];
    float si = 1.f/(1.f + expf(-iv));
    float sf = 1.f/(1.f + expf(-fv));
    float so = 1.f/(1.f + expf(-ov));
    int gi = (mrow*64 + m)*512 + jblk*8 + jj;
    float cn = sf*cbuf[gi] + si*tanhf(gv);
    cbuf[gi] = cn;
    float h = so*tanhf(cn);
    u16 hh = f2bf(h);
    hhi[gi] = hh;
    hlo[gi] = f2bf(h - bf2f(hh));
    if (gfout) gfout[gi] = h;
  }
}

template<bool ENC>
__global__ void __launch_bounds__(256) l0_fb(
    const float* __restrict__ x,
    const u16* __restrict__ predhi, const u16* __restrict__ predlo,
    const float* __restrict__ Wihf, const float* __restrict__ Whhf,
    const float* __restrict__ bih, const float* __restrict__ bhh,
    const u16* __restrict__ hphi, const u16* __restrict__ hplo,
    u16* __restrict__ hnhi, u16* __restrict__ hnlo,
    float* __restrict__ c0, int t)
{
  __shared__ float gl[64*33];
  __shared__ float bs[32];
  const int wg = blockIdx.x, tid = threadIdx.x;
  const int mrow = wg & 3, jblk = wg >> 2;
  const int lane = tid & 63, wv = tid >> 6;
  if (tid < 32){
    int n = ((tid >> 3) << 9) + jblk*8 + (tid & 7);
    bs[tid] = bih[n] + bhh[n];
  }
  const int ar = mrow*64 + wv*16 + (lane & 15);
  const int kc = (lane >> 4) << 3;
  const int cI = lane & 15;
  const int n0 = ((cI >> 3) << 9) + jblk*8 + (cI & 7);
  const int n1 = n0 + 1024;

  f32x4 acc0 = {0,0,0,0}, acc1 = {0,0,0,0};
  #pragma unroll
  for (int ks = 0; ks < 2; ++ks){
    int k = ks*32 + kc;
    short8 ah, al;
    if (ENC){
      const float* xb = x + ar*21504 + t;
      #pragma unroll
      for (int j = 0; j < 8; ++j){ HiLo s = split1(xb[(k + j)*336]); ah[j] = s.hi; al[j] = s.lo; }
    } else {
      ah = *(const short8*)(predhi + ar*64 + k);
      al = *(const short8*)(predlo + ar*64 + k);
    }
    short8 bh0, bl0, bh1, bl1;
    ldw8s(Wihf + n0*64 + k, bh0, bl0);
    ldw8s(Wihf + n1*64 + k, bh1, bl1);
    SMACC(acc0, ah, al, bh0, bl0);
    SMACC(acc1, ah, al, bh1, bl1);
  }
  const u16* hH = hphi + ar*512 + kc;
  const u16* hL = hplo + ar*512 + kc;
  #pragma unroll 4
  for (int ks = 0; ks < 16; ++ks){
    int k = ks*32;
    short8 ah = *(const short8*)(hH + k);
    short8 al = *(const short8*)(hL + k);
    short8 bh0, bl0, bh1, bl1;
    ldw8s(Whhf + n0*512 + kc + k, bh0, bl0);
    ldw8s(Whhf + n1*512 + kc + k, bh1, bl1);
    SMACC(acc0, ah, al, bh0, bl0);
    SMACC(acc1, ah, al, bh1, bl1);
  }
  cell_epilogue_fb(gl, bs, c0, hnhi, hnlo, nullptr, mrow, jblk, acc0, acc1, wv, lane, tid);
}

__global__ void __launch_bounds__(256) l1_fb(
    const float* __restrict__ Wihf, const float* __restrict__ Whhf,
    const float* __restrict__ bih, const float* __restrict__ bhh,
    const u16* __restrict__ h0hi, const u16* __restrict__ h0lo,
    const u16* __restrict__ h1phi, const u16* __restrict__ h1plo,
    u16* __restrict__ h1nhi, u16* __restrict__ h1nlo,
    float* __restrict__ c1, float* __restrict__ gfout)
{
  __shared__ float gl[64*33];
  __shared__ float bs[32];
  const int wg = blockIdx.x, tid = threadIdx.x;
  const int mrow = wg & 3, jblk = wg >> 2;
  const int lane = tid & 63, wv = tid >> 6;
  if (tid < 32){
    int n = ((tid >> 3) << 9) + jblk*8 + (tid & 7);
    bs[tid] = bih[n] + bhh[n];
  }
  const int ar = mrow*64 + wv*16 + (lane & 15);
  const int kc = (lane >> 4) << 3;
  const int cI = lane & 15;
  const int n0 = ((cI >> 3) << 9) + jblk*8 + (cI & 7);
  const int n1 = n0 + 1024;

  f32x4 acc0 = {0,0,0,0}, acc1 = {0,0,0,0};
  {
    const u16* hH = h0hi + ar*512 + kc;
    const u16* hL = h0lo + ar*512 + kc;
    #pragma unroll 4
    for (int ks = 0; ks < 16; ++ks){
      int k = ks*32;
      short8 ah = *(const short8*)(hH + k);
      short8 al = *(const short8*)(hL + k);
      short8 bh0, bl0, bh1, bl1;
      ldw8s(Wihf + n0*512 + kc + k, bh0, bl0);
      ldw8s(Wihf + n1*512 + kc + k, bh1, bl1);
      SMACC(acc0, ah, al, bh0, bl0);
      SMACC(acc1, ah, al, bh1, bl1);
    }
  }
  {
    const u16* hH = h1phi + ar*512 + kc;
    const u16* hL = h1plo + ar*512 + kc;
    #pragma unroll 4
    for (int ks = 0; ks < 16; ++ks){
      int k = ks*32;
      short8 ah = *(const short8*)(hH + k);
      short8 al = *(const short8*)(hL + k);
      short8 bh0, bl0, bh1, bl1;
      ldw8s(Whhf + n0*512 + kc + k, bh0, bl0);
      ldw8s(Whhf + n1*512 + kc + k, bh1, bl1);
      SMACC(acc0, ah, al, bh0, bl0);
      SMACC(acc1, ah, al, bh1, bl1);
    }
  }
  cell_epilogue_fb(gl, bs, c1, h1nhi, h1nlo, gfout, mrow, jblk, acc0, acc1, wv, lane, tid);
}

__global__ void __launch_bounds__(256) pred_fb(
    const u16* __restrict__ h1hi, const u16* __restrict__ h1lo,
    const float* __restrict__ Wout, const float* __restrict__ bout,
    u16* __restrict__ predhi, u16* __restrict__ predlo,
    float* __restrict__ out, int l)
{
  const int wg = blockIdx.x, tid = threadIdx.x;
  const int bsub = tid >> 6, d = tid & 63;
  const int b = wg*4 + bsub;
  float acc = bout[d];
  const u16* hH = h1hi + b*512;
  const u16* hL = h1lo + b*512;
  const float* wr = Wout + d*512;
  #pragma unroll 8
  for (int k = 0; k < 512; k += 8){
    short8 hv = *(const short8*)(hH + k);
    short8 lv = *(const short8*)(hL + k);
    #pragma unroll
    for (int j = 0; j < 8; ++j)
      acc += (bf2f((u16)hv[j]) + bf2f((u16)lv[j])) * wr[k + j];
  }
  HiLo s = split1(acc);
  predhi[b*64 + d] = (u16)s.hi;
  predlo[b*64 + d] = (u16)s.lo;
  out[131072 + (b*64 + d)*96 + l] = acc;
}

extern "C" void kernel_launch(void* const* d_in, const int* in_sizes, int n_in,
                              void* d_out, int out_size, void* d_ws, size_t ws_size,
                              hipStream_t stream)
{
  const float* x    = (const float*)d_in[0];
  const float* Wih0 = (const float*)d_in[1];
  const float* Whh0 = (const float*)d_in[2];
  const float* bih0 = (const float*)d_in[3];
  const float* bhh0 = (const float*)d_in[4];
  const float* Wih1 = (const float*)d_in[5];
  const float* Whh1 = (const float*)d_in[6];
  const float* bih1 = (const float*)d_in[7];
  const float* bhh1 = (const float*)d_in[8];
  const float* Wout = (const float*)d_in[9];
  const float* bout = (const float*)d_in[10];
  float* out = (float*)d_out;

  // ---- ws layout (identical offsets to R27)
  char* ws = (char*)d_ws;
  u16* h0h[2] = { (u16*)(ws + 0),       (u16*)(ws + 262144) };
  u16* h0l[2] = { (u16*)(ws + 524288),  (u16*)(ws + 786432) };
  u16* h1h[2] = { (u16*)(ws + 1048576), (u16*)(ws + 1310720) };
  u16* h1l[2] = { (u16*)(ws + 1572864), (u16*)(ws + 1835008) };
  unsigned* cnt = (unsigned*)(ws + 2097152);
  u16* Wcmb_h = (u16*)(ws + 2162688);
  u16* W1ih_h = Wcmb_h + 1048576;
  u16* W1hh_h = W1ih_h + 1048576;
  float* bb   = (float*)(W1hh_h + 1048576);
  const size_t NEED = 2162688u + 3u*2097152u + 8192u;   // ~8.5 MB
  // fallback layout (only used when ws too small)
  float* fb_c0 = (float*)(ws + 2162688);
  float* fb_c1 = (float*)(ws + 2686976);
  u16* predh   = (u16*)(ws + 3211264);
  u16* predl   = (u16*)(ws + 3244032);
  const bool ps = (ws_size >= NEED);

  (void)hipMemsetAsync(d_ws, 0, 3276800, stream);

  if (ps){
    wcomb_k<<<dim3(256), dim3(256), 0, stream>>>(Wih0, Wout, bout, bih0, bhh0,
                                                 Wcmb_h, bb);
    wcvt<<<dim3(4096), dim3(256), 0, stream>>>(Wih1, W1ih_h, 1048576);
    wcvt<<<dim3(4096), dim3(256), 0, stream>>>(Whh1, W1hh_h, 1048576);
    lstm_persist<<<dim3(256), dim3(256), 0, stream>>>(
        x, Whh0, Wih0, W1ih_h, W1hh_h, Wcmb_h, bb,
        bih0, bhh0, bih1, bhh1, Wout, bout, out, cnt,
        h0h[0], h0h[1], h1h[0], h1h[1]);
    pred_last<<<dim3(64), dim3(256), 0, stream>>>(h1h[1], Wout, bout, out);
  } else {
    for (int t = 0; t < 432; ++t){
      const int p = t & 1;
      float* gf = (t == 335) ? out : (float*)nullptr;
      if (t < 336)
        l0_fb<true><<<dim3(256), dim3(256), 0, stream>>>(
            x, predh, predl, Wih0, Whh0, bih0, bhh0,
            h0h[p^1], h0l[p^1], h0h[p], h0l[p], fb_c0, t);
      else
        l0_fb<false><<<dim3(256), dim3(256), 0, stream>>>(
            x, predh, predl, Wih0, Whh0, bih0, bhh0,
            h0h[p^1], h0l[p^1], h0h[p], h0l[p], fb_c0, t);
      l1_fb<<<dim3(256), dim3(256), 0, stream>>>(
          Wih1, Whh1, bih1, bhh1, h0h[p], h0l[p],
          h1h[p^1], h1l[p^1], h1h[p], h1l[p], fb_c1, gf);
      if (t >= 336)
        pred_fb<<<dim3(64), dim3(256), 0, stream>>>(
            h1h[p], h1l[p], Wout, bout, predh, predl, out, t - 336);
    }
  }
}

// Round 30
// 3169.186 us; speedup vs baseline: 6.8228x; 1.1858x over previous
//
#include <hip/hip_runtime.h>

typedef unsigned short u16;
typedef __attribute__((ext_vector_type(8))) short short8;
typedef __attribute__((ext_vector_type(4))) float f32x4;

#define AXR __ATOMIC_RELAXED, __HIP_MEMORY_SCOPE_AGENT

__device__ __forceinline__ float bf2f(u16 v){
  union { unsigned u; float f; } t; t.u = ((unsigned)v) << 16; return t.f;
}
__device__ __forceinline__ u16 f2bf(float f){
  union { float f; unsigned u; } t; t.f = f;
  unsigned u = t.u;
  return (u16)((u + 0x7fffu + ((u >> 16) & 1u)) >> 16);
}
struct HiLo { short hi, lo; };
__device__ __forceinline__ HiLo split1(float v){
  HiLo r;
  u16 h = f2bf(v);
  r.hi = (short)h;
  r.lo = (short)f2bf(v - bf2f(h));
  return r;
}
__device__ __forceinline__ void ldw8s(const float* __restrict__ p, short8& hi, short8& lo){
  #pragma unroll
  for (int j = 0; j < 8; ++j){ HiLo s = split1(p[j]); hi[j] = s.hi; lo[j] = s.lo; }
}

// ---- fast saturation-safe transcendentals (v_exp_f32 + v_rcp_f32) ----------
__device__ __forceinline__ float fsig(float v){
  return __builtin_amdgcn_rcpf(1.f + __expf(-v));      // -> 0 at -inf, 1 at +inf
}
__device__ __forceinline__ float ftanh(float v){
  return 1.f - 2.f*__builtin_amdgcn_rcpf(__expf(2.f*v) + 1.f);  // -> ±1, no NaN
}

#define MFMA(acc, a, b) acc = __builtin_amdgcn_mfma_f32_16x16x32_bf16(a, b, acc, 0,0,0)
#define SMACC(acc, ah, al, bh, bl) do{ MFMA(acc, ah, bh); MFMA(acc, ah, bl); MFMA(acc, al, bh); }while(0)

// ---- prepass: f32 -> bf16 (hi only, RNE) -----------------------------------
__global__ void wcvt(const float* __restrict__ s, u16* __restrict__ hi, int n){
  int i = blockIdx.x * blockDim.x + threadIdx.x;
  if (i < n) hi[i] = f2bf(s[i]);
}

// ---- prepass: Wcomb = Wih0 @ Wout (2048x512 bf16 hi), bb = b0 + Wih0@bout --
__global__ void __launch_bounds__(256) wcomb_k(
    const float* __restrict__ Wih0, const float* __restrict__ Wout,
    const float* __restrict__ bout, const float* __restrict__ bih0,
    const float* __restrict__ bhh0,
    u16* __restrict__ Wch, float* __restrict__ bb)
{
  __shared__ float wl[8*64];
  __shared__ float bo[64];
  const int wg = blockIdx.x, tid = threadIdx.x;
  const int r0 = wg*8;
  for (int i = tid; i < 512; i += 256) wl[i] = Wih0[(r0 + (i >> 6))*64 + (i & 63)];
  if (tid < 64) bo[tid] = bout[tid];
  __syncthreads();
  if (tid < 8){
    int n = r0 + tid;
    float a = bih0[n] + bhh0[n];
    #pragma unroll 8
    for (int d = 0; d < 64; ++d) a += wl[tid*64 + d]*bo[d];
    bb[n] = a;
  }
  #pragma unroll
  for (int jj = 0; jj < 2; ++jj){
    int j = tid + jj*256;
    float acc[8] = {0,0,0,0,0,0,0,0};
    for (int d = 0; d < 64; ++d){
      float wv = Wout[d*512 + j];
      #pragma unroll
      for (int r = 0; r < 8; ++r) acc[r] += wl[r*64 + d]*wv;
    }
    #pragma unroll
    for (int r = 0; r < 8; ++r) Wch[(r0 + r)*512 + j] = f2bf(acc[r]);
  }
}

// ---- init-only tree barrier ------------------------------------------------
__device__ __forceinline__ void gbar(unsigned* bar, unsigned phase){
  __syncthreads();
  if (threadIdx.x == 0){
    __threadfence();
    const unsigned gg = (unsigned)blockIdx.x >> 4;
    unsigned old = __hip_atomic_fetch_add(bar + 64 + gg*32, 1u, AXR);
    if (old == phase*16u - 1u){
      unsigned r = __hip_atomic_fetch_add(bar, 1u, AXR);
      if (r == phase*16u - 1u)
        __hip_atomic_store(bar + 32, phase, AXR);
    }
    while (__hip_atomic_load(bar + 32, AXR) < phase)
      __builtin_amdgcn_s_sleep(2);
    __threadfence();
  }
  __syncthreads();
}

// ---- global fallback barrier (R14 xbar) ------------------------------------
__device__ __forceinline__ void xbar(unsigned* bar, unsigned phase,
                                     unsigned xcd, unsigned pop, unsigned nx){
  __syncthreads();
  if (threadIdx.x == 0){
    unsigned old = __hip_atomic_fetch_add(bar + 832 + xcd*32, 1u, AXR);
    const bool leader = (old == phase*pop - 1u);
    if (leader){
      asm volatile("buffer_wbl2 sc1\n\ts_waitcnt vmcnt(0)" ::: "memory");
      unsigned r = __hip_atomic_fetch_add(bar + 1344, 1u, AXR);
      if (r == phase*nx - 1u)
        __hip_atomic_store(bar + 1376, phase, AXR);
    }
    while (__hip_atomic_load(bar + 1376, AXR) < phase)
      __builtin_amdgcn_s_sleep(2);
    if (leader){
      asm volatile("buffer_inv sc1\n\ts_waitcnt vmcnt(0)" ::: "memory");
      __hip_atomic_store(bar + 1088 + xcd*32, phase, AXR);
    } else {
      while (__hip_atomic_load(bar + 1088 + xcd*32, AXR) < phase)
        __builtin_amdgcn_s_sleep(1);
      asm volatile("buffer_inv\n\ts_waitcnt vmcnt(0)" ::: "memory");
    }
  }
  __syncthreads();
}

// ---- group-local FLAG-ARRAY barrier (R22) ----------------------------------
__device__ __forceinline__ void fbar(unsigned* bar, int g, int cg,
                                     unsigned phase, int tid){
  __syncthreads();
  unsigned* flags = bar + 4096 + g*1024;
  if (tid == 0)
    __hip_atomic_store(flags + cg*32, phase, AXR);
  if (tid < 64){
    const int i = tid & 31;
    while (__hip_atomic_load(flags + i*32, AXR) < phase)
      __builtin_amdgcn_s_sleep(1);
    asm volatile("buffer_inv\n\ts_waitcnt vmcnt(0)" ::: "memory");
  }
  __syncthreads();
}

// ---- LDS helpers (XOR-swizzled, G4) ----------------------------------------
__device__ __forceinline__ short8 lds8(const u16* base, int r, int kelem, int rowbytes){
  int bo = r*rowbytes + ((kelem*2) ^ ((r & 7) << 4));
  return *(const short8*)((const char*)base + bo);
}

// ---- h-block stage split into load (regs) and write (swizzled LDS) ---------
__device__ __forceinline__ void stage_ld(const u16* __restrict__ gh,
                                         short8* r, int tid){
  #pragma unroll
  for (int i = 0; i < 8; ++i)
    r[i] = *(const short8*)(gh + (tid + i*256)*8);
}
__device__ __forceinline__ void stage_wr(const short8* r, u16* sh, int tid){
  #pragma unroll
  for (int i = 0; i < 8; ++i){
    int e = (tid + i*256)*8;
    int row = e >> 9, col = e & 511;
    int bo = row*1024 + ((col*2) ^ ((row & 7) << 4));
    *(short8*)((char*)sh + bo) = r[i];
  }
}

// ---- persistent kernel: reg weights, x-prefetch, 4-barrier phases ----------
__global__ void __launch_bounds__(256, 1) lstm_persist(
    const float* __restrict__ x,
    const float* __restrict__ Whh0, const float* __restrict__ Wih0,
    const u16* __restrict__ W1ih_h, const u16* __restrict__ W1hh_h,
    const u16* __restrict__ Wcmb_h, const float* __restrict__ bb,
    const float* __restrict__ bih0, const float* __restrict__ bhh0,
    const float* __restrict__ bih1, const float* __restrict__ bhh1,
    const float* __restrict__ Wout, const float* __restrict__ bout,
    float* __restrict__ out, unsigned* __restrict__ cnt,
    u16* __restrict__ h0h0, u16* __restrict__ h0h1,
    u16* __restrict__ h1h0, u16* __restrict__ h1h1)
{
  __shared__ u16 hstA[16384], hstB[16384];       // 2x32KB: staged h blocks
  __shared__ u16 xsh[2048], xsl[2048];           // 8KB: x_t stage (un-aliased)
  __shared__ float glA[32*68];                   // l0 gate exchange
  __shared__ float glB[32*68];                   // l1 gate exchange
  __shared__ float pr[256];                      // pred partials
  __shared__ float bs0[64], bs1[64], bsd[64];
  __shared__ unsigned s_rank, s_pop, s_nx, s_all;

  const int wg = blockIdx.x, tid = threadIdx.x;
  const int lane = tid & 63, wv = tid >> 6;
  const int cI = lane & 15;
  const int kc = (lane >> 4) << 3;
  const int rl = wv*16 + cI;

  // ---- census ----
  unsigned xcd;
  asm volatile("s_getreg_b32 %0, hwreg(HW_REG_XCC_ID)" : "=s"(xcd));
  xcd &= 7u;
  if (tid == 0)
    s_rank = __hip_atomic_fetch_add(cnt + 576 + xcd*32, 1u, AXR);
  gbar(cnt, 1);
  if (tid == 0){
    unsigned nxl = 0, allc = 1;
    for (int i = 0; i < 8; ++i){
      unsigned pv = __hip_atomic_load(cnt + 576 + i*32, AXR);
      nxl += (pv != 0u) ? 1u : 0u;
      if (pv != 32u) allc = 0u;
    }
    s_pop = __hip_atomic_load(cnt + 576 + xcd*32, AXR);
    s_nx  = nxl;
    s_all = allc;
  }
  __syncthreads();
  const unsigned pop = s_pop, nx = s_nx;
  const bool allco = (s_all != 0u);
  const int g  = allco ? (int)xcd    : (wg & 7);
  const int cg = allco ? (int)s_rank : (wg >> 3);
  const int b0 = g*32;

  // ---- one-time init: biases + ALL weight fragments into registers ----
  if (tid < 64){
    int n = ((tid >> 4) << 9) + cg*16 + (tid & 15);
    bs0[tid] = bih0[n] + bhh0[n];
    bs1[tid] = bih1[n] + bhh1[n];
    bsd[tid] = bb[n];
  }
  const int nrow = wv*512 + cg*16 + cI;          // this thread's gate row
  const int nb = nrow*512 + kc;                  // K=512 frag base
  short8 w1ih_r[16], w1hh_r[16], wcmb_r[16], w0hh_r[16];
  #pragma unroll
  for (int ks = 0; ks < 16; ++ks){
    w1ih_r[ks] = *(const short8*)(W1ih_h + nb + ks*32);
    w1hh_r[ks] = *(const short8*)(W1hh_h + nb + ks*32);
    wcmb_r[ks] = *(const short8*)(Wcmb_h + nb + ks*32);
    short8 t;
    #pragma unroll
    for (int j = 0; j < 8; ++j) t[j] = (short)f2bf(Whh0[nb + ks*32 + j]);
    w0hh_r[ks] = t;
  }
  short8 w0ih_rh[2], w0ih_rl[2];                 // Wih0 frag (K=64), split
  #pragma unroll
  for (int ks = 0; ks < 2; ++ks){
    short8 th, tl;
    #pragma unroll
    for (int j = 0; j < 8; ++j){
      HiLo s = split1(Wih0[nrow*64 + ks*32 + kc + j]);
      th[j] = s.hi; tl[j] = s.lo;
    }
    w0ih_rh[ks] = th; w0ih_rl[ks] = tl;
  }

  // ---- prologue: stage x_0 (read next phase after sync1) ----
  #pragma unroll
  for (int i = 0; i < 8; ++i){
    int e = tid + i*256;
    int bb_ = e >> 6, d = e & 63;
    HiLo s = split1(x[(b0 + bb_)*21504 + d*336 + 0]);
    int bo = bb_*128 + ((d*2) ^ ((bb_ & 7) << 4));
    *(u16*)((char*)xsh + bo) = (u16)s.hi;
    *(u16*)((char*)xsl + bo) = (u16)s.lo;
  }
  __syncthreads();

  u16* H0h[2] = { h0h0, h0h1 };
  u16* H1h[2] = { h1h0, h1h1 };

  float c0r[2] = {0.f, 0.f}, c1r[2] = {0.f, 0.f};
  unsigned ep = 0;
  const int rb_ = (lane >> 4) << 2;
  const int hoff = b0*512;

  #define LDA(buf, kk, a0h_, a1h_) \
    short8 a0h_ = lds8(buf, cI, kc + (kk), 1024); \
    short8 a1h_ = lds8(buf, cI + 16, kc + (kk), 1024);

  #define CELL(GL, CREG, HDST, GF) { \
    u16* Hh_ = (HDST); \
    _Pragma("unroll") \
    for (int q = 0; q < 2; ++q){ \
      int e = tid + q*256; \
      int m = e >> 4, col = e & 15; \
      float iv = GL[m*68 + col]; \
      float fv = GL[m*68 + 16 + col]; \
      float gv = GL[m*68 + 32 + col]; \
      float ov = GL[m*68 + 48 + col]; \
      float cn = fsig(fv)*CREG[q] + fsig(iv)*ftanh(gv); \
      CREG[q] = cn; \
      float h = fsig(ov)*ftanh(cn); \
      int gi = (b0 + m)*512 + cg*16 + col; \
      Hh_[gi] = f2bf(h); \
      if (GF) ((float*)(GF))[gi] = h; \
    } }

  // ======== skewed encoder: phase k computes h0_k and h1_{k-1} ========
  // (k==336 computes h0_336, the decoder's first l0 step with zero input)
  for (int k = 0; k <= 336; ++k){
    const int p0 = k & 1;

    // ---- phase start: h-stage only (x_k already in xsh/xsl) ----
    short8 r0s[8], r1s[8];
    stage_ld(H0h[p0^1] + hoff, r0s, tid);
    if (k >= 1) stage_ld(H1h[p0] + hoff, r1s, tid);
    stage_wr(r0s, hstA, tid);
    if (k >= 1) stage_wr(r1s, hstB, tid);
    __syncthreads();

    // ---- MFMA block: x + fused(Whh0,W1ih) + W1hh (all weights in regs) ----
    f32x4 A0 = {0,0,0,0}, A1 = {0,0,0,0};
    f32x4 B0 = {0,0,0,0}, B1 = {0,0,0,0};
    if (k < 336){
      #pragma unroll
      for (int ks = 0; ks < 2; ++ks){
        int kk = ks*32 + kc;
        short8 a0h = lds8(xsh, cI, kk, 128);
        short8 a0l = lds8(xsl, cI, kk, 128);
        short8 a1h = lds8(xsh, cI + 16, kk, 128);
        short8 a1l = lds8(xsl, cI + 16, kk, 128);
        SMACC(A0, a0h, a0l, w0ih_rh[ks], w0ih_rl[ks]);
        SMACC(A1, a1h, a1l, w0ih_rh[ks], w0ih_rl[ks]);
      }
    }
    #pragma unroll
    for (int ks = 0; ks < 16; ++ks){             // fused: Whh0(REG) + W1ih(REG)
      int kk = ks*32;
      LDA(hstA, kk, a0h, a1h)
      MFMA(A0, a0h, w0hh_r[ks]);
      MFMA(A1, a1h, w0hh_r[ks]);
      MFMA(B0, a0h, w1ih_r[ks]);
      MFMA(B1, a1h, w1ih_r[ks]);
    }
    if (k >= 1){
      #pragma unroll
      for (int ks = 0; ks < 16; ++ks){           // W1hh (REG) over h1_{k-2}
        int kk = ks*32;
        LDA(hstB, kk, a0h, a1h)
        MFMA(B0, a0h, w1hh_r[ks]);
        MFMA(B1, a1h, w1hh_r[ks]);
      }
    }

    // ---- prefetch x_{k+1} into regs (hides under exchange+CELL) ----
    float xr[8];
    const bool ldx = (k + 1 < 336);
    if (ldx){
      #pragma unroll
      for (int i = 0; i < 8; ++i){
        int e = tid + i*256;
        xr[i] = x[(b0 + (e >> 6))*21504 + (e & 63)*336 + (k + 1)];
      }
    }

    // ---- exchange (no pre-sync: glA/glB idle since previous fbar) ----
    #pragma unroll
    for (int r = 0; r < 4; ++r){
      glA[(rb_ + r)*68 + rl]      = A0[r] + bs0[rl];
      glA[(16 + rb_ + r)*68 + rl] = A1[r] + bs0[rl];
    }
    if (k >= 1){
      #pragma unroll
      for (int r = 0; r < 4; ++r){
        glB[(rb_ + r)*68 + rl]      = B0[r] + bs1[rl];
        glB[(16 + rb_ + r)*68 + rl] = B1[r] + bs1[rl];
      }
    }
    __syncthreads();
    CELL(glA, c0r, H0h[p0], (float*)nullptr)
    if (k >= 1)  CELL(glB, c1r, H1h[p0^1], (k == 336) ? out : nullptr)
    if (ldx){                                    // write x_{k+1} stage (xst reads done)
      #pragma unroll
      for (int i = 0; i < 8; ++i){
        int e = tid + i*256;
        int bb_ = e >> 6, d = e & 63;
        HiLo s = split1(xr[i]);
        int bo = bb_*128 + ((d*2) ^ ((bb_ & 7) << 4));
        *(u16*)((char*)xsh + bo) = (u16)s.hi;
        *(u16*)((char*)xsl + bo) = (u16)s.lo;
      }
    }
    ++ep;
    if (allco) fbar(cnt, g, cg, ep, tid); else xbar(cnt, ep, xcd, pop, nx);
  }

  // ======== l1 catch-up: h1_336 (h0_336 buf[0], h1_335 buf[1]) ========
  {
    short8 r0s[8], r1s[8];
    stage_ld(H0h[0] + hoff, r0s, tid);
    stage_ld(H1h[1] + hoff, r1s, tid);
    stage_wr(r0s, hstA, tid);
    stage_wr(r1s, hstB, tid);
    __syncthreads();
    f32x4 B0 = {0,0,0,0}, B1 = {0,0,0,0};
    #pragma unroll
    for (int ks = 0; ks < 16; ++ks){
      int kk = ks*32;
      LDA(hstA, kk, a0h, a1h)
      MFMA(B0, a0h, w1ih_r[ks]);
      MFMA(B1, a1h, w1ih_r[ks]);
    }
    #pragma unroll
    for (int ks = 0; ks < 16; ++ks){
      int kk = ks*32;
      LDA(hstB, kk, a0h, a1h)
      MFMA(B0, a0h, w1hh_r[ks]);
      MFMA(B1, a1h, w1hh_r[ks]);
    }
    #pragma unroll
    for (int r = 0; r < 4; ++r){
      glB[(rb_ + r)*68 + rl]      = B0[r] + bs1[rl];
      glB[(16 + rb_ + r)*68 + rl] = B1[r] + bs1[rl];
    }
    __syncthreads();
    CELL(glB, c1r, H1h[0], (float*)nullptr)
    ++ep;
    if (allco) fbar(cnt, g, cg, ep, tid); else xbar(cnt, ep, xcd, pop, nx);
  }

  // ======== decoder: t = 337..431 ========
  for (int t = 337; t < 432; ++t){
    const int p = t & 1;

    // ---- phase A: h1_{t-1}->hstA (Wcomb+pred), h0_{t-1}->hstB (Whh0) ----
    {
      short8 r0s[8], r1s[8];
      stage_ld(H1h[p^1] + hoff, r0s, tid);
      stage_ld(H0h[p^1] + hoff, r1s, tid);
      stage_wr(r0s, hstA, tid);
      stage_wr(r1s, hstB, tid);
      __syncthreads();
      f32x4 A0 = {0,0,0,0}, A1 = {0,0,0,0};
      #pragma unroll
      for (int ks = 0; ks < 16; ++ks){
        int kk = ks*32;
        LDA(hstA, kk, a0h, a1h)
        MFMA(A0, a0h, wcmb_r[ks]);
        MFMA(A1, a1h, wcmb_r[ks]);
      }
      #pragma unroll
      for (int ks = 0; ks < 16; ++ks){           // Whh0 (REG) over h0_{t-1}
        int kk = ks*32;
        LDA(hstB, kk, a0h, a1h)
        MFMA(A0, a0h, w0hh_r[ks]);
        MFMA(A1, a1h, w0hh_r[ks]);
      }
      {                                          // pred l=t-337 from hstA
        const int d = tid & 63, kq = tid >> 6;
        float part = 0.f;
        const float* wr = Wout + d*512 + kq*128;
        #pragma unroll 4
        for (int kk = 0; kk < 128; kk += 8){
          short8 hv = lds8(hstA, cg, kq*128 + kk, 1024);
          #pragma unroll
          for (int j = 0; j < 8; ++j)
            part += bf2f((u16)hv[j]) * wr[kk + j];
        }
        pr[d*4 + kq] = part;
        __syncthreads();
        if (tid < 64){
          float v = pr[tid*4] + pr[tid*4+1] + pr[tid*4+2] + pr[tid*4+3] + bout[tid];
          out[131072 + ((b0 + cg)*64 + tid)*96 + (t - 337)] = v;
        }
      }
      #pragma unroll
      for (int r = 0; r < 4; ++r){
        glA[(rb_ + r)*68 + rl]      = A0[r] + bsd[rl];
        glA[(16 + rb_ + r)*68 + rl] = A1[r] + bsd[rl];
      }
      __syncthreads();
      CELL(glA, c0r, H0h[p], (float*)nullptr)
      ++ep;
      if (allco) fbar(cnt, g, cg, ep, tid); else xbar(cnt, ep, xcd, pop, nx);
    }

    // ---- phase B: h0_t->hstA (W1ih), h1_{t-1}->hstB (W1hh) ----
    {
      short8 r0s[8], r1s[8];
      stage_ld(H0h[p] + hoff, r0s, tid);
      stage_ld(H1h[p^1] + hoff, r1s, tid);
      stage_wr(r0s, hstA, tid);
      stage_wr(r1s, hstB, tid);
      __syncthreads();
      f32x4 B0 = {0,0,0,0}, B1 = {0,0,0,0};
      #pragma unroll
      for (int ks = 0; ks < 16; ++ks){
        int kk = ks*32;
        LDA(hstA, kk, a0h, a1h)
        MFMA(B0, a0h, w1ih_r[ks]);
        MFMA(B1, a1h, w1ih_r[ks]);
      }
      #pragma unroll
      for (int ks = 0; ks < 16; ++ks){
        int kk = ks*32;
        LDA(hstB, kk, a0h, a1h)
        MFMA(B0, a0h, w1hh_r[ks]);
        MFMA(B1, a1h, w1hh_r[ks]);
      }
      #pragma unroll
      for (int r = 0; r < 4; ++r){
        glB[(rb_ + r)*68 + rl]      = B0[r] + bs1[rl];
        glB[(16 + rb_ + r)*68 + rl] = B1[r] + bs1[rl];
      }
      __syncthreads();
      CELL(glB, c1r, H1h[p], (float*)nullptr)
      ++ep;
      if (allco) fbar(cnt, g, cg, ep, tid); else xbar(cnt, ep, xcd, pop, nx);
    }
  }
  #undef LDA
  #undef CELL
}

// ---- tail: pred for l=95 from h1_431 (parity 1) ----------------------------
__global__ void __launch_bounds__(256) pred_last(
    const u16* __restrict__ h1hi,
    const float* __restrict__ Wout, const float* __restrict__ bout,
    float* __restrict__ out)
{
  const int wg = blockIdx.x, tid = threadIdx.x;
  const int bsub = tid >> 6, d = tid & 63;
  const int b = wg*4 + bsub;
  float acc = bout[d];
  const u16* hH = h1hi + b*512;
  const float* wr = Wout + d*512;
  #pragma unroll 8
  for (int k = 0; k < 512; k += 8){
    short8 hv = *(const short8*)(hH + k);
    #pragma unroll
    for (int j = 0; j < 8; ++j)
      acc += bf2f((u16)hv[j]) * wr[k + j];
  }
  out[131072 + (b*64 + d)*96 + 95] = acc;
}

// ======================= fallback (R9 proven path) ==========================
__device__ __forceinline__ void cell_epilogue_fb(
    float* gl, const float* bs, float* __restrict__ cbuf,
    u16* __restrict__ hhi, u16* __restrict__ hlo,
    float* __restrict__ gfout, int mrow, int jblk,
    const f32x4& a0, const f32x4& a1, int wv, int lane, int tid)
{
  __syncthreads();
  const int rbase = wv*16 + ((lane >> 4) << 2);
  const int cI = lane & 15;
  #pragma unroll
  for (int r = 0; r < 4; ++r){
    gl[(rbase+r)*33 + cI]      = a0[r] + bs[cI];
    gl[(rbase+r)*33 + 16 + cI] = a1[r] + bs[16 + cI];
  }
  __syncthreads();
  #pragma unroll
  for (int q = 0; q < 2; ++q){
    int e = tid + q*256;
    int m = e >> 3, jj = e & 7;
    float iv = gl[m*33 + jj];
    float fv = gl[m*33 + 8 + jj];
    float gv = gl[m*33 + 16 + jj];
    float ov = gl[m*33 + 24 + jj];
    float si = 1.f/(1.f + expf(-iv));
    float sf = 1.f/(1.f + expf(-fv));
    float so = 1.f/(1.f + expf(-ov));
    int gi = (mrow*64 + m)*512 + jblk*8 + jj;
    float cn = sf*cbuf[gi] + si*tanhf(gv);
    cbuf[gi] = cn;
    float h = so*tanhf(cn);
    u16 hh = f2bf(h);
    hhi[gi] = hh;
    hlo[gi] = f2bf(h - bf2f(hh));
    if (gfout) gfout[gi] = h;
  }
}

template<bool ENC>
__global__ void __launch_bounds__(256) l0_fb(
    const float* __restrict__ x,
    const u16* __restrict__ predhi, const u16* __restrict__ predlo,
    const float* __restrict__ Wihf, const float* __restrict__ Whhf,
    const float* __restrict__ bih, const float* __restrict__ bhh,
    const u16* __restrict__ hphi, const u16* __restrict__ hplo,
    u16* __restrict__ hnhi, u16* __restrict__ hnlo,
    float* __restrict__ c0, int t)
{
  __shared__ float gl[64*33];
  __shared__ float bs[32];
  const int wg = blockIdx.x, tid = threadIdx.x;
  const int mrow = wg & 3, jblk = wg >> 2;
  const int lane = tid & 63, wv = tid >> 6;
  if (tid < 32){
    int n = ((tid >> 3) << 9) + jblk*8 + (tid & 7);
    bs[tid] = bih[n] + bhh[n];
  }
  const int ar = mrow*64 + wv*16 + (lane & 15);
  const int kc = (lane >> 4) << 3;
  const int cI = lane & 15;
  const int n0 = ((cI >> 3) << 9) + jblk*8 + (cI & 7);
  const int n1 = n0 + 1024;

  f32x4 acc0 = {0,0,0,0}, acc1 = {0,0,0,0};
  #pragma unroll
  for (int ks = 0; ks < 2; ++ks){
    int k = ks*32 + kc;
    short8 ah, al;
    if (ENC){
      const float* xb = x + ar*21504 + t;
      #pragma unroll
      for (int j = 0; j < 8; ++j){ HiLo s = split1(xb[(k + j)*336]); ah[j] = s.hi; al[j] = s.lo; }
    } else {
      ah = *(const short8*)(predhi + ar*64 + k);
      al = *(const short8*)(predlo + ar*64 + k);
    }
    short8 bh0, bl0, bh1, bl1;
    ldw8s(Wihf + n0*64 + k, bh0, bl0);
    ldw8s(Wihf + n1*64 + k, bh1, bl1);
    SMACC(acc0, ah, al, bh0, bl0);
    SMACC(acc1, ah, al, bh1, bl1);
  }
  const u16* hH = hphi + ar*512 + kc;
  const u16* hL = hplo + ar*512 + kc;
  #pragma unroll 4
  for (int ks = 0; ks < 16; ++ks){
    int k = ks*32;
    short8 ah = *(const short8*)(hH + k);
    short8 al = *(const short8*)(hL + k);
    short8 bh0, bl0, bh1, bl1;
    ldw8s(Whhf + n0*512 + kc + k, bh0, bl0);
    ldw8s(Whhf + n1*512 + kc + k, bh1, bl1);
    SMACC(acc0, ah, al, bh0, bl0);
    SMACC(acc1, ah, al, bh1, bl1);
  }
  cell_epilogue_fb(gl, bs, c0, hnhi, hnlo, nullptr, mrow, jblk, acc0, acc1, wv, lane, tid);
}

__global__ void __launch_bounds__(256) l1_fb(
    const float* __restrict__ Wihf, const float* __restrict__ Whhf,
    const float* __restrict__ bih, const float* __restrict__ bhh,
    const u16* __restrict__ h0hi, const u16* __restrict__ h0lo,
    const u16* __restrict__ h1phi, const u16* __restrict__ h1plo,
    u16* __restrict__ h1nhi, u16* __restrict__ h1nlo,
    float* __restrict__ c1, float* __restrict__ gfout)
{
  __shared__ float gl[64*33];
  __shared__ float bs[32];
  const int wg = blockIdx.x, tid = threadIdx.x;
  const int mrow = wg & 3, jblk = wg >> 2;
  const int lane = tid & 63, wv = tid >> 6;
  if (tid < 32){
    int n = ((tid >> 3) << 9) + jblk*8 + (tid & 7);
    bs[tid] = bih[n] + bhh[n];
  }
  const int ar = mrow*64 + wv*16 + (lane & 15);
  const int kc = (lane >> 4) << 3;
  const int cI = lane & 15;
  const int n0 = ((cI >> 3) << 9) + jblk*8 + (cI & 7);
  const int n1 = n0 + 1024;

  f32x4 acc0 = {0,0,0,0}, acc1 = {0,0,0,0};
  {
    const u16* hH = h0hi + ar*512 + kc;
    const u16* hL = h0lo + ar*512 + kc;
    #pragma unroll 4
    for (int ks = 0; ks < 16; ++ks){
      int k = ks*32;
      short8 ah = *(const short8*)(hH + k);
      short8 al = *(const short8*)(hL + k);
      short8 bh0, bl0, bh1, bl1;
      ldw8s(Wihf + n0*512 + kc + k, bh0, bl0);
      ldw8s(Wihf + n1*512 + kc + k, bh1, bl1);
      SMACC(acc0, ah, al, bh0, bl0);
      SMACC(acc1, ah, al, bh1, bl1);
    }
  }
  {
    const u16* hH = h1phi + ar*512 + kc;
    const u16* hL = h1plo + ar*512 + kc;
    #pragma unroll 4
    for (int ks = 0; ks < 16; ++ks){
      int k = ks*32;
      short8 ah = *(const short8*)(hH + k);
      short8 al = *(const short8*)(hL + k);
      short8 bh0, bl0, bh1, bl1;
      ldw8s(Whhf + n0*512 + kc + k, bh0, bl0);
      ldw8s(Whhf + n1*512 + kc + k, bh1, bl1);
      SMACC(acc0, ah, al, bh0, bl0);
      SMACC(acc1, ah, al, bh1, bl1);
    }
  }
  cell_epilogue_fb(gl, bs, c1, h1nhi, h1nlo, gfout, mrow, jblk, acc0, acc1, wv, lane, tid);
}

__global__ void __launch_bounds__(256) pred_fb(
    const u16* __restrict__ h1hi, const u16* __restrict__ h1lo,
    const float* __restrict__ Wout, const float* __restrict__ bout,
    u16* __restrict__ predhi, u16* __restrict__ predlo,
    float* __restrict__ out, int l)
{
  const int wg = blockIdx.x, tid = threadIdx.x;
  const int bsub = tid >> 6, d = tid & 63;
  const int b = wg*4 + bsub;
  float acc = bout[d];
  const u16* hH = h1hi + b*512;
  const u16* hL = h1lo + b*512;
  const float* wr = Wout + d*512;
  #pragma unroll 8
  for (int k = 0; k < 512; k += 8){
    short8 hv = *(const short8*)(hH + k);
    short8 lv = *(const short8*)(hL + k);
    #pragma unroll
    for (int j = 0; j < 8; ++j)
      acc += (bf2f((u16)hv[j]) + bf2f((u16)lv[j])) * wr[k + j];
  }
  HiLo s = split1(acc);
  predhi[b*64 + d] = (u16)s.hi;
  predlo[b*64 + d] = (u16)s.lo;
  out[131072 + (b*64 + d)*96 + l] = acc;
}

extern "C" void kernel_launch(void* const* d_in, const int* in_sizes, int n_in,
                              void* d_out, int out_size, void* d_ws, size_t ws_size,
                              hipStream_t stream)
{
  const float* x    = (const float*)d_in[0];
  const float* Wih0 = (const float*)d_in[1];
  const float* Whh0 = (const float*)d_in[2];
  const float* bih0 = (const float*)d_in[3];
  const float* bhh0 = (const float*)d_in[4];
  const float* Wih1 = (const float*)d_in[5];
  const float* Whh1 = (const float*)d_in[6];
  const float* bih1 = (const float*)d_in[7];
  const float* bhh1 = (const float*)d_in[8];
  const float* Wout = (const float*)d_in[9];
  const float* bout = (const float*)d_in[10];
  float* out = (float*)d_out;

  // ---- ws layout (identical offsets to R29)
  char* ws = (char*)d_ws;
  u16* h0h[2] = { (u16*)(ws + 0),       (u16*)(ws + 262144) };
  u16* h0l[2] = { (u16*)(ws + 524288),  (u16*)(ws + 786432) };
  u16* h1h[2] = { (u16*)(ws + 1048576), (u16*)(ws + 1310720) };
  u16* h1l[2] = { (u16*)(ws + 1572864), (u16*)(ws + 1835008) };
  unsigned* cnt = (unsigned*)(ws + 2097152);
  u16* Wcmb_h = (u16*)(ws + 2162688);
  u16* W1ih_h = Wcmb_h + 1048576;
  u16* W1hh_h = W1ih_h + 1048576;
  float* bb   = (float*)(W1hh_h + 1048576);
  const size_t NEED = 2162688u + 3u*2097152u + 8192u;   // ~8.5 MB
  // fallback layout (only used when ws too small)
  float* fb_c0 = (float*)(ws + 2162688);
  float* fb_c1 = (float*)(ws + 2686976);
  u16* predh   = (u16*)(ws + 3211264);
  u16* predl   = (u16*)(ws + 3244032);
  const bool ps = (ws_size >= NEED);

  (void)hipMemsetAsync(d_ws, 0, 3276800, stream);

  if (ps){
    wcomb_k<<<dim3(256), dim3(256), 0, stream>>>(Wih0, Wout, bout, bih0, bhh0,
                                                 Wcmb_h, bb);
    wcvt<<<dim3(4096), dim3(256), 0, stream>>>(Wih1, W1ih_h, 1048576);
    wcvt<<<dim3(4096), dim3(256), 0, stream>>>(Whh1, W1hh_h, 1048576);
    lstm_persist<<<dim3(256), dim3(256), 0, stream>>>(
        x, Whh0, Wih0, W1ih_h, W1hh_h, Wcmb_h, bb,
        bih0, bhh0, bih1, bhh1, Wout, bout, out, cnt,
        h0h[0], h0h[1], h1h[0], h1h[1]);
    pred_last<<<dim3(64), dim3(256), 0, stream>>>(h1h[1], Wout, bout, out);
  } else {
    for (int t = 0; t < 432; ++t){
      const int p = t & 1;
      float* gf = (t == 335) ? out : (float*)nullptr;
      if (t < 336)
        l0_fb<true><<<dim3(256), dim3(256), 0, stream>>>(
            x, predh, predl, Wih0, Whh0, bih0, bhh0,
            h0h[p^1], h0l[p^1], h0h[p], h0l[p], fb_c0, t);
      else
        l0_fb<false><<<dim3(256), dim3(256), 0, stream>>>(
            x, predh, predl, Wih0, Whh0, bih0, bhh0,
            h0h[p^1], h0l[p^1], h0h[p], h0l[p], fb_c0, t);
      l1_fb<<<dim3(256), dim3(256), 0, stream>>>(
          Wih1, Whh1, bih1, bhh1, h0h[p], h0l[p],
          h1h[p^1], h1l[p^1], h1h[p], h1l[p], fb_c1, gf);
      if (t >= 336)
        pred_fb<<<dim3(64), dim3(256), 0, stream>>>(
            h1h[p], h1l[p], Wout, bout, predh, predl, out, t - 336);
    }
  }
}